// Round 1
// baseline (3105.539 us; speedup 1.0000x reference)
//
#include <hip/hip_runtime.h>
#include <cmath>

// ============================================================================
// DeepTemplateMatchingModule on MI355X — round 1: correct fp32 implementation.
//
// Key algebraic simplification: conv5x5 -> conv5x5 -> conv5x5 with no
// intermediate nonlinearity == one conv13x13 (1 in-ch, 64 out-ch) with
// composed weights/bias. Composed on device (weights are runtime inputs).
//
// Pipeline:
//   compose1/compose2 : w1*w2 -> w12 (9x9,32), then *w3 -> weff (13x13,64)
//   conv_pool         : fused conv13x13 + maxpool(2x5,str 2x1) -> pooled
//   gemm_nt           : pooled(flat reshape!) @ lw^T + lb        -> lin
//   gemm_nt           : lin @ w_ih^T + b_ih                      -> gi
//   gru_rec           : 4-step scan over BATCH axis (each t independent)
//   scores/softmax/pv : cross attention  (P = softmax(t e^T); tt=|P^T t - e|)
//   head              : att-softmax, weighted reduce, 2-layer head, softmax
// ============================================================================

// ---- workspace layout (float offsets) ----
// eval: W=2048 T=2032 ; template: W=1040 T=1024 ; pooled (4,64,58,T)
static const size_t OFF_WEFF_E = 0;                         // 10816
static const size_t OFF_WEFF_T = 10816;                     // 10816
static const size_t OFF_BEFF_E = 21632;                     // 64
static const size_t OFF_BEFF_T = 21696;                     // 64
static const size_t OFF_W12_E  = 21760;                     // 2592
static const size_t OFF_W12_T  = 24352;                     // 2592
static const size_t OFF_B12_E  = 26944;                     // 32
static const size_t OFF_B12_T  = 26976;                     // 32
static const size_t OFF_POOL   = 27008;                     // 30,158,848 (max, eval)
// the following live inside the pooled region, used only after pool is dead:
static const size_t OFF_GI     = OFF_POOL;                  // 1,560,576
static const size_t OFF_P      = OFF_POOL + 1560576;        // 8,323,072
static const size_t OFF_TT     = OFF_POOL + 1560576 + 8323072; // 520,192
static const size_t OFF_LIN_E  = OFF_POOL + 30158848;       // 520,192
static const size_t OFF_LIN_T  = OFF_LIN_E + 520192;        // 262,144
// total = 30,968,192 floats = ~118 MiB

// ---------------------------------------------------------------------------
// compose1: w12[o,s] = sum_c (w2[o,c] conv w1[c,0]) ; 5+5-1=9 taps per dim.
// b12[o] = b2[o] + sum_c b1[c] * sum_u w2[o,c,u]
// ---------------------------------------------------------------------------
__global__ __launch_bounds__(256) void compose1_kernel(
    const float* __restrict__ w1, const float* __restrict__ b1,
    const float* __restrict__ w2, const float* __restrict__ b2,
    float* __restrict__ w12, float* __restrict__ b12) {
  __shared__ float s_w1[400];
  __shared__ float s_b1[16];
  const int tid = threadIdx.x;
  for (int i = tid; i < 400; i += 256) s_w1[i] = w1[i];
  if (tid < 16) s_b1[tid] = b1[tid];
  __syncthreads();
  for (int idx = tid; idx < 32 * 81; idx += 256) {
    const int o = idx / 81, s = idx % 81, sy = s / 9, sx = s % 9;
    const int uy0 = sy > 4 ? sy - 4 : 0, uy1 = sy < 4 ? sy : 4;
    const int ux0 = sx > 4 ? sx - 4 : 0, ux1 = sx < 4 ? sx : 4;
    float acc = 0.f;
    for (int c = 0; c < 16; ++c) {
      const float* w2p = w2 + (o * 16 + c) * 25;
      const float* w1p = s_w1 + c * 25;
      for (int uy = uy0; uy <= uy1; ++uy)
        for (int ux = ux0; ux <= ux1; ++ux)
          acc = fmaf(w2p[uy * 5 + ux], w1p[(sy - uy) * 5 + (sx - ux)], acc);
    }
    w12[idx] = acc;
  }
  if (tid < 32) {
    float acc = b2[tid];
    for (int c = 0; c < 16; ++c) {
      float sw = 0.f;
      const float* w2p = w2 + (tid * 16 + c) * 25;
      for (int u = 0; u < 25; ++u) sw += w2p[u];
      acc = fmaf(sw, s_b1[c], acc);
    }
    b12[tid] = acc;
  }
}

// ---------------------------------------------------------------------------
// compose2: weff[o,s](13x13) = sum_c w3[o,c] conv w12[c] ; beff likewise.
// grid 8 blocks (1352 outputs each).
// ---------------------------------------------------------------------------
__global__ __launch_bounds__(256) void compose2_kernel(
    const float* __restrict__ w12, const float* __restrict__ b12,
    const float* __restrict__ w3, const float* __restrict__ b3,
    float* __restrict__ weff, float* __restrict__ beff) {
  __shared__ float s_w12[2592];
  __shared__ float s_b12[32];
  const int tid = threadIdx.x;
  for (int i = tid; i < 2592; i += 256) s_w12[i] = w12[i];
  if (tid < 32) s_b12[tid] = b12[tid];
  __syncthreads();
  const int base_out = blockIdx.x * 1352;  // 8 * 1352 = 10816
  for (int idx = base_out + tid; idx < base_out + 1352; idx += 256) {
    const int o = idx / 169, s = idx % 169, sy = s / 13, sx = s % 13;
    const int uy0 = sy > 8 ? sy - 8 : 0, uy1 = sy < 4 ? sy : 4;
    const int ux0 = sx > 8 ? sx - 8 : 0, ux1 = sx < 4 ? sx : 4;
    float acc = 0.f;
    for (int c = 0; c < 32; ++c) {
      const float* w3p = w3 + (o * 32 + c) * 25;
      const float* wp  = s_w12 + c * 81;
      for (int uy = uy0; uy <= uy1; ++uy)
        for (int ux = ux0; ux <= ux1; ++ux)
          acc = fmaf(w3p[uy * 5 + ux], wp[(sy - uy) * 9 + (sx - ux)], acc);
    }
    weff[idx] = acc;
  }
  if (blockIdx.x == 0 && tid < 64) {
    float acc = b3[tid];
    for (int c = 0; c < 32; ++c) {
      float sw = 0.f;
      const float* w3p = w3 + (tid * 32 + c) * 25;
      for (int u = 0; u < 25; ++u) sw += w3p[u];
      acc = fmaf(sw, s_b12[c], acc);
    }
    beff[tid] = acc;
  }
}

// ---------------------------------------------------------------------------
// Fused conv13x13 + maxpool(2,5)/(2,1).
// Block tile: 1 pooled row (h) x 64 pooled cols x 64 channels, for one batch.
// Thread (c = tid&63, strip = tid>>6): 2 conv rows x 20 conv cols in regs,
// pooled 16 outputs. Input tile (14x80) + all weights (64x169) in LDS (~48KB).
// grid: (ceil(T/64), 58, 4)
// ---------------------------------------------------------------------------
__global__ __launch_bounds__(256) void conv_pool_kernel(
    const float* __restrict__ x, const float* __restrict__ weff,
    const float* __restrict__ beff, float* __restrict__ pooled,
    const int W, const int T) {
  __shared__ float s_w[64 * 169];
  __shared__ float s_b[64];
  __shared__ float s_in[14 * 80];
  const int tid = threadIdx.x;
  const int wb = blockIdx.x * 64;
  const int h  = blockIdx.y;
  const int b  = blockIdx.z;
  for (int i = tid; i < 64 * 169; i += 256) s_w[i] = weff[i];
  if (tid < 64) s_b[tid] = beff[tid];
  {
    const float* xrow = x + ((size_t)b * 128 + 2 * h) * W;
    for (int i = tid; i < 14 * 80; i += 256) {
      const int r = i / 80, cq = i - r * 80;
      int gc = wb + cq; if (gc > W - 1) gc = W - 1;  // clamp; clamped lanes never stored
      s_in[i] = xrow[(size_t)r * W + gc];
    }
  }
  __syncthreads();
  const int c  = tid & 63;
  const int x0 = (tid >> 6) * 16;
  float acc0[20] = {}, acc1[20] = {};
  const float* wr = s_w + c * 169;
  for (int y = 0; y < 14; ++y) {
    float rb[32];
#pragma unroll
    for (int j = 0; j < 32; ++j) rb[j] = s_in[y * 80 + x0 + j];
    const int y0 = (y < 13) ? y : 12;       // safe index, value masked below
    const int y1 = (y >= 1) ? (y - 1) : 0;
#pragma unroll
    for (int kx = 0; kx < 13; ++kx) {
      float w0 = wr[y0 * 13 + kx]; w0 = (y < 13) ? w0 : 0.f;   // conv row 2h   (ky=y)
      float w1 = wr[y1 * 13 + kx]; w1 = (y >= 1) ? w1 : 0.f;   // conv row 2h+1 (ky=y-1)
#pragma unroll
      for (int j = 0; j < 20; ++j) {
        acc0[j] = fmaf(w0, rb[kx + j], acc0[j]);
        acc1[j] = fmaf(w1, rb[kx + j], acc1[j]);
      }
    }
  }
  const float bias = s_b[c];
  float* outp = pooled + (((size_t)b * 64 + c) * 58 + h) * T + wb + x0;
#pragma unroll
  for (int jj = 0; jj < 16; ++jj) {
    float m = acc0[jj];
#pragma unroll
    for (int k = 1; k < 5; ++k) m = fmaxf(m, acc0[jj + k]);
#pragma unroll
    for (int k = 0; k < 5; ++k) m = fmaxf(m, acc1[jj + k]);
    if (wb + x0 + jj < T) outp[jj] = m + bias;
  }
}

// ---------------------------------------------------------------------------
// Generic fp32 GEMM: out[r][n] = sum_k A[r*K+k]*Wt[n*K+k] + bias[n]
// 64x64 tile per block, 4x4 per thread, K-chunks of 32. M == grid.x*64 exact.
// ---------------------------------------------------------------------------
__global__ __launch_bounds__(256) void gemm_nt_kernel(
    const float* __restrict__ A, const float* __restrict__ Wt,
    const float* __restrict__ bias, float* __restrict__ out,
    const int N, const int K) {
  __shared__ float sA[64 * 33];
  __shared__ float sB[64 * 33];
  const int tid = threadIdx.x;
  const int r0 = blockIdx.x * 64;
  const int n0 = blockIdx.y * 64;
  const int ty = tid >> 4, tx = tid & 15;
  float acc[4][4] = {};
  for (int kc = 0; kc < K; kc += 32) {
    __syncthreads();
#pragma unroll
    for (int rep = 0; rep < 8; ++rep) {
      const int l = tid + rep * 256;
      const int row = l >> 5, kk = l & 31;
      sA[row * 33 + kk] = A[(size_t)(r0 + row) * K + kc + kk];
      sB[row * 33 + kk] = Wt[(size_t)(n0 + row) * K + kc + kk];
    }
    __syncthreads();
#pragma unroll 8
    for (int kk = 0; kk < 32; ++kk) {
      const float a0 = sA[(ty * 4 + 0) * 33 + kk];
      const float a1 = sA[(ty * 4 + 1) * 33 + kk];
      const float a2 = sA[(ty * 4 + 2) * 33 + kk];
      const float a3 = sA[(ty * 4 + 3) * 33 + kk];
      const float b0 = sB[(tx * 4 + 0) * 33 + kk];
      const float b1 = sB[(tx * 4 + 1) * 33 + kk];
      const float b2 = sB[(tx * 4 + 2) * 33 + kk];
      const float b3 = sB[(tx * 4 + 3) * 33 + kk];
      acc[0][0] = fmaf(a0, b0, acc[0][0]); acc[0][1] = fmaf(a0, b1, acc[0][1]);
      acc[0][2] = fmaf(a0, b2, acc[0][2]); acc[0][3] = fmaf(a0, b3, acc[0][3]);
      acc[1][0] = fmaf(a1, b0, acc[1][0]); acc[1][1] = fmaf(a1, b1, acc[1][1]);
      acc[1][2] = fmaf(a1, b2, acc[1][2]); acc[1][3] = fmaf(a1, b3, acc[1][3]);
      acc[2][0] = fmaf(a2, b0, acc[2][0]); acc[2][1] = fmaf(a2, b1, acc[2][1]);
      acc[2][2] = fmaf(a2, b2, acc[2][2]); acc[2][3] = fmaf(a2, b3, acc[2][3]);
      acc[3][0] = fmaf(a3, b0, acc[3][0]); acc[3][1] = fmaf(a3, b1, acc[3][1]);
      acc[3][2] = fmaf(a3, b2, acc[3][2]); acc[3][3] = fmaf(a3, b3, acc[3][3]);
    }
  }
#pragma unroll
  for (int i = 0; i < 4; ++i)
#pragma unroll
    for (int j = 0; j < 4; ++j)
      out[(size_t)(r0 + ty * 4 + i) * N + n0 + tx * 4 + j] =
          acc[i][j] + bias[n0 + tx * 4 + j];
}

// ---------------------------------------------------------------------------
// GRU recurrence. Reference scans over the BATCH axis (4 steps); hidden state
// is per (t, 64) and every t is independent. gi = x@w_ih^T + b_ih precomputed.
// Block: 16 t-slots (4 per wave); lane owns gate-row j = part*64+lane.
// w_hh transposed in LDS ([d][j], stride 192 -> conflict-free reads).
// Writes ys in-place over the lin buffer (only gi is read).
// ---------------------------------------------------------------------------
__global__ __launch_bounds__(256) void gru_rec_kernel(
    float* __restrict__ xy, const float* __restrict__ gi,
    const float* __restrict__ whh, const float* __restrict__ bhh, const int T) {
  __shared__ float s_whh_t[64 * 192];  // [d][j]
  __shared__ float s_h[16][64];
  const int tid = threadIdx.x;
  const int lane = tid & 63, wave = tid >> 6;
  for (int i = tid; i < 192 * 64; i += 256) {
    const int j = i >> 6, d = i & 63;
    s_whh_t[d * 192 + j] = whh[i];
  }
  for (int i = tid; i < 16 * 64; i += 256) (&s_h[0][0])[i] = 0.f;
  const float bhr = bhh[lane], bhz = bhh[64 + lane], bhn = bhh[128 + lane];
  const int t0 = blockIdx.x * 16;
  __syncthreads();
  for (int b = 0; b < 4; ++b) {
    float gir[4], giz[4], gin[4];
#pragma unroll
    for (int sl = 0; sl < 4; ++sl) {
      int t = t0 + wave * 4 + sl; if (t > T - 1) t = T - 1;
      const float* girow = gi + ((size_t)b * T + t) * 192;
      gir[sl] = girow[lane]; giz[sl] = girow[64 + lane]; gin[sl] = girow[128 + lane];
    }
    float ahr[4] = {}, ahz[4] = {}, ahn[4] = {};
    for (int d = 0; d < 64; ++d) {
      const float wr_ = s_whh_t[d * 192 + lane];
      const float wz_ = s_whh_t[d * 192 + 64 + lane];
      const float wn_ = s_whh_t[d * 192 + 128 + lane];
#pragma unroll
      for (int sl = 0; sl < 4; ++sl) {
        const float hv = s_h[wave * 4 + sl][d];
        ahr[sl] = fmaf(wr_, hv, ahr[sl]);
        ahz[sl] = fmaf(wz_, hv, ahz[sl]);
        ahn[sl] = fmaf(wn_, hv, ahn[sl]);
      }
    }
    float hn[4];
#pragma unroll
    for (int sl = 0; sl < 4; ++sl) {
      const float r = 1.f / (1.f + __expf(-(gir[sl] + ahr[sl] + bhr)));
      const float z = 1.f / (1.f + __expf(-(giz[sl] + ahz[sl] + bhz)));
      const float n = tanhf(gin[sl] + r * (ahn[sl] + bhn));
      hn[sl] = (1.f - z) * n + z * s_h[wave * 4 + sl][lane];
    }
    __syncthreads();
#pragma unroll
    for (int sl = 0; sl < 4; ++sl) {
      const int t = t0 + wave * 4 + sl;
      s_h[wave * 4 + sl][lane] = hn[sl];
      if (t < T) xy[((size_t)b * T + t) * 64 + lane] = hn[sl];
    }
    __syncthreads();
  }
}

// ---------------------------------------------------------------------------
// scores: P[b,tau,eps] = sum_d t[b,tau,d]*e[b,eps,d].  grid (16,4), 64x64 tiles.
// ---------------------------------------------------------------------------
__global__ __launch_bounds__(256) void scores_kernel(
    const float* __restrict__ tmat, const float* __restrict__ emat,
    float* __restrict__ P) {
  __shared__ float sT[64 * 65];
  __shared__ float sE[64 * 65];
  const int tid = threadIdx.x;
  const int b = blockIdx.y;
  const int tau0 = blockIdx.x * 64;
  const int ty = tid >> 4, tx = tid & 15;
  for (int l = tid; l < 64 * 64; l += 256) {
    const int row = l >> 6, d = l & 63;
    sT[row * 65 + d] = tmat[((size_t)b * 1024 + tau0 + row) * 64 + d];
  }
  for (int et = 0; et < 32; ++et) {
    const int e0 = et * 64;
    __syncthreads();
    for (int l = tid; l < 64 * 64; l += 256) {
      const int row = l >> 6, d = l & 63;
      int eps = e0 + row; if (eps > 2031) eps = 2031;
      sE[row * 65 + d] = emat[((size_t)b * 2032 + eps) * 64 + d];
    }
    __syncthreads();
    float acc[4][4] = {};
#pragma unroll 8
    for (int kk = 0; kk < 64; ++kk) {
      const float a0 = sT[(ty * 4 + 0) * 65 + kk];
      const float a1 = sT[(ty * 4 + 1) * 65 + kk];
      const float a2 = sT[(ty * 4 + 2) * 65 + kk];
      const float a3 = sT[(ty * 4 + 3) * 65 + kk];
      const float b0 = sE[(tx * 4 + 0) * 65 + kk];
      const float b1 = sE[(tx * 4 + 1) * 65 + kk];
      const float b2 = sE[(tx * 4 + 2) * 65 + kk];
      const float b3 = sE[(tx * 4 + 3) * 65 + kk];
      acc[0][0] = fmaf(a0, b0, acc[0][0]); acc[0][1] = fmaf(a0, b1, acc[0][1]);
      acc[0][2] = fmaf(a0, b2, acc[0][2]); acc[0][3] = fmaf(a0, b3, acc[0][3]);
      acc[1][0] = fmaf(a1, b0, acc[1][0]); acc[1][1] = fmaf(a1, b1, acc[1][1]);
      acc[1][2] = fmaf(a1, b2, acc[1][2]); acc[1][3] = fmaf(a1, b3, acc[1][3]);
      acc[2][0] = fmaf(a2, b0, acc[2][0]); acc[2][1] = fmaf(a2, b1, acc[2][1]);
      acc[2][2] = fmaf(a2, b2, acc[2][2]); acc[2][3] = fmaf(a2, b3, acc[2][3]);
      acc[3][0] = fmaf(a3, b0, acc[3][0]); acc[3][1] = fmaf(a3, b1, acc[3][1]);
      acc[3][2] = fmaf(a3, b2, acc[3][2]); acc[3][3] = fmaf(a3, b3, acc[3][3]);
    }
#pragma unroll
    for (int i = 0; i < 4; ++i) {
      const size_t prow = ((size_t)b * 1024 + tau0 + ty * 4 + i) * 2032;
#pragma unroll
      for (int j = 0; j < 4; ++j) {
        const int eps = e0 + tx * 4 + j;
        if (eps < 2032) P[prow + eps] = acc[i][j];
      }
    }
  }
}

// ---------------------------------------------------------------------------
// row softmax over the eps axis (rows of length 2032). grid 4096.
// ---------------------------------------------------------------------------
__global__ __launch_bounds__(256) void softmax_rows_kernel(float* __restrict__ P) {
  float* r = P + (size_t)blockIdx.x * 2032;
  const int tid = threadIdx.x;
  const int lane = tid & 63, wave = tid >> 6;
  __shared__ float sred[4];
  float m = -3.4e38f;
  for (int i = tid; i < 2032; i += 256) m = fmaxf(m, r[i]);
#pragma unroll
  for (int off = 32; off > 0; off >>= 1) m = fmaxf(m, __shfl_down(m, off, 64));
  if (lane == 0) sred[wave] = m;
  __syncthreads();
  m = fmaxf(fmaxf(sred[0], sred[1]), fmaxf(sred[2], sred[3]));
  __syncthreads();
  float s = 0.f;
  float vals[8];
  int cnt = 0;
  for (int i = tid; i < 2032; i += 256) {
    const float v = __expf(r[i] - m);
    vals[cnt++] = v;
    s += v;
  }
#pragma unroll
  for (int off = 32; off > 0; off >>= 1) s += __shfl_down(s, off, 64);
  if (lane == 0) sred[wave] = s;
  __syncthreads();
  const float inv = 1.f / (sred[0] + sred[1] + sred[2] + sred[3]);
  cnt = 0;
  for (int i = tid; i < 2032; i += 256) r[i] = vals[cnt++] * inv;
}

// ---------------------------------------------------------------------------
// pv: tt[b,eps,d] = | sum_tau P[b,tau,eps]*t[b,tau,d]  -  e[b,eps,d] |
// grid (32,4): 64 eps x 64 d tiles, K=1024 in chunks of 32.
// ---------------------------------------------------------------------------
__global__ __launch_bounds__(256) void pv_kernel(
    const float* __restrict__ P, const float* __restrict__ tmat,
    const float* __restrict__ emat, float* __restrict__ tt) {
  __shared__ float sP[32 * 65];
  __shared__ float sT[32 * 65];
  const int tid = threadIdx.x;
  const int b = blockIdx.y;
  const int e0 = blockIdx.x * 64;
  const int ty = tid >> 4, tx = tid & 15;
  float acc[4][4] = {};
  for (int kc = 0; kc < 1024; kc += 32) {
    __syncthreads();
    for (int l = tid; l < 32 * 64; l += 256) {
      const int kk = l >> 6, j = l & 63;
      int eps = e0 + j; if (eps > 2031) eps = 2031;
      sP[kk * 65 + j] = P[((size_t)b * 1024 + kc + kk) * 2032 + eps];
      sT[kk * 65 + j] = tmat[((size_t)b * 1024 + kc + kk) * 64 + j];
    }
    __syncthreads();
#pragma unroll 8
    for (int kk = 0; kk < 32; ++kk) {
      const float a0 = sP[kk * 65 + ty * 4 + 0];
      const float a1 = sP[kk * 65 + ty * 4 + 1];
      const float a2 = sP[kk * 65 + ty * 4 + 2];
      const float a3 = sP[kk * 65 + ty * 4 + 3];
      const float b0 = sT[kk * 65 + tx * 4 + 0];
      const float b1 = sT[kk * 65 + tx * 4 + 1];
      const float b2 = sT[kk * 65 + tx * 4 + 2];
      const float b3 = sT[kk * 65 + tx * 4 + 3];
      acc[0][0] = fmaf(a0, b0, acc[0][0]); acc[0][1] = fmaf(a0, b1, acc[0][1]);
      acc[0][2] = fmaf(a0, b2, acc[0][2]); acc[0][3] = fmaf(a0, b3, acc[0][3]);
      acc[1][0] = fmaf(a1, b0, acc[1][0]); acc[1][1] = fmaf(a1, b1, acc[1][1]);
      acc[1][2] = fmaf(a1, b2, acc[1][2]); acc[1][3] = fmaf(a1, b3, acc[1][3]);
      acc[2][0] = fmaf(a2, b0, acc[2][0]); acc[2][1] = fmaf(a2, b1, acc[2][1]);
      acc[2][2] = fmaf(a2, b2, acc[2][2]); acc[2][3] = fmaf(a2, b3, acc[2][3]);
      acc[3][0] = fmaf(a3, b0, acc[3][0]); acc[3][1] = fmaf(a3, b1, acc[3][1]);
      acc[3][2] = fmaf(a3, b2, acc[3][2]); acc[3][3] = fmaf(a3, b3, acc[3][3]);
    }
  }
#pragma unroll
  for (int i = 0; i < 4; ++i) {
    const int eps = e0 + ty * 4 + i;
    if (eps < 2032) {
#pragma unroll
      for (int j = 0; j < 4; ++j) {
        const int d = tx * 4 + j;
        const size_t idx = ((size_t)b * 2032 + eps) * 64 + d;
        tt[idx] = fabsf(acc[i][j] - emat[idx]);
      }
    }
  }
}

// ---------------------------------------------------------------------------
// head: att = softmax(e@a_w+a_b); red = sum_eps tt*att; h=relu(red@h_w^T+h_b);
// out = softmax(h@c_w^T + c_b).  One block per batch.
// ---------------------------------------------------------------------------
__global__ __launch_bounds__(256) void head_kernel(
    const float* __restrict__ emat, const float* __restrict__ tt,
    const float* __restrict__ a_w, const float* __restrict__ a_b,
    const float* __restrict__ h_w, const float* __restrict__ h_b,
    const float* __restrict__ c_w, const float* __restrict__ c_b,
    float* __restrict__ out) {
  __shared__ float s_att[2032];
  __shared__ float s_aw[64];
  __shared__ float sred[4];
  __shared__ float s_part[4][64];
  __shared__ float s_redv[64];
  __shared__ float s_hv[128];
  const int tid = threadIdx.x;
  const int lane = tid & 63, wave = tid >> 6;
  const int b = blockIdx.x;
  if (tid < 64) s_aw[tid] = a_w[tid];
  __syncthreads();
  const float ab = a_b[0];
  float m = -3.4e38f;
  for (int i = tid; i < 2032; i += 256) {
    const float* er = emat + ((size_t)b * 2032 + i) * 64;
    float acc = ab;
    for (int d = 0; d < 64; ++d) acc = fmaf(er[d], s_aw[d], acc);
    s_att[i] = acc;
    m = fmaxf(m, acc);
  }
#pragma unroll
  for (int off = 32; off > 0; off >>= 1) m = fmaxf(m, __shfl_down(m, off, 64));
  if (lane == 0) sred[wave] = m;
  __syncthreads();
  m = fmaxf(fmaxf(sred[0], sred[1]), fmaxf(sred[2], sred[3]));
  __syncthreads();
  float ssum = 0.f;
  for (int i = tid; i < 2032; i += 256) {
    const float v = __expf(s_att[i] - m);
    s_att[i] = v;
    ssum += v;
  }
#pragma unroll
  for (int off = 32; off > 0; off >>= 1) ssum += __shfl_down(ssum, off, 64);
  if (lane == 0) sred[wave] = ssum;
  __syncthreads();  // also publishes all s_att writes
  const float inv = 1.f / (sred[0] + sred[1] + sred[2] + sred[3]);
  // red[d] = inv * sum_eps tt[b,eps,d]*att[eps]
  float accp = 0.f;
  for (int i = wave; i < 2032; i += 4)
    accp = fmaf(tt[((size_t)b * 2032 + i) * 64 + lane], s_att[i], accp);
  s_part[wave][lane] = accp;
  __syncthreads();
  if (tid < 64)
    s_redv[tid] = (s_part[0][tid] + s_part[1][tid] + s_part[2][tid] + s_part[3][tid]) * inv;
  __syncthreads();
  if (tid < 128) {
    float acc = h_b[tid];
    const float* hw = h_w + tid * 64;
    for (int d = 0; d < 64; ++d) acc = fmaf(s_redv[d], hw[d], acc);
    s_hv[tid] = fmaxf(acc, 0.f);
  }
  __syncthreads();
  if (tid == 0) {
    float l0 = c_b[0], l1 = c_b[1];
    for (int j = 0; j < 128; ++j) {
      l0 = fmaf(s_hv[j], c_w[j], l0);
      l1 = fmaf(s_hv[j], c_w[128 + j], l1);
    }
    const float mm = fmaxf(l0, l1);
    const float e0 = __expf(l0 - mm), e1 = __expf(l1 - mm);
    const float invs = 1.f / (e0 + e1);
    out[b * 2 + 0] = e0 * invs;
    out[b * 2 + 1] = e1 * invs;
  }
}

// ===========================================================================
extern "C" void kernel_launch(void* const* d_in, const int* in_sizes, int n_in,
                              void* d_out, int out_size, void* d_ws, size_t ws_size,
                              hipStream_t stream) {
  const float* evaluation = (const float*)d_in[0];
  const float* templ      = (const float*)d_in[1];
  const float* e_w1 = (const float*)d_in[2];
  const float* e_b1 = (const float*)d_in[3];
  const float* e_w2 = (const float*)d_in[4];
  const float* e_b2 = (const float*)d_in[5];
  const float* e_w3 = (const float*)d_in[6];
  const float* e_b3 = (const float*)d_in[7];
  const float* el_w = (const float*)d_in[8];
  const float* el_b = (const float*)d_in[9];
  const float* eg_wih = (const float*)d_in[10];
  const float* eg_whh = (const float*)d_in[11];
  const float* eg_bih = (const float*)d_in[12];
  const float* eg_bhh = (const float*)d_in[13];
  const float* t_w1 = (const float*)d_in[14];
  const float* t_b1 = (const float*)d_in[15];
  const float* t_w2 = (const float*)d_in[16];
  const float* t_b2 = (const float*)d_in[17];
  const float* t_w3 = (const float*)d_in[18];
  const float* t_b3 = (const float*)d_in[19];
  const float* tl_w = (const float*)d_in[20];
  const float* tl_b = (const float*)d_in[21];
  const float* tg_wih = (const float*)d_in[22];
  const float* tg_whh = (const float*)d_in[23];
  const float* tg_bih = (const float*)d_in[24];
  const float* tg_bhh = (const float*)d_in[25];
  const float* a_w = (const float*)d_in[26];
  const float* a_b = (const float*)d_in[27];
  const float* h_w = (const float*)d_in[28];
  const float* h_b = (const float*)d_in[29];
  const float* c_w = (const float*)d_in[30];
  const float* c_b = (const float*)d_in[31];

  float* ws = (float*)d_ws;
  float* weff_e = ws + OFF_WEFF_E;
  float* weff_t = ws + OFF_WEFF_T;
  float* beff_e = ws + OFF_BEFF_E;
  float* beff_t = ws + OFF_BEFF_T;
  float* w12_e  = ws + OFF_W12_E;
  float* w12_t  = ws + OFF_W12_T;
  float* b12_e  = ws + OFF_B12_E;
  float* b12_t  = ws + OFF_B12_T;
  float* pool   = ws + OFF_POOL;
  float* gibuf  = ws + OFF_GI;
  float* Pbuf   = ws + OFF_P;
  float* ttbuf  = ws + OFF_TT;
  float* lin_e  = ws + OFF_LIN_E;
  float* lin_t  = ws + OFF_LIN_T;

  // weight composition (3 linear convs -> one 13x13 conv)
  compose1_kernel<<<1, 256, 0, stream>>>(e_w1, e_b1, e_w2, e_b2, w12_e, b12_e);
  compose1_kernel<<<1, 256, 0, stream>>>(t_w1, t_b1, t_w2, t_b2, w12_t, b12_t);
  compose2_kernel<<<8, 256, 0, stream>>>(w12_e, b12_e, e_w3, e_b3, weff_e, beff_e);
  compose2_kernel<<<8, 256, 0, stream>>>(w12_t, b12_t, t_w3, t_b3, weff_t, beff_t);

  // eval branch conv+pool then linear (3712 -> 64) on flat reshape
  conv_pool_kernel<<<dim3(32, 58, 4), 256, 0, stream>>>(evaluation, weff_e, beff_e, pool, 2048, 2032);
  gemm_nt_kernel<<<dim3(127, 1), 256, 0, stream>>>(pool, el_w, el_b, lin_e, 64, 3712);
  // template branch (reuses pooled buffer)
  conv_pool_kernel<<<dim3(16, 58, 4), 256, 0, stream>>>(templ, weff_t, beff_t, pool, 1040, 1024);
  gemm_nt_kernel<<<dim3(64, 1), 256, 0, stream>>>(pool, tl_w, tl_b, lin_t, 64, 3712);

  // GRU (scan over batch axis; gi precomputed as GEMM, recurrence in-place)
  gemm_nt_kernel<<<dim3(127, 3), 256, 0, stream>>>(lin_e, eg_wih, eg_bih, gibuf, 192, 64);
  gru_rec_kernel<<<127, 256, 0, stream>>>(lin_e, gibuf, eg_whh, eg_bhh, 2032);
  gemm_nt_kernel<<<dim3(64, 3), 256, 0, stream>>>(lin_t, tg_wih, tg_bih, gibuf, 192, 64);
  gru_rec_kernel<<<64, 256, 0, stream>>>(lin_t, gibuf, tg_whh, tg_bhh, 1024);

  // cross attention + head
  scores_kernel<<<dim3(16, 4), 256, 0, stream>>>(lin_t, lin_e, Pbuf);
  softmax_rows_kernel<<<4096, 256, 0, stream>>>(Pbuf);
  pv_kernel<<<dim3(32, 4), 256, 0, stream>>>(Pbuf, lin_t, lin_e, ttbuf);
  head_kernel<<<4, 256, 0, stream>>>(lin_e, ttbuf, a_w, a_b, h_w, h_b, c_w, c_b,
                                     (float*)d_out);
}

// Round 2
// 2095.814 us; speedup vs baseline: 1.4818x; 1.4818x over previous
//
#include <hip/hip_runtime.h>
#include <cmath>

// ============================================================================
// DeepTemplateMatchingModule on MI355X — round 2.
// R1 post-mortem: compose2 was latency-bound (8 blocks, serial scalar global
// loads, 400us each -> 1.6ms total). conv_pool VALUBusy 37% (I$ thrash from
// full unroll + cndmask masks).
// R2: single fused compose kernel per branch (64 blocks, LDS-staged weights);
// conv_pool rewritten with ping-pong register rows (no masks), bounded-size
// inner loop, float4 LDS broadcasts, 2 pooled rows per block.
// ============================================================================

// ---- workspace layout (float offsets) ----
static const size_t OFF_WEFF_E = 0;                         // 10816
static const size_t OFF_WEFF_T = 10816;                     // 10816
static const size_t OFF_BEFF_E = 21632;                     // 64
static const size_t OFF_BEFF_T = 21696;                     // 64
static const size_t OFF_POOL   = 27008;                     // 30,158,848 (max, eval)
static const size_t OFF_GI     = OFF_POOL;                  // 1,560,576
static const size_t OFF_P      = OFF_POOL + 1560576;        // 8,323,072
static const size_t OFF_TT     = OFF_POOL + 1560576 + 8323072; // 520,192
static const size_t OFF_LIN_E  = OFF_POOL + 30158848;       // 520,192
static const size_t OFF_LIN_T  = OFF_LIN_E + 520192;        // 262,144

// ---------------------------------------------------------------------------
// Fused weight composition: (w1 conv w2 conv w3) -> weff 13x13, 64 out ch.
// grid 64: block o computes weff[o] and beff[o]. All weights in LDS; w12 is
// recomputed per block (cheap, 0.5M fma) to avoid a dependent kernel chain.
// ---------------------------------------------------------------------------
__global__ __launch_bounds__(256) void compose_fused_kernel(
    const float* __restrict__ w1, const float* __restrict__ b1,
    const float* __restrict__ w2, const float* __restrict__ b2,
    const float* __restrict__ w3, const float* __restrict__ b3,
    float* __restrict__ weff, float* __restrict__ beff) {
  __shared__ float s_w1[400];      // 16 x 25
  __shared__ float s_w2[12800];    // 32 x 16 x 25
  __shared__ float s_w3o[800];     // w3[o] : 32 x 25
  __shared__ float s_w12[2592];    // 32 x 9 x 9
  __shared__ float s_b1[16], s_b2[32], s_b12[32];
  const int tid = threadIdx.x;
  const int o = blockIdx.x;
  for (int i = tid; i < 400; i += 256) s_w1[i] = w1[i];
  for (int i = tid; i < 12800; i += 256) s_w2[i] = w2[i];
  for (int i = tid; i < 800; i += 256) s_w3o[i] = w3[o * 800 + i];
  if (tid < 16) s_b1[tid] = b1[tid];
  if (tid < 32) s_b2[tid] = b2[tid];
  __syncthreads();
  // w12[c12, sy, sx] = sum_c1 w2[c12,c1] conv w1[c1]
  for (int idx = tid; idx < 2592; idx += 256) {
    const int c12 = idx / 81, s = idx % 81, sy = s / 9, sx = s % 9;
    const int uy0 = sy > 4 ? sy - 4 : 0, uy1 = sy < 4 ? sy : 4;
    const int ux0 = sx > 4 ? sx - 4 : 0, ux1 = sx < 4 ? sx : 4;
    float acc = 0.f;
    for (int c1 = 0; c1 < 16; ++c1) {
      const float* w2p = s_w2 + (c12 * 16 + c1) * 25;
      const float* w1p = s_w1 + c1 * 25;
      for (int uy = uy0; uy <= uy1; ++uy)
        for (int ux = ux0; ux <= ux1; ++ux)
          acc = fmaf(w2p[uy * 5 + ux], w1p[(sy - uy) * 5 + (sx - ux)], acc);
    }
    s_w12[idx] = acc;
  }
  // b12[c12] = b2[c12] + sum_c1 b1[c1] * sum_u w2[c12,c1,u]
  if (tid < 32) {
    float acc = s_b2[tid];
    for (int c1 = 0; c1 < 16; ++c1) {
      float sw = 0.f;
      const float* w2p = s_w2 + (tid * 16 + c1) * 25;
      for (int u = 0; u < 25; ++u) sw += w2p[u];
      acc = fmaf(sw, s_b1[c1], acc);
    }
    s_b12[tid] = acc;
  }
  __syncthreads();
  // weff[o, sy, sx] (13x13) = sum_c12 w3[o,c12] conv w12[c12]
  if (tid < 169) {
    const int sy = tid / 13, sx = tid % 13;
    const int uy0 = sy > 8 ? sy - 8 : 0, uy1 = sy < 4 ? sy : 4;
    const int ux0 = sx > 8 ? sx - 8 : 0, ux1 = sx < 4 ? sx : 4;
    float acc = 0.f;
    for (int c = 0; c < 32; ++c) {
      const float* w3p = s_w3o + c * 25;
      const float* wp = s_w12 + c * 81;
      for (int uy = uy0; uy <= uy1; ++uy)
        for (int ux = ux0; ux <= ux1; ++ux)
          acc = fmaf(w3p[uy * 5 + ux], wp[(sy - uy) * 9 + (sx - ux)], acc);
    }
    weff[o * 169 + tid] = acc;
  }
  if (tid == 255) {
    float acc = b3[o];
    for (int c = 0; c < 32; ++c) {
      float sw = 0.f;
      const float* w3p = s_w3o + c * 25;
      for (int u = 0; u < 25; ++u) sw += w3p[u];
      acc = fmaf(sw, s_b12[c], acc);
    }
    beff[o] = acc;
  }
}

// ---------------------------------------------------------------------------
// Fused conv13x13 + maxpool(2,5)/(2,1). Block: 2 pooled rows x 64 pooled cols
// x 64 ch for one batch. Thread (c=tid&63, strip=(tid>>6)*16). Ping-pong
// register rows: weight row y multiplies input row y (acc0, conv row 2h) and
// input row y+1 (acc1, conv row 2h+1) — no masks, no dynamic row select.
// Outer y-loop kept rolled (6x2+1 steps, ~9KB body) to stay inside I$.
// grid: (ceil(T/64), 29, 4)
// ---------------------------------------------------------------------------
#define CP_STEP(Y, CUR, NXT)                                              \
  {                                                                       \
    _Pragma("unroll") for (int j = 0; j < 8; ++j)                         \
        *(float4*)((NXT) + 4 * j) =                                       \
            *(const float4*)(s_in + ((Y) + 1) * 80 + x0 + 4 * j);         \
    _Pragma("unroll") for (int kx = 0; kx < 13; ++kx) {                   \
      const float wv = wr[(Y)*13 + kx];                                   \
      _Pragma("unroll") for (int j = 0; j < 20; ++j) {                    \
        acc0[j] = fmaf(wv, (CUR)[kx + j], acc0[j]);                       \
        acc1[j] = fmaf(wv, (NXT)[kx + j], acc1[j]);                       \
      }                                                                   \
    }                                                                     \
  }

__global__ __launch_bounds__(256, 3) void conv_pool_kernel(
    const float* __restrict__ x, const float* __restrict__ weff,
    const float* __restrict__ beff, float* __restrict__ pooled,
    const int W, const int T) {
  __shared__ __align__(16) float s_w[64 * 169];
  __shared__ float s_b[64];
  __shared__ __align__(16) float s_in[14 * 80];
  const int tid = threadIdx.x;
  const int wb = blockIdx.x * 64;
  const int b = blockIdx.z;
  for (int i = tid; i < 64 * 169; i += 256) s_w[i] = weff[i];
  if (tid < 64) s_b[tid] = beff[tid];
  const int c = tid & 63;
  const int x0 = (tid >> 6) * 16;
  const float* wr = s_w + c * 169;
  const float bias = beff[c];  // also cached via s_b; scalar read is fine
  for (int hh = 0; hh < 2; ++hh) {
    const int h = blockIdx.y * 2 + hh;
    __syncthreads();  // publish weights (hh=0) / protect s_in reuse (hh=1)
    {
      const float* xrow = x + ((size_t)b * 128 + 2 * h) * W;
      for (int i = tid; i < 14 * 80; i += 256) {
        const int r = i / 80, cq = i - r * 80;
        int gc = wb + cq;
        if (gc > W - 1) gc = W - 1;  // clamped lanes never feed stored outputs
        s_in[i] = xrow[(size_t)r * W + gc];
      }
    }
    __syncthreads();
    float acc0[20] = {}, acc1[20] = {};
    float ra[32], rb[32];
#pragma unroll
    for (int j = 0; j < 8; ++j)
      *(float4*)(ra + 4 * j) = *(const float4*)(s_in + x0 + 4 * j);
#pragma unroll 1
    for (int yy = 0; yy < 6; ++yy) {
      CP_STEP(2 * yy, ra, rb)
      CP_STEP(2 * yy + 1, rb, ra)
    }
    CP_STEP(12, ra, rb)
    float* outp = pooled + (((size_t)b * 64 + c) * 58 + h) * T + wb + x0;
#pragma unroll
    for (int jj = 0; jj < 16; ++jj) {
      float m = acc0[jj];
#pragma unroll
      for (int k = 1; k < 5; ++k) m = fmaxf(m, acc0[jj + k]);
#pragma unroll
      for (int k = 0; k < 5; ++k) m = fmaxf(m, acc1[jj + k]);
      if (wb + x0 + jj < T) outp[jj] = m + bias;
    }
  }
}

// ---------------------------------------------------------------------------
// Generic fp32 GEMM: out[r][n] = sum_k A[r*K+k]*Wt[n*K+k] + bias[n]
// 64x64 tile per block, 4x4 per thread, K-chunks of 32. M == grid.x*64 exact.
// ---------------------------------------------------------------------------
__global__ __launch_bounds__(256) void gemm_nt_kernel(
    const float* __restrict__ A, const float* __restrict__ Wt,
    const float* __restrict__ bias, float* __restrict__ out,
    const int N, const int K) {
  __shared__ float sA[64 * 33];
  __shared__ float sB[64 * 33];
  const int tid = threadIdx.x;
  const int r0 = blockIdx.x * 64;
  const int n0 = blockIdx.y * 64;
  const int ty = tid >> 4, tx = tid & 15;
  float acc[4][4] = {};
  for (int kc = 0; kc < K; kc += 32) {
    __syncthreads();
#pragma unroll
    for (int rep = 0; rep < 8; ++rep) {
      const int l = tid + rep * 256;
      const int row = l >> 5, kk = l & 31;
      sA[row * 33 + kk] = A[(size_t)(r0 + row) * K + kc + kk];
      sB[row * 33 + kk] = Wt[(size_t)(n0 + row) * K + kc + kk];
    }
    __syncthreads();
#pragma unroll 8
    for (int kk = 0; kk < 32; ++kk) {
      const float a0 = sA[(ty * 4 + 0) * 33 + kk];
      const float a1 = sA[(ty * 4 + 1) * 33 + kk];
      const float a2 = sA[(ty * 4 + 2) * 33 + kk];
      const float a3 = sA[(ty * 4 + 3) * 33 + kk];
      const float b0 = sB[(tx * 4 + 0) * 33 + kk];
      const float b1 = sB[(tx * 4 + 1) * 33 + kk];
      const float b2 = sB[(tx * 4 + 2) * 33 + kk];
      const float b3 = sB[(tx * 4 + 3) * 33 + kk];
      acc[0][0] = fmaf(a0, b0, acc[0][0]); acc[0][1] = fmaf(a0, b1, acc[0][1]);
      acc[0][2] = fmaf(a0, b2, acc[0][2]); acc[0][3] = fmaf(a0, b3, acc[0][3]);
      acc[1][0] = fmaf(a1, b0, acc[1][0]); acc[1][1] = fmaf(a1, b1, acc[1][1]);
      acc[1][2] = fmaf(a1, b2, acc[1][2]); acc[1][3] = fmaf(a1, b3, acc[1][3]);
      acc[2][0] = fmaf(a2, b0, acc[2][0]); acc[2][1] = fmaf(a2, b1, acc[2][1]);
      acc[2][2] = fmaf(a2, b2, acc[2][2]); acc[2][3] = fmaf(a2, b3, acc[2][3]);
      acc[3][0] = fmaf(a3, b0, acc[3][0]); acc[3][1] = fmaf(a3, b1, acc[3][1]);
      acc[3][2] = fmaf(a3, b2, acc[3][2]); acc[3][3] = fmaf(a3, b3, acc[3][3]);
    }
  }
#pragma unroll
  for (int i = 0; i < 4; ++i)
#pragma unroll
    for (int j = 0; j < 4; ++j)
      out[(size_t)(r0 + ty * 4 + i) * N + n0 + tx * 4 + j] =
          acc[i][j] + bias[n0 + tx * 4 + j];
}

// ---------------------------------------------------------------------------
// GRU recurrence (scan over BATCH axis, 4 steps; every t independent).
// ---------------------------------------------------------------------------
__global__ __launch_bounds__(256) void gru_rec_kernel(
    float* __restrict__ xy, const float* __restrict__ gi,
    const float* __restrict__ whh, const float* __restrict__ bhh, const int T) {
  __shared__ float s_whh_t[64 * 192];  // [d][j]
  __shared__ float s_h[16][64];
  const int tid = threadIdx.x;
  const int lane = tid & 63, wave = tid >> 6;
  for (int i = tid; i < 192 * 64; i += 256) {
    const int j = i >> 6, d = i & 63;
    s_whh_t[d * 192 + j] = whh[i];
  }
  for (int i = tid; i < 16 * 64; i += 256) (&s_h[0][0])[i] = 0.f;
  const float bhr = bhh[lane], bhz = bhh[64 + lane], bhn = bhh[128 + lane];
  const int t0 = blockIdx.x * 16;
  __syncthreads();
  for (int b = 0; b < 4; ++b) {
    float gir[4], giz[4], gin[4];
#pragma unroll
    for (int sl = 0; sl < 4; ++sl) {
      int t = t0 + wave * 4 + sl; if (t > T - 1) t = T - 1;
      const float* girow = gi + ((size_t)b * T + t) * 192;
      gir[sl] = girow[lane]; giz[sl] = girow[64 + lane]; gin[sl] = girow[128 + lane];
    }
    float ahr[4] = {}, ahz[4] = {}, ahn[4] = {};
    for (int d = 0; d < 64; ++d) {
      const float wr_ = s_whh_t[d * 192 + lane];
      const float wz_ = s_whh_t[d * 192 + 64 + lane];
      const float wn_ = s_whh_t[d * 192 + 128 + lane];
#pragma unroll
      for (int sl = 0; sl < 4; ++sl) {
        const float hv = s_h[wave * 4 + sl][d];
        ahr[sl] = fmaf(wr_, hv, ahr[sl]);
        ahz[sl] = fmaf(wz_, hv, ahz[sl]);
        ahn[sl] = fmaf(wn_, hv, ahn[sl]);
      }
    }
    float hn[4];
#pragma unroll
    for (int sl = 0; sl < 4; ++sl) {
      const float r = 1.f / (1.f + __expf(-(gir[sl] + ahr[sl] + bhr)));
      const float z = 1.f / (1.f + __expf(-(giz[sl] + ahz[sl] + bhz)));
      const float n = tanhf(gin[sl] + r * (ahn[sl] + bhn));
      hn[sl] = (1.f - z) * n + z * s_h[wave * 4 + sl][lane];
    }
    __syncthreads();
#pragma unroll
    for (int sl = 0; sl < 4; ++sl) {
      const int t = t0 + wave * 4 + sl;
      s_h[wave * 4 + sl][lane] = hn[sl];
      if (t < T) xy[((size_t)b * T + t) * 64 + lane] = hn[sl];
    }
    __syncthreads();
  }
}

// ---------------------------------------------------------------------------
// scores: P[b,tau,eps] = sum_d t[b,tau,d]*e[b,eps,d].  grid (16,4).
// ---------------------------------------------------------------------------
__global__ __launch_bounds__(256) void scores_kernel(
    const float* __restrict__ tmat, const float* __restrict__ emat,
    float* __restrict__ P) {
  __shared__ float sT[64 * 65];
  __shared__ float sE[64 * 65];
  const int tid = threadIdx.x;
  const int b = blockIdx.y;
  const int tau0 = blockIdx.x * 64;
  const int ty = tid >> 4, tx = tid & 15;
  for (int l = tid; l < 64 * 64; l += 256) {
    const int row = l >> 6, d = l & 63;
    sT[row * 65 + d] = tmat[((size_t)b * 1024 + tau0 + row) * 64 + d];
  }
  for (int et = 0; et < 32; ++et) {
    const int e0 = et * 64;
    __syncthreads();
    for (int l = tid; l < 64 * 64; l += 256) {
      const int row = l >> 6, d = l & 63;
      int eps = e0 + row; if (eps > 2031) eps = 2031;
      sE[row * 65 + d] = emat[((size_t)b * 2032 + eps) * 64 + d];
    }
    __syncthreads();
    float acc[4][4] = {};
#pragma unroll 8
    for (int kk = 0; kk < 64; ++kk) {
      const float a0 = sT[(ty * 4 + 0) * 65 + kk];
      const float a1 = sT[(ty * 4 + 1) * 65 + kk];
      const float a2 = sT[(ty * 4 + 2) * 65 + kk];
      const float a3 = sT[(ty * 4 + 3) * 65 + kk];
      const float b0 = sE[(tx * 4 + 0) * 65 + kk];
      const float b1 = sE[(tx * 4 + 1) * 65 + kk];
      const float b2 = sE[(tx * 4 + 2) * 65 + kk];
      const float b3 = sE[(tx * 4 + 3) * 65 + kk];
      acc[0][0] = fmaf(a0, b0, acc[0][0]); acc[0][1] = fmaf(a0, b1, acc[0][1]);
      acc[0][2] = fmaf(a0, b2, acc[0][2]); acc[0][3] = fmaf(a0, b3, acc[0][3]);
      acc[1][0] = fmaf(a1, b0, acc[1][0]); acc[1][1] = fmaf(a1, b1, acc[1][1]);
      acc[1][2] = fmaf(a1, b2, acc[1][2]); acc[1][3] = fmaf(a1, b3, acc[1][3]);
      acc[2][0] = fmaf(a2, b0, acc[2][0]); acc[2][1] = fmaf(a2, b1, acc[2][1]);
      acc[2][2] = fmaf(a2, b2, acc[2][2]); acc[2][3] = fmaf(a2, b3, acc[2][3]);
      acc[3][0] = fmaf(a3, b0, acc[3][0]); acc[3][1] = fmaf(a3, b1, acc[3][1]);
      acc[3][2] = fmaf(a3, b2, acc[3][2]); acc[3][3] = fmaf(a3, b3, acc[3][3]);
    }
#pragma unroll
    for (int i = 0; i < 4; ++i) {
      const size_t prow = ((size_t)b * 1024 + tau0 + ty * 4 + i) * 2032;
#pragma unroll
      for (int j = 0; j < 4; ++j) {
        const int eps = e0 + tx * 4 + j;
        if (eps < 2032) P[prow + eps] = acc[i][j];
      }
    }
  }
}

// ---------------------------------------------------------------------------
// row softmax over eps (rows of length 2032). grid 4096.
// ---------------------------------------------------------------------------
__global__ __launch_bounds__(256) void softmax_rows_kernel(float* __restrict__ P) {
  float* r = P + (size_t)blockIdx.x * 2032;
  const int tid = threadIdx.x;
  const int lane = tid & 63, wave = tid >> 6;
  __shared__ float sred[4];
  float m = -3.4e38f;
  for (int i = tid; i < 2032; i += 256) m = fmaxf(m, r[i]);
#pragma unroll
  for (int off = 32; off > 0; off >>= 1) m = fmaxf(m, __shfl_down(m, off, 64));
  if (lane == 0) sred[wave] = m;
  __syncthreads();
  m = fmaxf(fmaxf(sred[0], sred[1]), fmaxf(sred[2], sred[3]));
  __syncthreads();
  float s = 0.f;
  float vals[8];
  int cnt = 0;
  for (int i = tid; i < 2032; i += 256) {
    const float v = __expf(r[i] - m);
    vals[cnt++] = v;
    s += v;
  }
#pragma unroll
  for (int off = 32; off > 0; off >>= 1) s += __shfl_down(s, off, 64);
  if (lane == 0) sred[wave] = s;
  __syncthreads();
  const float inv = 1.f / (sred[0] + sred[1] + sred[2] + sred[3]);
  cnt = 0;
  for (int i = tid; i < 2032; i += 256) r[i] = vals[cnt++] * inv;
}

// ---------------------------------------------------------------------------
// pv: tt[b,eps,d] = | sum_tau P[b,tau,eps]*t[b,tau,d]  -  e[b,eps,d] |
// ---------------------------------------------------------------------------
__global__ __launch_bounds__(256) void pv_kernel(
    const float* __restrict__ P, const float* __restrict__ tmat,
    const float* __restrict__ emat, float* __restrict__ tt) {
  __shared__ float sP[32 * 65];
  __shared__ float sT[32 * 65];
  const int tid = threadIdx.x;
  const int b = blockIdx.y;
  const int e0 = blockIdx.x * 64;
  const int ty = tid >> 4, tx = tid & 15;
  float acc[4][4] = {};
  for (int kc = 0; kc < 1024; kc += 32) {
    __syncthreads();
    for (int l = tid; l < 32 * 64; l += 256) {
      const int kk = l >> 6, j = l & 63;
      int eps = e0 + j; if (eps > 2031) eps = 2031;
      sP[kk * 65 + j] = P[((size_t)b * 1024 + kc + kk) * 2032 + eps];
      sT[kk * 65 + j] = tmat[((size_t)b * 1024 + kc + kk) * 64 + j];
    }
    __syncthreads();
#pragma unroll 8
    for (int kk = 0; kk < 32; ++kk) {
      const float a0 = sP[kk * 65 + ty * 4 + 0];
      const float a1 = sP[kk * 65 + ty * 4 + 1];
      const float a2 = sP[kk * 65 + ty * 4 + 2];
      const float a3 = sP[kk * 65 + ty * 4 + 3];
      const float b0 = sT[kk * 65 + tx * 4 + 0];
      const float b1 = sT[kk * 65 + tx * 4 + 1];
      const float b2 = sT[kk * 65 + tx * 4 + 2];
      const float b3 = sT[kk * 65 + tx * 4 + 3];
      acc[0][0] = fmaf(a0, b0, acc[0][0]); acc[0][1] = fmaf(a0, b1, acc[0][1]);
      acc[0][2] = fmaf(a0, b2, acc[0][2]); acc[0][3] = fmaf(a0, b3, acc[0][3]);
      acc[1][0] = fmaf(a1, b0, acc[1][0]); acc[1][1] = fmaf(a1, b1, acc[1][1]);
      acc[1][2] = fmaf(a1, b2, acc[1][2]); acc[1][3] = fmaf(a1, b3, acc[1][3]);
      acc[2][0] = fmaf(a2, b0, acc[2][0]); acc[2][1] = fmaf(a2, b1, acc[2][1]);
      acc[2][2] = fmaf(a2, b2, acc[2][2]); acc[2][3] = fmaf(a2, b3, acc[2][3]);
      acc[3][0] = fmaf(a3, b0, acc[3][0]); acc[3][1] = fmaf(a3, b1, acc[3][1]);
      acc[3][2] = fmaf(a3, b2, acc[3][2]); acc[3][3] = fmaf(a3, b3, acc[3][3]);
    }
  }
#pragma unroll
  for (int i = 0; i < 4; ++i) {
    const int eps = e0 + ty * 4 + i;
    if (eps < 2032) {
#pragma unroll
      for (int j = 0; j < 4; ++j) {
        const int d = tx * 4 + j;
        const size_t idx = ((size_t)b * 2032 + eps) * 64 + d;
        tt[idx] = fabsf(acc[i][j] - emat[idx]);
      }
    }
  }
}

// ---------------------------------------------------------------------------
// head: att softmax + weighted reduce + 2-layer MLP + final softmax.
// ---------------------------------------------------------------------------
__global__ __launch_bounds__(256) void head_kernel(
    const float* __restrict__ emat, const float* __restrict__ tt,
    const float* __restrict__ a_w, const float* __restrict__ a_b,
    const float* __restrict__ h_w, const float* __restrict__ h_b,
    const float* __restrict__ c_w, const float* __restrict__ c_b,
    float* __restrict__ out) {
  __shared__ float s_att[2032];
  __shared__ float s_aw[64];
  __shared__ float sred[4];
  __shared__ float s_part[4][64];
  __shared__ float s_redv[64];
  __shared__ float s_hv[128];
  const int tid = threadIdx.x;
  const int lane = tid & 63, wave = tid >> 6;
  const int b = blockIdx.x;
  if (tid < 64) s_aw[tid] = a_w[tid];
  __syncthreads();
  const float ab = a_b[0];
  float m = -3.4e38f;
  for (int i = tid; i < 2032; i += 256) {
    const float* er = emat + ((size_t)b * 2032 + i) * 64;
    float acc = ab;
    for (int d = 0; d < 64; ++d) acc = fmaf(er[d], s_aw[d], acc);
    s_att[i] = acc;
    m = fmaxf(m, acc);
  }
#pragma unroll
  for (int off = 32; off > 0; off >>= 1) m = fmaxf(m, __shfl_down(m, off, 64));
  if (lane == 0) sred[wave] = m;
  __syncthreads();
  m = fmaxf(fmaxf(sred[0], sred[1]), fmaxf(sred[2], sred[3]));
  __syncthreads();
  float ssum = 0.f;
  for (int i = tid; i < 2032; i += 256) {
    const float v = __expf(s_att[i] - m);
    s_att[i] = v;
    ssum += v;
  }
#pragma unroll
  for (int off = 32; off > 0; off >>= 1) ssum += __shfl_down(ssum, off, 64);
  if (lane == 0) sred[wave] = ssum;
  __syncthreads();
  const float inv = 1.f / (sred[0] + sred[1] + sred[2] + sred[3]);
  float accp = 0.f;
  for (int i = wave; i < 2032; i += 4)
    accp = fmaf(tt[((size_t)b * 2032 + i) * 64 + lane], s_att[i], accp);
  s_part[wave][lane] = accp;
  __syncthreads();
  if (tid < 64)
    s_redv[tid] = (s_part[0][tid] + s_part[1][tid] + s_part[2][tid] + s_part[3][tid]) * inv;
  __syncthreads();
  if (tid < 128) {
    float acc = h_b[tid];
    const float* hw = h_w + tid * 64;
    for (int d = 0; d < 64; ++d) acc = fmaf(s_redv[d], hw[d], acc);
    s_hv[tid] = fmaxf(acc, 0.f);
  }
  __syncthreads();
  if (tid == 0) {
    float l0 = c_b[0], l1 = c_b[1];
    for (int j = 0; j < 128; ++j) {
      l0 = fmaf(s_hv[j], c_w[j], l0);
      l1 = fmaf(s_hv[j], c_w[128 + j], l1);
    }
    const float mm = fmaxf(l0, l1);
    const float e0 = __expf(l0 - mm), e1 = __expf(l1 - mm);
    const float invs = 1.f / (e0 + e1);
    out[b * 2 + 0] = e0 * invs;
    out[b * 2 + 1] = e1 * invs;
  }
}

// ===========================================================================
extern "C" void kernel_launch(void* const* d_in, const int* in_sizes, int n_in,
                              void* d_out, int out_size, void* d_ws, size_t ws_size,
                              hipStream_t stream) {
  const float* evaluation = (const float*)d_in[0];
  const float* templ      = (const float*)d_in[1];
  const float* e_w1 = (const float*)d_in[2];
  const float* e_b1 = (const float*)d_in[3];
  const float* e_w2 = (const float*)d_in[4];
  const float* e_b2 = (const float*)d_in[5];
  const float* e_w3 = (const float*)d_in[6];
  const float* e_b3 = (const float*)d_in[7];
  const float* el_w = (const float*)d_in[8];
  const float* el_b = (const float*)d_in[9];
  const float* eg_wih = (const float*)d_in[10];
  const float* eg_whh = (const float*)d_in[11];
  const float* eg_bih = (const float*)d_in[12];
  const float* eg_bhh = (const float*)d_in[13];
  const float* t_w1 = (const float*)d_in[14];
  const float* t_b1 = (const float*)d_in[15];
  const float* t_w2 = (const float*)d_in[16];
  const float* t_b2 = (const float*)d_in[17];
  const float* t_w3 = (const float*)d_in[18];
  const float* t_b3 = (const float*)d_in[19];
  const float* tl_w = (const float*)d_in[20];
  const float* tl_b = (const float*)d_in[21];
  const float* tg_wih = (const float*)d_in[22];
  const float* tg_whh = (const float*)d_in[23];
  const float* tg_bih = (const float*)d_in[24];
  const float* tg_bhh = (const float*)d_in[25];
  const float* a_w = (const float*)d_in[26];
  const float* a_b = (const float*)d_in[27];
  const float* h_w = (const float*)d_in[28];
  const float* h_b = (const float*)d_in[29];
  const float* c_w = (const float*)d_in[30];
  const float* c_b = (const float*)d_in[31];

  float* ws = (float*)d_ws;
  float* weff_e = ws + OFF_WEFF_E;
  float* weff_t = ws + OFF_WEFF_T;
  float* beff_e = ws + OFF_BEFF_E;
  float* beff_t = ws + OFF_BEFF_T;
  float* pool   = ws + OFF_POOL;
  float* gibuf  = ws + OFF_GI;
  float* Pbuf   = ws + OFF_P;
  float* ttbuf  = ws + OFF_TT;
  float* lin_e  = ws + OFF_LIN_E;
  float* lin_t  = ws + OFF_LIN_T;

  // fused weight composition (3 linear convs -> one 13x13 conv), 64 blocks ea
  compose_fused_kernel<<<64, 256, 0, stream>>>(e_w1, e_b1, e_w2, e_b2, e_w3, e_b3, weff_e, beff_e);
  compose_fused_kernel<<<64, 256, 0, stream>>>(t_w1, t_b1, t_w2, t_b2, t_w3, t_b3, weff_t, beff_t);

  // eval branch conv+pool then linear (3712 -> 64) on flat reshape
  conv_pool_kernel<<<dim3(32, 29, 4), 256, 0, stream>>>(evaluation, weff_e, beff_e, pool, 2048, 2032);
  gemm_nt_kernel<<<dim3(127, 1), 256, 0, stream>>>(pool, el_w, el_b, lin_e, 64, 3712);
  // template branch (reuses pooled buffer)
  conv_pool_kernel<<<dim3(16, 29, 4), 256, 0, stream>>>(templ, weff_t, beff_t, pool, 1040, 1024);
  gemm_nt_kernel<<<dim3(64, 1), 256, 0, stream>>>(pool, tl_w, tl_b, lin_t, 64, 3712);

  // GRU (scan over batch axis; gi precomputed as GEMM, recurrence in-place)
  gemm_nt_kernel<<<dim3(127, 3), 256, 0, stream>>>(lin_e, eg_wih, eg_bih, gibuf, 192, 64);
  gru_rec_kernel<<<127, 256, 0, stream>>>(lin_e, gibuf, eg_whh, eg_bhh, 2032);
  gemm_nt_kernel<<<dim3(64, 3), 256, 0, stream>>>(lin_t, tg_wih, tg_bih, gibuf, 192, 64);
  gru_rec_kernel<<<64, 256, 0, stream>>>(lin_t, gibuf, tg_whh, tg_bhh, 1024);

  // cross attention + head
  scores_kernel<<<dim3(16, 4), 256, 0, stream>>>(lin_t, lin_e, Pbuf);
  softmax_rows_kernel<<<4096, 256, 0, stream>>>(Pbuf);
  pv_kernel<<<dim3(32, 4), 256, 0, stream>>>(Pbuf, lin_t, lin_e, ttbuf);
  head_kernel<<<4, 256, 0, stream>>>(lin_e, ttbuf, a_w, a_b, h_w, h_b, c_w, c_b,
                                     (float*)d_out);
}

// Round 3
// 1604.401 us; speedup vs baseline: 1.9356x; 1.3063x over previous
//
#include <hip/hip_runtime.h>
#include <cmath>

// ============================================================================
// DeepTemplateMatchingModule on MI355X — round 3.
// R2 post-mortem: conv_pool 346us @71% VALU (OK for fp32); the other ~1.5ms
// is spread across small-grid latency-bound GEMMs (127/64/128 blocks = 1
// wave/SIMD, half the CUs idle). R3: split-K pool-GEMM with atomics (1016
// blocks), scores retiled to 1024 blocks (K=64 one-shot), pv split over tau
// (512 blocks, atomic PV; |PV-e| folded into head), softmax rows via LDS.
// lin bias folded into the gi GEMM bias (lin only feeds the GRU through gi).
// ============================================================================

// ---- workspace layout (float offsets) ----
static const size_t OFF_WEFF_E  = 0;                          // 10816
static const size_t OFF_WEFF_T  = 10816;                      // 10816
static const size_t OFF_BEFF_E  = 21632;                      // 64
static const size_t OFF_BEFF_T  = 21696;                      // 64
static const size_t OFF_BIAS2_E = 21760;                      // 192
static const size_t OFF_BIAS2_T = 21952;                      // 192
static const size_t OFF_POOL    = 27008;                      // 30,158,848 (eval)
static const size_t OFF_GI      = OFF_POOL;                   // 1,560,576
static const size_t OFF_P       = OFF_POOL + 1560576;         // 8,323,072
static const size_t OFF_PV      = OFF_P + 8323072;            // 520,192
static const size_t OFF_LIN_E   = OFF_POOL + 30158848;        // 520,192
static const size_t OFF_LIN_T   = OFF_LIN_E + 520192;         // 262,144

// ---------------------------------------------------------------------------
// Fused weight composition: (w1 conv w2 conv w3) -> weff 13x13, 64 out ch.
// ---------------------------------------------------------------------------
__global__ __launch_bounds__(256) void compose_fused_kernel(
    const float* __restrict__ w1, const float* __restrict__ b1,
    const float* __restrict__ w2, const float* __restrict__ b2,
    const float* __restrict__ w3, const float* __restrict__ b3,
    float* __restrict__ weff, float* __restrict__ beff) {
  __shared__ float s_w1[400];
  __shared__ float s_w2[12800];
  __shared__ float s_w3o[800];
  __shared__ float s_w12[2592];
  __shared__ float s_b1[16], s_b2[32], s_b12[32];
  const int tid = threadIdx.x;
  const int o = blockIdx.x;
  for (int i = tid; i < 400; i += 256) s_w1[i] = w1[i];
  for (int i = tid; i < 12800; i += 256) s_w2[i] = w2[i];
  for (int i = tid; i < 800; i += 256) s_w3o[i] = w3[o * 800 + i];
  if (tid < 16) s_b1[tid] = b1[tid];
  if (tid < 32) s_b2[tid] = b2[tid];
  __syncthreads();
  for (int idx = tid; idx < 2592; idx += 256) {
    const int c12 = idx / 81, s = idx % 81, sy = s / 9, sx = s % 9;
    const int uy0 = sy > 4 ? sy - 4 : 0, uy1 = sy < 4 ? sy : 4;
    const int ux0 = sx > 4 ? sx - 4 : 0, ux1 = sx < 4 ? sx : 4;
    float acc = 0.f;
    for (int c1 = 0; c1 < 16; ++c1) {
      const float* w2p = s_w2 + (c12 * 16 + c1) * 25;
      const float* w1p = s_w1 + c1 * 25;
      for (int uy = uy0; uy <= uy1; ++uy)
        for (int ux = ux0; ux <= ux1; ++ux)
          acc = fmaf(w2p[uy * 5 + ux], w1p[(sy - uy) * 5 + (sx - ux)], acc);
    }
    s_w12[idx] = acc;
  }
  if (tid < 32) {
    float acc = s_b2[tid];
    for (int c1 = 0; c1 < 16; ++c1) {
      float sw = 0.f;
      const float* w2p = s_w2 + (tid * 16 + c1) * 25;
      for (int u = 0; u < 25; ++u) sw += w2p[u];
      acc = fmaf(sw, s_b1[c1], acc);
    }
    s_b12[tid] = acc;
  }
  __syncthreads();
  if (tid < 169) {
    const int sy = tid / 13, sx = tid % 13;
    const int uy0 = sy > 8 ? sy - 8 : 0, uy1 = sy < 4 ? sy : 4;
    const int ux0 = sx > 8 ? sx - 8 : 0, ux1 = sx < 4 ? sx : 4;
    float acc = 0.f;
    for (int c = 0; c < 32; ++c) {
      const float* w3p = s_w3o + c * 25;
      const float* wp = s_w12 + c * 81;
      for (int uy = uy0; uy <= uy1; ++uy)
        for (int ux = ux0; ux <= ux1; ++ux)
          acc = fmaf(w3p[uy * 5 + ux], wp[(sy - uy) * 9 + (sx - ux)], acc);
    }
    weff[o * 169 + tid] = acc;
  }
  if (tid == 255) {
    float acc = b3[o];
    for (int c = 0; c < 32; ++c) {
      float sw = 0.f;
      const float* w3p = s_w3o + c * 25;
      for (int u = 0; u < 25; ++u) sw += w3p[u];
      acc = fmaf(sw, s_b12[c], acc);
    }
    beff[o] = acc;
  }
}

// ---------------------------------------------------------------------------
// bias2[j] = b_ih[j] + sum_d w_ih[j,d] * lb[d]   (lin-bias folded into gi)
// ---------------------------------------------------------------------------
__global__ __launch_bounds__(256) void gi_bias_kernel(
    const float* __restrict__ wih, const float* __restrict__ bih,
    const float* __restrict__ lb, float* __restrict__ bias2) {
  __shared__ float s_lb[64];
  const int tid = threadIdx.x;
  if (tid < 64) s_lb[tid] = lb[tid];
  __syncthreads();
  if (tid < 192) {
    float acc = bih[tid];
    const float* wr = wih + tid * 64;
    for (int d = 0; d < 64; ++d) acc = fmaf(wr[d], s_lb[d], acc);
    bias2[tid] = acc;
  }
}

// ---------------------------------------------------------------------------
// Fused conv13x13 + maxpool(2,5)/(2,1). (unchanged from R2: 71% VALUBusy)
// ---------------------------------------------------------------------------
#define CP_STEP(Y, CUR, NXT)                                              \
  {                                                                       \
    _Pragma("unroll") for (int j = 0; j < 8; ++j)                         \
        *(float4*)((NXT) + 4 * j) =                                       \
            *(const float4*)(s_in + ((Y) + 1) * 80 + x0 + 4 * j);         \
    _Pragma("unroll") for (int kx = 0; kx < 13; ++kx) {                   \
      const float wv = wr[(Y)*13 + kx];                                   \
      _Pragma("unroll") for (int j = 0; j < 20; ++j) {                    \
        acc0[j] = fmaf(wv, (CUR)[kx + j], acc0[j]);                       \
        acc1[j] = fmaf(wv, (NXT)[kx + j], acc1[j]);                       \
      }                                                                   \
    }                                                                     \
  }

__global__ __launch_bounds__(256, 3) void conv_pool_kernel(
    const float* __restrict__ x, const float* __restrict__ weff,
    const float* __restrict__ beff, float* __restrict__ pooled,
    const int W, const int T) {
  __shared__ __align__(16) float s_w[64 * 169];
  __shared__ float s_b[64];
  __shared__ __align__(16) float s_in[14 * 80];
  const int tid = threadIdx.x;
  const int wb = blockIdx.x * 64;
  const int b = blockIdx.z;
  for (int i = tid; i < 64 * 169; i += 256) s_w[i] = weff[i];
  if (tid < 64) s_b[tid] = beff[tid];
  const int c = tid & 63;
  const int x0 = (tid >> 6) * 16;
  const float* wr = s_w + c * 169;
  const float bias = beff[c];
  for (int hh = 0; hh < 2; ++hh) {
    const int h = blockIdx.y * 2 + hh;
    __syncthreads();
    {
      const float* xrow = x + ((size_t)b * 128 + 2 * h) * W;
      for (int i = tid; i < 14 * 80; i += 256) {
        const int r = i / 80, cq = i - r * 80;
        int gc = wb + cq;
        if (gc > W - 1) gc = W - 1;
        s_in[i] = xrow[(size_t)r * W + gc];
      }
    }
    __syncthreads();
    float acc0[20] = {}, acc1[20] = {};
    float ra[32], rb[32];
#pragma unroll
    for (int j = 0; j < 8; ++j)
      *(float4*)(ra + 4 * j) = *(const float4*)(s_in + x0 + 4 * j);
#pragma unroll 1
    for (int yy = 0; yy < 6; ++yy) {
      CP_STEP(2 * yy, ra, rb)
      CP_STEP(2 * yy + 1, rb, ra)
    }
    CP_STEP(12, ra, rb)
    float* outp = pooled + (((size_t)b * 64 + c) * 58 + h) * T + wb + x0;
#pragma unroll
    for (int jj = 0; jj < 16; ++jj) {
      float m = acc0[jj];
#pragma unroll
      for (int k = 1; k < 5; ++k) m = fmaxf(m, acc0[jj + k]);
#pragma unroll
      for (int k = 0; k < 5; ++k) m = fmaxf(m, acc1[jj + k]);
      if (wb + x0 + jj < T) outp[jj] = m + bias;
    }
  }
}

// ---------------------------------------------------------------------------
// Split-K GEMM (pool @ lw^T), N=64, no bias; atomicAdd into zero-init out.
// grid (Mtiles, 8 K-slices). K=3712 = 116 chunks of 32; slice s does chunks
// [s*116/8, (s+1)*116/8). float4 staging; 4x4 per thread.
// ---------------------------------------------------------------------------
__global__ __launch_bounds__(256) void gemm_splitk_kernel(
    const float* __restrict__ A, const float* __restrict__ Wt,
    float* __restrict__ out) {
  __shared__ __align__(16) float sA[64 * 33];
  __shared__ __align__(16) float sB[64 * 33];
  const int tid = threadIdx.x;
  const int r0 = blockIdx.x * 64;
  const int s = blockIdx.y;
  const int c0 = (s * 116) / 8, c1 = ((s + 1) * 116) / 8;
  const int ty = tid >> 4, tx = tid & 15;
  float acc[4][4] = {};
  for (int ch = c0; ch < c1; ++ch) {
    const int kc = ch * 32;
    __syncthreads();
#pragma unroll
    for (int r = 0; r < 2; ++r) {
      const int q = tid + r * 256;          // 512 quads per array
      const int row = q >> 3, qq = q & 7;
      const float4 va = *(const float4*)&A[(size_t)(r0 + row) * 3712 + kc + qq * 4];
      const float4 vb = *(const float4*)&Wt[(size_t)row * 3712 + kc + qq * 4];
      sA[row * 33 + qq * 4 + 0] = va.x; sA[row * 33 + qq * 4 + 1] = va.y;
      sA[row * 33 + qq * 4 + 2] = va.z; sA[row * 33 + qq * 4 + 3] = va.w;
      sB[row * 33 + qq * 4 + 0] = vb.x; sB[row * 33 + qq * 4 + 1] = vb.y;
      sB[row * 33 + qq * 4 + 2] = vb.z; sB[row * 33 + qq * 4 + 3] = vb.w;
    }
    __syncthreads();
#pragma unroll 8
    for (int kk = 0; kk < 32; ++kk) {
      const float a0 = sA[(ty * 4 + 0) * 33 + kk];
      const float a1 = sA[(ty * 4 + 1) * 33 + kk];
      const float a2 = sA[(ty * 4 + 2) * 33 + kk];
      const float a3 = sA[(ty * 4 + 3) * 33 + kk];
      const float b0 = sB[(tx * 4 + 0) * 33 + kk];
      const float b1 = sB[(tx * 4 + 1) * 33 + kk];
      const float b2 = sB[(tx * 4 + 2) * 33 + kk];
      const float b3 = sB[(tx * 4 + 3) * 33 + kk];
      acc[0][0] = fmaf(a0, b0, acc[0][0]); acc[0][1] = fmaf(a0, b1, acc[0][1]);
      acc[0][2] = fmaf(a0, b2, acc[0][2]); acc[0][3] = fmaf(a0, b3, acc[0][3]);
      acc[1][0] = fmaf(a1, b0, acc[1][0]); acc[1][1] = fmaf(a1, b1, acc[1][1]);
      acc[1][2] = fmaf(a1, b2, acc[1][2]); acc[1][3] = fmaf(a1, b3, acc[1][3]);
      acc[2][0] = fmaf(a2, b0, acc[2][0]); acc[2][1] = fmaf(a2, b1, acc[2][1]);
      acc[2][2] = fmaf(a2, b2, acc[2][2]); acc[2][3] = fmaf(a2, b3, acc[2][3]);
      acc[3][0] = fmaf(a3, b0, acc[3][0]); acc[3][1] = fmaf(a3, b1, acc[3][1]);
      acc[3][2] = fmaf(a3, b2, acc[3][2]); acc[3][3] = fmaf(a3, b3, acc[3][3]);
    }
  }
#pragma unroll
  for (int i = 0; i < 4; ++i)
#pragma unroll
    for (int j = 0; j < 4; ++j)
      atomicAdd(&out[(size_t)(r0 + ty * 4 + i) * 64 + tx * 4 + j], acc[i][j]);
}

// ---------------------------------------------------------------------------
// Generic fp32 GEMM (used for gi = lin0 @ w_ih^T + bias2). K multiple of 32.
// ---------------------------------------------------------------------------
__global__ __launch_bounds__(256) void gemm_nt_kernel(
    const float* __restrict__ A, const float* __restrict__ Wt,
    const float* __restrict__ bias, float* __restrict__ out,
    const int N, const int K) {
  __shared__ float sA[64 * 33];
  __shared__ float sB[64 * 33];
  const int tid = threadIdx.x;
  const int r0 = blockIdx.x * 64;
  const int n0 = blockIdx.y * 64;
  const int ty = tid >> 4, tx = tid & 15;
  float acc[4][4] = {};
  for (int kc = 0; kc < K; kc += 32) {
    __syncthreads();
#pragma unroll
    for (int rep = 0; rep < 8; ++rep) {
      const int l = tid + rep * 256;
      const int row = l >> 5, kk = l & 31;
      sA[row * 33 + kk] = A[(size_t)(r0 + row) * K + kc + kk];
      sB[row * 33 + kk] = Wt[(size_t)(n0 + row) * K + kc + kk];
    }
    __syncthreads();
#pragma unroll 8
    for (int kk = 0; kk < 32; ++kk) {
      const float a0 = sA[(ty * 4 + 0) * 33 + kk];
      const float a1 = sA[(ty * 4 + 1) * 33 + kk];
      const float a2 = sA[(ty * 4 + 2) * 33 + kk];
      const float a3 = sA[(ty * 4 + 3) * 33 + kk];
      const float b0 = sB[(tx * 4 + 0) * 33 + kk];
      const float b1 = sB[(tx * 4 + 1) * 33 + kk];
      const float b2 = sB[(tx * 4 + 2) * 33 + kk];
      const float b3 = sB[(tx * 4 + 3) * 33 + kk];
      acc[0][0] = fmaf(a0, b0, acc[0][0]); acc[0][1] = fmaf(a0, b1, acc[0][1]);
      acc[0][2] = fmaf(a0, b2, acc[0][2]); acc[0][3] = fmaf(a0, b3, acc[0][3]);
      acc[1][0] = fmaf(a1, b0, acc[1][0]); acc[1][1] = fmaf(a1, b1, acc[1][1]);
      acc[1][2] = fmaf(a1, b2, acc[1][2]); acc[1][3] = fmaf(a1, b3, acc[1][3]);
      acc[2][0] = fmaf(a2, b0, acc[2][0]); acc[2][1] = fmaf(a2, b1, acc[2][1]);
      acc[2][2] = fmaf(a2, b2, acc[2][2]); acc[2][3] = fmaf(a2, b3, acc[2][3]);
      acc[3][0] = fmaf(a3, b0, acc[3][0]); acc[3][1] = fmaf(a3, b1, acc[3][1]);
      acc[3][2] = fmaf(a3, b2, acc[3][2]); acc[3][3] = fmaf(a3, b3, acc[3][3]);
    }
  }
#pragma unroll
  for (int i = 0; i < 4; ++i)
#pragma unroll
    for (int j = 0; j < 4; ++j)
      out[(size_t)(r0 + ty * 4 + i) * N + n0 + tx * 4 + j] =
          acc[i][j] + bias[n0 + tx * 4 + j];
}

// ---------------------------------------------------------------------------
// GRU recurrence (scan over BATCH axis, 4 steps; every t independent).
// ---------------------------------------------------------------------------
__global__ __launch_bounds__(256) void gru_rec_kernel(
    float* __restrict__ xy, const float* __restrict__ gi,
    const float* __restrict__ whh, const float* __restrict__ bhh, const int T) {
  __shared__ float s_whh_t[64 * 192];
  __shared__ float s_h[16][64];
  const int tid = threadIdx.x;
  const int lane = tid & 63, wave = tid >> 6;
  for (int i = tid; i < 192 * 64; i += 256) {
    const int j = i >> 6, d = i & 63;
    s_whh_t[d * 192 + j] = whh[i];
  }
  for (int i = tid; i < 16 * 64; i += 256) (&s_h[0][0])[i] = 0.f;
  const float bhr = bhh[lane], bhz = bhh[64 + lane], bhn = bhh[128 + lane];
  const int t0 = blockIdx.x * 16;
  __syncthreads();
  for (int b = 0; b < 4; ++b) {
    float gir[4], giz[4], gin[4];
#pragma unroll
    for (int sl = 0; sl < 4; ++sl) {
      int t = t0 + wave * 4 + sl; if (t > T - 1) t = T - 1;
      const float* girow = gi + ((size_t)b * T + t) * 192;
      gir[sl] = girow[lane]; giz[sl] = girow[64 + lane]; gin[sl] = girow[128 + lane];
    }
    float ahr[4] = {}, ahz[4] = {}, ahn[4] = {};
    for (int d = 0; d < 64; ++d) {
      const float wr_ = s_whh_t[d * 192 + lane];
      const float wz_ = s_whh_t[d * 192 + 64 + lane];
      const float wn_ = s_whh_t[d * 192 + 128 + lane];
#pragma unroll
      for (int sl = 0; sl < 4; ++sl) {
        const float hv = s_h[wave * 4 + sl][d];
        ahr[sl] = fmaf(wr_, hv, ahr[sl]);
        ahz[sl] = fmaf(wz_, hv, ahz[sl]);
        ahn[sl] = fmaf(wn_, hv, ahn[sl]);
      }
    }
    float hn[4];
#pragma unroll
    for (int sl = 0; sl < 4; ++sl) {
      const float r = 1.f / (1.f + __expf(-(gir[sl] + ahr[sl] + bhr)));
      const float z = 1.f / (1.f + __expf(-(giz[sl] + ahz[sl] + bhz)));
      const float n = tanhf(gin[sl] + r * (ahn[sl] + bhn));
      hn[sl] = (1.f - z) * n + z * s_h[wave * 4 + sl][lane];
    }
    __syncthreads();
#pragma unroll
    for (int sl = 0; sl < 4; ++sl) {
      const int t = t0 + wave * 4 + sl;
      s_h[wave * 4 + sl][lane] = hn[sl];
      if (t < T) xy[((size_t)b * T + t) * 64 + lane] = hn[sl];
    }
    __syncthreads();
  }
}

// ---------------------------------------------------------------------------
// scores: P[b,tau,eps] = sum_d t[b,tau,d]*e[b,eps,d].
// grid (16 tau-tiles, 16 eps-tiles, 4 b); K=64 one-shot; 64x128 per block,
// 4x8 per thread. 1024 blocks.
// ---------------------------------------------------------------------------
__global__ __launch_bounds__(256) void scores_kernel(
    const float* __restrict__ tmat, const float* __restrict__ emat,
    float* __restrict__ P) {
  __shared__ __align__(16) float sT[64 * 68];
  __shared__ __align__(16) float sE[128 * 68];
  const int tid = threadIdx.x;
  const int b = blockIdx.z;
  const int tau0 = blockIdx.x * 64;
  const int e0 = blockIdx.y * 128;
#pragma unroll
  for (int r = 0; r < 4; ++r) {  // 1024 quads of sT
    const int q = tid + r * 256;
    const int row = q >> 4, qq = q & 15;
    const float4 v = *(const float4*)&tmat[((size_t)b * 1024 + tau0 + row) * 64 + qq * 4];
    *(float4*)&sT[row * 68 + qq * 4] = v;
  }
#pragma unroll
  for (int r = 0; r < 8; ++r) {  // 2048 quads of sE
    const int q = tid + r * 256;
    const int row = q >> 4, qq = q & 15;
    int eps = e0 + row; if (eps > 2031) eps = 2031;
    const float4 v = *(const float4*)&emat[((size_t)b * 2032 + eps) * 64 + qq * 4];
    *(float4*)&sE[row * 68 + qq * 4] = v;
  }
  __syncthreads();
  const int ty = tid >> 4, tx = tid & 15;
  float acc[4][8] = {};
#pragma unroll 4
  for (int q = 0; q < 16; ++q) {
    const int kk = q * 4;
    float4 av[4], bv[8];
#pragma unroll
    for (int i = 0; i < 4; ++i) av[i] = *(const float4*)&sT[(ty * 4 + i) * 68 + kk];
#pragma unroll
    for (int j = 0; j < 8; ++j) bv[j] = *(const float4*)&sE[(tx * 8 + j) * 68 + kk];
#pragma unroll
    for (int i = 0; i < 4; ++i)
#pragma unroll
      for (int j = 0; j < 8; ++j) {
        acc[i][j] = fmaf(av[i].x, bv[j].x, acc[i][j]);
        acc[i][j] = fmaf(av[i].y, bv[j].y, acc[i][j]);
        acc[i][j] = fmaf(av[i].z, bv[j].z, acc[i][j]);
        acc[i][j] = fmaf(av[i].w, bv[j].w, acc[i][j]);
      }
  }
#pragma unroll
  for (int i = 0; i < 4; ++i) {
    const size_t prow = ((size_t)b * 1024 + tau0 + ty * 4 + i) * 2032;
#pragma unroll
    for (int j = 0; j < 8; ++j) {
      const int eps = e0 + tx * 8 + j;
      if (eps < 2032) P[prow + eps] = acc[i][j];
    }
  }
}

// ---------------------------------------------------------------------------
// row softmax over eps (rows of length 2032), row cached in LDS. grid 4096.
// ---------------------------------------------------------------------------
__global__ __launch_bounds__(256) void softmax_rows_kernel(float* __restrict__ P) {
  __shared__ float s_row[2032];
  __shared__ float sred[4];
  float* r = P + (size_t)blockIdx.x * 2032;
  const int tid = threadIdx.x;
  const int lane = tid & 63, wave = tid >> 6;
  float m = -3.4e38f;
  for (int i = tid; i < 2032; i += 256) {
    const float v = r[i];
    s_row[i] = v;
    m = fmaxf(m, v);
  }
#pragma unroll
  for (int off = 32; off > 0; off >>= 1) m = fmaxf(m, __shfl_down(m, off, 64));
  if (lane == 0) sred[wave] = m;
  __syncthreads();
  m = fmaxf(fmaxf(sred[0], sred[1]), fmaxf(sred[2], sred[3]));
  __syncthreads();
  float s = 0.f;
  float vals[8];
  int cnt = 0;
  for (int i = tid; i < 2032; i += 256) {
    const float v = __expf(s_row[i] - m);
    vals[cnt++] = v;
    s += v;
  }
#pragma unroll
  for (int off = 32; off > 0; off >>= 1) s += __shfl_down(s, off, 64);
  if (lane == 0) sred[wave] = s;
  __syncthreads();
  const float inv = 1.f / (sred[0] + sred[1] + sred[2] + sred[3]);
  cnt = 0;
  for (int i = tid; i < 2032; i += 256) r[i] = vals[cnt++] * inv;
}

// ---------------------------------------------------------------------------
// pv partial: PV[b,eps,d] += sum_{tau in slice} P[b,tau,eps]*t[b,tau,d]
// grid (32 eps-tiles, 4 tau-slices, 4 b); atomicAdd into zero-init PV.
// ---------------------------------------------------------------------------
__global__ __launch_bounds__(256) void pv_kernel(
    const float* __restrict__ P, const float* __restrict__ tmat,
    float* __restrict__ PV) {
  __shared__ float sP[32 * 65];
  __shared__ float sT[32 * 65];
  const int tid = threadIdx.x;
  const int b = blockIdx.z;
  const int e0 = blockIdx.x * 64;
  const int tau_base = blockIdx.y * 256;
  const int ty = tid >> 4, tx = tid & 15;
  float acc[4][4] = {};
  for (int kc = tau_base; kc < tau_base + 256; kc += 32) {
    __syncthreads();
    for (int l = tid; l < 32 * 64; l += 256) {
      const int kk = l >> 6, j = l & 63;
      int eps = e0 + j; if (eps > 2031) eps = 2031;
      sP[kk * 65 + j] = P[((size_t)b * 1024 + kc + kk) * 2032 + eps];
      sT[kk * 65 + j] = tmat[((size_t)b * 1024 + kc + kk) * 64 + j];
    }
    __syncthreads();
#pragma unroll 8
    for (int kk = 0; kk < 32; ++kk) {
      const float a0 = sP[kk * 65 + ty * 4 + 0];
      const float a1 = sP[kk * 65 + ty * 4 + 1];
      const float a2 = sP[kk * 65 + ty * 4 + 2];
      const float a3 = sP[kk * 65 + ty * 4 + 3];
      const float b0 = sT[kk * 65 + tx * 4 + 0];
      const float b1 = sT[kk * 65 + tx * 4 + 1];
      const float b2 = sT[kk * 65 + tx * 4 + 2];
      const float b3 = sT[kk * 65 + tx * 4 + 3];
      acc[0][0] = fmaf(a0, b0, acc[0][0]); acc[0][1] = fmaf(a0, b1, acc[0][1]);
      acc[0][2] = fmaf(a0, b2, acc[0][2]); acc[0][3] = fmaf(a0, b3, acc[0][3]);
      acc[1][0] = fmaf(a1, b0, acc[1][0]); acc[1][1] = fmaf(a1, b1, acc[1][1]);
      acc[1][2] = fmaf(a1, b2, acc[1][2]); acc[1][3] = fmaf(a1, b3, acc[1][3]);
      acc[2][0] = fmaf(a2, b0, acc[2][0]); acc[2][1] = fmaf(a2, b1, acc[2][1]);
      acc[2][2] = fmaf(a2, b2, acc[2][2]); acc[2][3] = fmaf(a2, b3, acc[2][3]);
      acc[3][0] = fmaf(a3, b0, acc[3][0]); acc[3][1] = fmaf(a3, b1, acc[3][1]);
      acc[3][2] = fmaf(a3, b2, acc[3][2]); acc[3][3] = fmaf(a3, b3, acc[3][3]);
    }
  }
#pragma unroll
  for (int i = 0; i < 4; ++i) {
    const int eps = e0 + ty * 4 + i;
    if (eps < 2032) {
#pragma unroll
      for (int j = 0; j < 4; ++j)
        atomicAdd(&PV[((size_t)b * 2032 + eps) * 64 + tx * 4 + j], acc[i][j]);
    }
  }
}

// ---------------------------------------------------------------------------
// head: att softmax + weighted reduce of |PV - e| + 2-layer MLP + softmax.
// ---------------------------------------------------------------------------
__global__ __launch_bounds__(256) void head_kernel(
    const float* __restrict__ emat, const float* __restrict__ PV,
    const float* __restrict__ a_w, const float* __restrict__ a_b,
    const float* __restrict__ h_w, const float* __restrict__ h_b,
    const float* __restrict__ c_w, const float* __restrict__ c_b,
    float* __restrict__ out) {
  __shared__ float s_att[2032];
  __shared__ float s_aw[64];
  __shared__ float sred[4];
  __shared__ float s_part[4][64];
  __shared__ float s_redv[64];
  __shared__ float s_hv[128];
  const int tid = threadIdx.x;
  const int lane = tid & 63, wave = tid >> 6;
  const int b = blockIdx.x;
  if (tid < 64) s_aw[tid] = a_w[tid];
  __syncthreads();
  const float ab = a_b[0];
  float m = -3.4e38f;
  for (int i = tid; i < 2032; i += 256) {
    const float* er = emat + ((size_t)b * 2032 + i) * 64;
    float acc = ab;
    for (int d = 0; d < 64; ++d) acc = fmaf(er[d], s_aw[d], acc);
    s_att[i] = acc;
    m = fmaxf(m, acc);
  }
#pragma unroll
  for (int off = 32; off > 0; off >>= 1) m = fmaxf(m, __shfl_down(m, off, 64));
  if (lane == 0) sred[wave] = m;
  __syncthreads();
  m = fmaxf(fmaxf(sred[0], sred[1]), fmaxf(sred[2], sred[3]));
  __syncthreads();
  float ssum = 0.f;
  for (int i = tid; i < 2032; i += 256) {
    const float v = __expf(s_att[i] - m);
    s_att[i] = v;
    ssum += v;
  }
#pragma unroll
  for (int off = 32; off > 0; off >>= 1) ssum += __shfl_down(ssum, off, 64);
  if (lane == 0) sred[wave] = ssum;
  __syncthreads();
  const float inv = 1.f / (sred[0] + sred[1] + sred[2] + sred[3]);
  float accp = 0.f;
  for (int i = wave; i < 2032; i += 4) {
    const size_t idx = ((size_t)b * 2032 + i) * 64 + lane;
    accp = fmaf(fabsf(PV[idx] - emat[idx]), s_att[i], accp);
  }
  s_part[wave][lane] = accp;
  __syncthreads();
  if (tid < 64)
    s_redv[tid] = (s_part[0][tid] + s_part[1][tid] + s_part[2][tid] + s_part[3][tid]) * inv;
  __syncthreads();
  if (tid < 128) {
    float acc = h_b[tid];
    const float* hw = h_w + tid * 64;
    for (int d = 0; d < 64; ++d) acc = fmaf(s_redv[d], hw[d], acc);
    s_hv[tid] = fmaxf(acc, 0.f);
  }
  __syncthreads();
  if (tid == 0) {
    float l0 = c_b[0], l1 = c_b[1];
    for (int j = 0; j < 128; ++j) {
      l0 = fmaf(s_hv[j], c_w[j], l0);
      l1 = fmaf(s_hv[j], c_w[128 + j], l1);
    }
    const float mm = fmaxf(l0, l1);
    const float e0 = __expf(l0 - mm), e1 = __expf(l1 - mm);
    const float invs = 1.f / (e0 + e1);
    out[b * 2 + 0] = e0 * invs;
    out[b * 2 + 1] = e1 * invs;
  }
}

// ===========================================================================
extern "C" void kernel_launch(void* const* d_in, const int* in_sizes, int n_in,
                              void* d_out, int out_size, void* d_ws, size_t ws_size,
                              hipStream_t stream) {
  const float* evaluation = (const float*)d_in[0];
  const float* templ      = (const float*)d_in[1];
  const float* e_w1 = (const float*)d_in[2];
  const float* e_b1 = (const float*)d_in[3];
  const float* e_w2 = (const float*)d_in[4];
  const float* e_b2 = (const float*)d_in[5];
  const float* e_w3 = (const float*)d_in[6];
  const float* e_b3 = (const float*)d_in[7];
  const float* el_w = (const float*)d_in[8];
  const float* el_b = (const float*)d_in[9];
  const float* eg_wih = (const float*)d_in[10];
  const float* eg_whh = (const float*)d_in[11];
  const float* eg_bih = (const float*)d_in[12];
  const float* eg_bhh = (const float*)d_in[13];
  const float* t_w1 = (const float*)d_in[14];
  const float* t_b1 = (const float*)d_in[15];
  const float* t_w2 = (const float*)d_in[16];
  const float* t_b2 = (const float*)d_in[17];
  const float* t_w3 = (const float*)d_in[18];
  const float* t_b3 = (const float*)d_in[19];
  const float* tl_w = (const float*)d_in[20];
  const float* tl_b = (const float*)d_in[21];
  const float* tg_wih = (const float*)d_in[22];
  const float* tg_whh = (const float*)d_in[23];
  const float* tg_bih = (const float*)d_in[24];
  const float* tg_bhh = (const float*)d_in[25];
  const float* a_w = (const float*)d_in[26];
  const float* a_b = (const float*)d_in[27];
  const float* h_w = (const float*)d_in[28];
  const float* h_b = (const float*)d_in[29];
  const float* c_w = (const float*)d_in[30];
  const float* c_b = (const float*)d_in[31];

  float* ws = (float*)d_ws;
  float* weff_e  = ws + OFF_WEFF_E;
  float* weff_t  = ws + OFF_WEFF_T;
  float* beff_e  = ws + OFF_BEFF_E;
  float* beff_t  = ws + OFF_BEFF_T;
  float* bias2_e = ws + OFF_BIAS2_E;
  float* bias2_t = ws + OFF_BIAS2_T;
  float* pool    = ws + OFF_POOL;
  float* gibuf   = ws + OFF_GI;
  float* Pbuf    = ws + OFF_P;
  float* PVbuf   = ws + OFF_PV;
  float* lin_e   = ws + OFF_LIN_E;
  float* lin_t   = ws + OFF_LIN_T;

  // weight composition + folded gi biases (independent small kernels)
  compose_fused_kernel<<<64, 256, 0, stream>>>(e_w1, e_b1, e_w2, e_b2, e_w3, e_b3, weff_e, beff_e);
  compose_fused_kernel<<<64, 256, 0, stream>>>(t_w1, t_b1, t_w2, t_b2, t_w3, t_b3, weff_t, beff_t);
  gi_bias_kernel<<<1, 256, 0, stream>>>(eg_wih, eg_bih, el_b, bias2_e);
  gi_bias_kernel<<<1, 256, 0, stream>>>(tg_wih, tg_bih, tl_b, bias2_t);

  // zero lin_e + lin_t (contiguous) for split-K atomics
  hipMemsetAsync(lin_e, 0, (520192 + 262144) * sizeof(float), stream);

  // eval branch: conv+pool -> split-K linear (no bias; folded into gi)
  conv_pool_kernel<<<dim3(32, 29, 4), 256, 0, stream>>>(evaluation, weff_e, beff_e, pool, 2048, 2032);
  gemm_splitk_kernel<<<dim3(127, 8), 256, 0, stream>>>(pool, el_w, lin_e);
  // template branch
  conv_pool_kernel<<<dim3(16, 29, 4), 256, 0, stream>>>(templ, weff_t, beff_t, pool, 1040, 1024);
  gemm_splitk_kernel<<<dim3(64, 8), 256, 0, stream>>>(pool, tl_w, lin_t);

  // zero PV (lives in dead pool region; must follow last pool read)
  hipMemsetAsync(PVbuf, 0, 520192 * sizeof(float), stream);

  // GRU (scan over batch axis)
  gemm_nt_kernel<<<dim3(127, 3), 256, 0, stream>>>(lin_e, eg_wih, bias2_e, gibuf, 192, 64);
  gru_rec_kernel<<<127, 256, 0, stream>>>(lin_e, gibuf, eg_whh, eg_bhh, 2032);
  gemm_nt_kernel<<<dim3(64, 3), 256, 0, stream>>>(lin_t, tg_wih, bias2_t, gibuf, 192, 64);
  gru_rec_kernel<<<64, 256, 0, stream>>>(lin_t, gibuf, tg_whh, tg_bhh, 1024);

  // cross attention + head
  scores_kernel<<<dim3(16, 16, 4), 256, 0, stream>>>(lin_t, lin_e, Pbuf);
  softmax_rows_kernel<<<4096, 256, 0, stream>>>(Pbuf);
  pv_kernel<<<dim3(32, 4, 4), 256, 0, stream>>>(Pbuf, lin_t, PVbuf);
  head_kernel<<<4, 256, 0, stream>>>(lin_e, PVbuf, a_w, a_b, h_w, h_b, c_w, c_b,
                                     (float*)d_out);
}

// Round 4
// 1294.828 us; speedup vs baseline: 2.3984x; 1.2391x over previous
//
#include <hip/hip_runtime.h>
#include <cmath>

// ============================================================================
// DeepTemplateMatchingModule on MI355X — round 4.
// R3 post-mortem: conv_pool (fp32 VALU, 73% busy) = 344+172us is the top
// dispatch and near its fp32 structural floor (~263us). R4: conv13x13+pool
// rewritten as implicit-GEMM on bf16 MFMA (mfma_f32_32x32x16_bf16):
//   - compose kernel emits weights as bf16, padded 13x16 taps (pad=0),
//     232 u16/channel stride (odd*16B -> conflict-free A reads)
//   - conv kernel: x tile -> bf16 LDS -> im2col[14][64][24] (48B col stride,
//     all 8 bank groups, b128-aligned; kx pads hold harmless garbage since
//     the matching A slots are 0) -> 13 K-steps x 2 MFMA per wave
//   - pool 2x5 fused via LDS epilogue (D frags -> s_out -> sliding max)
// Also FIXED a latent overlap: OFF_LIN_E was POOL+30,158,848 but pooled is
// 30,171,136 floats — split-K readers raced lin_e writers on 12,288 floats.
// ============================================================================

typedef unsigned short u16;
typedef __attribute__((ext_vector_type(8))) short bf16x8;
typedef __attribute__((ext_vector_type(8))) unsigned short u16x8;
typedef __attribute__((ext_vector_type(16))) float f32x16;

__device__ __forceinline__ u16 f2bf(float f) {
  unsigned int x = __float_as_uint(f);
  return (u16)((x + 0x7fffu + ((x >> 16) & 1u)) >> 16);
}

// ---- workspace layout (float offsets) ----
static const size_t OFF_BEFF_E  = 0;                         // 64
static const size_t OFF_BEFF_T  = 64;                        // 64
static const size_t OFF_BIAS2_E = 128;                       // 192
static const size_t OFF_BIAS2_T = 320;                       // 192
static const size_t OFF_WBF_E   = 512;                       // 7424 (14848 u16)
static const size_t OFF_WBF_T   = 7936;                      // 7424
static const size_t OFF_POOL    = 15360;                     // 30,171,136 (eval)
static const size_t OFF_GI      = OFF_POOL;                  // 1,560,576
static const size_t OFF_P       = OFF_POOL + 1560576;        // 8,323,072
static const size_t OFF_PV      = OFF_P + 8323072;           // 520,192
static const size_t OFF_LIN_E   = OFF_POOL + 30171136;       // 520,192 (no overlap!)
static const size_t OFF_LIN_T   = OFF_LIN_E + 520192;        // 262,144

// ---------------------------------------------------------------------------
// Fused weight composition -> bf16 padded layout weffp[64][13][16] with
// per-channel stride 232 u16 (13*16 + 8 pad). kx slots 13..15 are ZERO
// (they multiply garbage im2col values). beff stays fp32.
// ---------------------------------------------------------------------------
__global__ __launch_bounds__(256) void compose_fused_kernel(
    const float* __restrict__ w1, const float* __restrict__ b1,
    const float* __restrict__ w2, const float* __restrict__ b2,
    const float* __restrict__ w3, const float* __restrict__ b3,
    u16* __restrict__ weffp, float* __restrict__ beff) {
  __shared__ float s_w1[400];
  __shared__ float s_w2[12800];
  __shared__ float s_w3o[800];
  __shared__ float s_w12[2592];
  __shared__ float s_b1[16], s_b2[32], s_b12[32];
  const int tid = threadIdx.x;
  const int o = blockIdx.x;
  for (int i = tid; i < 400; i += 256) s_w1[i] = w1[i];
  for (int i = tid; i < 12800; i += 256) s_w2[i] = w2[i];
  for (int i = tid; i < 800; i += 256) s_w3o[i] = w3[o * 800 + i];
  if (tid < 16) s_b1[tid] = b1[tid];
  if (tid < 32) s_b2[tid] = b2[tid];
  __syncthreads();
  for (int idx = tid; idx < 2592; idx += 256) {
    const int c12 = idx / 81, s = idx % 81, sy = s / 9, sx = s % 9;
    const int uy0 = sy > 4 ? sy - 4 : 0, uy1 = sy < 4 ? sy : 4;
    const int ux0 = sx > 4 ? sx - 4 : 0, ux1 = sx < 4 ? sx : 4;
    float acc = 0.f;
    for (int c1 = 0; c1 < 16; ++c1) {
      const float* w2p = s_w2 + (c12 * 16 + c1) * 25;
      const float* w1p = s_w1 + c1 * 25;
      for (int uy = uy0; uy <= uy1; ++uy)
        for (int ux = ux0; ux <= ux1; ++ux)
          acc = fmaf(w2p[uy * 5 + ux], w1p[(sy - uy) * 5 + (sx - ux)], acc);
    }
    s_w12[idx] = acc;
  }
  if (tid < 32) {
    float acc = s_b2[tid];
    for (int c1 = 0; c1 < 16; ++c1) {
      float sw = 0.f;
      const float* w2p = s_w2 + (tid * 16 + c1) * 25;
      for (int u = 0; u < 25; ++u) sw += w2p[u];
      acc = fmaf(sw, s_b1[c1], acc);
    }
    s_b12[tid] = acc;
  }
  __syncthreads();
  if (tid < 169) {
    const int sy = tid / 13, sx = tid % 13;
    const int uy0 = sy > 8 ? sy - 8 : 0, uy1 = sy < 4 ? sy : 4;
    const int ux0 = sx > 8 ? sx - 8 : 0, ux1 = sx < 4 ? sx : 4;
    float acc = 0.f;
    for (int c = 0; c < 32; ++c) {
      const float* w3p = s_w3o + c * 25;
      const float* wp = s_w12 + c * 81;
      for (int uy = uy0; uy <= uy1; ++uy)
        for (int ux = ux0; ux <= ux1; ++ux)
          acc = fmaf(w3p[uy * 5 + ux], wp[(sy - uy) * 9 + (sx - ux)], acc);
    }
    weffp[o * 232 + sy * 16 + sx] = f2bf(acc);
  } else if (tid < 208) {
    const int p = tid - 169;  // zero the kx=13..15 pad slots (39 of them)
    weffp[o * 232 + (p / 3) * 16 + 13 + (p % 3)] = 0;
  }
  if (tid == 255) {
    float acc = b3[o];
    for (int c = 0; c < 32; ++c) {
      float sw = 0.f;
      const float* w3p = s_w3o + c * 25;
      for (int u = 0; u < 25; ++u) sw += w3p[u];
      acc = fmaf(sw, s_b12[c], acc);
    }
    beff[o] = acc;
  }
}

// ---------------------------------------------------------------------------
// bias2[j] = b_ih[j] + sum_d w_ih[j,d] * lb[d]   (lin-bias folded into gi)
// ---------------------------------------------------------------------------
__global__ __launch_bounds__(256) void gi_bias_kernel(
    const float* __restrict__ wih, const float* __restrict__ bih,
    const float* __restrict__ lb, float* __restrict__ bias2) {
  __shared__ float s_lb[64];
  const int tid = threadIdx.x;
  if (tid < 64) s_lb[tid] = lb[tid];
  __syncthreads();
  if (tid < 192) {
    float acc = bih[tid];
    const float* wr = wih + tid * 64;
    for (int d = 0; d < 64; ++d) acc = fmaf(wr[d], s_lb[d], acc);
    bias2[tid] = acc;
  }
}

// ---------------------------------------------------------------------------
// MFMA conv13x13 + maxpool(2,5)/(2,1).
// Block: (b, pooled row h, 60 pooled cols at cb). Conv tile: 2 rows x 64
// cols x 64 ch. Wave w: conv row 2h+(w&1), channels (w>>1)*32..+31, both
// 32-col n-tiles. K = 13 steps of 16 (one ky row each, kx padded to 16).
//   A[m=c][k]: lane m=lane&31, k=(lane>>5)*8+j  (8 consecutive kx -> b128)
//   B[k][n=col]: lane n=lane&31, same k-grouping (im2col b128)
//   D: col=lane&31, row=(reg&3)+8*(reg>>2)+4*(lane>>5)   [m74/m101 layout]
// grid: (ceil(T/60), 58, 4)
// ---------------------------------------------------------------------------
__global__ __launch_bounds__(256, 2) void conv_pool_mfma_kernel(
    const float* __restrict__ x, const u16* __restrict__ weffp,
    const float* __restrict__ beff, float* __restrict__ pooled,
    const int W, const int T) {
  __shared__ __align__(16) char s_union[45248];  // s_x+im2col | s_out
  __shared__ __align__(16) char s_wreg[29696];   // weights | s_pool
  u16* s_x = (u16*)s_union;              // [14][80] bf16
  u16* s_im = (u16*)(s_union + 2240);    // [14][64][24] bf16 (48B col stride)
  float* s_out = (float*)s_union;        // [2][64][65] f32 (after K-loop)
  u16* s_w = (u16*)s_wreg;               // [64][232] bf16
  float* s_pool = (float*)s_wreg;        // [64][61] f32 (after K-loop)

  const int tid = threadIdx.x;
  const int lane = tid & 63, wave = tid >> 6;
  const int cb = blockIdx.x * 60;
  const int h = blockIdx.y, b = blockIdx.z;

  for (int i = tid; i < 1856; i += 256)  // 29696B = 1856 x 16B
    ((uint4*)s_w)[i] = ((const uint4*)weffp)[i];
  {
    const float* xb = x + ((size_t)b * 128 + 2 * h) * W;
    for (int i = tid; i < 14 * 80; i += 256) {
      const int r = i / 80, cq = i - r * 80;
      int gc = cb + cq;
      if (gc > W - 1) gc = W - 1;  // clamped cols never feed stored outputs
      s_x[i] = f2bf(xb[(size_t)r * W + gc]);
    }
  }
  __syncthreads();
  // im2col: s_im[ky][col][0..15] = s_x[ky][col..col+15]; slots 13..15 carry
  // garbage x values which the zero A-pads annihilate.
  for (int p = tid; p < 896; p += 256) {
    const int ky = p >> 6, col = p & 63;
    const u16* src = s_x + ky * 80 + col;
    u16x8 v0, v1;
#pragma unroll
    for (int j = 0; j < 8; ++j) { v0[j] = src[j]; v1[j] = src[8 + j]; }
    u16* dst = s_im + (ky * 64 + col) * 24;
    *(u16x8*)dst = v0;
    *(u16x8*)(dst + 8) = v1;
  }
  __syncthreads();
  const int rsel = wave & 1, cm = (wave >> 1) * 32;
  const int l31 = lane & 31, g8 = (lane >> 5) * 8;
  f32x16 acc0 = {}, acc1 = {};
  const u16* aw = s_w + (cm + l31) * 232 + g8;
  const u16* bw = s_im + (rsel * 64 + l31) * 24 + g8;
#pragma unroll
  for (int ky = 0; ky < 13; ++ky) {
    bf16x8 a = *(const bf16x8*)(aw + ky * 16);
    bf16x8 b0 = *(const bf16x8*)(bw + ky * 64 * 24);
    bf16x8 b1 = *(const bf16x8*)(bw + ky * 64 * 24 + 32 * 24);
    acc0 = __builtin_amdgcn_mfma_f32_32x32x16_bf16(a, b0, acc0, 0, 0, 0);
    acc1 = __builtin_amdgcn_mfma_f32_32x32x16_bf16(a, b1, acc1, 0, 0, 0);
  }
  __syncthreads();  // weights + im2col dead; reuse LDS for epilogue
#pragma unroll
  for (int r = 0; r < 16; ++r) {
    const int c = cm + (r & 3) + 8 * (r >> 2) + (g8 >> 1);  // +4*(lane>>5)
    float* o = s_out + (rsel * 64 + c) * 65;
    o[l31] = acc0[r];
    o[32 + l31] = acc1[r];
  }
  __syncthreads();
  {
    const int pc = tid & 63, tg = tid >> 6;
    const int t0 = tg * 15;  // 4 x 15 = 60 pooled cols
    const float bias = beff[pc];
    const float* r0p = s_out + pc * 65 + t0;
    const float* r1p = s_out + (64 + pc) * 65 + t0;
    float w0[19], w1[19];
#pragma unroll
    for (int j = 0; j < 19; ++j) { w0[j] = r0p[j]; w1[j] = r1p[j]; }
#pragma unroll
    for (int i = 0; i < 15; ++i) {
      float m = w0[i];
#pragma unroll
      for (int k = 1; k < 5; ++k) m = fmaxf(m, w0[i + k]);
#pragma unroll
      for (int k = 0; k < 5; ++k) m = fmaxf(m, w1[i + k]);
      s_pool[pc * 61 + t0 + i] = m + bias;
    }
  }
  __syncthreads();
  for (int i = tid; i < 3840; i += 256) {
    const int c = i / 60, t = i - c * 60;
    const int gt = cb + t;
    if (gt < T)
      pooled[(((size_t)b * 64 + c) * 58 + h) * T + gt] = s_pool[c * 61 + t];
  }
}

// ---------------------------------------------------------------------------
// Split-K GEMM (pool @ lw^T), N=64, no bias; atomicAdd into zero-init out.
// ---------------------------------------------------------------------------
__global__ __launch_bounds__(256) void gemm_splitk_kernel(
    const float* __restrict__ A, const float* __restrict__ Wt,
    float* __restrict__ out) {
  __shared__ __align__(16) float sA[64 * 33];
  __shared__ __align__(16) float sB[64 * 33];
  const int tid = threadIdx.x;
  const int r0 = blockIdx.x * 64;
  const int s = blockIdx.y;
  const int c0 = (s * 116) / 8, c1 = ((s + 1) * 116) / 8;
  const int ty = tid >> 4, tx = tid & 15;
  float acc[4][4] = {};
  for (int ch = c0; ch < c1; ++ch) {
    const int kc = ch * 32;
    __syncthreads();
#pragma unroll
    for (int r = 0; r < 2; ++r) {
      const int q = tid + r * 256;
      const int row = q >> 3, qq = q & 7;
      const float4 va = *(const float4*)&A[(size_t)(r0 + row) * 3712 + kc + qq * 4];
      const float4 vb = *(const float4*)&Wt[(size_t)row * 3712 + kc + qq * 4];
      sA[row * 33 + qq * 4 + 0] = va.x; sA[row * 33 + qq * 4 + 1] = va.y;
      sA[row * 33 + qq * 4 + 2] = va.z; sA[row * 33 + qq * 4 + 3] = va.w;
      sB[row * 33 + qq * 4 + 0] = vb.x; sB[row * 33 + qq * 4 + 1] = vb.y;
      sB[row * 33 + qq * 4 + 2] = vb.z; sB[row * 33 + qq * 4 + 3] = vb.w;
    }
    __syncthreads();
#pragma unroll 8
    for (int kk = 0; kk < 32; ++kk) {
      const float a0 = sA[(ty * 4 + 0) * 33 + kk];
      const float a1 = sA[(ty * 4 + 1) * 33 + kk];
      const float a2 = sA[(ty * 4 + 2) * 33 + kk];
      const float a3 = sA[(ty * 4 + 3) * 33 + kk];
      const float b0 = sB[(tx * 4 + 0) * 33 + kk];
      const float b1 = sB[(tx * 4 + 1) * 33 + kk];
      const float b2 = sB[(tx * 4 + 2) * 33 + kk];
      const float b3 = sB[(tx * 4 + 3) * 33 + kk];
      acc[0][0] = fmaf(a0, b0, acc[0][0]); acc[0][1] = fmaf(a0, b1, acc[0][1]);
      acc[0][2] = fmaf(a0, b2, acc[0][2]); acc[0][3] = fmaf(a0, b3, acc[0][3]);
      acc[1][0] = fmaf(a1, b0, acc[1][0]); acc[1][1] = fmaf(a1, b1, acc[1][1]);
      acc[1][2] = fmaf(a1, b2, acc[1][2]); acc[1][3] = fmaf(a1, b3, acc[1][3]);
      acc[2][0] = fmaf(a2, b0, acc[2][0]); acc[2][1] = fmaf(a2, b1, acc[2][1]);
      acc[2][2] = fmaf(a2, b2, acc[2][2]); acc[2][3] = fmaf(a2, b3, acc[2][3]);
      acc[3][0] = fmaf(a3, b0, acc[3][0]); acc[3][1] = fmaf(a3, b1, acc[3][1]);
      acc[3][2] = fmaf(a3, b2, acc[3][2]); acc[3][3] = fmaf(a3, b3, acc[3][3]);
    }
  }
#pragma unroll
  for (int i = 0; i < 4; ++i)
#pragma unroll
    for (int j = 0; j < 4; ++j)
      atomicAdd(&out[(size_t)(r0 + ty * 4 + i) * 64 + tx * 4 + j], acc[i][j]);
}

// ---------------------------------------------------------------------------
// Generic fp32 GEMM (gi = lin @ w_ih^T + bias2). K multiple of 32.
// ---------------------------------------------------------------------------
__global__ __launch_bounds__(256) void gemm_nt_kernel(
    const float* __restrict__ A, const float* __restrict__ Wt,
    const float* __restrict__ bias, float* __restrict__ out,
    const int N, const int K) {
  __shared__ float sA[64 * 33];
  __shared__ float sB[64 * 33];
  const int tid = threadIdx.x;
  const int r0 = blockIdx.x * 64;
  const int n0 = blockIdx.y * 64;
  const int ty = tid >> 4, tx = tid & 15;
  float acc[4][4] = {};
  for (int kc = 0; kc < K; kc += 32) {
    __syncthreads();
#pragma unroll
    for (int rep = 0; rep < 8; ++rep) {
      const int l = tid + rep * 256;
      const int row = l >> 5, kk = l & 31;
      sA[row * 33 + kk] = A[(size_t)(r0 + row) * K + kc + kk];
      sB[row * 33 + kk] = Wt[(size_t)(n0 + row) * K + kc + kk];
    }
    __syncthreads();
#pragma unroll 8
    for (int kk = 0; kk < 32; ++kk) {
      const float a0 = sA[(ty * 4 + 0) * 33 + kk];
      const float a1 = sA[(ty * 4 + 1) * 33 + kk];
      const float a2 = sA[(ty * 4 + 2) * 33 + kk];
      const float a3 = sA[(ty * 4 + 3) * 33 + kk];
      const float b0 = sB[(tx * 4 + 0) * 33 + kk];
      const float b1 = sB[(tx * 4 + 1) * 33 + kk];
      const float b2 = sB[(tx * 4 + 2) * 33 + kk];
      const float b3 = sB[(tx * 4 + 3) * 33 + kk];
      acc[0][0] = fmaf(a0, b0, acc[0][0]); acc[0][1] = fmaf(a0, b1, acc[0][1]);
      acc[0][2] = fmaf(a0, b2, acc[0][2]); acc[0][3] = fmaf(a0, b3, acc[0][3]);
      acc[1][0] = fmaf(a1, b0, acc[1][0]); acc[1][1] = fmaf(a1, b1, acc[1][1]);
      acc[1][2] = fmaf(a1, b2, acc[1][2]); acc[1][3] = fmaf(a1, b3, acc[1][3]);
      acc[2][0] = fmaf(a2, b0, acc[2][0]); acc[2][1] = fmaf(a2, b1, acc[2][1]);
      acc[2][2] = fmaf(a2, b2, acc[2][2]); acc[2][3] = fmaf(a2, b3, acc[2][3]);
      acc[3][0] = fmaf(a3, b0, acc[3][0]); acc[3][1] = fmaf(a3, b1, acc[3][1]);
      acc[3][2] = fmaf(a3, b2, acc[3][2]); acc[3][3] = fmaf(a3, b3, acc[3][3]);
    }
  }
#pragma unroll
  for (int i = 0; i < 4; ++i)
#pragma unroll
    for (int j = 0; j < 4; ++j)
      out[(size_t)(r0 + ty * 4 + i) * N + n0 + tx * 4 + j] =
          acc[i][j] + bias[n0 + tx * 4 + j];
}

// ---------------------------------------------------------------------------
// GRU recurrence (scan over BATCH axis, 4 steps; every t independent).
// ---------------------------------------------------------------------------
__global__ __launch_bounds__(256) void gru_rec_kernel(
    float* __restrict__ xy, const float* __restrict__ gi,
    const float* __restrict__ whh, const float* __restrict__ bhh, const int T) {
  __shared__ float s_whh_t[64 * 192];
  __shared__ float s_h[16][64];
  const int tid = threadIdx.x;
  const int lane = tid & 63, wave = tid >> 6;
  for (int i = tid; i < 192 * 64; i += 256) {
    const int j = i >> 6, d = i & 63;
    s_whh_t[d * 192 + j] = whh[i];
  }
  for (int i = tid; i < 16 * 64; i += 256) (&s_h[0][0])[i] = 0.f;
  const float bhr = bhh[lane], bhz = bhh[64 + lane], bhn = bhh[128 + lane];
  const int t0 = blockIdx.x * 16;
  __syncthreads();
  for (int b = 0; b < 4; ++b) {
    float gir[4], giz[4], gin[4];
#pragma unroll
    for (int sl = 0; sl < 4; ++sl) {
      int t = t0 + wave * 4 + sl; if (t > T - 1) t = T - 1;
      const float* girow = gi + ((size_t)b * T + t) * 192;
      gir[sl] = girow[lane]; giz[sl] = girow[64 + lane]; gin[sl] = girow[128 + lane];
    }
    float ahr[4] = {}, ahz[4] = {}, ahn[4] = {};
    for (int d = 0; d < 64; ++d) {
      const float wr_ = s_whh_t[d * 192 + lane];
      const float wz_ = s_whh_t[d * 192 + 64 + lane];
      const float wn_ = s_whh_t[d * 192 + 128 + lane];
#pragma unroll
      for (int sl = 0; sl < 4; ++sl) {
        const float hv = s_h[wave * 4 + sl][d];
        ahr[sl] = fmaf(wr_, hv, ahr[sl]);
        ahz[sl] = fmaf(wz_, hv, ahz[sl]);
        ahn[sl] = fmaf(wn_, hv, ahn[sl]);
      }
    }
    float hn[4];
#pragma unroll
    for (int sl = 0; sl < 4; ++sl) {
      const float r = 1.f / (1.f + __expf(-(gir[sl] + ahr[sl] + bhr)));
      const float z = 1.f / (1.f + __expf(-(giz[sl] + ahz[sl] + bhz)));
      const float n = tanhf(gin[sl] + r * (ahn[sl] + bhn));
      hn[sl] = (1.f - z) * n + z * s_h[wave * 4 + sl][lane];
    }
    __syncthreads();
#pragma unroll
    for (int sl = 0; sl < 4; ++sl) {
      const int t = t0 + wave * 4 + sl;
      s_h[wave * 4 + sl][lane] = hn[sl];
      if (t < T) xy[((size_t)b * T + t) * 64 + lane] = hn[sl];
    }
    __syncthreads();
  }
}

// ---------------------------------------------------------------------------
// scores: P[b,tau,eps] = sum_d t[b,tau,d]*e[b,eps,d].
// grid (16 tau-tiles, 16 eps-tiles, 4 b); K=64 one-shot.
// ---------------------------------------------------------------------------
__global__ __launch_bounds__(256) void scores_kernel(
    const float* __restrict__ tmat, const float* __restrict__ emat,
    float* __restrict__ P) {
  __shared__ __align__(16) float sT[64 * 68];
  __shared__ __align__(16) float sE[128 * 68];
  const int tid = threadIdx.x;
  const int b = blockIdx.z;
  const int tau0 = blockIdx.x * 64;
  const int e0 = blockIdx.y * 128;
#pragma unroll
  for (int r = 0; r < 4; ++r) {
    const int q = tid + r * 256;
    const int row = q >> 4, qq = q & 15;
    const float4 v = *(const float4*)&tmat[((size_t)b * 1024 + tau0 + row) * 64 + qq * 4];
    *(float4*)&sT[row * 68 + qq * 4] = v;
  }
#pragma unroll
  for (int r = 0; r < 8; ++r) {
    const int q = tid + r * 256;
    const int row = q >> 4, qq = q & 15;
    int eps = e0 + row; if (eps > 2031) eps = 2031;
    const float4 v = *(const float4*)&emat[((size_t)b * 2032 + eps) * 64 + qq * 4];
    *(float4*)&sE[row * 68 + qq * 4] = v;
  }
  __syncthreads();
  const int ty = tid >> 4, tx = tid & 15;
  float acc[4][8] = {};
#pragma unroll 4
  for (int q = 0; q < 16; ++q) {
    const int kk = q * 4;
    float4 av[4], bv[8];
#pragma unroll
    for (int i = 0; i < 4; ++i) av[i] = *(const float4*)&sT[(ty * 4 + i) * 68 + kk];
#pragma unroll
    for (int j = 0; j < 8; ++j) bv[j] = *(const float4*)&sE[(tx * 8 + j) * 68 + kk];
#pragma unroll
    for (int i = 0; i < 4; ++i)
#pragma unroll
      for (int j = 0; j < 8; ++j) {
        acc[i][j] = fmaf(av[i].x, bv[j].x, acc[i][j]);
        acc[i][j] = fmaf(av[i].y, bv[j].y, acc[i][j]);
        acc[i][j] = fmaf(av[i].z, bv[j].z, acc[i][j]);
        acc[i][j] = fmaf(av[i].w, bv[j].w, acc[i][j]);
      }
  }
#pragma unroll
  for (int i = 0; i < 4; ++i) {
    const size_t prow = ((size_t)b * 1024 + tau0 + ty * 4 + i) * 2032;
#pragma unroll
    for (int j = 0; j < 8; ++j) {
      const int eps = e0 + tx * 8 + j;
      if (eps < 2032) P[prow + eps] = acc[i][j];
    }
  }
}

// ---------------------------------------------------------------------------
// row softmax over eps (rows of length 2032), row cached in LDS. grid 4096.
// ---------------------------------------------------------------------------
__global__ __launch_bounds__(256) void softmax_rows_kernel(float* __restrict__ P) {
  __shared__ float s_row[2032];
  __shared__ float sred[4];
  float* r = P + (size_t)blockIdx.x * 2032;
  const int tid = threadIdx.x;
  const int lane = tid & 63, wave = tid >> 6;
  float m = -3.4e38f;
  for (int i = tid; i < 2032; i += 256) {
    const float v = r[i];
    s_row[i] = v;
    m = fmaxf(m, v);
  }
#pragma unroll
  for (int off = 32; off > 0; off >>= 1) m = fmaxf(m, __shfl_down(m, off, 64));
  if (lane == 0) sred[wave] = m;
  __syncthreads();
  m = fmaxf(fmaxf(sred[0], sred[1]), fmaxf(sred[2], sred[3]));
  __syncthreads();
  float s = 0.f;
  float vals[8];
  int cnt = 0;
  for (int i = tid; i < 2032; i += 256) {
    const float v = __expf(s_row[i] - m);
    vals[cnt++] = v;
    s += v;
  }
#pragma unroll
  for (int off = 32; off > 0; off >>= 1) s += __shfl_down(s, off, 64);
  if (lane == 0) sred[wave] = s;
  __syncthreads();
  const float inv = 1.f / (sred[0] + sred[1] + sred[2] + sred[3]);
  cnt = 0;
  for (int i = tid; i < 2032; i += 256) r[i] = vals[cnt++] * inv;
}

// ---------------------------------------------------------------------------
// pv partial: PV[b,eps,d] += sum_{tau slice} P[b,tau,eps]*t[b,tau,d]
// grid (32 eps-tiles, 4 tau-slices, 4 b); atomicAdd into zero-init PV.
// ---------------------------------------------------------------------------
__global__ __launch_bounds__(256) void pv_kernel(
    const float* __restrict__ P, const float* __restrict__ tmat,
    float* __restrict__ PV) {
  __shared__ float sP[32 * 65];
  __shared__ float sT[32 * 65];
  const int tid = threadIdx.x;
  const int b = blockIdx.z;
  const int e0 = blockIdx.x * 64;
  const int tau_base = blockIdx.y * 256;
  const int ty = tid >> 4, tx = tid & 15;
  float acc[4][4] = {};
  for (int kc = tau_base; kc < tau_base + 256; kc += 32) {
    __syncthreads();
    for (int l = tid; l < 32 * 64; l += 256) {
      const int kk = l >> 6, j = l & 63;
      int eps = e0 + j; if (eps > 2031) eps = 2031;
      sP[kk * 65 + j] = P[((size_t)b * 1024 + kc + kk) * 2032 + eps];
      sT[kk * 65 + j] = tmat[((size_t)b * 1024 + kc + kk) * 64 + j];
    }
    __syncthreads();
#pragma unroll 8
    for (int kk = 0; kk < 32; ++kk) {
      const float a0 = sP[kk * 65 + ty * 4 + 0];
      const float a1 = sP[kk * 65 + ty * 4 + 1];
      const float a2 = sP[kk * 65 + ty * 4 + 2];
      const float a3 = sP[kk * 65 + ty * 4 + 3];
      const float b0 = sT[kk * 65 + tx * 4 + 0];
      const float b1 = sT[kk * 65 + tx * 4 + 1];
      const float b2 = sT[kk * 65 + tx * 4 + 2];
      const float b3 = sT[kk * 65 + tx * 4 + 3];
      acc[0][0] = fmaf(a0, b0, acc[0][0]); acc[0][1] = fmaf(a0, b1, acc[0][1]);
      acc[0][2] = fmaf(a0, b2, acc[0][2]); acc[0][3] = fmaf(a0, b3, acc[0][3]);
      acc[1][0] = fmaf(a1, b0, acc[1][0]); acc[1][1] = fmaf(a1, b1, acc[1][1]);
      acc[1][2] = fmaf(a1, b2, acc[1][2]); acc[1][3] = fmaf(a1, b3, acc[1][3]);
      acc[2][0] = fmaf(a2, b0, acc[2][0]); acc[2][1] = fmaf(a2, b1, acc[2][1]);
      acc[2][2] = fmaf(a2, b2, acc[2][2]); acc[2][3] = fmaf(a2, b3, acc[2][3]);
      acc[3][0] = fmaf(a3, b0, acc[3][0]); acc[3][1] = fmaf(a3, b1, acc[3][1]);
      acc[3][2] = fmaf(a3, b2, acc[3][2]); acc[3][3] = fmaf(a3, b3, acc[3][3]);
    }
  }
#pragma unroll
  for (int i = 0; i < 4; ++i) {
    const int eps = e0 + ty * 4 + i;
    if (eps < 2032) {
#pragma unroll
      for (int j = 0; j < 4; ++j)
        atomicAdd(&PV[((size_t)b * 2032 + eps) * 64 + tx * 4 + j], acc[i][j]);
    }
  }
}

// ---------------------------------------------------------------------------
// head: att softmax + weighted reduce of |PV - e| + 2-layer MLP + softmax.
// ---------------------------------------------------------------------------
__global__ __launch_bounds__(256) void head_kernel(
    const float* __restrict__ emat, const float* __restrict__ PV,
    const float* __restrict__ a_w, const float* __restrict__ a_b,
    const float* __restrict__ h_w, const float* __restrict__ h_b,
    const float* __restrict__ c_w, const float* __restrict__ c_b,
    float* __restrict__ out) {
  __shared__ float s_att[2032];
  __shared__ float s_aw[64];
  __shared__ float sred[4];
  __shared__ float s_part[4][64];
  __shared__ float s_redv[64];
  __shared__ float s_hv[128];
  const int tid = threadIdx.x;
  const int lane = tid & 63, wave = tid >> 6;
  const int b = blockIdx.x;
  if (tid < 64) s_aw[tid] = a_w[tid];
  __syncthreads();
  const float ab = a_b[0];
  float m = -3.4e38f;
  for (int i = tid; i < 2032; i += 256) {
    const float* er = emat + ((size_t)b * 2032 + i) * 64;
    float acc = ab;
    for (int d = 0; d < 64; ++d) acc = fmaf(er[d], s_aw[d], acc);
    s_att[i] = acc;
    m = fmaxf(m, acc);
  }
#pragma unroll
  for (int off = 32; off > 0; off >>= 1) m = fmaxf(m, __shfl_down(m, off, 64));
  if (lane == 0) sred[wave] = m;
  __syncthreads();
  m = fmaxf(fmaxf(sred[0], sred[1]), fmaxf(sred[2], sred[3]));
  __syncthreads();
  float ssum = 0.f;
  for (int i = tid; i < 2032; i += 256) {
    const float v = __expf(s_att[i] - m);
    s_att[i] = v;
    ssum += v;
  }
#pragma unroll
  for (int off = 32; off > 0; off >>= 1) ssum += __shfl_down(ssum, off, 64);
  if (lane == 0) sred[wave] = ssum;
  __syncthreads();
  const float inv = 1.f / (sred[0] + sred[1] + sred[2] + sred[3]);
  float accp = 0.f;
  for (int i = wave; i < 2032; i += 4) {
    const size_t idx = ((size_t)b * 2032 + i) * 64 + lane;
    accp = fmaf(fabsf(PV[idx] - emat[idx]), s_att[i], accp);
  }
  s_part[wave][lane] = accp;
  __syncthreads();
  if (tid < 64)
    s_redv[tid] = (s_part[0][tid] + s_part[1][tid] + s_part[2][tid] + s_part[3][tid]) * inv;
  __syncthreads();
  if (tid < 128) {
    float acc = h_b[tid];
    const float* hw = h_w + tid * 64;
    for (int d = 0; d < 64; ++d) acc = fmaf(s_redv[d], hw[d], acc);
    s_hv[tid] = fmaxf(acc, 0.f);
  }
  __syncthreads();
  if (tid == 0) {
    float l0 = c_b[0], l1 = c_b[1];
    for (int j = 0; j < 128; ++j) {
      l0 = fmaf(s_hv[j], c_w[j], l0);
      l1 = fmaf(s_hv[j], c_w[128 + j], l1);
    }
    const float mm = fmaxf(l0, l1);
    const float e0 = __expf(l0 - mm), e1 = __expf(l1 - mm);
    const float invs = 1.f / (e0 + e1);
    out[b * 2 + 0] = e0 * invs;
    out[b * 2 + 1] = e1 * invs;
  }
}

// ===========================================================================
extern "C" void kernel_launch(void* const* d_in, const int* in_sizes, int n_in,
                              void* d_out, int out_size, void* d_ws, size_t ws_size,
                              hipStream_t stream) {
  const float* evaluation = (const float*)d_in[0];
  const float* templ      = (const float*)d_in[1];
  const float* e_w1 = (const float*)d_in[2];
  const float* e_b1 = (const float*)d_in[3];
  const float* e_w2 = (const float*)d_in[4];
  const float* e_b2 = (const float*)d_in[5];
  const float* e_w3 = (const float*)d_in[6];
  const float* e_b3 = (const float*)d_in[7];
  const float* el_w = (const float*)d_in[8];
  const float* el_b = (const float*)d_in[9];
  const float* eg_wih = (const float*)d_in[10];
  const float* eg_whh = (const float*)d_in[11];
  const float* eg_bih = (const float*)d_in[12];
  const float* eg_bhh = (const float*)d_in[13];
  const float* t_w1 = (const float*)d_in[14];
  const float* t_b1 = (const float*)d_in[15];
  const float* t_w2 = (const float*)d_in[16];
  const float* t_b2 = (const float*)d_in[17];
  const float* t_w3 = (const float*)d_in[18];
  const float* t_b3 = (const float*)d_in[19];
  const float* tl_w = (const float*)d_in[20];
  const float* tl_b = (const float*)d_in[21];
  const float* tg_wih = (const float*)d_in[22];
  const float* tg_whh = (const float*)d_in[23];
  const float* tg_bih = (const float*)d_in[24];
  const float* tg_bhh = (const float*)d_in[25];
  const float* a_w = (const float*)d_in[26];
  const float* a_b = (const float*)d_in[27];
  const float* h_w = (const float*)d_in[28];
  const float* h_b = (const float*)d_in[29];
  const float* c_w = (const float*)d_in[30];
  const float* c_b = (const float*)d_in[31];

  float* ws = (float*)d_ws;
  float* beff_e  = ws + OFF_BEFF_E;
  float* beff_t  = ws + OFF_BEFF_T;
  float* bias2_e = ws + OFF_BIAS2_E;
  float* bias2_t = ws + OFF_BIAS2_T;
  u16*   wbf_e   = (u16*)(ws + OFF_WBF_E);
  u16*   wbf_t   = (u16*)(ws + OFF_WBF_T);
  float* pool    = ws + OFF_POOL;
  float* gibuf   = ws + OFF_GI;
  float* Pbuf    = ws + OFF_P;
  float* PVbuf   = ws + OFF_PV;
  float* lin_e   = ws + OFF_LIN_E;
  float* lin_t   = ws + OFF_LIN_T;

  // weight composition (emits bf16-padded conv weights) + folded gi biases
  compose_fused_kernel<<<64, 256, 0, stream>>>(e_w1, e_b1, e_w2, e_b2, e_w3, e_b3, wbf_e, beff_e);
  compose_fused_kernel<<<64, 256, 0, stream>>>(t_w1, t_b1, t_w2, t_b2, t_w3, t_b3, wbf_t, beff_t);
  gi_bias_kernel<<<1, 256, 0, stream>>>(eg_wih, eg_bih, el_b, bias2_e);
  gi_bias_kernel<<<1, 256, 0, stream>>>(tg_wih, tg_bih, tl_b, bias2_t);

  // zero lin_e + lin_t (contiguous) for split-K atomics
  hipMemsetAsync(lin_e, 0, (520192 + 262144) * sizeof(float), stream);

  // eval branch: MFMA conv+pool -> split-K linear (bias folded into gi)
  conv_pool_mfma_kernel<<<dim3(34, 58, 4), 256, 0, stream>>>(evaluation, wbf_e, beff_e, pool, 2048, 2032);
  gemm_splitk_kernel<<<dim3(127, 8), 256, 0, stream>>>(pool, el_w, lin_e);
  // template branch
  conv_pool_mfma_kernel<<<dim3(18, 58, 4), 256, 0, stream>>>(templ, wbf_t, beff_t, pool, 1040, 1024);
  gemm_splitk_kernel<<<dim3(64, 8), 256, 0, stream>>>(pool, tl_w, lin_t);

  // zero PV (lives in dead pool region; must follow last pool read)
  hipMemsetAsync(PVbuf, 0, 520192 * sizeof(float), stream);

  // GRU (scan over batch axis)
  gemm_nt_kernel<<<dim3(127, 3), 256, 0, stream>>>(lin_e, eg_wih, bias2_e, gibuf, 192, 64);
  gru_rec_kernel<<<127, 256, 0, stream>>>(lin_e, gibuf, eg_whh, eg_bhh, 2032);
  gemm_nt_kernel<<<dim3(64, 3), 256, 0, stream>>>(lin_t, tg_wih, bias2_t, gibuf, 192, 64);
  gru_rec_kernel<<<64, 256, 0, stream>>>(lin_t, gibuf, tg_whh, tg_bhh, 1024);

  // cross attention + head
  scores_kernel<<<dim3(16, 16, 4), 256, 0, stream>>>(lin_t, lin_e, Pbuf);
  softmax_rows_kernel<<<4096, 256, 0, stream>>>(Pbuf);
  pv_kernel<<<dim3(32, 4, 4), 256, 0, stream>>>(Pbuf, lin_t, PVbuf);
  head_kernel<<<4, 256, 0, stream>>>(lin_e, PVbuf, a_w, a_b, h_w, h_b, c_w, c_b,
                                     (float*)d_out);
}

// Round 5
// 820.043 us; speedup vs baseline: 3.7870x; 1.5790x over previous
//
#include <hip/hip_runtime.h>
#include <cmath>

// ============================================================================
// DeepTemplateMatchingModule on MI355X — round 5.
// R4 post-mortem: compose_fused was the hidden top dispatch (251us x2 = 502us,
// VALU 5%, occupancy 2.8%, 162K LDS conflicts — divergent variable-bound
// loops + serial LDS dep chains + redundant w12 recompute per block).
// R5: compose split into two dense kernels with ZERO-PADDED operands so all
// tap loops are fixed 5x5 (no divergence, unrollable):
//   compose12  : w12pad[32][17][17] (grid 32 x 2 branches)    ~2us
//   compose_weff: weff bf16 padded (grid 64 x 2 branches)     ~5us
// Also: pooled tensor stored as bf16 (conv epilogue converts; split-K GEMM
// stages bf16->fp32 in LDS) — halves the biggest intermediate's HBM traffic.
// ============================================================================

typedef unsigned short u16;
typedef __attribute__((ext_vector_type(8))) short bf16x8;
typedef __attribute__((ext_vector_type(8))) unsigned short u16x8;
typedef __attribute__((ext_vector_type(16))) float f32x16;

__device__ __forceinline__ u16 f2bf(float f) {
  unsigned int x = __float_as_uint(f);
  return (u16)((x + 0x7fffu + ((x >> 16) & 1u)) >> 16);
}
__device__ __forceinline__ float bf2f(u16 v) {
  return __uint_as_float(((unsigned int)v) << 16);
}

// ---- workspace layout (float offsets) ----
static const size_t OFF_BEFF_E  = 0;          // 64
static const size_t OFF_BEFF_T  = 64;         // 64
static const size_t OFF_BIAS2_E = 128;        // 192
static const size_t OFF_BIAS2_T = 320;        // 192
static const size_t OFF_WBF_E   = 512;        // 7424 floats (14848 u16)
static const size_t OFF_WBF_T   = 7936;       // 7424
static const size_t OFF_W12P_E  = 15360;      // 9248 (32 x 17 x 17, padded)
static const size_t OFF_W12P_T  = 24608;      // 9248
static const size_t OFF_B12_E   = 33856;      // 32
static const size_t OFF_B12_T   = 33888;      // 32
static const size_t OFF_POOL    = 33920;      // u16! 30,171,136 u16 = 15,085,568 f
// reused inside dead pool region (pool dead after last split-K):
static const size_t OFF_GI      = OFF_POOL;                   // 1,560,576 f
static const size_t OFF_P       = OFF_POOL + 1560576;         // 8,323,072 f
static const size_t OFF_PV      = OFF_P + 8323072;            // 520,192 f
static const size_t OFF_LIN_E   = OFF_POOL + 15085568;        // 520,192 f
static const size_t OFF_LIN_T   = OFF_LIN_E + 520192;         // 262,144 f

// ---------------------------------------------------------------------------
// compose12: w12pad[c12][17][17] = sum_c1 w2[c12,c1] conv w1[c1], zero-padded
// (real 9x9 at [4..12][4..12]).  b12 likewise.  Fixed 5x5 tap loops via
// zero-padded w1 (13x13). grid (32 c12, 2 branches), 320 threads.
// ---------------------------------------------------------------------------
__global__ __launch_bounds__(320) void compose12_kernel(
    const float* __restrict__ w1e, const float* __restrict__ b1e,
    const float* __restrict__ w2e, const float* __restrict__ b2e,
    const float* __restrict__ w1t, const float* __restrict__ b1t,
    const float* __restrict__ w2t, const float* __restrict__ b2t,
    float* __restrict__ w12p_e, float* __restrict__ w12p_t,
    float* __restrict__ b12o_e, float* __restrict__ b12o_t) {
  const int br = blockIdx.y;
  const float* w1 = br ? w1t : w1e;
  const float* b1 = br ? b1t : b1e;
  const float* w2 = br ? w2t : w2e;
  const float* b2 = br ? b2t : b2e;
  float* w12p = br ? w12p_t : w12p_e;
  float* b12o = br ? b12o_t : b12o_e;
  const int c12 = blockIdx.x;
  __shared__ float s_w1pad[16 * 169];  // [c1][13][13], w1 at [4..8][4..8]
  __shared__ float s_w2c[400];         // w2[c12] : 16 x 25
  __shared__ float s_b1[16];
  const int tid = threadIdx.x;
  for (int i = tid; i < 2704; i += 320) s_w1pad[i] = 0.f;
  if (tid < 16) s_b1[tid] = b1[tid];
  __syncthreads();
  for (int i = tid; i < 400; i += 320) {
    const int c1 = i / 25, r = (i % 25) / 5, cc = i % 5;
    s_w1pad[c1 * 169 + (r + 4) * 13 + (cc + 4)] = w1[i];
    s_w2c[i] = w2[c12 * 400 + i];
  }
  __syncthreads();
  if (tid < 289) {
    const int py = tid / 17, px = tid % 17;
    float v = 0.f;
    if (py >= 4 && py <= 12 && px >= 4 && px <= 12) {
      const int sy = py - 4, sx = px - 4;
      float accs[2] = {0.f, 0.f};
      for (int c1 = 0; c1 < 16; ++c1) {
        const float* w2p = s_w2c + c1 * 25;
        const float* w1p = s_w1pad + c1 * 169 + (sy + 4) * 13 + (sx + 4);
#pragma unroll
        for (int uy = 0; uy < 5; ++uy)
#pragma unroll
          for (int ux = 0; ux < 5; ++ux)
            accs[uy & 1] = fmaf(w2p[uy * 5 + ux], w1p[-(uy * 13) - ux], accs[uy & 1]);
      }
      v = accs[0] + accs[1];
    }
    w12p[c12 * 289 + tid] = v;
  } else if (tid == 300) {
    float acc = b2[c12];
    for (int c1 = 0; c1 < 16; ++c1) {
      float sw = 0.f;
      for (int u = 0; u < 25; ++u) sw += s_w2c[c1 * 25 + u];
      acc = fmaf(sw, s_b1[c1], acc);
    }
    b12o[c12] = acc;
  }
}

// ---------------------------------------------------------------------------
// compose_weff: weff[o][13][13] = sum_c12 w3[o,c12] conv w12pad[c12]; emits
// bf16 padded layout weffp[o][13][16] stride 232 u16 (kx pads = 0). beff.
// grid (64 o, 2 branches), 256 threads, fixed 5x5 tap loops.
// ---------------------------------------------------------------------------
__global__ __launch_bounds__(256) void compose_weff_kernel(
    const float* __restrict__ w3e, const float* __restrict__ b3e,
    const float* __restrict__ w3t, const float* __restrict__ b3t,
    const float* __restrict__ w12p_e, const float* __restrict__ w12p_t,
    const float* __restrict__ b12_e, const float* __restrict__ b12_t,
    u16* __restrict__ wbf_e, u16* __restrict__ wbf_t,
    float* __restrict__ beff_e, float* __restrict__ beff_t) {
  const int br = blockIdx.y;
  const float* w3 = br ? w3t : w3e;
  const float* b3 = br ? b3t : b3e;
  const float* w12p = br ? w12p_t : w12p_e;
  const float* b12 = br ? b12_t : b12_e;
  u16* weffp = br ? wbf_t : wbf_e;
  float* beff = br ? beff_t : beff_e;
  const int o = blockIdx.x;
  __shared__ float s_pad[32 * 289];  // 9248 floats
  __shared__ float s_w3o[800];
  __shared__ float s_b12[32];
  const int tid = threadIdx.x;
  for (int i = tid; i < 9248; i += 256) s_pad[i] = w12p[i];
  for (int i = tid; i < 800; i += 256) s_w3o[i] = w3[o * 800 + i];
  if (tid < 32) s_b12[tid] = b12[tid];
  __syncthreads();
  if (tid < 169) {
    const int sy = tid / 13, sx = tid % 13;
    float accs[4] = {0.f, 0.f, 0.f, 0.f};
#pragma unroll 4
    for (int c = 0; c < 32; ++c) {
      const float* w3p = s_w3o + c * 25;
      const float* wp = s_pad + c * 289 + (sy + 4) * 17 + (sx + 4);
#pragma unroll
      for (int uy = 0; uy < 5; ++uy)
#pragma unroll
        for (int ux = 0; ux < 5; ++ux)
          accs[c & 3] = fmaf(w3p[uy * 5 + ux], wp[-(uy * 17) - ux], accs[c & 3]);
    }
    weffp[o * 232 + sy * 16 + sx] = f2bf(accs[0] + accs[1] + accs[2] + accs[3]);
  } else if (tid < 208) {
    const int p = tid - 169;  // zero the kx=13..15 pad slots
    weffp[o * 232 + (p / 3) * 16 + 13 + (p % 3)] = 0;
  } else if (tid == 208) {
    float acc = b3[o];
    for (int c = 0; c < 32; ++c) {
      float sw = 0.f;
      for (int u = 0; u < 25; ++u) sw += s_w3o[c * 25 + u];
      acc = fmaf(sw, s_b12[c], acc);
    }
    beff[o] = acc;
  }
}

// ---------------------------------------------------------------------------
// bias2[j] = b_ih[j] + sum_d w_ih[j,d] * lb[d]  (lin bias folded into gi);
// grid 2 (branch select).
// ---------------------------------------------------------------------------
__global__ __launch_bounds__(256) void gi_bias_kernel(
    const float* __restrict__ wih_e, const float* __restrict__ bih_e,
    const float* __restrict__ lb_e, float* __restrict__ bias2_e,
    const float* __restrict__ wih_t, const float* __restrict__ bih_t,
    const float* __restrict__ lb_t, float* __restrict__ bias2_t) {
  const int br = blockIdx.x;
  const float* wih = br ? wih_t : wih_e;
  const float* bih = br ? bih_t : bih_e;
  const float* lb = br ? lb_t : lb_e;
  float* bias2 = br ? bias2_t : bias2_e;
  __shared__ float s_lb[64];
  const int tid = threadIdx.x;
  if (tid < 64) s_lb[tid] = lb[tid];
  __syncthreads();
  if (tid < 192) {
    float acc = bih[tid];
    const float* wr = wih + tid * 64;
    for (int d = 0; d < 64; ++d) acc = fmaf(wr[d], s_lb[d], acc);
    bias2[tid] = acc;
  }
}

// ---------------------------------------------------------------------------
// MFMA conv13x13 + maxpool(2,5)/(2,1); pooled stored as bf16.
// grid: (ceil(T/60), 58, 4). (structure from R4; epilogue converts to bf16)
// ---------------------------------------------------------------------------
__global__ __launch_bounds__(256, 2) void conv_pool_mfma_kernel(
    const float* __restrict__ x, const u16* __restrict__ weffp,
    const float* __restrict__ beff, u16* __restrict__ pooled,
    const int W, const int T) {
  __shared__ __align__(16) char s_union[45248];  // s_x+im2col | s_out
  __shared__ __align__(16) char s_wreg[29696];   // weights | s_pool
  u16* s_x = (u16*)s_union;              // [14][80] bf16
  u16* s_im = (u16*)(s_union + 2240);    // [14][64][24] bf16 (48B col stride)
  float* s_out = (float*)s_union;        // [2][64][65] f32 (after K-loop)
  u16* s_w = (u16*)s_wreg;               // [64][232] bf16
  float* s_pool = (float*)s_wreg;        // [64][61] f32 (after K-loop)

  const int tid = threadIdx.x;
  const int lane = tid & 63, wave = tid >> 6;
  const int cb = blockIdx.x * 60;
  const int h = blockIdx.y, b = blockIdx.z;

  for (int i = tid; i < 1856; i += 256)
    ((uint4*)s_w)[i] = ((const uint4*)weffp)[i];
  {
    const float* xb = x + ((size_t)b * 128 + 2 * h) * W;
    for (int i = tid; i < 14 * 80; i += 256) {
      const int r = i / 80, cq = i - r * 80;
      int gc = cb + cq;
      if (gc > W - 1) gc = W - 1;
      s_x[i] = f2bf(xb[(size_t)r * W + gc]);
    }
  }
  __syncthreads();
  for (int p = tid; p < 896; p += 256) {
    const int ky = p >> 6, col = p & 63;
    const u16* src = s_x + ky * 80 + col;
    u16x8 v0, v1;
#pragma unroll
    for (int j = 0; j < 8; ++j) { v0[j] = src[j]; v1[j] = src[8 + j]; }
    u16* dst = s_im + (ky * 64 + col) * 24;
    *(u16x8*)dst = v0;
    *(u16x8*)(dst + 8) = v1;
  }
  __syncthreads();
  const int rsel = wave & 1, cm = (wave >> 1) * 32;
  const int l31 = lane & 31, g8 = (lane >> 5) * 8;
  f32x16 acc0 = {}, acc1 = {};
  const u16* aw = s_w + (cm + l31) * 232 + g8;
  const u16* bw = s_im + (rsel * 64 + l31) * 24 + g8;
#pragma unroll
  for (int ky = 0; ky < 13; ++ky) {
    bf16x8 a = *(const bf16x8*)(aw + ky * 16);
    bf16x8 b0 = *(const bf16x8*)(bw + ky * 64 * 24);
    bf16x8 b1 = *(const bf16x8*)(bw + ky * 64 * 24 + 32 * 24);
    acc0 = __builtin_amdgcn_mfma_f32_32x32x16_bf16(a, b0, acc0, 0, 0, 0);
    acc1 = __builtin_amdgcn_mfma_f32_32x32x16_bf16(a, b1, acc1, 0, 0, 0);
  }
  __syncthreads();
#pragma unroll
  for (int r = 0; r < 16; ++r) {
    const int c = cm + (r & 3) + 8 * (r >> 2) + (g8 >> 1);
    float* o = s_out + (rsel * 64 + c) * 65;
    o[l31] = acc0[r];
    o[32 + l31] = acc1[r];
  }
  __syncthreads();
  {
    const int pc = tid & 63, tg = tid >> 6;
    const int t0 = tg * 15;
    const float bias = beff[pc];
    const float* r0p = s_out + pc * 65 + t0;
    const float* r1p = s_out + (64 + pc) * 65 + t0;
    float w0[19], w1[19];
#pragma unroll
    for (int j = 0; j < 19; ++j) { w0[j] = r0p[j]; w1[j] = r1p[j]; }
#pragma unroll
    for (int i = 0; i < 15; ++i) {
      float m = w0[i];
#pragma unroll
      for (int k = 1; k < 5; ++k) m = fmaxf(m, w0[i + k]);
#pragma unroll
      for (int k = 0; k < 5; ++k) m = fmaxf(m, w1[i + k]);
      s_pool[pc * 61 + t0 + i] = m + bias;
    }
  }
  __syncthreads();
  for (int i = tid; i < 3840; i += 256) {
    const int c = i / 60, t = i - c * 60;
    const int gt = cb + t;
    if (gt < T)
      pooled[(((size_t)b * 64 + c) * 58 + h) * T + gt] = f2bf(s_pool[c * 61 + t]);
  }
}

// ---------------------------------------------------------------------------
// Split-K GEMM (bf16 pool @ fp32 lw^T), N=64; atomicAdd into zero-init out.
// grid (Mtiles, 8 K-slices). bf16 A converted to fp32 in LDS staging.
// ---------------------------------------------------------------------------
__global__ __launch_bounds__(256) void gemm_splitk_kernel(
    const u16* __restrict__ A, const float* __restrict__ Wt,
    float* __restrict__ out) {
  __shared__ __align__(16) float sA[64 * 33];
  __shared__ __align__(16) float sB[64 * 33];
  const int tid = threadIdx.x;
  const int r0 = blockIdx.x * 64;
  const int s = blockIdx.y;
  const int c0 = (s * 116) / 8, c1 = ((s + 1) * 116) / 8;
  const int ty = tid >> 4, tx = tid & 15;
  float acc[4][4] = {};
  for (int ch = c0; ch < c1; ++ch) {
    const int kc = ch * 32;
    __syncthreads();
    {
      const int row = tid >> 2, seg = tid & 3;  // 64 rows x 4 segs of 8
      const u16x8 va = *(const u16x8*)&A[(size_t)(r0 + row) * 3712 + kc + seg * 8];
#pragma unroll
      for (int j = 0; j < 8; ++j) sA[row * 33 + seg * 8 + j] = bf2f(va[j]);
    }
#pragma unroll
    for (int r = 0; r < 2; ++r) {
      const int q = tid + r * 256;
      const int row = q >> 3, qq = q & 7;
      const float4 vb = *(const float4*)&Wt[(size_t)row * 3712 + kc + qq * 4];
      sB[row * 33 + qq * 4 + 0] = vb.x; sB[row * 33 + qq * 4 + 1] = vb.y;
      sB[row * 33 + qq * 4 + 2] = vb.z; sB[row * 33 + qq * 4 + 3] = vb.w;
    }
    __syncthreads();
#pragma unroll 8
    for (int kk = 0; kk < 32; ++kk) {
      const float a0 = sA[(ty * 4 + 0) * 33 + kk];
      const float a1 = sA[(ty * 4 + 1) * 33 + kk];
      const float a2 = sA[(ty * 4 + 2) * 33 + kk];
      const float a3 = sA[(ty * 4 + 3) * 33 + kk];
      const float b0 = sB[(tx * 4 + 0) * 33 + kk];
      const float b1 = sB[(tx * 4 + 1) * 33 + kk];
      const float b2 = sB[(tx * 4 + 2) * 33 + kk];
      const float b3 = sB[(tx * 4 + 3) * 33 + kk];
      acc[0][0] = fmaf(a0, b0, acc[0][0]); acc[0][1] = fmaf(a0, b1, acc[0][1]);
      acc[0][2] = fmaf(a0, b2, acc[0][2]); acc[0][3] = fmaf(a0, b3, acc[0][3]);
      acc[1][0] = fmaf(a1, b0, acc[1][0]); acc[1][1] = fmaf(a1, b1, acc[1][1]);
      acc[1][2] = fmaf(a1, b2, acc[1][2]); acc[1][3] = fmaf(a1, b3, acc[1][3]);
      acc[2][0] = fmaf(a2, b0, acc[2][0]); acc[2][1] = fmaf(a2, b1, acc[2][1]);
      acc[2][2] = fmaf(a2, b2, acc[2][2]); acc[2][3] = fmaf(a2, b3, acc[2][3]);
      acc[3][0] = fmaf(a3, b0, acc[3][0]); acc[3][1] = fmaf(a3, b1, acc[3][1]);
      acc[3][2] = fmaf(a3, b2, acc[3][2]); acc[3][3] = fmaf(a3, b3, acc[3][3]);
    }
  }
#pragma unroll
  for (int i = 0; i < 4; ++i)
#pragma unroll
    for (int j = 0; j < 4; ++j)
      atomicAdd(&out[(size_t)(r0 + ty * 4 + i) * 64 + tx * 4 + j], acc[i][j]);
}

// ---------------------------------------------------------------------------
// Generic fp32 GEMM (gi = lin @ w_ih^T + bias2). K multiple of 32.
// ---------------------------------------------------------------------------
__global__ __launch_bounds__(256) void gemm_nt_kernel(
    const float* __restrict__ A, const float* __restrict__ Wt,
    const float* __restrict__ bias, float* __restrict__ out,
    const int N, const int K) {
  __shared__ float sA[64 * 33];
  __shared__ float sB[64 * 33];
  const int tid = threadIdx.x;
  const int r0 = blockIdx.x * 64;
  const int n0 = blockIdx.y * 64;
  const int ty = tid >> 4, tx = tid & 15;
  float acc[4][4] = {};
  for (int kc = 0; kc < K; kc += 32) {
    __syncthreads();
#pragma unroll
    for (int rep = 0; rep < 8; ++rep) {
      const int l = tid + rep * 256;
      const int row = l >> 5, kk = l & 31;
      sA[row * 33 + kk] = A[(size_t)(r0 + row) * K + kc + kk];
      sB[row * 33 + kk] = Wt[(size_t)(n0 + row) * K + kc + kk];
    }
    __syncthreads();
#pragma unroll 8
    for (int kk = 0; kk < 32; ++kk) {
      const float a0 = sA[(ty * 4 + 0) * 33 + kk];
      const float a1 = sA[(ty * 4 + 1) * 33 + kk];
      const float a2 = sA[(ty * 4 + 2) * 33 + kk];
      const float a3 = sA[(ty * 4 + 3) * 33 + kk];
      const float b0 = sB[(tx * 4 + 0) * 33 + kk];
      const float b1 = sB[(tx * 4 + 1) * 33 + kk];
      const float b2 = sB[(tx * 4 + 2) * 33 + kk];
      const float b3 = sB[(tx * 4 + 3) * 33 + kk];
      acc[0][0] = fmaf(a0, b0, acc[0][0]); acc[0][1] = fmaf(a0, b1, acc[0][1]);
      acc[0][2] = fmaf(a0, b2, acc[0][2]); acc[0][3] = fmaf(a0, b3, acc[0][3]);
      acc[1][0] = fmaf(a1, b0, acc[1][0]); acc[1][1] = fmaf(a1, b1, acc[1][1]);
      acc[1][2] = fmaf(a1, b2, acc[1][2]); acc[1][3] = fmaf(a1, b3, acc[1][3]);
      acc[2][0] = fmaf(a2, b0, acc[2][0]); acc[2][1] = fmaf(a2, b1, acc[2][1]);
      acc[2][2] = fmaf(a2, b2, acc[2][2]); acc[2][3] = fmaf(a2, b3, acc[2][3]);
      acc[3][0] = fmaf(a3, b0, acc[3][0]); acc[3][1] = fmaf(a3, b1, acc[3][1]);
      acc[3][2] = fmaf(a3, b2, acc[3][2]); acc[3][3] = fmaf(a3, b3, acc[3][3]);
    }
  }
#pragma unroll
  for (int i = 0; i < 4; ++i)
#pragma unroll
    for (int j = 0; j < 4; ++j)
      out[(size_t)(r0 + ty * 4 + i) * N + n0 + tx * 4 + j] =
          acc[i][j] + bias[n0 + tx * 4 + j];
}

// ---------------------------------------------------------------------------
// GRU recurrence (scan over BATCH axis, 4 steps; every t independent).
// ---------------------------------------------------------------------------
__global__ __launch_bounds__(256) void gru_rec_kernel(
    float* __restrict__ xy, const float* __restrict__ gi,
    const float* __restrict__ whh, const float* __restrict__ bhh, const int T) {
  __shared__ float s_whh_t[64 * 192];
  __shared__ float s_h[16][64];
  const int tid = threadIdx.x;
  const int lane = tid & 63, wave = tid >> 6;
  for (int i = tid; i < 192 * 64; i += 256) {
    const int j = i >> 6, d = i & 63;
    s_whh_t[d * 192 + j] = whh[i];
  }
  for (int i = tid; i < 16 * 64; i += 256) (&s_h[0][0])[i] = 0.f;
  const float bhr = bhh[lane], bhz = bhh[64 + lane], bhn = bhh[128 + lane];
  const int t0 = blockIdx.x * 16;
  __syncthreads();
  for (int b = 0; b < 4; ++b) {
    float gir[4], giz[4], gin[4];
#pragma unroll
    for (int sl = 0; sl < 4; ++sl) {
      int t = t0 + wave * 4 + sl; if (t > T - 1) t = T - 1;
      const float* girow = gi + ((size_t)b * T + t) * 192;
      gir[sl] = girow[lane]; giz[sl] = girow[64 + lane]; gin[sl] = girow[128 + lane];
    }
    float ahr[4] = {}, ahz[4] = {}, ahn[4] = {};
    for (int d = 0; d < 64; ++d) {
      const float wr_ = s_whh_t[d * 192 + lane];
      const float wz_ = s_whh_t[d * 192 + 64 + lane];
      const float wn_ = s_whh_t[d * 192 + 128 + lane];
#pragma unroll
      for (int sl = 0; sl < 4; ++sl) {
        const float hv = s_h[wave * 4 + sl][d];
        ahr[sl] = fmaf(wr_, hv, ahr[sl]);
        ahz[sl] = fmaf(wz_, hv, ahz[sl]);
        ahn[sl] = fmaf(wn_, hv, ahn[sl]);
      }
    }
    float hn[4];
#pragma unroll
    for (int sl = 0; sl < 4; ++sl) {
      const float r = 1.f / (1.f + __expf(-(gir[sl] + ahr[sl] + bhr)));
      const float z = 1.f / (1.f + __expf(-(giz[sl] + ahz[sl] + bhz)));
      const float n = tanhf(gin[sl] + r * (ahn[sl] + bhn));
      hn[sl] = (1.f - z) * n + z * s_h[wave * 4 + sl][lane];
    }
    __syncthreads();
#pragma unroll
    for (int sl = 0; sl < 4; ++sl) {
      const int t = t0 + wave * 4 + sl;
      s_h[wave * 4 + sl][lane] = hn[sl];
      if (t < T) xy[((size_t)b * T + t) * 64 + lane] = hn[sl];
    }
    __syncthreads();
  }
}

// ---------------------------------------------------------------------------
// scores: P[b,tau,eps] = sum_d t[b,tau,d]*e[b,eps,d].
// grid (16 tau-tiles, 16 eps-tiles, 4 b); K=64 one-shot.
// ---------------------------------------------------------------------------
__global__ __launch_bounds__(256) void scores_kernel(
    const float* __restrict__ tmat, const float* __restrict__ emat,
    float* __restrict__ P) {
  __shared__ __align__(16) float sT[64 * 68];
  __shared__ __align__(16) float sE[128 * 68];
  const int tid = threadIdx.x;
  const int b = blockIdx.z;
  const int tau0 = blockIdx.x * 64;
  const int e0 = blockIdx.y * 128;
#pragma unroll
  for (int r = 0; r < 4; ++r) {
    const int q = tid + r * 256;
    const int row = q >> 4, qq = q & 15;
    const float4 v = *(const float4*)&tmat[((size_t)b * 1024 + tau0 + row) * 64 + qq * 4];
    *(float4*)&sT[row * 68 + qq * 4] = v;
  }
#pragma unroll
  for (int r = 0; r < 8; ++r) {
    const int q = tid + r * 256;
    const int row = q >> 4, qq = q & 15;
    int eps = e0 + row; if (eps > 2031) eps = 2031;
    const float4 v = *(const float4*)&emat[((size_t)b * 2032 + eps) * 64 + qq * 4];
    *(float4*)&sE[row * 68 + qq * 4] = v;
  }
  __syncthreads();
  const int ty = tid >> 4, tx = tid & 15;
  float acc[4][8] = {};
#pragma unroll 4
  for (int q = 0; q < 16; ++q) {
    const int kk = q * 4;
    float4 av[4], bv[8];
#pragma unroll
    for (int i = 0; i < 4; ++i) av[i] = *(const float4*)&sT[(ty * 4 + i) * 68 + kk];
#pragma unroll
    for (int j = 0; j < 8; ++j) bv[j] = *(const float4*)&sE[(tx * 8 + j) * 68 + kk];
#pragma unroll
    for (int i = 0; i < 4; ++i)
#pragma unroll
      for (int j = 0; j < 8; ++j) {
        acc[i][j] = fmaf(av[i].x, bv[j].x, acc[i][j]);
        acc[i][j] = fmaf(av[i].y, bv[j].y, acc[i][j]);
        acc[i][j] = fmaf(av[i].z, bv[j].z, acc[i][j]);
        acc[i][j] = fmaf(av[i].w, bv[j].w, acc[i][j]);
      }
  }
#pragma unroll
  for (int i = 0; i < 4; ++i) {
    const size_t prow = ((size_t)b * 1024 + tau0 + ty * 4 + i) * 2032;
#pragma unroll
    for (int j = 0; j < 8; ++j) {
      const int eps = e0 + tx * 8 + j;
      if (eps < 2032) P[prow + eps] = acc[i][j];
    }
  }
}

// ---------------------------------------------------------------------------
// row softmax over eps (rows of length 2032), row cached in LDS. grid 4096.
// ---------------------------------------------------------------------------
__global__ __launch_bounds__(256) void softmax_rows_kernel(float* __restrict__ P) {
  __shared__ float s_row[2032];
  __shared__ float sred[4];
  float* r = P + (size_t)blockIdx.x * 2032;
  const int tid = threadIdx.x;
  const int lane = tid & 63, wave = tid >> 6;
  float m = -3.4e38f;
  for (int i = tid; i < 2032; i += 256) {
    const float v = r[i];
    s_row[i] = v;
    m = fmaxf(m, v);
  }
#pragma unroll
  for (int off = 32; off > 0; off >>= 1) m = fmaxf(m, __shfl_down(m, off, 64));
  if (lane == 0) sred[wave] = m;
  __syncthreads();
  m = fmaxf(fmaxf(sred[0], sred[1]), fmaxf(sred[2], sred[3]));
  __syncthreads();
  float s = 0.f;
  float vals[8];
  int cnt = 0;
  for (int i = tid; i < 2032; i += 256) {
    const float v = __expf(s_row[i] - m);
    vals[cnt++] = v;
    s += v;
  }
#pragma unroll
  for (int off = 32; off > 0; off >>= 1) s += __shfl_down(s, off, 64);
  if (lane == 0) sred[wave] = s;
  __syncthreads();
  const float inv = 1.f / (sred[0] + sred[1] + sred[2] + sred[3]);
  cnt = 0;
  for (int i = tid; i < 2032; i += 256) r[i] = vals[cnt++] * inv;
}

// ---------------------------------------------------------------------------
// pv partial: PV[b,eps,d] += sum_{tau slice} P[b,tau,eps]*t[b,tau,d]
// grid (32 eps-tiles, 4 tau-slices, 4 b); atomicAdd into zero-init PV.
// ---------------------------------------------------------------------------
__global__ __launch_bounds__(256) void pv_kernel(
    const float* __restrict__ P, const float* __restrict__ tmat,
    float* __restrict__ PV) {
  __shared__ float sP[32 * 65];
  __shared__ float sT[32 * 65];
  const int tid = threadIdx.x;
  const int b = blockIdx.z;
  const int e0 = blockIdx.x * 64;
  const int tau_base = blockIdx.y * 256;
  const int ty = tid >> 4, tx = tid & 15;
  float acc[4][4] = {};
  for (int kc = tau_base; kc < tau_base + 256; kc += 32) {
    __syncthreads();
    for (int l = tid; l < 32 * 64; l += 256) {
      const int kk = l >> 6, j = l & 63;
      int eps = e0 + j; if (eps > 2031) eps = 2031;
      sP[kk * 65 + j] = P[((size_t)b * 1024 + kc + kk) * 2032 + eps];
      sT[kk * 65 + j] = tmat[((size_t)b * 1024 + kc + kk) * 64 + j];
    }
    __syncthreads();
#pragma unroll 8
    for (int kk = 0; kk < 32; ++kk) {
      const float a0 = sP[kk * 65 + ty * 4 + 0];
      const float a1 = sP[kk * 65 + ty * 4 + 1];
      const float a2 = sP[kk * 65 + ty * 4 + 2];
      const float a3 = sP[kk * 65 + ty * 4 + 3];
      const float b0 = sT[kk * 65 + tx * 4 + 0];
      const float b1 = sT[kk * 65 + tx * 4 + 1];
      const float b2 = sT[kk * 65 + tx * 4 + 2];
      const float b3 = sT[kk * 65 + tx * 4 + 3];
      acc[0][0] = fmaf(a0, b0, acc[0][0]); acc[0][1] = fmaf(a0, b1, acc[0][1]);
      acc[0][2] = fmaf(a0, b2, acc[0][2]); acc[0][3] = fmaf(a0, b3, acc[0][3]);
      acc[1][0] = fmaf(a1, b0, acc[1][0]); acc[1][1] = fmaf(a1, b1, acc[1][1]);
      acc[1][2] = fmaf(a1, b2, acc[1][2]); acc[1][3] = fmaf(a1, b3, acc[1][3]);
      acc[2][0] = fmaf(a2, b0, acc[2][0]); acc[2][1] = fmaf(a2, b1, acc[2][1]);
      acc[2][2] = fmaf(a2, b2, acc[2][2]); acc[2][3] = fmaf(a2, b3, acc[2][3]);
      acc[3][0] = fmaf(a3, b0, acc[3][0]); acc[3][1] = fmaf(a3, b1, acc[3][1]);
      acc[3][2] = fmaf(a3, b2, acc[3][2]); acc[3][3] = fmaf(a3, b3, acc[3][3]);
    }
  }
#pragma unroll
  for (int i = 0; i < 4; ++i) {
    const int eps = e0 + ty * 4 + i;
    if (eps < 2032) {
#pragma unroll
      for (int j = 0; j < 4; ++j)
        atomicAdd(&PV[((size_t)b * 2032 + eps) * 64 + tx * 4 + j], acc[i][j]);
    }
  }
}

// ---------------------------------------------------------------------------
// head: att softmax + weighted reduce of |PV - e| + 2-layer MLP + softmax.
// ---------------------------------------------------------------------------
__global__ __launch_bounds__(256) void head_kernel(
    const float* __restrict__ emat, const float* __restrict__ PV,
    const float* __restrict__ a_w, const float* __restrict__ a_b,
    const float* __restrict__ h_w, const float* __restrict__ h_b,
    const float* __restrict__ c_w, const float* __restrict__ c_b,
    float* __restrict__ out) {
  __shared__ float s_att[2032];
  __shared__ float s_aw[64];
  __shared__ float sred[4];
  __shared__ float s_part[4][64];
  __shared__ float s_redv[64];
  __shared__ float s_hv[128];
  const int tid = threadIdx.x;
  const int lane = tid & 63, wave = tid >> 6;
  const int b = blockIdx.x;
  if (tid < 64) s_aw[tid] = a_w[tid];
  __syncthreads();
  const float ab = a_b[0];
  float m = -3.4e38f;
  for (int i = tid; i < 2032; i += 256) {
    const float* er = emat + ((size_t)b * 2032 + i) * 64;
    float acc = ab;
    for (int d = 0; d < 64; ++d) acc = fmaf(er[d], s_aw[d], acc);
    s_att[i] = acc;
    m = fmaxf(m, acc);
  }
#pragma unroll
  for (int off = 32; off > 0; off >>= 1) m = fmaxf(m, __shfl_down(m, off, 64));
  if (lane == 0) sred[wave] = m;
  __syncthreads();
  m = fmaxf(fmaxf(sred[0], sred[1]), fmaxf(sred[2], sred[3]));
  __syncthreads();
  float ssum = 0.f;
  for (int i = tid; i < 2032; i += 256) {
    const float v = __expf(s_att[i] - m);
    s_att[i] = v;
    ssum += v;
  }
#pragma unroll
  for (int off = 32; off > 0; off >>= 1) ssum += __shfl_down(ssum, off, 64);
  if (lane == 0) sred[wave] = ssum;
  __syncthreads();
  const float inv = 1.f / (sred[0] + sred[1] + sred[2] + sred[3]);
  float accp = 0.f;
  for (int i = wave; i < 2032; i += 4) {
    const size_t idx = ((size_t)b * 2032 + i) * 64 + lane;
    accp = fmaf(fabsf(PV[idx] - emat[idx]), s_att[i], accp);
  }
  s_part[wave][lane] = accp;
  __syncthreads();
  if (tid < 64)
    s_redv[tid] = (s_part[0][tid] + s_part[1][tid] + s_part[2][tid] + s_part[3][tid]) * inv;
  __syncthreads();
  if (tid < 128) {
    float acc = h_b[tid];
    const float* hw = h_w + tid * 64;
    for (int d = 0; d < 64; ++d) acc = fmaf(s_redv[d], hw[d], acc);
    s_hv[tid] = fmaxf(acc, 0.f);
  }
  __syncthreads();
  if (tid == 0) {
    float l0 = c_b[0], l1 = c_b[1];
    for (int j = 0; j < 128; ++j) {
      l0 = fmaf(s_hv[j], c_w[j], l0);
      l1 = fmaf(s_hv[j], c_w[128 + j], l1);
    }
    const float mm = fmaxf(l0, l1);
    const float e0 = __expf(l0 - mm), e1 = __expf(l1 - mm);
    const float invs = 1.f / (e0 + e1);
    out[b * 2 + 0] = e0 * invs;
    out[b * 2 + 1] = e1 * invs;
  }
}

// ===========================================================================
extern "C" void kernel_launch(void* const* d_in, const int* in_sizes, int n_in,
                              void* d_out, int out_size, void* d_ws, size_t ws_size,
                              hipStream_t stream) {
  const float* evaluation = (const float*)d_in[0];
  const float* templ      = (const float*)d_in[1];
  const float* e_w1 = (const float*)d_in[2];
  const float* e_b1 = (const float*)d_in[3];
  const float* e_w2 = (const float*)d_in[4];
  const float* e_b2 = (const float*)d_in[5];
  const float* e_w3 = (const float*)d_in[6];
  const float* e_b3 = (const float*)d_in[7];
  const float* el_w = (const float*)d_in[8];
  const float* el_b = (const float*)d_in[9];
  const float* eg_wih = (const float*)d_in[10];
  const float* eg_whh = (const float*)d_in[11];
  const float* eg_bih = (const float*)d_in[12];
  const float* eg_bhh = (const float*)d_in[13];
  const float* t_w1 = (const float*)d_in[14];
  const float* t_b1 = (const float*)d_in[15];
  const float* t_w2 = (const float*)d_in[16];
  const float* t_b2 = (const float*)d_in[17];
  const float* t_w3 = (const float*)d_in[18];
  const float* t_b3 = (const float*)d_in[19];
  const float* tl_w = (const float*)d_in[20];
  const float* tl_b = (const float*)d_in[21];
  const float* tg_wih = (const float*)d_in[22];
  const float* tg_whh = (const float*)d_in[23];
  const float* tg_bih = (const float*)d_in[24];
  const float* tg_bhh = (const float*)d_in[25];
  const float* a_w = (const float*)d_in[26];
  const float* a_b = (const float*)d_in[27];
  const float* h_w = (const float*)d_in[28];
  const float* h_b = (const float*)d_in[29];
  const float* c_w = (const float*)d_in[30];
  const float* c_b = (const float*)d_in[31];

  float* ws = (float*)d_ws;
  float* beff_e  = ws + OFF_BEFF_E;
  float* beff_t  = ws + OFF_BEFF_T;
  float* bias2_e = ws + OFF_BIAS2_E;
  float* bias2_t = ws + OFF_BIAS2_T;
  u16*   wbf_e   = (u16*)(ws + OFF_WBF_E);
  u16*   wbf_t   = (u16*)(ws + OFF_WBF_T);
  float* w12p_e  = ws + OFF_W12P_E;
  float* w12p_t  = ws + OFF_W12P_T;
  float* b12_e   = ws + OFF_B12_E;
  float* b12_t   = ws + OFF_B12_T;
  u16*   pool    = (u16*)(ws + OFF_POOL);
  float* gibuf   = ws + OFF_GI;
  float* Pbuf    = ws + OFF_P;
  float* PVbuf   = ws + OFF_PV;
  float* lin_e   = ws + OFF_LIN_E;
  float* lin_t   = ws + OFF_LIN_T;

  // weight composition chain (dense fixed-bound kernels) + folded gi biases
  compose12_kernel<<<dim3(32, 2), 320, 0, stream>>>(
      e_w1, e_b1, e_w2, e_b2, t_w1, t_b1, t_w2, t_b2, w12p_e, w12p_t, b12_e, b12_t);
  compose_weff_kernel<<<dim3(64, 2), 256, 0, stream>>>(
      e_w3, e_b3, t_w3, t_b3, w12p_e, w12p_t, b12_e, b12_t, wbf_e, wbf_t, beff_e, beff_t);
  gi_bias_kernel<<<2, 256, 0, stream>>>(eg_wih, eg_bih, el_b, bias2_e,
                                        tg_wih, tg_bih, tl_b, bias2_t);

  // zero lin_e + lin_t (contiguous) for split-K atomics
  hipMemsetAsync(lin_e, 0, (520192 + 262144) * sizeof(float), stream);

  // eval branch: MFMA conv+pool (bf16 out) -> split-K linear
  conv_pool_mfma_kernel<<<dim3(34, 58, 4), 256, 0, stream>>>(evaluation, wbf_e, beff_e, pool, 2048, 2032);
  gemm_splitk_kernel<<<dim3(127, 8), 256, 0, stream>>>(pool, el_w, lin_e);
  // template branch
  conv_pool_mfma_kernel<<<dim3(18, 58, 4), 256, 0, stream>>>(templ, wbf_t, beff_t, pool, 1040, 1024);
  gemm_splitk_kernel<<<dim3(64, 8), 256, 0, stream>>>(pool, tl_w, lin_t);

  // zero PV (lives in dead pool region; must follow last pool read)
  hipMemsetAsync(PVbuf, 0, 520192 * sizeof(float), stream);

  // GRU (scan over batch axis)
  gemm_nt_kernel<<<dim3(127, 3), 256, 0, stream>>>(lin_e, eg_wih, bias2_e, gibuf, 192, 64);
  gru_rec_kernel<<<127, 256, 0, stream>>>(lin_e, gibuf, eg_whh, eg_bhh, 2032);
  gemm_nt_kernel<<<dim3(64, 3), 256, 0, stream>>>(lin_t, tg_wih, bias2_t, gibuf, 192, 64);
  gru_rec_kernel<<<64, 256, 0, stream>>>(lin_t, gibuf, tg_whh, tg_bhh, 1024);

  // cross attention + head
  scores_kernel<<<dim3(16, 16, 4), 256, 0, stream>>>(lin_t, lin_e, Pbuf);
  softmax_rows_kernel<<<4096, 256, 0, stream>>>(Pbuf);
  pv_kernel<<<dim3(32, 4, 4), 256, 0, stream>>>(Pbuf, lin_t, PVbuf);
  head_kernel<<<4, 256, 0, stream>>>(lin_e, PVbuf, a_w, a_b, h_w, h_b, c_w, c_b,
                                     (float*)d_out);
}

// Round 6
// 703.736 us; speedup vs baseline: 4.4129x; 1.1653x over previous
//
#include <hip/hip_runtime.h>
#include <cmath>

// ============================================================================
// DeepTemplateMatchingModule on MI355X — round 6.
// R5 post-mortem: head_kernel was top dispatch at 152us — grid=4 blocks,
// occupancy 0.17%, VALU 0.07%: pure serial HBM latency (4 MB walked by 16
// waves). R6: head split into 4 stages with proper parallelism:
//   att_logits (128 blk, wave-per-row coalesced dot) -> att_softmax (4 blk,
//   LDS) -> red_reduce (64 blk, coalesced |PV-e|*att partials + one
//   64-float atomicAdd/blk) -> mlp (4 blk, trivial).
// red zero-init folded into the PV memset. Everything else unchanged.
// ============================================================================

typedef unsigned short u16;
typedef __attribute__((ext_vector_type(8))) short bf16x8;
typedef __attribute__((ext_vector_type(8))) unsigned short u16x8;
typedef __attribute__((ext_vector_type(16))) float f32x16;

__device__ __forceinline__ u16 f2bf(float f) {
  unsigned int x = __float_as_uint(f);
  return (u16)((x + 0x7fffu + ((x >> 16) & 1u)) >> 16);
}
__device__ __forceinline__ float bf2f(u16 v) {
  return __uint_as_float(((unsigned int)v) << 16);
}

// ---- workspace layout (float offsets) ----
static const size_t OFF_BEFF_E  = 0;          // 64
static const size_t OFF_BEFF_T  = 64;         // 64
static const size_t OFF_BIAS2_E = 128;        // 192
static const size_t OFF_BIAS2_T = 320;        // 192
static const size_t OFF_WBF_E   = 512;        // 7424 floats (14848 u16)
static const size_t OFF_WBF_T   = 7936;       // 7424
static const size_t OFF_W12P_E  = 15360;      // 9248 (32 x 17 x 17, padded)
static const size_t OFF_W12P_T  = 24608;      // 9248
static const size_t OFF_B12_E   = 33856;      // 32
static const size_t OFF_B12_T   = 33888;      // 32
static const size_t OFF_POOL    = 33920;      // u16! 30,171,136 u16 = 15,085,568 f
// reused inside dead pool region (pool dead after last split-K):
static const size_t OFF_GI      = OFF_POOL;                   // 1,560,576 f
static const size_t OFF_P       = OFF_POOL + 1560576;         // 8,323,072 f
static const size_t OFF_PV      = OFF_P + 8323072;            // 520,192 f
static const size_t OFF_RED     = OFF_PV + 520192;            // 256 f (with PV memset)
static const size_t OFF_LIN_E   = OFF_POOL + 15085568;        // 520,192 f
static const size_t OFF_LIN_T   = OFF_LIN_E + 520192;         // 262,144 f
static const size_t OFF_ATT     = OFF_LIN_T + 262144;         // 8,128 f (logits/att)

// ---------------------------------------------------------------------------
// compose12: w12pad[c12][17][17] = sum_c1 w2[c12,c1] conv w1[c1], zero-padded
// ---------------------------------------------------------------------------
__global__ __launch_bounds__(320) void compose12_kernel(
    const float* __restrict__ w1e, const float* __restrict__ b1e,
    const float* __restrict__ w2e, const float* __restrict__ b2e,
    const float* __restrict__ w1t, const float* __restrict__ b1t,
    const float* __restrict__ w2t, const float* __restrict__ b2t,
    float* __restrict__ w12p_e, float* __restrict__ w12p_t,
    float* __restrict__ b12o_e, float* __restrict__ b12o_t) {
  const int br = blockIdx.y;
  const float* w1 = br ? w1t : w1e;
  const float* b1 = br ? b1t : b1e;
  const float* w2 = br ? w2t : w2e;
  const float* b2 = br ? b2t : b2e;
  float* w12p = br ? w12p_t : w12p_e;
  float* b12o = br ? b12o_t : b12o_e;
  const int c12 = blockIdx.x;
  __shared__ float s_w1pad[16 * 169];
  __shared__ float s_w2c[400];
  __shared__ float s_b1[16];
  const int tid = threadIdx.x;
  for (int i = tid; i < 2704; i += 320) s_w1pad[i] = 0.f;
  if (tid < 16) s_b1[tid] = b1[tid];
  __syncthreads();
  for (int i = tid; i < 400; i += 320) {
    const int c1 = i / 25, r = (i % 25) / 5, cc = i % 5;
    s_w1pad[c1 * 169 + (r + 4) * 13 + (cc + 4)] = w1[i];
    s_w2c[i] = w2[c12 * 400 + i];
  }
  __syncthreads();
  if (tid < 289) {
    const int py = tid / 17, px = tid % 17;
    float v = 0.f;
    if (py >= 4 && py <= 12 && px >= 4 && px <= 12) {
      const int sy = py - 4, sx = px - 4;
      float accs[2] = {0.f, 0.f};
      for (int c1 = 0; c1 < 16; ++c1) {
        const float* w2p = s_w2c + c1 * 25;
        const float* w1p = s_w1pad + c1 * 169 + (sy + 4) * 13 + (sx + 4);
#pragma unroll
        for (int uy = 0; uy < 5; ++uy)
#pragma unroll
          for (int ux = 0; ux < 5; ++ux)
            accs[uy & 1] = fmaf(w2p[uy * 5 + ux], w1p[-(uy * 13) - ux], accs[uy & 1]);
      }
      v = accs[0] + accs[1];
    }
    w12p[c12 * 289 + tid] = v;
  } else if (tid == 300) {
    float acc = b2[c12];
    for (int c1 = 0; c1 < 16; ++c1) {
      float sw = 0.f;
      for (int u = 0; u < 25; ++u) sw += s_w2c[c1 * 25 + u];
      acc = fmaf(sw, s_b1[c1], acc);
    }
    b12o[c12] = acc;
  }
}

// ---------------------------------------------------------------------------
// compose_weff: weff bf16 padded [o][13][16] stride 232 u16; beff fp32.
// ---------------------------------------------------------------------------
__global__ __launch_bounds__(256) void compose_weff_kernel(
    const float* __restrict__ w3e, const float* __restrict__ b3e,
    const float* __restrict__ w3t, const float* __restrict__ b3t,
    const float* __restrict__ w12p_e, const float* __restrict__ w12p_t,
    const float* __restrict__ b12_e, const float* __restrict__ b12_t,
    u16* __restrict__ wbf_e, u16* __restrict__ wbf_t,
    float* __restrict__ beff_e, float* __restrict__ beff_t) {
  const int br = blockIdx.y;
  const float* w3 = br ? w3t : w3e;
  const float* b3 = br ? b3t : b3e;
  const float* w12p = br ? w12p_t : w12p_e;
  const float* b12 = br ? b12_t : b12_e;
  u16* weffp = br ? wbf_t : wbf_e;
  float* beff = br ? beff_t : beff_e;
  const int o = blockIdx.x;
  __shared__ float s_pad[32 * 289];
  __shared__ float s_w3o[800];
  __shared__ float s_b12[32];
  const int tid = threadIdx.x;
  for (int i = tid; i < 9248; i += 256) s_pad[i] = w12p[i];
  for (int i = tid; i < 800; i += 256) s_w3o[i] = w3[o * 800 + i];
  if (tid < 32) s_b12[tid] = b12[tid];
  __syncthreads();
  if (tid < 169) {
    const int sy = tid / 13, sx = tid % 13;
    float accs[4] = {0.f, 0.f, 0.f, 0.f};
#pragma unroll 4
    for (int c = 0; c < 32; ++c) {
      const float* w3p = s_w3o + c * 25;
      const float* wp = s_pad + c * 289 + (sy + 4) * 17 + (sx + 4);
#pragma unroll
      for (int uy = 0; uy < 5; ++uy)
#pragma unroll
        for (int ux = 0; ux < 5; ++ux)
          accs[c & 3] = fmaf(w3p[uy * 5 + ux], wp[-(uy * 17) - ux], accs[c & 3]);
    }
    weffp[o * 232 + sy * 16 + sx] = f2bf(accs[0] + accs[1] + accs[2] + accs[3]);
  } else if (tid < 208) {
    const int p = tid - 169;
    weffp[o * 232 + (p / 3) * 16 + 13 + (p % 3)] = 0;
  } else if (tid == 208) {
    float acc = b3[o];
    for (int c = 0; c < 32; ++c) {
      float sw = 0.f;
      for (int u = 0; u < 25; ++u) sw += s_w3o[c * 25 + u];
      acc = fmaf(sw, s_b12[c], acc);
    }
    beff[o] = acc;
  }
}

// ---------------------------------------------------------------------------
// bias2[j] = b_ih[j] + sum_d w_ih[j,d]*lb[d]; grid 2 (branch select).
// ---------------------------------------------------------------------------
__global__ __launch_bounds__(256) void gi_bias_kernel(
    const float* __restrict__ wih_e, const float* __restrict__ bih_e,
    const float* __restrict__ lb_e, float* __restrict__ bias2_e,
    const float* __restrict__ wih_t, const float* __restrict__ bih_t,
    const float* __restrict__ lb_t, float* __restrict__ bias2_t) {
  const int br = blockIdx.x;
  const float* wih = br ? wih_t : wih_e;
  const float* bih = br ? bih_t : bih_e;
  const float* lb = br ? lb_t : lb_e;
  float* bias2 = br ? bias2_t : bias2_e;
  __shared__ float s_lb[64];
  const int tid = threadIdx.x;
  if (tid < 64) s_lb[tid] = lb[tid];
  __syncthreads();
  if (tid < 192) {
    float acc = bih[tid];
    const float* wr = wih + tid * 64;
    for (int d = 0; d < 64; ++d) acc = fmaf(wr[d], s_lb[d], acc);
    bias2[tid] = acc;
  }
}

// ---------------------------------------------------------------------------
// MFMA conv13x13 + maxpool(2,5)/(2,1); pooled stored as bf16.
// ---------------------------------------------------------------------------
__global__ __launch_bounds__(256, 2) void conv_pool_mfma_kernel(
    const float* __restrict__ x, const u16* __restrict__ weffp,
    const float* __restrict__ beff, u16* __restrict__ pooled,
    const int W, const int T) {
  __shared__ __align__(16) char s_union[45248];
  __shared__ __align__(16) char s_wreg[29696];
  u16* s_x = (u16*)s_union;
  u16* s_im = (u16*)(s_union + 2240);
  float* s_out = (float*)s_union;
  u16* s_w = (u16*)s_wreg;
  float* s_pool = (float*)s_wreg;

  const int tid = threadIdx.x;
  const int lane = tid & 63, wave = tid >> 6;
  const int cb = blockIdx.x * 60;
  const int h = blockIdx.y, b = blockIdx.z;

  for (int i = tid; i < 1856; i += 256)
    ((uint4*)s_w)[i] = ((const uint4*)weffp)[i];
  {
    const float* xb = x + ((size_t)b * 128 + 2 * h) * W;
    for (int i = tid; i < 14 * 80; i += 256) {
      const int r = i / 80, cq = i - r * 80;
      int gc = cb + cq;
      if (gc > W - 1) gc = W - 1;
      s_x[i] = f2bf(xb[(size_t)r * W + gc]);
    }
  }
  __syncthreads();
  for (int p = tid; p < 896; p += 256) {
    const int ky = p >> 6, col = p & 63;
    const u16* src = s_x + ky * 80 + col;
    u16x8 v0, v1;
#pragma unroll
    for (int j = 0; j < 8; ++j) { v0[j] = src[j]; v1[j] = src[8 + j]; }
    u16* dst = s_im + (ky * 64 + col) * 24;
    *(u16x8*)dst = v0;
    *(u16x8*)(dst + 8) = v1;
  }
  __syncthreads();
  const int rsel = wave & 1, cm = (wave >> 1) * 32;
  const int l31 = lane & 31, g8 = (lane >> 5) * 8;
  f32x16 acc0 = {}, acc1 = {};
  const u16* aw = s_w + (cm + l31) * 232 + g8;
  const u16* bw = s_im + (rsel * 64 + l31) * 24 + g8;
#pragma unroll
  for (int ky = 0; ky < 13; ++ky) {
    bf16x8 a = *(const bf16x8*)(aw + ky * 16);
    bf16x8 b0 = *(const bf16x8*)(bw + ky * 64 * 24);
    bf16x8 b1 = *(const bf16x8*)(bw + ky * 64 * 24 + 32 * 24);
    acc0 = __builtin_amdgcn_mfma_f32_32x32x16_bf16(a, b0, acc0, 0, 0, 0);
    acc1 = __builtin_amdgcn_mfma_f32_32x32x16_bf16(a, b1, acc1, 0, 0, 0);
  }
  __syncthreads();
#pragma unroll
  for (int r = 0; r < 16; ++r) {
    const int c = cm + (r & 3) + 8 * (r >> 2) + (g8 >> 1);
    float* o = s_out + (rsel * 64 + c) * 65;
    o[l31] = acc0[r];
    o[32 + l31] = acc1[r];
  }
  __syncthreads();
  {
    const int pc = tid & 63, tg = tid >> 6;
    const int t0 = tg * 15;
    const float bias = beff[pc];
    const float* r0p = s_out + pc * 65 + t0;
    const float* r1p = s_out + (64 + pc) * 65 + t0;
    float w0[19], w1[19];
#pragma unroll
    for (int j = 0; j < 19; ++j) { w0[j] = r0p[j]; w1[j] = r1p[j]; }
#pragma unroll
    for (int i = 0; i < 15; ++i) {
      float m = w0[i];
#pragma unroll
      for (int k = 1; k < 5; ++k) m = fmaxf(m, w0[i + k]);
#pragma unroll
      for (int k = 0; k < 5; ++k) m = fmaxf(m, w1[i + k]);
      s_pool[pc * 61 + t0 + i] = m + bias;
    }
  }
  __syncthreads();
  for (int i = tid; i < 3840; i += 256) {
    const int c = i / 60, t = i - c * 60;
    const int gt = cb + t;
    if (gt < T)
      pooled[(((size_t)b * 64 + c) * 58 + h) * T + gt] = f2bf(s_pool[c * 61 + t]);
  }
}

// ---------------------------------------------------------------------------
// Split-K GEMM (bf16 pool @ fp32 lw^T), N=64; atomicAdd into zero-init out.
// ---------------------------------------------------------------------------
__global__ __launch_bounds__(256) void gemm_splitk_kernel(
    const u16* __restrict__ A, const float* __restrict__ Wt,
    float* __restrict__ out) {
  __shared__ __align__(16) float sA[64 * 33];
  __shared__ __align__(16) float sB[64 * 33];
  const int tid = threadIdx.x;
  const int r0 = blockIdx.x * 64;
  const int s = blockIdx.y;
  const int c0 = (s * 116) / 8, c1 = ((s + 1) * 116) / 8;
  const int ty = tid >> 4, tx = tid & 15;
  float acc[4][4] = {};
  for (int ch = c0; ch < c1; ++ch) {
    const int kc = ch * 32;
    __syncthreads();
    {
      const int row = tid >> 2, seg = tid & 3;
      const u16x8 va = *(const u16x8*)&A[(size_t)(r0 + row) * 3712 + kc + seg * 8];
#pragma unroll
      for (int j = 0; j < 8; ++j) sA[row * 33 + seg * 8 + j] = bf2f(va[j]);
    }
#pragma unroll
    for (int r = 0; r < 2; ++r) {
      const int q = tid + r * 256;
      const int row = q >> 3, qq = q & 7;
      const float4 vb = *(const float4*)&Wt[(size_t)row * 3712 + kc + qq * 4];
      sB[row * 33 + qq * 4 + 0] = vb.x; sB[row * 33 + qq * 4 + 1] = vb.y;
      sB[row * 33 + qq * 4 + 2] = vb.z; sB[row * 33 + qq * 4 + 3] = vb.w;
    }
    __syncthreads();
#pragma unroll 8
    for (int kk = 0; kk < 32; ++kk) {
      const float a0 = sA[(ty * 4 + 0) * 33 + kk];
      const float a1 = sA[(ty * 4 + 1) * 33 + kk];
      const float a2 = sA[(ty * 4 + 2) * 33 + kk];
      const float a3 = sA[(ty * 4 + 3) * 33 + kk];
      const float b0 = sB[(tx * 4 + 0) * 33 + kk];
      const float b1 = sB[(tx * 4 + 1) * 33 + kk];
      const float b2 = sB[(tx * 4 + 2) * 33 + kk];
      const float b3 = sB[(tx * 4 + 3) * 33 + kk];
      acc[0][0] = fmaf(a0, b0, acc[0][0]); acc[0][1] = fmaf(a0, b1, acc[0][1]);
      acc[0][2] = fmaf(a0, b2, acc[0][2]); acc[0][3] = fmaf(a0, b3, acc[0][3]);
      acc[1][0] = fmaf(a1, b0, acc[1][0]); acc[1][1] = fmaf(a1, b1, acc[1][1]);
      acc[1][2] = fmaf(a1, b2, acc[1][2]); acc[1][3] = fmaf(a1, b3, acc[1][3]);
      acc[2][0] = fmaf(a2, b0, acc[2][0]); acc[2][1] = fmaf(a2, b1, acc[2][1]);
      acc[2][2] = fmaf(a2, b2, acc[2][2]); acc[2][3] = fmaf(a2, b3, acc[2][3]);
      acc[3][0] = fmaf(a3, b0, acc[3][0]); acc[3][1] = fmaf(a3, b1, acc[3][1]);
      acc[3][2] = fmaf(a3, b2, acc[3][2]); acc[3][3] = fmaf(a3, b3, acc[3][3]);
    }
  }
#pragma unroll
  for (int i = 0; i < 4; ++i)
#pragma unroll
    for (int j = 0; j < 4; ++j)
      atomicAdd(&out[(size_t)(r0 + ty * 4 + i) * 64 + tx * 4 + j], acc[i][j]);
}

// ---------------------------------------------------------------------------
// Generic fp32 GEMM (gi = lin @ w_ih^T + bias2). K multiple of 32.
// ---------------------------------------------------------------------------
__global__ __launch_bounds__(256) void gemm_nt_kernel(
    const float* __restrict__ A, const float* __restrict__ Wt,
    const float* __restrict__ bias, float* __restrict__ out,
    const int N, const int K) {
  __shared__ float sA[64 * 33];
  __shared__ float sB[64 * 33];
  const int tid = threadIdx.x;
  const int r0 = blockIdx.x * 64;
  const int n0 = blockIdx.y * 64;
  const int ty = tid >> 4, tx = tid & 15;
  float acc[4][4] = {};
  for (int kc = 0; kc < K; kc += 32) {
    __syncthreads();
#pragma unroll
    for (int rep = 0; rep < 8; ++rep) {
      const int l = tid + rep * 256;
      const int row = l >> 5, kk = l & 31;
      sA[row * 33 + kk] = A[(size_t)(r0 + row) * K + kc + kk];
      sB[row * 33 + kk] = Wt[(size_t)(n0 + row) * K + kc + kk];
    }
    __syncthreads();
#pragma unroll 8
    for (int kk = 0; kk < 32; ++kk) {
      const float a0 = sA[(ty * 4 + 0) * 33 + kk];
      const float a1 = sA[(ty * 4 + 1) * 33 + kk];
      const float a2 = sA[(ty * 4 + 2) * 33 + kk];
      const float a3 = sA[(ty * 4 + 3) * 33 + kk];
      const float b0 = sB[(tx * 4 + 0) * 33 + kk];
      const float b1 = sB[(tx * 4 + 1) * 33 + kk];
      const float b2 = sB[(tx * 4 + 2) * 33 + kk];
      const float b3 = sB[(tx * 4 + 3) * 33 + kk];
      acc[0][0] = fmaf(a0, b0, acc[0][0]); acc[0][1] = fmaf(a0, b1, acc[0][1]);
      acc[0][2] = fmaf(a0, b2, acc[0][2]); acc[0][3] = fmaf(a0, b3, acc[0][3]);
      acc[1][0] = fmaf(a1, b0, acc[1][0]); acc[1][1] = fmaf(a1, b1, acc[1][1]);
      acc[1][2] = fmaf(a1, b2, acc[1][2]); acc[1][3] = fmaf(a1, b3, acc[1][3]);
      acc[2][0] = fmaf(a2, b0, acc[2][0]); acc[2][1] = fmaf(a2, b1, acc[2][1]);
      acc[2][2] = fmaf(a2, b2, acc[2][2]); acc[2][3] = fmaf(a2, b3, acc[2][3]);
      acc[3][0] = fmaf(a3, b0, acc[3][0]); acc[3][1] = fmaf(a3, b1, acc[3][1]);
      acc[3][2] = fmaf(a3, b2, acc[3][2]); acc[3][3] = fmaf(a3, b3, acc[3][3]);
    }
  }
#pragma unroll
  for (int i = 0; i < 4; ++i)
#pragma unroll
    for (int j = 0; j < 4; ++j)
      out[(size_t)(r0 + ty * 4 + i) * N + n0 + tx * 4 + j] =
          acc[i][j] + bias[n0 + tx * 4 + j];
}

// ---------------------------------------------------------------------------
// GRU recurrence (scan over BATCH axis, 4 steps; every t independent).
// ---------------------------------------------------------------------------
__global__ __launch_bounds__(256) void gru_rec_kernel(
    float* __restrict__ xy, const float* __restrict__ gi,
    const float* __restrict__ whh, const float* __restrict__ bhh, const int T) {
  __shared__ float s_whh_t[64 * 192];
  __shared__ float s_h[16][64];
  const int tid = threadIdx.x;
  const int lane = tid & 63, wave = tid >> 6;
  for (int i = tid; i < 192 * 64; i += 256) {
    const int j = i >> 6, d = i & 63;
    s_whh_t[d * 192 + j] = whh[i];
  }
  for (int i = tid; i < 16 * 64; i += 256) (&s_h[0][0])[i] = 0.f;
  const float bhr = bhh[lane], bhz = bhh[64 + lane], bhn = bhh[128 + lane];
  const int t0 = blockIdx.x * 16;
  __syncthreads();
  for (int b = 0; b < 4; ++b) {
    float gir[4], giz[4], gin[4];
#pragma unroll
    for (int sl = 0; sl < 4; ++sl) {
      int t = t0 + wave * 4 + sl; if (t > T - 1) t = T - 1;
      const float* girow = gi + ((size_t)b * T + t) * 192;
      gir[sl] = girow[lane]; giz[sl] = girow[64 + lane]; gin[sl] = girow[128 + lane];
    }
    float ahr[4] = {}, ahz[4] = {}, ahn[4] = {};
    for (int d = 0; d < 64; ++d) {
      const float wr_ = s_whh_t[d * 192 + lane];
      const float wz_ = s_whh_t[d * 192 + 64 + lane];
      const float wn_ = s_whh_t[d * 192 + 128 + lane];
#pragma unroll
      for (int sl = 0; sl < 4; ++sl) {
        const float hv = s_h[wave * 4 + sl][d];
        ahr[sl] = fmaf(wr_, hv, ahr[sl]);
        ahz[sl] = fmaf(wz_, hv, ahz[sl]);
        ahn[sl] = fmaf(wn_, hv, ahn[sl]);
      }
    }
    float hn[4];
#pragma unroll
    for (int sl = 0; sl < 4; ++sl) {
      const float r = 1.f / (1.f + __expf(-(gir[sl] + ahr[sl] + bhr)));
      const float z = 1.f / (1.f + __expf(-(giz[sl] + ahz[sl] + bhz)));
      const float n = tanhf(gin[sl] + r * (ahn[sl] + bhn));
      hn[sl] = (1.f - z) * n + z * s_h[wave * 4 + sl][lane];
    }
    __syncthreads();
#pragma unroll
    for (int sl = 0; sl < 4; ++sl) {
      const int t = t0 + wave * 4 + sl;
      s_h[wave * 4 + sl][lane] = hn[sl];
      if (t < T) xy[((size_t)b * T + t) * 64 + lane] = hn[sl];
    }
    __syncthreads();
  }
}

// ---------------------------------------------------------------------------
// scores: P[b,tau,eps] = sum_d t[b,tau,d]*e[b,eps,d]. grid (16,16,4), K=64.
// ---------------------------------------------------------------------------
__global__ __launch_bounds__(256) void scores_kernel(
    const float* __restrict__ tmat, const float* __restrict__ emat,
    float* __restrict__ P) {
  __shared__ __align__(16) float sT[64 * 68];
  __shared__ __align__(16) float sE[128 * 68];
  const int tid = threadIdx.x;
  const int b = blockIdx.z;
  const int tau0 = blockIdx.x * 64;
  const int e0 = blockIdx.y * 128;
#pragma unroll
  for (int r = 0; r < 4; ++r) {
    const int q = tid + r * 256;
    const int row = q >> 4, qq = q & 15;
    const float4 v = *(const float4*)&tmat[((size_t)b * 1024 + tau0 + row) * 64 + qq * 4];
    *(float4*)&sT[row * 68 + qq * 4] = v;
  }
#pragma unroll
  for (int r = 0; r < 8; ++r) {
    const int q = tid + r * 256;
    const int row = q >> 4, qq = q & 15;
    int eps = e0 + row; if (eps > 2031) eps = 2031;
    const float4 v = *(const float4*)&emat[((size_t)b * 2032 + eps) * 64 + qq * 4];
    *(float4*)&sE[row * 68 + qq * 4] = v;
  }
  __syncthreads();
  const int ty = tid >> 4, tx = tid & 15;
  float acc[4][8] = {};
#pragma unroll 4
  for (int q = 0; q < 16; ++q) {
    const int kk = q * 4;
    float4 av[4], bv[8];
#pragma unroll
    for (int i = 0; i < 4; ++i) av[i] = *(const float4*)&sT[(ty * 4 + i) * 68 + kk];
#pragma unroll
    for (int j = 0; j < 8; ++j) bv[j] = *(const float4*)&sE[(tx * 8 + j) * 68 + kk];
#pragma unroll
    for (int i = 0; i < 4; ++i)
#pragma unroll
      for (int j = 0; j < 8; ++j) {
        acc[i][j] = fmaf(av[i].x, bv[j].x, acc[i][j]);
        acc[i][j] = fmaf(av[i].y, bv[j].y, acc[i][j]);
        acc[i][j] = fmaf(av[i].z, bv[j].z, acc[i][j]);
        acc[i][j] = fmaf(av[i].w, bv[j].w, acc[i][j]);
      }
  }
#pragma unroll
  for (int i = 0; i < 4; ++i) {
    const size_t prow = ((size_t)b * 1024 + tau0 + ty * 4 + i) * 2032;
#pragma unroll
    for (int j = 0; j < 8; ++j) {
      const int eps = e0 + tx * 8 + j;
      if (eps < 2032) P[prow + eps] = acc[i][j];
    }
  }
}

// ---------------------------------------------------------------------------
// row softmax over eps (rows of length 2032), row cached in LDS. grid 4096.
// ---------------------------------------------------------------------------
__global__ __launch_bounds__(256) void softmax_rows_kernel(float* __restrict__ P) {
  __shared__ float s_row[2032];
  __shared__ float sred[4];
  float* r = P + (size_t)blockIdx.x * 2032;
  const int tid = threadIdx.x;
  const int lane = tid & 63, wave = tid >> 6;
  float m = -3.4e38f;
  for (int i = tid; i < 2032; i += 256) {
    const float v = r[i];
    s_row[i] = v;
    m = fmaxf(m, v);
  }
#pragma unroll
  for (int off = 32; off > 0; off >>= 1) m = fmaxf(m, __shfl_down(m, off, 64));
  if (lane == 0) sred[wave] = m;
  __syncthreads();
  m = fmaxf(fmaxf(sred[0], sred[1]), fmaxf(sred[2], sred[3]));
  __syncthreads();
  float s = 0.f;
  float vals[8];
  int cnt = 0;
  for (int i = tid; i < 2032; i += 256) {
    const float v = __expf(s_row[i] - m);
    vals[cnt++] = v;
    s += v;
  }
#pragma unroll
  for (int off = 32; off > 0; off >>= 1) s += __shfl_down(s, off, 64);
  if (lane == 0) sred[wave] = s;
  __syncthreads();
  const float inv = 1.f / (sred[0] + sred[1] + sred[2] + sred[3]);
  cnt = 0;
  for (int i = tid; i < 2032; i += 256) r[i] = vals[cnt++] * inv;
}

// ---------------------------------------------------------------------------
// pv partial: PV[b,eps,d] += sum_{tau slice} P[b,tau,eps]*t[b,tau,d]
// ---------------------------------------------------------------------------
__global__ __launch_bounds__(256) void pv_kernel(
    const float* __restrict__ P, const float* __restrict__ tmat,
    float* __restrict__ PV) {
  __shared__ float sP[32 * 65];
  __shared__ float sT[32 * 65];
  const int tid = threadIdx.x;
  const int b = blockIdx.z;
  const int e0 = blockIdx.x * 64;
  const int tau_base = blockIdx.y * 256;
  const int ty = tid >> 4, tx = tid & 15;
  float acc[4][4] = {};
  for (int kc = tau_base; kc < tau_base + 256; kc += 32) {
    __syncthreads();
    for (int l = tid; l < 32 * 64; l += 256) {
      const int kk = l >> 6, j = l & 63;
      int eps = e0 + j; if (eps > 2031) eps = 2031;
      sP[kk * 65 + j] = P[((size_t)b * 1024 + kc + kk) * 2032 + eps];
      sT[kk * 65 + j] = tmat[((size_t)b * 1024 + kc + kk) * 64 + j];
    }
    __syncthreads();
#pragma unroll 8
    for (int kk = 0; kk < 32; ++kk) {
      const float a0 = sP[kk * 65 + ty * 4 + 0];
      const float a1 = sP[kk * 65 + ty * 4 + 1];
      const float a2 = sP[kk * 65 + ty * 4 + 2];
      const float a3 = sP[kk * 65 + ty * 4 + 3];
      const float b0 = sT[kk * 65 + tx * 4 + 0];
      const float b1 = sT[kk * 65 + tx * 4 + 1];
      const float b2 = sT[kk * 65 + tx * 4 + 2];
      const float b3 = sT[kk * 65 + tx * 4 + 3];
      acc[0][0] = fmaf(a0, b0, acc[0][0]); acc[0][1] = fmaf(a0, b1, acc[0][1]);
      acc[0][2] = fmaf(a0, b2, acc[0][2]); acc[0][3] = fmaf(a0, b3, acc[0][3]);
      acc[1][0] = fmaf(a1, b0, acc[1][0]); acc[1][1] = fmaf(a1, b1, acc[1][1]);
      acc[1][2] = fmaf(a1, b2, acc[1][2]); acc[1][3] = fmaf(a1, b3, acc[1][3]);
      acc[2][0] = fmaf(a2, b0, acc[2][0]); acc[2][1] = fmaf(a2, b1, acc[2][1]);
      acc[2][2] = fmaf(a2, b2, acc[2][2]); acc[2][3] = fmaf(a2, b3, acc[2][3]);
      acc[3][0] = fmaf(a3, b0, acc[3][0]); acc[3][1] = fmaf(a3, b1, acc[3][1]);
      acc[3][2] = fmaf(a3, b2, acc[3][2]); acc[3][3] = fmaf(a3, b3, acc[3][3]);
    }
  }
#pragma unroll
  for (int i = 0; i < 4; ++i) {
    const int eps = e0 + ty * 4 + i;
    if (eps < 2032) {
#pragma unroll
      for (int j = 0; j < 4; ++j)
        atomicAdd(&PV[((size_t)b * 2032 + eps) * 64 + tx * 4 + j], acc[i][j]);
    }
  }
}

// ---------------------------------------------------------------------------
// att_logits: logits[b,i] = dot(e[b,i,:], a_w) + a_b. grid (32, 4); one wave
// per row (coalesced 64-lane read + 6-shuffle reduce), 16 rows/wave.
// ---------------------------------------------------------------------------
__global__ __launch_bounds__(256) void att_logits_kernel(
    const float* __restrict__ emat, const float* __restrict__ a_w,
    const float* __restrict__ a_b, float* __restrict__ logits) {
  __shared__ float s_aw[64];
  const int tid = threadIdx.x;
  const int lane = tid & 63, wave = tid >> 6;
  if (tid < 64) s_aw[tid] = a_w[tid];
  __syncthreads();
  const int b = blockIdx.y;
  const float ab = a_b[0];
  const int base = blockIdx.x * 64 + wave * 16;
#pragma unroll 4
  for (int r = 0; r < 16; ++r) {
    const int i = base + r;
    if (i < 2032) {
      float v = emat[((size_t)b * 2032 + i) * 64 + lane] * s_aw[lane];
#pragma unroll
      for (int off = 32; off > 0; off >>= 1) v += __shfl_down(v, off, 64);
      if (lane == 0) logits[b * 2032 + i] = v + ab;
    }
  }
}

// ---------------------------------------------------------------------------
// att_softmax: in-place softmax over 2032 logits per batch. grid 4.
// ---------------------------------------------------------------------------
__global__ __launch_bounds__(256) void att_softmax_kernel(float* __restrict__ att) {
  __shared__ float s_v[2032];
  __shared__ float sred[4];
  float* r = att + (size_t)blockIdx.x * 2032;
  const int tid = threadIdx.x;
  const int lane = tid & 63, wave = tid >> 6;
  float m = -3.4e38f;
  for (int i = tid; i < 2032; i += 256) {
    const float v = r[i];
    s_v[i] = v;
    m = fmaxf(m, v);
  }
#pragma unroll
  for (int off = 32; off > 0; off >>= 1) m = fmaxf(m, __shfl_down(m, off, 64));
  if (lane == 0) sred[wave] = m;
  __syncthreads();
  m = fmaxf(fmaxf(sred[0], sred[1]), fmaxf(sred[2], sred[3]));
  __syncthreads();
  float s = 0.f;
  float vals[8];
  int cnt = 0;
  for (int i = tid; i < 2032; i += 256) {
    const float v = __expf(s_v[i] - m);
    vals[cnt++] = v;
    s += v;
  }
#pragma unroll
  for (int off = 32; off > 0; off >>= 1) s += __shfl_down(s, off, 64);
  if (lane == 0) sred[wave] = s;
  __syncthreads();
  const float inv = 1.f / (sred[0] + sred[1] + sred[2] + sred[3]);
  cnt = 0;
  for (int i = tid; i < 2032; i += 256) r[i] = vals[cnt++] * inv;
}

// ---------------------------------------------------------------------------
// red_reduce: red[b,d] += sum_{i in slice} |PV-e|[b,i,d] * att[b,i].
// grid (16 slices, 4 b); lane=d coalesced; one 64-float atomicAdd per block.
// ---------------------------------------------------------------------------
__global__ __launch_bounds__(256) void red_reduce_kernel(
    const float* __restrict__ emat, const float* __restrict__ PV,
    const float* __restrict__ att, float* __restrict__ red) {
  __shared__ float s_part[4][64];
  const int tid = threadIdx.x;
  const int lane = tid & 63, wave = tid >> 6;
  const int b = blockIdx.y;
  const int i0 = blockIdx.x * 127;
  float acc = 0.f;
  for (int i = i0 + wave; i < i0 + 127; i += 4) {
    const size_t idx = ((size_t)b * 2032 + i) * 64 + lane;
    acc = fmaf(fabsf(PV[idx] - emat[idx]), att[b * 2032 + i], acc);
  }
  s_part[wave][lane] = acc;
  __syncthreads();
  if (tid < 64)
    atomicAdd(&red[b * 64 + tid],
              s_part[0][tid] + s_part[1][tid] + s_part[2][tid] + s_part[3][tid]);
}

// ---------------------------------------------------------------------------
// mlp: h = relu(red@h_w^T + h_b); out = softmax(h@c_w^T + c_b). grid 4.
// ---------------------------------------------------------------------------
__global__ __launch_bounds__(128) void mlp_kernel(
    const float* __restrict__ red, const float* __restrict__ h_w,
    const float* __restrict__ h_b, const float* __restrict__ c_w,
    const float* __restrict__ c_b, float* __restrict__ out) {
  __shared__ float s_red[64];
  __shared__ float s_hv[128];
  const int tid = threadIdx.x;
  const int b = blockIdx.x;
  if (tid < 64) s_red[tid] = red[b * 64 + tid];
  __syncthreads();
  {
    float acc = h_b[tid];
    const float* hw = h_w + tid * 64;
    for (int d = 0; d < 64; ++d) acc = fmaf(s_red[d], hw[d], acc);
    s_hv[tid] = fmaxf(acc, 0.f);
  }
  __syncthreads();
  if (tid == 0) {
    float l0 = c_b[0], l1 = c_b[1];
    for (int j = 0; j < 128; ++j) {
      l0 = fmaf(s_hv[j], c_w[j], l0);
      l1 = fmaf(s_hv[j], c_w[128 + j], l1);
    }
    const float mm = fmaxf(l0, l1);
    const float e0 = __expf(l0 - mm), e1 = __expf(l1 - mm);
    const float invs = 1.f / (e0 + e1);
    out[b * 2 + 0] = e0 * invs;
    out[b * 2 + 1] = e1 * invs;
  }
}

// ===========================================================================
extern "C" void kernel_launch(void* const* d_in, const int* in_sizes, int n_in,
                              void* d_out, int out_size, void* d_ws, size_t ws_size,
                              hipStream_t stream) {
  const float* evaluation = (const float*)d_in[0];
  const float* templ      = (const float*)d_in[1];
  const float* e_w1 = (const float*)d_in[2];
  const float* e_b1 = (const float*)d_in[3];
  const float* e_w2 = (const float*)d_in[4];
  const float* e_b2 = (const float*)d_in[5];
  const float* e_w3 = (const float*)d_in[6];
  const float* e_b3 = (const float*)d_in[7];
  const float* el_w = (const float*)d_in[8];
  const float* el_b = (const float*)d_in[9];
  const float* eg_wih = (const float*)d_in[10];
  const float* eg_whh = (const float*)d_in[11];
  const float* eg_bih = (const float*)d_in[12];
  const float* eg_bhh = (const float*)d_in[13];
  const float* t_w1 = (const float*)d_in[14];
  const float* t_b1 = (const float*)d_in[15];
  const float* t_w2 = (const float*)d_in[16];
  const float* t_b2 = (const float*)d_in[17];
  const float* t_w3 = (const float*)d_in[18];
  const float* t_b3 = (const float*)d_in[19];
  const float* tl_w = (const float*)d_in[20];
  const float* tl_b = (const float*)d_in[21];
  const float* tg_wih = (const float*)d_in[22];
  const float* tg_whh = (const float*)d_in[23];
  const float* tg_bih = (const float*)d_in[24];
  const float* tg_bhh = (const float*)d_in[25];
  const float* a_w = (const float*)d_in[26];
  const float* a_b = (const float*)d_in[27];
  const float* h_w = (const float*)d_in[28];
  const float* h_b = (const float*)d_in[29];
  const float* c_w = (const float*)d_in[30];
  const float* c_b = (const float*)d_in[31];

  float* ws = (float*)d_ws;
  float* beff_e  = ws + OFF_BEFF_E;
  float* beff_t  = ws + OFF_BEFF_T;
  float* bias2_e = ws + OFF_BIAS2_E;
  float* bias2_t = ws + OFF_BIAS2_T;
  u16*   wbf_e   = (u16*)(ws + OFF_WBF_E);
  u16*   wbf_t   = (u16*)(ws + OFF_WBF_T);
  float* w12p_e  = ws + OFF_W12P_E;
  float* w12p_t  = ws + OFF_W12P_T;
  float* b12_e   = ws + OFF_B12_E;
  float* b12_t   = ws + OFF_B12_T;
  u16*   pool    = (u16*)(ws + OFF_POOL);
  float* gibuf   = ws + OFF_GI;
  float* Pbuf    = ws + OFF_P;
  float* PVbuf   = ws + OFF_PV;
  float* redbuf  = ws + OFF_RED;
  float* lin_e   = ws + OFF_LIN_E;
  float* lin_t   = ws + OFF_LIN_T;
  float* attbuf  = ws + OFF_ATT;

  // weight composition chain + folded gi biases
  compose12_kernel<<<dim3(32, 2), 320, 0, stream>>>(
      e_w1, e_b1, e_w2, e_b2, t_w1, t_b1, t_w2, t_b2, w12p_e, w12p_t, b12_e, b12_t);
  compose_weff_kernel<<<dim3(64, 2), 256, 0, stream>>>(
      e_w3, e_b3, t_w3, t_b3, w12p_e, w12p_t, b12_e, b12_t, wbf_e, wbf_t, beff_e, beff_t);
  gi_bias_kernel<<<2, 256, 0, stream>>>(eg_wih, eg_bih, el_b, bias2_e,
                                        tg_wih, tg_bih, tl_b, bias2_t);

  // zero lin_e + lin_t (contiguous) for split-K atomics
  hipMemsetAsync(lin_e, 0, (520192 + 262144) * sizeof(float), stream);

  // eval branch: MFMA conv+pool (bf16 out) -> split-K linear
  conv_pool_mfma_kernel<<<dim3(34, 58, 4), 256, 0, stream>>>(evaluation, wbf_e, beff_e, pool, 2048, 2032);
  gemm_splitk_kernel<<<dim3(127, 8), 256, 0, stream>>>(pool, el_w, lin_e);
  // template branch
  conv_pool_mfma_kernel<<<dim3(18, 58, 4), 256, 0, stream>>>(templ, wbf_t, beff_t, pool, 1040, 1024);
  gemm_splitk_kernel<<<dim3(64, 8), 256, 0, stream>>>(pool, tl_w, lin_t);

  // zero PV + red (contiguous; lives in dead pool region, after last pool read)
  hipMemsetAsync(PVbuf, 0, (520192 + 256) * sizeof(float), stream);

  // GRU (scan over batch axis)
  gemm_nt_kernel<<<dim3(127, 3), 256, 0, stream>>>(lin_e, eg_wih, bias2_e, gibuf, 192, 64);
  gru_rec_kernel<<<127, 256, 0, stream>>>(lin_e, gibuf, eg_whh, eg_bhh, 2032);
  gemm_nt_kernel<<<dim3(64, 3), 256, 0, stream>>>(lin_t, tg_wih, bias2_t, gibuf, 192, 64);
  gru_rec_kernel<<<64, 256, 0, stream>>>(lin_t, gibuf, tg_whh, tg_bhh, 1024);

  // cross attention
  scores_kernel<<<dim3(16, 16, 4), 256, 0, stream>>>(lin_t, lin_e, Pbuf);
  softmax_rows_kernel<<<4096, 256, 0, stream>>>(Pbuf);
  pv_kernel<<<dim3(32, 4, 4), 256, 0, stream>>>(Pbuf, lin_t, PVbuf);

  // head (parallelized): logits -> softmax -> weighted reduce -> MLP
  att_logits_kernel<<<dim3(32, 4), 256, 0, stream>>>(lin_e, a_w, a_b, attbuf);
  att_softmax_kernel<<<4, 256, 0, stream>>>(attbuf);
  red_reduce_kernel<<<dim3(16, 4), 256, 0, stream>>>(lin_e, PVbuf, attbuf, redbuf);
  mlp_kernel<<<4, 128, 0, stream>>>(redbuf, h_w, h_b, c_w, c_b, (float*)d_out);
}

// Round 7
// 545.186 us; speedup vs baseline: 5.6963x; 1.2908x over previous
//
#include <hip/hip_runtime.h>
#include <cmath>

// ============================================================================
// DeepTemplateMatchingModule on MI355X — round 7.
// R6 post-mortem: conv_pool_mfma top at 127us with MfmaUtil 8% / VALU 24% /
// occupancy 21% — 75KB LDS = 2 blocks/CU and 6 barrier-separated phases; the
// 29.7KB weight stage is pure overhead. gemm_splitk is fp32-VALU-bound
// (~30K cyc/block) by arithmetic. R7:
//   conv: weights moved LDS->VGPR (13 x bf16x8 per wave, L1-hot global
//     loads) -> LDS 49KB -> 3 blocks/CU, one fewer barrier.
//   splitk: rewritten on 32x32x16 bf16 MFMA (lw pre-converted to bf16;
//     K-chunks of 64 in LDS, 72-u16 stride = 16B-aligned; atomic epilogue).
// ============================================================================

typedef unsigned short u16;
typedef __attribute__((ext_vector_type(8))) short bf16x8;
typedef __attribute__((ext_vector_type(8))) unsigned short u16x8;
typedef __attribute__((ext_vector_type(16))) float f32x16;

__device__ __forceinline__ u16 f2bf(float f) {
  unsigned int x = __float_as_uint(f);
  return (u16)((x + 0x7fffu + ((x >> 16) & 1u)) >> 16);
}
__device__ __forceinline__ float bf2f(u16 v) {
  return __uint_as_float(((unsigned int)v) << 16);
}

// ---- workspace layout (float offsets) ----
static const size_t OFF_BEFF_E  = 0;          // 64
static const size_t OFF_BEFF_T  = 64;         // 64
static const size_t OFF_BIAS2_E = 128;        // 192
static const size_t OFF_BIAS2_T = 320;        // 192
static const size_t OFF_WBF_E   = 512;        // 7424 floats (14848 u16)
static const size_t OFF_WBF_T   = 7936;       // 7424
static const size_t OFF_W12P_E  = 15360;      // 9248
static const size_t OFF_W12P_T  = 24608;      // 9248
static const size_t OFF_B12_E   = 33856;      // 32
static const size_t OFF_B12_T   = 33888;      // 32
static const size_t OFF_LWBF_E  = 33920;      // 118,784 f (237,568 u16)
static const size_t OFF_LWBF_T  = 152704;     // 118,784 f
static const size_t OFF_POOL    = 271488;     // u16! 30,171,136 u16
// reused inside dead pool region (pool dead after last split-K):
static const size_t OFF_GI      = OFF_POOL;                   // 1,560,576 f
static const size_t OFF_P       = OFF_POOL + 1560576;         // 8,323,072 f
static const size_t OFF_PV      = OFF_P + 8323072;            // 520,192 f
static const size_t OFF_RED     = OFF_PV + 520192;            // 256 f
static const size_t OFF_LIN_E   = OFF_POOL + 15085568;        // 520,192 f
static const size_t OFF_LIN_T   = OFF_LIN_E + 520192;         // 262,144 f
static const size_t OFF_ATT     = OFF_LIN_T + 262144;         // 8,128 f

// ---------------------------------------------------------------------------
// compose12: w12pad[c12][17][17] = sum_c1 w2[c12,c1] conv w1[c1], zero-padded
// ---------------------------------------------------------------------------
__global__ __launch_bounds__(320) void compose12_kernel(
    const float* __restrict__ w1e, const float* __restrict__ b1e,
    const float* __restrict__ w2e, const float* __restrict__ b2e,
    const float* __restrict__ w1t, const float* __restrict__ b1t,
    const float* __restrict__ w2t, const float* __restrict__ b2t,
    float* __restrict__ w12p_e, float* __restrict__ w12p_t,
    float* __restrict__ b12o_e, float* __restrict__ b12o_t) {
  const int br = blockIdx.y;
  const float* w1 = br ? w1t : w1e;
  const float* b1 = br ? b1t : b1e;
  const float* w2 = br ? w2t : w2e;
  const float* b2 = br ? b2t : b2e;
  float* w12p = br ? w12p_t : w12p_e;
  float* b12o = br ? b12o_t : b12o_e;
  const int c12 = blockIdx.x;
  __shared__ float s_w1pad[16 * 169];
  __shared__ float s_w2c[400];
  __shared__ float s_b1[16];
  const int tid = threadIdx.x;
  for (int i = tid; i < 2704; i += 320) s_w1pad[i] = 0.f;
  if (tid < 16) s_b1[tid] = b1[tid];
  __syncthreads();
  for (int i = tid; i < 400; i += 320) {
    const int c1 = i / 25, r = (i % 25) / 5, cc = i % 5;
    s_w1pad[c1 * 169 + (r + 4) * 13 + (cc + 4)] = w1[i];
    s_w2c[i] = w2[c12 * 400 + i];
  }
  __syncthreads();
  if (tid < 289) {
    const int py = tid / 17, px = tid % 17;
    float v = 0.f;
    if (py >= 4 && py <= 12 && px >= 4 && px <= 12) {
      const int sy = py - 4, sx = px - 4;
      float accs[2] = {0.f, 0.f};
      for (int c1 = 0; c1 < 16; ++c1) {
        const float* w2p = s_w2c + c1 * 25;
        const float* w1p = s_w1pad + c1 * 169 + (sy + 4) * 13 + (sx + 4);
#pragma unroll
        for (int uy = 0; uy < 5; ++uy)
#pragma unroll
          for (int ux = 0; ux < 5; ++ux)
            accs[uy & 1] = fmaf(w2p[uy * 5 + ux], w1p[-(uy * 13) - ux], accs[uy & 1]);
      }
      v = accs[0] + accs[1];
    }
    w12p[c12 * 289 + tid] = v;
  } else if (tid == 300) {
    float acc = b2[c12];
    for (int c1 = 0; c1 < 16; ++c1) {
      float sw = 0.f;
      for (int u = 0; u < 25; ++u) sw += s_w2c[c1 * 25 + u];
      acc = fmaf(sw, s_b1[c1], acc);
    }
    b12o[c12] = acc;
  }
}

// ---------------------------------------------------------------------------
// compose_weff: weff bf16 padded [o][13][16] stride 232 u16; beff fp32.
// ---------------------------------------------------------------------------
__global__ __launch_bounds__(256) void compose_weff_kernel(
    const float* __restrict__ w3e, const float* __restrict__ b3e,
    const float* __restrict__ w3t, const float* __restrict__ b3t,
    const float* __restrict__ w12p_e, const float* __restrict__ w12p_t,
    const float* __restrict__ b12_e, const float* __restrict__ b12_t,
    u16* __restrict__ wbf_e, u16* __restrict__ wbf_t,
    float* __restrict__ beff_e, float* __restrict__ beff_t) {
  const int br = blockIdx.y;
  const float* w3 = br ? w3t : w3e;
  const float* b3 = br ? b3t : b3e;
  const float* w12p = br ? w12p_t : w12p_e;
  const float* b12 = br ? b12_t : b12_e;
  u16* weffp = br ? wbf_t : wbf_e;
  float* beff = br ? beff_t : beff_e;
  const int o = blockIdx.x;
  __shared__ float s_pad[32 * 289];
  __shared__ float s_w3o[800];
  __shared__ float s_b12[32];
  const int tid = threadIdx.x;
  for (int i = tid; i < 9248; i += 256) s_pad[i] = w12p[i];
  for (int i = tid; i < 800; i += 256) s_w3o[i] = w3[o * 800 + i];
  if (tid < 32) s_b12[tid] = b12[tid];
  __syncthreads();
  if (tid < 169) {
    const int sy = tid / 13, sx = tid % 13;
    float accs[4] = {0.f, 0.f, 0.f, 0.f};
#pragma unroll 4
    for (int c = 0; c < 32; ++c) {
      const float* w3p = s_w3o + c * 25;
      const float* wp = s_pad + c * 289 + (sy + 4) * 17 + (sx + 4);
#pragma unroll
      for (int uy = 0; uy < 5; ++uy)
#pragma unroll
        for (int ux = 0; ux < 5; ++ux)
          accs[c & 3] = fmaf(w3p[uy * 5 + ux], wp[-(uy * 17) - ux], accs[c & 3]);
    }
    weffp[o * 232 + sy * 16 + sx] = f2bf(accs[0] + accs[1] + accs[2] + accs[3]);
  } else if (tid < 208) {
    const int p = tid - 169;
    weffp[o * 232 + (p / 3) * 16 + 13 + (p % 3)] = 0;
  } else if (tid == 208) {
    float acc = b3[o];
    for (int c = 0; c < 32; ++c) {
      float sw = 0.f;
      for (int u = 0; u < 25; ++u) sw += s_w3o[c * 25 + u];
      acc = fmaf(sw, s_b12[c], acc);
    }
    beff[o] = acc;
  }
}

// ---------------------------------------------------------------------------
// bias2[j] = b_ih[j] + sum_d w_ih[j,d]*lb[d]; grid 2 (branch select).
// ---------------------------------------------------------------------------
__global__ __launch_bounds__(256) void gi_bias_kernel(
    const float* __restrict__ wih_e, const float* __restrict__ bih_e,
    const float* __restrict__ lb_e, float* __restrict__ bias2_e,
    const float* __restrict__ wih_t, const float* __restrict__ bih_t,
    const float* __restrict__ lb_t, float* __restrict__ bias2_t) {
  const int br = blockIdx.x;
  const float* wih = br ? wih_t : wih_e;
  const float* bih = br ? bih_t : bih_e;
  const float* lb = br ? lb_t : lb_e;
  float* bias2 = br ? bias2_t : bias2_e;
  __shared__ float s_lb[64];
  const int tid = threadIdx.x;
  if (tid < 64) s_lb[tid] = lb[tid];
  __syncthreads();
  if (tid < 192) {
    float acc = bih[tid];
    const float* wr = wih + tid * 64;
    for (int d = 0; d < 64; ++d) acc = fmaf(wr[d], s_lb[d], acc);
    bias2[tid] = acc;
  }
}

// ---------------------------------------------------------------------------
// tobf16: convert both lw matrices (3712x64 fp32) to bf16. grid (232, 2).
// ---------------------------------------------------------------------------
__global__ __launch_bounds__(256) void tobf16_kernel(
    const float* __restrict__ a, const float* __restrict__ b,
    u16* __restrict__ oa, u16* __restrict__ ob) {
  const float* src = blockIdx.y ? b : a;
  u16* dst = blockIdx.y ? ob : oa;
  const int i = (blockIdx.x * 256 + threadIdx.x) * 4;  // 232*1024 = 237,568
  const float4 v = *(const float4*)&src[i];
  dst[i] = f2bf(v.x); dst[i + 1] = f2bf(v.y);
  dst[i + 2] = f2bf(v.z); dst[i + 3] = f2bf(v.w);
}

// ---------------------------------------------------------------------------
// MFMA conv13x13 + maxpool(2,5)/(2,1); pooled stored as bf16.
// R7: weights in VGPRs (13 x bf16x8 per wave, direct from L1-hot global) —
// no weight LDS stage; LDS 48.9KB -> 3 blocks/CU.
// grid: (ceil(T/60), 58, 4)
// ---------------------------------------------------------------------------
__global__ __launch_bounds__(256, 3) void conv_pool_mfma_kernel(
    const float* __restrict__ x, const u16* __restrict__ weffp,
    const float* __restrict__ beff, u16* __restrict__ pooled,
    const int W, const int T) {
  __shared__ __align__(16) char s_all[48896];
  u16* s_x = (u16*)s_all;               // [14][80] bf16  (2240 B)
  u16* s_im = (u16*)(s_all + 2240);     // [14][64][24] bf16 (43008 B)
  float* s_out = (float*)s_all;         // [2][64][65] f32 (33280 B, after MFMA)
  float* s_pool = (float*)(s_all + 33280);  // [64][61] f32 (15616 B)

  const int tid = threadIdx.x;
  const int lane = tid & 63, wave = tid >> 6;
  const int cb = blockIdx.x * 60;
  const int h = blockIdx.y, b = blockIdx.z;
  const int rsel = wave & 1, cm = (wave >> 1) * 32;
  const int l31 = lane & 31, g8 = (lane >> 5) * 8;

  // weight fragments straight to VGPRs (no LDS, no barrier dependency)
  bf16x8 wfrag[13];
  {
    const u16* aw = weffp + (cm + l31) * 232 + g8;
#pragma unroll
    for (int ky = 0; ky < 13; ++ky) wfrag[ky] = *(const bf16x8*)(aw + ky * 16);
  }
  {
    const float* xb = x + ((size_t)b * 128 + 2 * h) * W;
    for (int i = tid; i < 14 * 80; i += 256) {
      const int r = i / 80, cq = i - r * 80;
      int gc = cb + cq;
      if (gc > W - 1) gc = W - 1;  // clamped cols never feed stored outputs
      s_x[i] = f2bf(xb[(size_t)r * W + gc]);
    }
  }
  __syncthreads();
  for (int p = tid; p < 896; p += 256) {
    const int ky = p >> 6, col = p & 63;
    const u16* src = s_x + ky * 80 + col;
    u16x8 v0, v1;
#pragma unroll
    for (int j = 0; j < 8; ++j) { v0[j] = src[j]; v1[j] = src[8 + j]; }
    u16* dst = s_im + (ky * 64 + col) * 24;
    *(u16x8*)dst = v0;
    *(u16x8*)(dst + 8) = v1;
  }
  __syncthreads();
  f32x16 acc0 = {}, acc1 = {};
  const u16* bw = s_im + (rsel * 64 + l31) * 24 + g8;
#pragma unroll
  for (int ky = 0; ky < 13; ++ky) {
    bf16x8 b0 = *(const bf16x8*)(bw + ky * 64 * 24);
    bf16x8 b1 = *(const bf16x8*)(bw + ky * 64 * 24 + 32 * 24);
    acc0 = __builtin_amdgcn_mfma_f32_32x32x16_bf16(wfrag[ky], b0, acc0, 0, 0, 0);
    acc1 = __builtin_amdgcn_mfma_f32_32x32x16_bf16(wfrag[ky], b1, acc1, 0, 0, 0);
  }
  __syncthreads();  // im2col dead; reuse LDS for epilogue
#pragma unroll
  for (int r = 0; r < 16; ++r) {
    const int c = cm + (r & 3) + 8 * (r >> 2) + (g8 >> 1);  // +4*(lane>>5)
    float* o = s_out + (rsel * 64 + c) * 65;
    o[l31] = acc0[r];
    o[32 + l31] = acc1[r];
  }
  __syncthreads();
  {
    const int pc = tid & 63, tg = tid >> 6;
    const int t0 = tg * 15;
    const float bias = beff[pc];
    const float* r0p = s_out + pc * 65 + t0;
    const float* r1p = s_out + (64 + pc) * 65 + t0;
    float w0[19], w1[19];
#pragma unroll
    for (int j = 0; j < 19; ++j) { w0[j] = r0p[j]; w1[j] = r1p[j]; }
#pragma unroll
    for (int i = 0; i < 15; ++i) {
      float m = w0[i];
#pragma unroll
      for (int k = 1; k < 5; ++k) m = fmaxf(m, w0[i + k]);
#pragma unroll
      for (int k = 0; k < 5; ++k) m = fmaxf(m, w1[i + k]);
      s_pool[pc * 61 + t0 + i] = m + bias;
    }
  }
  __syncthreads();
  for (int i = tid; i < 3840; i += 256) {
    const int c = i / 60, t = i - c * 60;
    const int gt = cb + t;
    if (gt < T)
      pooled[(((size_t)b * 64 + c) * 58 + h) * T + gt] = f2bf(s_pool[c * 61 + t]);
  }
}

// ---------------------------------------------------------------------------
// Split-K GEMM on bf16 MFMA: out[r][n] += pool_bf16[r][:] . lw_bf16[n][:]
// grid (Mtiles, 8 slices). 58 K-chunks of 64 split over slices. Per chunk:
// stage sA/sB 64x64 bf16 (72-u16 row stride: 16B-aligned, 4-way worst).
// Wave w -> C-tile (m-half = w&1, n-half = w>>1), 4 MFMA/chunk.
// ---------------------------------------------------------------------------
__global__ __launch_bounds__(256) void gemm_splitk_mfma_kernel(
    const u16* __restrict__ A, const u16* __restrict__ Bw,
    float* __restrict__ out) {
  __shared__ __align__(16) u16 sA[64 * 72];
  __shared__ __align__(16) u16 sB[64 * 72];
  const int tid = threadIdx.x;
  const int r0 = blockIdx.x * 64;
  const int s = blockIdx.y;
  const int ch0 = (s * 58) / 8, ch1 = ((s + 1) * 58) / 8;
  const int lane = tid & 63, wave = tid >> 6;
  const int l31 = lane & 31, g8 = (lane >> 5) * 8;
  const int mh = (wave & 1) * 32, nh = (wave >> 1) * 32;
  const int srow = tid >> 2, sseg = (tid & 3) * 16;
  f32x16 acc = {};
  for (int ch = ch0; ch < ch1; ++ch) {
    const int kc = ch * 64;
    __syncthreads();
    {
      const u16* ap = &A[(size_t)(r0 + srow) * 3712 + kc + sseg];
      const u16* bp = &Bw[(size_t)srow * 3712 + kc + sseg];
      u16* da = &sA[srow * 72 + sseg];
      u16* db = &sB[srow * 72 + sseg];
      *(u16x8*)da = *(const u16x8*)ap;
      *(u16x8*)(da + 8) = *(const u16x8*)(ap + 8);
      *(u16x8*)db = *(const u16x8*)bp;
      *(u16x8*)(db + 8) = *(const u16x8*)(bp + 8);
    }
    __syncthreads();
#pragma unroll
    for (int ks = 0; ks < 4; ++ks) {
      bf16x8 a = *(const bf16x8*)&sA[(mh + l31) * 72 + ks * 16 + g8];
      bf16x8 b = *(const bf16x8*)&sB[(nh + l31) * 72 + ks * 16 + g8];
      acc = __builtin_amdgcn_mfma_f32_32x32x16_bf16(a, b, acc, 0, 0, 0);
    }
  }
#pragma unroll
  for (int r = 0; r < 16; ++r) {
    const int row = mh + (r & 3) + 8 * (r >> 2) + (g8 >> 1);
    atomicAdd(&out[(size_t)(r0 + row) * 64 + nh + l31], acc[r]);
  }
}

// ---------------------------------------------------------------------------
// Generic fp32 GEMM (gi = lin @ w_ih^T + bias2). K multiple of 32.
// ---------------------------------------------------------------------------
__global__ __launch_bounds__(256) void gemm_nt_kernel(
    const float* __restrict__ A, const float* __restrict__ Wt,
    const float* __restrict__ bias, float* __restrict__ out,
    const int N, const int K) {
  __shared__ float sA[64 * 33];
  __shared__ float sB[64 * 33];
  const int tid = threadIdx.x;
  const int r0 = blockIdx.x * 64;
  const int n0 = blockIdx.y * 64;
  const int ty = tid >> 4, tx = tid & 15;
  float acc[4][4] = {};
  for (int kc = 0; kc < K; kc += 32) {
    __syncthreads();
#pragma unroll
    for (int rep = 0; rep < 8; ++rep) {
      const int l = tid + rep * 256;
      const int row = l >> 5, kk = l & 31;
      sA[row * 33 + kk] = A[(size_t)(r0 + row) * K + kc + kk];
      sB[row * 33 + kk] = Wt[(size_t)(n0 + row) * K + kc + kk];
    }
    __syncthreads();
#pragma unroll 8
    for (int kk = 0; kk < 32; ++kk) {
      const float a0 = sA[(ty * 4 + 0) * 33 + kk];
      const float a1 = sA[(ty * 4 + 1) * 33 + kk];
      const float a2 = sA[(ty * 4 + 2) * 33 + kk];
      const float a3 = sA[(ty * 4 + 3) * 33 + kk];
      const float b0 = sB[(tx * 4 + 0) * 33 + kk];
      const float b1 = sB[(tx * 4 + 1) * 33 + kk];
      const float b2 = sB[(tx * 4 + 2) * 33 + kk];
      const float b3 = sB[(tx * 4 + 3) * 33 + kk];
      acc[0][0] = fmaf(a0, b0, acc[0][0]); acc[0][1] = fmaf(a0, b1, acc[0][1]);
      acc[0][2] = fmaf(a0, b2, acc[0][2]); acc[0][3] = fmaf(a0, b3, acc[0][3]);
      acc[1][0] = fmaf(a1, b0, acc[1][0]); acc[1][1] = fmaf(a1, b1, acc[1][1]);
      acc[1][2] = fmaf(a1, b2, acc[1][2]); acc[1][3] = fmaf(a1, b3, acc[1][3]);
      acc[2][0] = fmaf(a2, b0, acc[2][0]); acc[2][1] = fmaf(a2, b1, acc[2][1]);
      acc[2][2] = fmaf(a2, b2, acc[2][2]); acc[2][3] = fmaf(a2, b3, acc[2][3]);
      acc[3][0] = fmaf(a3, b0, acc[3][0]); acc[3][1] = fmaf(a3, b1, acc[3][1]);
      acc[3][2] = fmaf(a3, b2, acc[3][2]); acc[3][3] = fmaf(a3, b3, acc[3][3]);
    }
  }
#pragma unroll
  for (int i = 0; i < 4; ++i)
#pragma unroll
    for (int j = 0; j < 4; ++j)
      out[(size_t)(r0 + ty * 4 + i) * N + n0 + tx * 4 + j] =
          acc[i][j] + bias[n0 + tx * 4 + j];
}

// ---------------------------------------------------------------------------
// GRU recurrence (scan over BATCH axis, 4 steps; every t independent).
// ---------------------------------------------------------------------------
__global__ __launch_bounds__(256) void gru_rec_kernel(
    float* __restrict__ xy, const float* __restrict__ gi,
    const float* __restrict__ whh, const float* __restrict__ bhh, const int T) {
  __shared__ float s_whh_t[64 * 192];
  __shared__ float s_h[16][64];
  const int tid = threadIdx.x;
  const int lane = tid & 63, wave = tid >> 6;
  for (int i = tid; i < 192 * 64; i += 256) {
    const int j = i >> 6, d = i & 63;
    s_whh_t[d * 192 + j] = whh[i];
  }
  for (int i = tid; i < 16 * 64; i += 256) (&s_h[0][0])[i] = 0.f;
  const float bhr = bhh[lane], bhz = bhh[64 + lane], bhn = bhh[128 + lane];
  const int t0 = blockIdx.x * 16;
  __syncthreads();
  for (int b = 0; b < 4; ++b) {
    float gir[4], giz[4], gin[4];
#pragma unroll
    for (int sl = 0; sl < 4; ++sl) {
      int t = t0 + wave * 4 + sl; if (t > T - 1) t = T - 1;
      const float* girow = gi + ((size_t)b * T + t) * 192;
      gir[sl] = girow[lane]; giz[sl] = girow[64 + lane]; gin[sl] = girow[128 + lane];
    }
    float ahr[4] = {}, ahz[4] = {}, ahn[4] = {};
    for (int d = 0; d < 64; ++d) {
      const float wr_ = s_whh_t[d * 192 + lane];
      const float wz_ = s_whh_t[d * 192 + 64 + lane];
      const float wn_ = s_whh_t[d * 192 + 128 + lane];
#pragma unroll
      for (int sl = 0; sl < 4; ++sl) {
        const float hv = s_h[wave * 4 + sl][d];
        ahr[sl] = fmaf(wr_, hv, ahr[sl]);
        ahz[sl] = fmaf(wz_, hv, ahz[sl]);
        ahn[sl] = fmaf(wn_, hv, ahn[sl]);
      }
    }
    float hn[4];
#pragma unroll
    for (int sl = 0; sl < 4; ++sl) {
      const float r = 1.f / (1.f + __expf(-(gir[sl] + ahr[sl] + bhr)));
      const float z = 1.f / (1.f + __expf(-(giz[sl] + ahz[sl] + bhz)));
      const float n = tanhf(gin[sl] + r * (ahn[sl] + bhn));
      hn[sl] = (1.f - z) * n + z * s_h[wave * 4 + sl][lane];
    }
    __syncthreads();
#pragma unroll
    for (int sl = 0; sl < 4; ++sl) {
      const int t = t0 + wave * 4 + sl;
      s_h[wave * 4 + sl][lane] = hn[sl];
      if (t < T) xy[((size_t)b * T + t) * 64 + lane] = hn[sl];
    }
    __syncthreads();
  }
}

// ---------------------------------------------------------------------------
// scores: P[b,tau,eps] = sum_d t[b,tau,d]*e[b,eps,d]. grid (16,16,4), K=64.
// ---------------------------------------------------------------------------
__global__ __launch_bounds__(256) void scores_kernel(
    const float* __restrict__ tmat, const float* __restrict__ emat,
    float* __restrict__ P) {
  __shared__ __align__(16) float sT[64 * 68];
  __shared__ __align__(16) float sE[128 * 68];
  const int tid = threadIdx.x;
  const int b = blockIdx.z;
  const int tau0 = blockIdx.x * 64;
  const int e0 = blockIdx.y * 128;
#pragma unroll
  for (int r = 0; r < 4; ++r) {
    const int q = tid + r * 256;
    const int row = q >> 4, qq = q & 15;
    const float4 v = *(const float4*)&tmat[((size_t)b * 1024 + tau0 + row) * 64 + qq * 4];
    *(float4*)&sT[row * 68 + qq * 4] = v;
  }
#pragma unroll
  for (int r = 0; r < 8; ++r) {
    const int q = tid + r * 256;
    const int row = q >> 4, qq = q & 15;
    int eps = e0 + row; if (eps > 2031) eps = 2031;
    const float4 v = *(const float4*)&emat[((size_t)b * 2032 + eps) * 64 + qq * 4];
    *(float4*)&sE[row * 68 + qq * 4] = v;
  }
  __syncthreads();
  const int ty = tid >> 4, tx = tid & 15;
  float acc[4][8] = {};
#pragma unroll 4
  for (int q = 0; q < 16; ++q) {
    const int kk = q * 4;
    float4 av[4], bv[8];
#pragma unroll
    for (int i = 0; i < 4; ++i) av[i] = *(const float4*)&sT[(ty * 4 + i) * 68 + kk];
#pragma unroll
    for (int j = 0; j < 8; ++j) bv[j] = *(const float4*)&sE[(tx * 8 + j) * 68 + kk];
#pragma unroll
    for (int i = 0; i < 4; ++i)
#pragma unroll
      for (int j = 0; j < 8; ++j) {
        acc[i][j] = fmaf(av[i].x, bv[j].x, acc[i][j]);
        acc[i][j] = fmaf(av[i].y, bv[j].y, acc[i][j]);
        acc[i][j] = fmaf(av[i].z, bv[j].z, acc[i][j]);
        acc[i][j] = fmaf(av[i].w, bv[j].w, acc[i][j]);
      }
  }
#pragma unroll
  for (int i = 0; i < 4; ++i) {
    const size_t prow = ((size_t)b * 1024 + tau0 + ty * 4 + i) * 2032;
#pragma unroll
    for (int j = 0; j < 8; ++j) {
      const int eps = e0 + tx * 8 + j;
      if (eps < 2032) P[prow + eps] = acc[i][j];
    }
  }
}

// ---------------------------------------------------------------------------
// row softmax over eps (rows of length 2032), row cached in LDS. grid 4096.
// ---------------------------------------------------------------------------
__global__ __launch_bounds__(256) void softmax_rows_kernel(float* __restrict__ P) {
  __shared__ float s_row[2032];
  __shared__ float sred[4];
  float* r = P + (size_t)blockIdx.x * 2032;
  const int tid = threadIdx.x;
  const int lane = tid & 63, wave = tid >> 6;
  float m = -3.4e38f;
  for (int i = tid; i < 2032; i += 256) {
    const float v = r[i];
    s_row[i] = v;
    m = fmaxf(m, v);
  }
#pragma unroll
  for (int off = 32; off > 0; off >>= 1) m = fmaxf(m, __shfl_down(m, off, 64));
  if (lane == 0) sred[wave] = m;
  __syncthreads();
  m = fmaxf(fmaxf(sred[0], sred[1]), fmaxf(sred[2], sred[3]));
  __syncthreads();
  float s = 0.f;
  float vals[8];
  int cnt = 0;
  for (int i = tid; i < 2032; i += 256) {
    const float v = __expf(s_row[i] - m);
    vals[cnt++] = v;
    s += v;
  }
#pragma unroll
  for (int off = 32; off > 0; off >>= 1) s += __shfl_down(s, off, 64);
  if (lane == 0) sred[wave] = s;
  __syncthreads();
  const float inv = 1.f / (sred[0] + sred[1] + sred[2] + sred[3]);
  cnt = 0;
  for (int i = tid; i < 2032; i += 256) r[i] = vals[cnt++] * inv;
}

// ---------------------------------------------------------------------------
// pv partial: PV[b,eps,d] += sum_{tau slice} P[b,tau,eps]*t[b,tau,d]
// ---------------------------------------------------------------------------
__global__ __launch_bounds__(256) void pv_kernel(
    const float* __restrict__ P, const float* __restrict__ tmat,
    float* __restrict__ PV) {
  __shared__ float sP[32 * 65];
  __shared__ float sT[32 * 65];
  const int tid = threadIdx.x;
  const int b = blockIdx.z;
  const int e0 = blockIdx.x * 64;
  const int tau_base = blockIdx.y * 256;
  const int ty = tid >> 4, tx = tid & 15;
  float acc[4][4] = {};
  for (int kc = tau_base; kc < tau_base + 256; kc += 32) {
    __syncthreads();
    for (int l = tid; l < 32 * 64; l += 256) {
      const int kk = l >> 6, j = l & 63;
      int eps = e0 + j; if (eps > 2031) eps = 2031;
      sP[kk * 65 + j] = P[((size_t)b * 1024 + kc + kk) * 2032 + eps];
      sT[kk * 65 + j] = tmat[((size_t)b * 1024 + kc + kk) * 64 + j];
    }
    __syncthreads();
#pragma unroll 8
    for (int kk = 0; kk < 32; ++kk) {
      const float a0 = sP[kk * 65 + ty * 4 + 0];
      const float a1 = sP[kk * 65 + ty * 4 + 1];
      const float a2 = sP[kk * 65 + ty * 4 + 2];
      const float a3 = sP[kk * 65 + ty * 4 + 3];
      const float b0 = sT[kk * 65 + tx * 4 + 0];
      const float b1 = sT[kk * 65 + tx * 4 + 1];
      const float b2 = sT[kk * 65 + tx * 4 + 2];
      const float b3 = sT[kk * 65 + tx * 4 + 3];
      acc[0][0] = fmaf(a0, b0, acc[0][0]); acc[0][1] = fmaf(a0, b1, acc[0][1]);
      acc[0][2] = fmaf(a0, b2, acc[0][2]); acc[0][3] = fmaf(a0, b3, acc[0][3]);
      acc[1][0] = fmaf(a1, b0, acc[1][0]); acc[1][1] = fmaf(a1, b1, acc[1][1]);
      acc[1][2] = fmaf(a1, b2, acc[1][2]); acc[1][3] = fmaf(a1, b3, acc[1][3]);
      acc[2][0] = fmaf(a2, b0, acc[2][0]); acc[2][1] = fmaf(a2, b1, acc[2][1]);
      acc[2][2] = fmaf(a2, b2, acc[2][2]); acc[2][3] = fmaf(a2, b3, acc[2][3]);
      acc[3][0] = fmaf(a3, b0, acc[3][0]); acc[3][1] = fmaf(a3, b1, acc[3][1]);
      acc[3][2] = fmaf(a3, b2, acc[3][2]); acc[3][3] = fmaf(a3, b3, acc[3][3]);
    }
  }
#pragma unroll
  for (int i = 0; i < 4; ++i) {
    const int eps = e0 + ty * 4 + i;
    if (eps < 2032) {
#pragma unroll
      for (int j = 0; j < 4; ++j)
        atomicAdd(&PV[((size_t)b * 2032 + eps) * 64 + tx * 4 + j], acc[i][j]);
    }
  }
}

// ---------------------------------------------------------------------------
// att_logits: logits[b,i] = dot(e[b,i,:], a_w) + a_b. grid (32, 4).
// ---------------------------------------------------------------------------
__global__ __launch_bounds__(256) void att_logits_kernel(
    const float* __restrict__ emat, const float* __restrict__ a_w,
    const float* __restrict__ a_b, float* __restrict__ logits) {
  __shared__ float s_aw[64];
  const int tid = threadIdx.x;
  const int lane = tid & 63, wave = tid >> 6;
  if (tid < 64) s_aw[tid] = a_w[tid];
  __syncthreads();
  const int b = blockIdx.y;
  const float ab = a_b[0];
  const int base = blockIdx.x * 64 + wave * 16;
#pragma unroll 4
  for (int r = 0; r < 16; ++r) {
    const int i = base + r;
    if (i < 2032) {
      float v = emat[((size_t)b * 2032 + i) * 64 + lane] * s_aw[lane];
#pragma unroll
      for (int off = 32; off > 0; off >>= 1) v += __shfl_down(v, off, 64);
      if (lane == 0) logits[b * 2032 + i] = v + ab;
    }
  }
}

// ---------------------------------------------------------------------------
// att_softmax: in-place softmax over 2032 logits per batch. grid 4.
// ---------------------------------------------------------------------------
__global__ __launch_bounds__(256) void att_softmax_kernel(float* __restrict__ att) {
  __shared__ float s_v[2032];
  __shared__ float sred[4];
  float* r = att + (size_t)blockIdx.x * 2032;
  const int tid = threadIdx.x;
  const int lane = tid & 63, wave = tid >> 6;
  float m = -3.4e38f;
  for (int i = tid; i < 2032; i += 256) {
    const float v = r[i];
    s_v[i] = v;
    m = fmaxf(m, v);
  }
#pragma unroll
  for (int off = 32; off > 0; off >>= 1) m = fmaxf(m, __shfl_down(m, off, 64));
  if (lane == 0) sred[wave] = m;
  __syncthreads();
  m = fmaxf(fmaxf(sred[0], sred[1]), fmaxf(sred[2], sred[3]));
  __syncthreads();
  float s = 0.f;
  float vals[8];
  int cnt = 0;
  for (int i = tid; i < 2032; i += 256) {
    const float v = __expf(s_v[i] - m);
    vals[cnt++] = v;
    s += v;
  }
#pragma unroll
  for (int off = 32; off > 0; off >>= 1) s += __shfl_down(s, off, 64);
  if (lane == 0) sred[wave] = s;
  __syncthreads();
  const float inv = 1.f / (sred[0] + sred[1] + sred[2] + sred[3]);
  cnt = 0;
  for (int i = tid; i < 2032; i += 256) r[i] = vals[cnt++] * inv;
}

// ---------------------------------------------------------------------------
// red_reduce: red[b,d] += sum_{i in slice} |PV-e|[b,i,d] * att[b,i].
// ---------------------------------------------------------------------------
__global__ __launch_bounds__(256) void red_reduce_kernel(
    const float* __restrict__ emat, const float* __restrict__ PV,
    const float* __restrict__ att, float* __restrict__ red) {
  __shared__ float s_part[4][64];
  const int tid = threadIdx.x;
  const int lane = tid & 63, wave = tid >> 6;
  const int b = blockIdx.y;
  const int i0 = blockIdx.x * 127;
  float acc = 0.f;
  for (int i = i0 + wave; i < i0 + 127; i += 4) {
    const size_t idx = ((size_t)b * 2032 + i) * 64 + lane;
    acc = fmaf(fabsf(PV[idx] - emat[idx]), att[b * 2032 + i], acc);
  }
  s_part[wave][lane] = acc;
  __syncthreads();
  if (tid < 64)
    atomicAdd(&red[b * 64 + tid],
              s_part[0][tid] + s_part[1][tid] + s_part[2][tid] + s_part[3][tid]);
}

// ---------------------------------------------------------------------------
// mlp: h = relu(red@h_w^T + h_b); out = softmax(h@c_w^T + c_b). grid 4.
// ---------------------------------------------------------------------------
__global__ __launch_bounds__(128) void mlp_kernel(
    const float* __restrict__ red, const float* __restrict__ h_w,
    const float* __restrict__ h_b, const float* __restrict__ c_w,
    const float* __restrict__ c_b, float* __restrict__ out) {
  __shared__ float s_red[64];
  __shared__ float s_hv[128];
  const int tid = threadIdx.x;
  const int b = blockIdx.x;
  if (tid < 64) s_red[tid] = red[b * 64 + tid];
  __syncthreads();
  {
    float acc = h_b[tid];
    const float* hw = h_w + tid * 64;
    for (int d = 0; d < 64; ++d) acc = fmaf(s_red[d], hw[d], acc);
    s_hv[tid] = fmaxf(acc, 0.f);
  }
  __syncthreads();
  if (tid == 0) {
    float l0 = c_b[0], l1 = c_b[1];
    for (int j = 0; j < 128; ++j) {
      l0 = fmaf(s_hv[j], c_w[j], l0);
      l1 = fmaf(s_hv[j], c_w[128 + j], l1);
    }
    const float mm = fmaxf(l0, l1);
    const float e0 = __expf(l0 - mm), e1 = __expf(l1 - mm);
    const float invs = 1.f / (e0 + e1);
    out[b * 2 + 0] = e0 * invs;
    out[b * 2 + 1] = e1 * invs;
  }
}

// ===========================================================================
extern "C" void kernel_launch(void* const* d_in, const int* in_sizes, int n_in,
                              void* d_out, int out_size, void* d_ws, size_t ws_size,
                              hipStream_t stream) {
  const float* evaluation = (const float*)d_in[0];
  const float* templ      = (const float*)d_in[1];
  const float* e_w1 = (const float*)d_in[2];
  const float* e_b1 = (const float*)d_in[3];
  const float* e_w2 = (const float*)d_in[4];
  const float* e_b2 = (const float*)d_in[5];
  const float* e_w3 = (const float*)d_in[6];
  const float* e_b3 = (const float*)d_in[7];
  const float* el_w = (const float*)d_in[8];
  const float* el_b = (const float*)d_in[9];
  const float* eg_wih = (const float*)d_in[10];
  const float* eg_whh = (const float*)d_in[11];
  const float* eg_bih = (const float*)d_in[12];
  const float* eg_bhh = (const float*)d_in[13];
  const float* t_w1 = (const float*)d_in[14];
  const float* t_b1 = (const float*)d_in[15];
  const float* t_w2 = (const float*)d_in[16];
  const float* t_b2 = (const float*)d_in[17];
  const float* t_w3 = (const float*)d_in[18];
  const float* t_b3 = (const float*)d_in[19];
  const float* tl_w = (const float*)d_in[20];
  const float* tl_b = (const float*)d_in[21];
  const float* tg_wih = (const float*)d_in[22];
  const float* tg_whh = (const float*)d_in[23];
  const float* tg_bih = (const float*)d_in[24];
  const float* tg_bhh = (const float*)d_in[25];
  const float* a_w = (const float*)d_in[26];
  const float* a_b = (const float*)d_in[27];
  const float* h_w = (const float*)d_in[28];
  const float* h_b = (const float*)d_in[29];
  const float* c_w = (const float*)d_in[30];
  const float* c_b = (const float*)d_in[31];

  float* ws = (float*)d_ws;
  float* beff_e  = ws + OFF_BEFF_E;
  float* beff_t  = ws + OFF_BEFF_T;
  float* bias2_e = ws + OFF_BIAS2_E;
  float* bias2_t = ws + OFF_BIAS2_T;
  u16*   wbf_e   = (u16*)(ws + OFF_WBF_E);
  u16*   wbf_t   = (u16*)(ws + OFF_WBF_T);
  float* w12p_e  = ws + OFF_W12P_E;
  float* w12p_t  = ws + OFF_W12P_T;
  float* b12_e   = ws + OFF_B12_E;
  float* b12_t   = ws + OFF_B12_T;
  u16*   lwbf_e  = (u16*)(ws + OFF_LWBF_E);
  u16*   lwbf_t  = (u16*)(ws + OFF_LWBF_T);
  u16*   pool    = (u16*)(ws + OFF_POOL);
  float* gibuf   = ws + OFF_GI;
  float* Pbuf    = ws + OFF_P;
  float* PVbuf   = ws + OFF_PV;
  float* redbuf  = ws + OFF_RED;
  float* lin_e   = ws + OFF_LIN_E;
  float* lin_t   = ws + OFF_LIN_T;
  float* attbuf  = ws + OFF_ATT;

  // weight composition chain + folded gi biases + lw->bf16
  compose12_kernel<<<dim3(32, 2), 320, 0, stream>>>(
      e_w1, e_b1, e_w2, e_b2, t_w1, t_b1, t_w2, t_b2, w12p_e, w12p_t, b12_e, b12_t);
  compose_weff_kernel<<<dim3(64, 2), 256, 0, stream>>>(
      e_w3, e_b3, t_w3, t_b3, w12p_e, w12p_t, b12_e, b12_t, wbf_e, wbf_t, beff_e, beff_t);
  gi_bias_kernel<<<2, 256, 0, stream>>>(eg_wih, eg_bih, el_b, bias2_e,
                                        tg_wih, tg_bih, tl_b, bias2_t);
  tobf16_kernel<<<dim3(232, 2), 256, 0, stream>>>(el_w, tl_w, lwbf_e, lwbf_t);

  // zero lin_e + lin_t (contiguous) for split-K atomics
  hipMemsetAsync(lin_e, 0, (520192 + 262144) * sizeof(float), stream);

  // eval branch: MFMA conv+pool (bf16 out) -> MFMA split-K linear
  conv_pool_mfma_kernel<<<dim3(34, 58, 4), 256, 0, stream>>>(evaluation, wbf_e, beff_e, pool, 2048, 2032);
  gemm_splitk_mfma_kernel<<<dim3(127, 8), 256, 0, stream>>>(pool, lwbf_e, lin_e);
  // template branch
  conv_pool_mfma_kernel<<<dim3(18, 58, 4), 256, 0, stream>>>(templ, wbf_t, beff_t, pool, 1040, 1024);
  gemm_splitk_mfma_kernel<<<dim3(64, 8), 256, 0, stream>>>(pool, lwbf_t, lin_t);

  // zero PV + red (contiguous; lives in dead pool region, after last pool read)
  hipMemsetAsync(PVbuf, 0, (520192 + 256) * sizeof(float), stream);

  // GRU (scan over batch axis)
  gemm_nt_kernel<<<dim3(127, 3), 256, 0, stream>>>(lin_e, eg_wih, bias2_e, gibuf, 192, 64);
  gru_rec_kernel<<<127, 256, 0, stream>>>(lin_e, gibuf, eg_whh, eg_bhh, 2032);
  gemm_nt_kernel<<<dim3(64, 3), 256, 0, stream>>>(lin_t, tg_wih, bias2_t, gibuf, 192, 64);
  gru_rec_kernel<<<64, 256, 0, stream>>>(lin_t, gibuf, tg_whh, tg_bhh, 1024);

  // cross attention
  scores_kernel<<<dim3(16, 16, 4), 256, 0, stream>>>(lin_t, lin_e, Pbuf);
  softmax_rows_kernel<<<4096, 256, 0, stream>>>(Pbuf);
  pv_kernel<<<dim3(32, 4, 4), 256, 0, stream>>>(Pbuf, lin_t, PVbuf);

  // head: logits -> softmax -> weighted reduce -> MLP
  att_logits_kernel<<<dim3(32, 4), 256, 0, stream>>>(lin_e, a_w, a_b, attbuf);
  att_softmax_kernel<<<4, 256, 0, stream>>>(attbuf);
  red_reduce_kernel<<<dim3(16, 4), 256, 0, stream>>>(lin_e, PVbuf, attbuf, redbuf);
  mlp_kernel<<<4, 128, 0, stream>>>(redbuf, h_w, h_b, c_w, c_b, (float*)d_out);
}

// Round 8
// 478.960 us; speedup vs baseline: 6.4839x; 1.1383x over previous
//
#include <hip/hip_runtime.h>
#include <cmath>

// ============================================================================
// DeepTemplateMatchingModule on MI355X — round 8.
// R7 post-mortem: conv at 103us, MfmaUtil 10%/VALU 29%/60% idle — the im2col
// phase (14336 ds_read_u16 + 1792 b128 writes + barrier per block) is the
// stall; VGPR=68 caps occupancy at 16 waves/CU.
// R8: axis swap K=ky(pad 16), loop kx (13 MFMA steps). B-fragment becomes
// ky-contiguous reads of a TRANSPOSED x tile s_xT[col][ky] (stride 24 u16,
// per-lane 16B aligned) — im2col eliminated. Two shifted copies (conv-row
// parity) keep rsel=1 aligned. Weights repacked wkx[kx][c][ky16] by compose.
// LDS 49->24.8 KB (s_out/s_pool bf16) -> 4 blocks/CU. P stored bf16
// (scores/softmax/pv: saves ~66 MB HBM). pooled stores paired u32.
// ============================================================================

typedef unsigned short u16;
typedef unsigned int u32;
typedef __attribute__((ext_vector_type(8))) short bf16x8;
typedef __attribute__((ext_vector_type(8))) unsigned short u16x8;
typedef __attribute__((ext_vector_type(16))) float f32x16;

__device__ __forceinline__ u16 f2bf(float f) {
  unsigned int x = __float_as_uint(f);
  return (u16)((x + 0x7fffu + ((x >> 16) & 1u)) >> 16);
}
__device__ __forceinline__ float bf2f(u16 v) {
  return __uint_as_float(((unsigned int)v) << 16);
}

// ---- workspace layout (float offsets) ----
static const size_t OFF_BEFF_E  = 0;          // 64
static const size_t OFF_BEFF_T  = 64;         // 64
static const size_t OFF_BIAS2_E = 128;        // 192
static const size_t OFF_BIAS2_T = 320;        // 192
static const size_t OFF_WBF_E   = 512;        // 6656 f used (13312 u16)
static const size_t OFF_WBF_T   = 7936;       // 6656 f
static const size_t OFF_W12P_E  = 15360;      // 9248
static const size_t OFF_W12P_T  = 24608;      // 9248
static const size_t OFF_B12_E   = 33856;      // 32
static const size_t OFF_B12_T   = 33888;      // 32
static const size_t OFF_LWBF_E  = 33920;      // 118,784 f (237,568 u16)
static const size_t OFF_LWBF_T  = 152704;     // 118,784 f
static const size_t OFF_POOL    = 271488;     // u16! 30,171,136 u16
// reused inside dead pool region (pool dead after last split-K):
static const size_t OFF_GI      = OFF_POOL;                   // 1,560,576 f
static const size_t OFF_P       = OFF_POOL + 1560576;         // u16 now (8.3M u16)
static const size_t OFF_PV      = OFF_P + 8323072;            // 520,192 f
static const size_t OFF_RED     = OFF_PV + 520192;            // 256 f
static const size_t OFF_LIN_E   = OFF_POOL + 15085568;        // 520,192 f
static const size_t OFF_LIN_T   = OFF_LIN_E + 520192;         // 262,144 f
static const size_t OFF_ATT     = OFF_LIN_T + 262144;         // 8,128 f

// ---------------------------------------------------------------------------
// compose12: w12pad[c12][17][17] = sum_c1 w2[c12,c1] conv w1[c1], zero-padded
// ---------------------------------------------------------------------------
__global__ __launch_bounds__(320) void compose12_kernel(
    const float* __restrict__ w1e, const float* __restrict__ b1e,
    const float* __restrict__ w2e, const float* __restrict__ b2e,
    const float* __restrict__ w1t, const float* __restrict__ b1t,
    const float* __restrict__ w2t, const float* __restrict__ b2t,
    float* __restrict__ w12p_e, float* __restrict__ w12p_t,
    float* __restrict__ b12o_e, float* __restrict__ b12o_t) {
  const int br = blockIdx.y;
  const float* w1 = br ? w1t : w1e;
  const float* b1 = br ? b1t : b1e;
  const float* w2 = br ? w2t : w2e;
  const float* b2 = br ? b2t : b2e;
  float* w12p = br ? w12p_t : w12p_e;
  float* b12o = br ? b12o_t : b12o_e;
  const int c12 = blockIdx.x;
  __shared__ float s_w1pad[16 * 169];
  __shared__ float s_w2c[400];
  __shared__ float s_b1[16];
  const int tid = threadIdx.x;
  for (int i = tid; i < 2704; i += 320) s_w1pad[i] = 0.f;
  if (tid < 16) s_b1[tid] = b1[tid];
  __syncthreads();
  for (int i = tid; i < 400; i += 320) {
    const int c1 = i / 25, r = (i % 25) / 5, cc = i % 5;
    s_w1pad[c1 * 169 + (r + 4) * 13 + (cc + 4)] = w1[i];
    s_w2c[i] = w2[c12 * 400 + i];
  }
  __syncthreads();
  if (tid < 289) {
    const int py = tid / 17, px = tid % 17;
    float v = 0.f;
    if (py >= 4 && py <= 12 && px >= 4 && px <= 12) {
      const int sy = py - 4, sx = px - 4;
      float accs[2] = {0.f, 0.f};
      for (int c1 = 0; c1 < 16; ++c1) {
        const float* w2p = s_w2c + c1 * 25;
        const float* w1p = s_w1pad + c1 * 169 + (sy + 4) * 13 + (sx + 4);
#pragma unroll
        for (int uy = 0; uy < 5; ++uy)
#pragma unroll
          for (int ux = 0; ux < 5; ++ux)
            accs[uy & 1] = fmaf(w2p[uy * 5 + ux], w1p[-(uy * 13) - ux], accs[uy & 1]);
      }
      v = accs[0] + accs[1];
    }
    w12p[c12 * 289 + tid] = v;
  } else if (tid == 300) {
    float acc = b2[c12];
    for (int c1 = 0; c1 < 16; ++c1) {
      float sw = 0.f;
      for (int u = 0; u < 25; ++u) sw += s_w2c[c1 * 25 + u];
      acc = fmaf(sw, s_b1[c1], acc);
    }
    b12o[c12] = acc;
  }
}

// ---------------------------------------------------------------------------
// compose_weff: emits wkx[kx][o][ky16] bf16 (ky 13..15 zero); beff fp32.
// ---------------------------------------------------------------------------
__global__ __launch_bounds__(256) void compose_weff_kernel(
    const float* __restrict__ w3e, const float* __restrict__ b3e,
    const float* __restrict__ w3t, const float* __restrict__ b3t,
    const float* __restrict__ w12p_e, const float* __restrict__ w12p_t,
    const float* __restrict__ b12_e, const float* __restrict__ b12_t,
    u16* __restrict__ wbf_e, u16* __restrict__ wbf_t,
    float* __restrict__ beff_e, float* __restrict__ beff_t) {
  const int br = blockIdx.y;
  const float* w3 = br ? w3t : w3e;
  const float* b3 = br ? b3t : b3e;
  const float* w12p = br ? w12p_t : w12p_e;
  const float* b12 = br ? b12_t : b12_e;
  u16* weffp = br ? wbf_t : wbf_e;
  float* beff = br ? beff_t : beff_e;
  const int o = blockIdx.x;
  __shared__ float s_pad[32 * 289];
  __shared__ float s_w3o[800];
  __shared__ float s_b12[32];
  const int tid = threadIdx.x;
  for (int i = tid; i < 9248; i += 256) s_pad[i] = w12p[i];
  for (int i = tid; i < 800; i += 256) s_w3o[i] = w3[o * 800 + i];
  if (tid < 32) s_b12[tid] = b12[tid];
  __syncthreads();
  if (tid < 169) {
    const int sy = tid / 13, sx = tid % 13;  // sy = ky, sx = kx
    float accs[4] = {0.f, 0.f, 0.f, 0.f};
#pragma unroll 4
    for (int c = 0; c < 32; ++c) {
      const float* w3p = s_w3o + c * 25;
      const float* wp = s_pad + c * 289 + (sy + 4) * 17 + (sx + 4);
#pragma unroll
      for (int uy = 0; uy < 5; ++uy)
#pragma unroll
        for (int ux = 0; ux < 5; ++ux)
          accs[c & 3] = fmaf(w3p[uy * 5 + ux], wp[-(uy * 17) - ux], accs[c & 3]);
    }
    weffp[sx * 1024 + o * 16 + sy] = f2bf(accs[0] + accs[1] + accs[2] + accs[3]);
  } else if (tid < 208) {
    const int p = tid - 169;  // 13 kx x 3 ky-pads
    weffp[(p / 3) * 1024 + o * 16 + 13 + (p % 3)] = 0;
  } else if (tid == 208) {
    float acc = b3[o];
    for (int c = 0; c < 32; ++c) {
      float sw = 0.f;
      for (int u = 0; u < 25; ++u) sw += s_w3o[c * 25 + u];
      acc = fmaf(sw, s_b12[c], acc);
    }
    beff[o] = acc;
  }
}

// ---------------------------------------------------------------------------
// bias2[j] = b_ih[j] + sum_d w_ih[j,d]*lb[d]; grid 2 (branch select).
// ---------------------------------------------------------------------------
__global__ __launch_bounds__(256) void gi_bias_kernel(
    const float* __restrict__ wih_e, const float* __restrict__ bih_e,
    const float* __restrict__ lb_e, float* __restrict__ bias2_e,
    const float* __restrict__ wih_t, const float* __restrict__ bih_t,
    const float* __restrict__ lb_t, float* __restrict__ bias2_t) {
  const int br = blockIdx.x;
  const float* wih = br ? wih_t : wih_e;
  const float* bih = br ? bih_t : bih_e;
  const float* lb = br ? lb_t : lb_e;
  float* bias2 = br ? bias2_t : bias2_e;
  __shared__ float s_lb[64];
  const int tid = threadIdx.x;
  if (tid < 64) s_lb[tid] = lb[tid];
  __syncthreads();
  if (tid < 192) {
    float acc = bih[tid];
    const float* wr = wih + tid * 64;
    for (int d = 0; d < 64; ++d) acc = fmaf(wr[d], s_lb[d], acc);
    bias2[tid] = acc;
  }
}

// ---------------------------------------------------------------------------
// tobf16: convert both lw matrices (3712x64 fp32) to bf16. grid (232, 2).
// ---------------------------------------------------------------------------
__global__ __launch_bounds__(256) void tobf16_kernel(
    const float* __restrict__ a, const float* __restrict__ b,
    u16* __restrict__ oa, u16* __restrict__ ob) {
  const float* src = blockIdx.y ? b : a;
  u16* dst = blockIdx.y ? ob : oa;
  const int i = (blockIdx.x * 256 + threadIdx.x) * 4;
  const float4 v = *(const float4*)&src[i];
  dst[i] = f2bf(v.x); dst[i + 1] = f2bf(v.y);
  dst[i + 2] = f2bf(v.z); dst[i + 3] = f2bf(v.w);
}

// ---------------------------------------------------------------------------
// MFMA conv13x13 + maxpool(2,5)/(2,1); pooled bf16.
// R8: K=ky (pad 16), kx-loop of 13 MFMA. x staged TRANSPOSED s_xT[col][ky]
// (stride 24 u16: per-lane 16B-aligned b128 B-fragments) — no im2col.
// Two shifted copies: s_xA (conv row 2h: ky slot = x row), s_xB (conv row
// 2h+1: slot = x row - 1) so both parities read at offset g8 (aligned).
// ky pad slots zeroed (pair with zero weights: 0*0). LDS 24.8 KB.
// grid: (ceil(T/60), 58, 4)
// ---------------------------------------------------------------------------
__global__ __launch_bounds__(256, 4) void conv_pool_mfma_kernel(
    const float* __restrict__ x, const u16* __restrict__ wkx,
    const float* __restrict__ beff, u16* __restrict__ pooled,
    const int W, const int T) {
  __shared__ __align__(16) char s_all[24832];
  u16* s_xA = (u16*)s_all;              // [80][24]: x rows 0..13, slots 14..15 = 0
  u16* s_xB = (u16*)(s_all + 3840);     // [80][24]: x rows 1..13 at 0..12, 13..15 = 0
  u16* s_out = (u16*)s_all;             // [2][64][66] bf16 (after MFMA)
  u16* s_pool = (u16*)(s_all + 16896);  // [64][62] bf16

  const int tid = threadIdx.x;
  const int lane = tid & 63, wave = tid >> 6;
  const int cb = blockIdx.x * 60;
  const int h = blockIdx.y, b = blockIdx.z;
  const int rsel = wave & 1, cm = (wave >> 1) * 32;
  const int l31 = lane & 31, g8 = (lane >> 5) * 8;

  // weight fragments straight to VGPRs (L1-hot; wkx[kx][c][ky16])
  bf16x8 wfrag[13];
  {
    const u16* aw = wkx + (cm + l31) * 16 + g8;
#pragma unroll
    for (int kx = 0; kx < 13; ++kx) wfrag[kx] = *(const bf16x8*)(aw + kx * 1024);
  }
  // zero the ky-pad slots (A:14,15  B:13,14,15)
  for (int i = tid; i < 400; i += 256) {
    const int col = i / 5, s = i % 5;
    if (s < 2) s_xA[col * 24 + 14 + s] = 0;
    else s_xB[col * 24 + 11 + s] = 0;
  }
  {
    const float* xb = x + ((size_t)b * 128 + 2 * h) * W;
    for (int i = tid; i < 14 * 80; i += 256) {
      const int r = i / 80, cq = i - r * 80;
      int gc = cb + cq;
      if (gc > W - 1) gc = W - 1;  // clamped cols never feed stored outputs
      const u16 v = f2bf(xb[(size_t)r * W + gc]);
      s_xA[cq * 24 + r] = v;
      if (r >= 1) s_xB[cq * 24 + r - 1] = v;
    }
  }
  __syncthreads();
  f32x16 acc0 = {}, acc1 = {};
  const u16* bx = (rsel ? s_xB : s_xA) + g8;
#pragma unroll
  for (int kx = 0; kx < 13; ++kx) {
    bf16x8 b0 = *(const bf16x8*)(bx + (l31 + kx) * 24);
    bf16x8 b1 = *(const bf16x8*)(bx + (32 + l31 + kx) * 24);
    acc0 = __builtin_amdgcn_mfma_f32_32x32x16_bf16(wfrag[kx], b0, acc0, 0, 0, 0);
    acc1 = __builtin_amdgcn_mfma_f32_32x32x16_bf16(wfrag[kx], b1, acc1, 0, 0, 0);
  }
  __syncthreads();  // x tiles dead; reuse LDS for epilogue
#pragma unroll
  for (int r = 0; r < 16; ++r) {
    const int c = cm + (r & 3) + 8 * (r >> 2) + (g8 >> 1);  // +4*(lane>>5)
    u16* o = s_out + (rsel * 64 + c) * 66;
    o[l31] = f2bf(acc0[r]);
    o[32 + l31] = f2bf(acc1[r]);
  }
  __syncthreads();
  {
    const int pc = tid & 63, tg = tid >> 6;
    const int t0 = tg * 15;  // 4 x 15 = 60 pooled cols
    const float bias = beff[pc];
    const u16* r0p = s_out + pc * 66 + t0;
    const u16* r1p = s_out + (64 + pc) * 66 + t0;
    float w0[19], w1[19];
#pragma unroll
    for (int j = 0; j < 19; ++j) { w0[j] = bf2f(r0p[j]); w1[j] = bf2f(r1p[j]); }
#pragma unroll
    for (int i = 0; i < 15; ++i) {
      float m = w0[i];
#pragma unroll
      for (int k = 1; k < 5; ++k) m = fmaxf(m, w0[i + k]);
#pragma unroll
      for (int k = 0; k < 5; ++k) m = fmaxf(m, w1[i + k]);
      s_pool[pc * 62 + t0 + i] = f2bf(m + bias);
    }
  }
  __syncthreads();
  // paired u32 stores (T even, cb even -> pairs never straddle the edge)
  for (int i = tid; i < 1920; i += 256) {
    const int c = i / 30, tp = i - c * 30;
    const int gt = cb + 2 * tp;
    if (gt < T) {
      const u32 pair = *(const u32*)&s_pool[c * 62 + 2 * tp];
      *(u32*)&pooled[(((size_t)b * 64 + c) * 58 + h) * T + gt] = pair;
    }
  }
}

// ---------------------------------------------------------------------------
// Split-K GEMM on bf16 MFMA: out[r][n] += pool_bf16[r][:] . lw_bf16[n][:]
// ---------------------------------------------------------------------------
__global__ __launch_bounds__(256) void gemm_splitk_mfma_kernel(
    const u16* __restrict__ A, const u16* __restrict__ Bw,
    float* __restrict__ out) {
  __shared__ __align__(16) u16 sA[64 * 72];
  __shared__ __align__(16) u16 sB[64 * 72];
  const int tid = threadIdx.x;
  const int r0 = blockIdx.x * 64;
  const int s = blockIdx.y;
  const int ch0 = (s * 58) / 8, ch1 = ((s + 1) * 58) / 8;
  const int lane = tid & 63, wave = tid >> 6;
  const int l31 = lane & 31, g8 = (lane >> 5) * 8;
  const int mh = (wave & 1) * 32, nh = (wave >> 1) * 32;
  const int srow = tid >> 2, sseg = (tid & 3) * 16;
  f32x16 acc = {};
  for (int ch = ch0; ch < ch1; ++ch) {
    const int kc = ch * 64;
    __syncthreads();
    {
      const u16* ap = &A[(size_t)(r0 + srow) * 3712 + kc + sseg];
      const u16* bp = &Bw[(size_t)srow * 3712 + kc + sseg];
      u16* da = &sA[srow * 72 + sseg];
      u16* db = &sB[srow * 72 + sseg];
      *(u16x8*)da = *(const u16x8*)ap;
      *(u16x8*)(da + 8) = *(const u16x8*)(ap + 8);
      *(u16x8*)db = *(const u16x8*)bp;
      *(u16x8*)(db + 8) = *(const u16x8*)(bp + 8);
    }
    __syncthreads();
#pragma unroll
    for (int ks = 0; ks < 4; ++ks) {
      bf16x8 a = *(const bf16x8*)&sA[(mh + l31) * 72 + ks * 16 + g8];
      bf16x8 b = *(const bf16x8*)&sB[(nh + l31) * 72 + ks * 16 + g8];
      acc = __builtin_amdgcn_mfma_f32_32x32x16_bf16(a, b, acc, 0, 0, 0);
    }
  }
#pragma unroll
  for (int r = 0; r < 16; ++r) {
    const int row = mh + (r & 3) + 8 * (r >> 2) + (g8 >> 1);
    atomicAdd(&out[(size_t)(r0 + row) * 64 + nh + l31], acc[r]);
  }
}

// ---------------------------------------------------------------------------
// Generic fp32 GEMM (gi = lin @ w_ih^T + bias2). K multiple of 32.
// ---------------------------------------------------------------------------
__global__ __launch_bounds__(256) void gemm_nt_kernel(
    const float* __restrict__ A, const float* __restrict__ Wt,
    const float* __restrict__ bias, float* __restrict__ out,
    const int N, const int K) {
  __shared__ float sA[64 * 33];
  __shared__ float sB[64 * 33];
  const int tid = threadIdx.x;
  const int r0 = blockIdx.x * 64;
  const int n0 = blockIdx.y * 64;
  const int ty = tid >> 4, tx = tid & 15;
  float acc[4][4] = {};
  for (int kc = 0; kc < K; kc += 32) {
    __syncthreads();
#pragma unroll
    for (int rep = 0; rep < 8; ++rep) {
      const int l = tid + rep * 256;
      const int row = l >> 5, kk = l & 31;
      sA[row * 33 + kk] = A[(size_t)(r0 + row) * K + kc + kk];
      sB[row * 33 + kk] = Wt[(size_t)(n0 + row) * K + kc + kk];
    }
    __syncthreads();
#pragma unroll 8
    for (int kk = 0; kk < 32; ++kk) {
      const float a0 = sA[(ty * 4 + 0) * 33 + kk];
      const float a1 = sA[(ty * 4 + 1) * 33 + kk];
      const float a2 = sA[(ty * 4 + 2) * 33 + kk];
      const float a3 = sA[(ty * 4 + 3) * 33 + kk];
      const float b0 = sB[(tx * 4 + 0) * 33 + kk];
      const float b1 = sB[(tx * 4 + 1) * 33 + kk];
      const float b2 = sB[(tx * 4 + 2) * 33 + kk];
      const float b3 = sB[(tx * 4 + 3) * 33 + kk];
      acc[0][0] = fmaf(a0, b0, acc[0][0]); acc[0][1] = fmaf(a0, b1, acc[0][1]);
      acc[0][2] = fmaf(a0, b2, acc[0][2]); acc[0][3] = fmaf(a0, b3, acc[0][3]);
      acc[1][0] = fmaf(a1, b0, acc[1][0]); acc[1][1] = fmaf(a1, b1, acc[1][1]);
      acc[1][2] = fmaf(a1, b2, acc[1][2]); acc[1][3] = fmaf(a1, b3, acc[1][3]);
      acc[2][0] = fmaf(a2, b0, acc[2][0]); acc[2][1] = fmaf(a2, b1, acc[2][1]);
      acc[2][2] = fmaf(a2, b2, acc[2][2]); acc[2][3] = fmaf(a2, b3, acc[2][3]);
      acc[3][0] = fmaf(a3, b0, acc[3][0]); acc[3][1] = fmaf(a3, b1, acc[3][1]);
      acc[3][2] = fmaf(a3, b2, acc[3][2]); acc[3][3] = fmaf(a3, b3, acc[3][3]);
    }
  }
#pragma unroll
  for (int i = 0; i < 4; ++i)
#pragma unroll
    for (int j = 0; j < 4; ++j)
      out[(size_t)(r0 + ty * 4 + i) * N + n0 + tx * 4 + j] =
          acc[i][j] + bias[n0 + tx * 4 + j];
}

// ---------------------------------------------------------------------------
// GRU recurrence (scan over BATCH axis, 4 steps; every t independent).
// ---------------------------------------------------------------------------
__global__ __launch_bounds__(256) void gru_rec_kernel(
    float* __restrict__ xy, const float* __restrict__ gi,
    const float* __restrict__ whh, const float* __restrict__ bhh, const int T) {
  __shared__ float s_whh_t[64 * 192];
  __shared__ float s_h[16][64];
  const int tid = threadIdx.x;
  const int lane = tid & 63, wave = tid >> 6;
  for (int i = tid; i < 192 * 64; i += 256) {
    const int j = i >> 6, d = i & 63;
    s_whh_t[d * 192 + j] = whh[i];
  }
  for (int i = tid; i < 16 * 64; i += 256) (&s_h[0][0])[i] = 0.f;
  const float bhr = bhh[lane], bhz = bhh[64 + lane], bhn = bhh[128 + lane];
  const int t0 = blockIdx.x * 16;
  __syncthreads();
  for (int b = 0; b < 4; ++b) {
    float gir[4], giz[4], gin[4];
#pragma unroll
    for (int sl = 0; sl < 4; ++sl) {
      int t = t0 + wave * 4 + sl; if (t > T - 1) t = T - 1;
      const float* girow = gi + ((size_t)b * T + t) * 192;
      gir[sl] = girow[lane]; giz[sl] = girow[64 + lane]; gin[sl] = girow[128 + lane];
    }
    float ahr[4] = {}, ahz[4] = {}, ahn[4] = {};
    for (int d = 0; d < 64; ++d) {
      const float wr_ = s_whh_t[d * 192 + lane];
      const float wz_ = s_whh_t[d * 192 + 64 + lane];
      const float wn_ = s_whh_t[d * 192 + 128 + lane];
#pragma unroll
      for (int sl = 0; sl < 4; ++sl) {
        const float hv = s_h[wave * 4 + sl][d];
        ahr[sl] = fmaf(wr_, hv, ahr[sl]);
        ahz[sl] = fmaf(wz_, hv, ahz[sl]);
        ahn[sl] = fmaf(wn_, hv, ahn[sl]);
      }
    }
    float hn[4];
#pragma unroll
    for (int sl = 0; sl < 4; ++sl) {
      const float r = 1.f / (1.f + __expf(-(gir[sl] + ahr[sl] + bhr)));
      const float z = 1.f / (1.f + __expf(-(giz[sl] + ahz[sl] + bhz)));
      const float n = tanhf(gin[sl] + r * (ahn[sl] + bhn));
      hn[sl] = (1.f - z) * n + z * s_h[wave * 4 + sl][lane];
    }
    __syncthreads();
#pragma unroll
    for (int sl = 0; sl < 4; ++sl) {
      const int t = t0 + wave * 4 + sl;
      s_h[wave * 4 + sl][lane] = hn[sl];
      if (t < T) xy[((size_t)b * T + t) * 64 + lane] = hn[sl];
    }
    __syncthreads();
  }
}

// ---------------------------------------------------------------------------
// scores: P[b,tau,eps] = sum_d t[b,tau,d]*e[b,eps,d]; P stored bf16.
// ---------------------------------------------------------------------------
__global__ __launch_bounds__(256) void scores_kernel(
    const float* __restrict__ tmat, const float* __restrict__ emat,
    u16* __restrict__ P) {
  __shared__ __align__(16) float sT[64 * 68];
  __shared__ __align__(16) float sE[128 * 68];
  const int tid = threadIdx.x;
  const int b = blockIdx.z;
  const int tau0 = blockIdx.x * 64;
  const int e0 = blockIdx.y * 128;
#pragma unroll
  for (int r = 0; r < 4; ++r) {
    const int q = tid + r * 256;
    const int row = q >> 4, qq = q & 15;
    const float4 v = *(const float4*)&tmat[((size_t)b * 1024 + tau0 + row) * 64 + qq * 4];
    *(float4*)&sT[row * 68 + qq * 4] = v;
  }
#pragma unroll
  for (int r = 0; r < 8; ++r) {
    const int q = tid + r * 256;
    const int row = q >> 4, qq = q & 15;
    int eps = e0 + row; if (eps > 2031) eps = 2031;
    const float4 v = *(const float4*)&emat[((size_t)b * 2032 + eps) * 64 + qq * 4];
    *(float4*)&sE[row * 68 + qq * 4] = v;
  }
  __syncthreads();
  const int ty = tid >> 4, tx = tid & 15;
  float acc[4][8] = {};
#pragma unroll 4
  for (int q = 0; q < 16; ++q) {
    const int kk = q * 4;
    float4 av[4], bv[8];
#pragma unroll
    for (int i = 0; i < 4; ++i) av[i] = *(const float4*)&sT[(ty * 4 + i) * 68 + kk];
#pragma unroll
    for (int j = 0; j < 8; ++j) bv[j] = *(const float4*)&sE[(tx * 8 + j) * 68 + kk];
#pragma unroll
    for (int i = 0; i < 4; ++i)
#pragma unroll
      for (int j = 0; j < 8; ++j) {
        acc[i][j] = fmaf(av[i].x, bv[j].x, acc[i][j]);
        acc[i][j] = fmaf(av[i].y, bv[j].y, acc[i][j]);
        acc[i][j] = fmaf(av[i].z, bv[j].z, acc[i][j]);
        acc[i][j] = fmaf(av[i].w, bv[j].w, acc[i][j]);
      }
  }
#pragma unroll
  for (int i = 0; i < 4; ++i) {
    const size_t prow = ((size_t)b * 1024 + tau0 + ty * 4 + i) * 2032;
#pragma unroll
    for (int j = 0; j < 8; ++j) {
      const int eps = e0 + tx * 8 + j;
      if (eps < 2032) P[prow + eps] = f2bf(acc[i][j]);
    }
  }
}

// ---------------------------------------------------------------------------
// row softmax over eps (bf16 rows of 2032, fp32 math). grid 4096.
// ---------------------------------------------------------------------------
__global__ __launch_bounds__(256) void softmax_rows_kernel(u16* __restrict__ P) {
  __shared__ float s_row[2032];
  __shared__ float sred[4];
  u16* r = P + (size_t)blockIdx.x * 2032;
  const int tid = threadIdx.x;
  const int lane = tid & 63, wave = tid >> 6;
  float m = -3.4e38f;
  for (int i = tid; i < 2032; i += 256) {
    const float v = bf2f(r[i]);
    s_row[i] = v;
    m = fmaxf(m, v);
  }
#pragma unroll
  for (int off = 32; off > 0; off >>= 1) m = fmaxf(m, __shfl_down(m, off, 64));
  if (lane == 0) sred[wave] = m;
  __syncthreads();
  m = fmaxf(fmaxf(sred[0], sred[1]), fmaxf(sred[2], sred[3]));
  __syncthreads();
  float s = 0.f;
  float vals[8];
  int cnt = 0;
  for (int i = tid; i < 2032; i += 256) {
    const float v = __expf(s_row[i] - m);
    vals[cnt++] = v;
    s += v;
  }
#pragma unroll
  for (int off = 32; off > 0; off >>= 1) s += __shfl_down(s, off, 64);
  if (lane == 0) sred[wave] = s;
  __syncthreads();
  const float inv = 1.f / (sred[0] + sred[1] + sred[2] + sred[3]);
  cnt = 0;
  for (int i = tid; i < 2032; i += 256) r[i] = f2bf(vals[cnt++] * inv);
}

// ---------------------------------------------------------------------------
// pv partial: PV[b,eps,d] += sum_{tau slice} P[b,tau,eps]*t[b,tau,d] (P bf16)
// ---------------------------------------------------------------------------
__global__ __launch_bounds__(256) void pv_kernel(
    const u16* __restrict__ P, const float* __restrict__ tmat,
    float* __restrict__ PV) {
  __shared__ float sP[32 * 65];
  __shared__ float sT[32 * 65];
  const int tid = threadIdx.x;
  const int b = blockIdx.z;
  const int e0 = blockIdx.x * 64;
  const int tau_base = blockIdx.y * 256;
  const int ty = tid >> 4, tx = tid & 15;
  float acc[4][4] = {};
  for (int kc = tau_base; kc < tau_base + 256; kc += 32) {
    __syncthreads();
    for (int l = tid; l < 32 * 64; l += 256) {
      const int kk = l >> 6, j = l & 63;
      int eps = e0 + j; if (eps > 2031) eps = 2031;
      sP[kk * 65 + j] = bf2f(P[((size_t)b * 1024 + kc + kk) * 2032 + eps]);
      sT[kk * 65 + j] = tmat[((size_t)b * 1024 + kc + kk) * 64 + j];
    }
    __syncthreads();
#pragma unroll 8
    for (int kk = 0; kk < 32; ++kk) {
      const float a0 = sP[kk * 65 + ty * 4 + 0];
      const float a1 = sP[kk * 65 + ty * 4 + 1];
      const float a2 = sP[kk * 65 + ty * 4 + 2];
      const float a3 = sP[kk * 65 + ty * 4 + 3];
      const float b0 = sT[kk * 65 + tx * 4 + 0];
      const float b1 = sT[kk * 65 + tx * 4 + 1];
      const float b2 = sT[kk * 65 + tx * 4 + 2];
      const float b3 = sT[kk * 65 + tx * 4 + 3];
      acc[0][0] = fmaf(a0, b0, acc[0][0]); acc[0][1] = fmaf(a0, b1, acc[0][1]);
      acc[0][2] = fmaf(a0, b2, acc[0][2]); acc[0][3] = fmaf(a0, b3, acc[0][3]);
      acc[1][0] = fmaf(a1, b0, acc[1][0]); acc[1][1] = fmaf(a1, b1, acc[1][1]);
      acc[1][2] = fmaf(a1, b2, acc[1][2]); acc[1][3] = fmaf(a1, b3, acc[1][3]);
      acc[2][0] = fmaf(a2, b0, acc[2][0]); acc[2][1] = fmaf(a2, b1, acc[2][1]);
      acc[2][2] = fmaf(a2, b2, acc[2][2]); acc[2][3] = fmaf(a2, b3, acc[2][3]);
      acc[3][0] = fmaf(a3, b0, acc[3][0]); acc[3][1] = fmaf(a3, b1, acc[3][1]);
      acc[3][2] = fmaf(a3, b2, acc[3][2]); acc[3][3] = fmaf(a3, b3, acc[3][3]);
    }
  }
#pragma unroll
  for (int i = 0; i < 4; ++i) {
    const int eps = e0 + ty * 4 + i;
    if (eps < 2032) {
#pragma unroll
      for (int j = 0; j < 4; ++j)
        atomicAdd(&PV[((size_t)b * 2032 + eps) * 64 + tx * 4 + j], acc[i][j]);
    }
  }
}

// ---------------------------------------------------------------------------
// att_logits: logits[b,i] = dot(e[b,i,:], a_w) + a_b. grid (32, 4).
// ---------------------------------------------------------------------------
__global__ __launch_bounds__(256) void att_logits_kernel(
    const float* __restrict__ emat, const float* __restrict__ a_w,
    const float* __restrict__ a_b, float* __restrict__ logits) {
  __shared__ float s_aw[64];
  const int tid = threadIdx.x;
  const int lane = tid & 63, wave = tid >> 6;
  if (tid < 64) s_aw[tid] = a_w[tid];
  __syncthreads();
  const int b = blockIdx.y;
  const float ab = a_b[0];
  const int base = blockIdx.x * 64 + wave * 16;
#pragma unroll 4
  for (int r = 0; r < 16; ++r) {
    const int i = base + r;
    if (i < 2032) {
      float v = emat[((size_t)b * 2032 + i) * 64 + lane] * s_aw[lane];
#pragma unroll
      for (int off = 32; off > 0; off >>= 1) v += __shfl_down(v, off, 64);
      if (lane == 0) logits[b * 2032 + i] = v + ab;
    }
  }
}

// ---------------------------------------------------------------------------
// att_softmax: in-place softmax over 2032 logits per batch. grid 4.
// ---------------------------------------------------------------------------
__global__ __launch_bounds__(256) void att_softmax_kernel(float* __restrict__ att) {
  __shared__ float s_v[2032];
  __shared__ float sred[4];
  float* r = att + (size_t)blockIdx.x * 2032;
  const int tid = threadIdx.x;
  const int lane = tid & 63, wave = tid >> 6;
  float m = -3.4e38f;
  for (int i = tid; i < 2032; i += 256) {
    const float v = r[i];
    s_v[i] = v;
    m = fmaxf(m, v);
  }
#pragma unroll
  for (int off = 32; off > 0; off >>= 1) m = fmaxf(m, __shfl_down(m, off, 64));
  if (lane == 0) sred[wave] = m;
  __syncthreads();
  m = fmaxf(fmaxf(sred[0], sred[1]), fmaxf(sred[2], sred[3]));
  __syncthreads();
  float s = 0.f;
  float vals[8];
  int cnt = 0;
  for (int i = tid; i < 2032; i += 256) {
    const float v = __expf(s_v[i] - m);
    vals[cnt++] = v;
    s += v;
  }
#pragma unroll
  for (int off = 32; off > 0; off >>= 1) s += __shfl_down(s, off, 64);
  if (lane == 0) sred[wave] = s;
  __syncthreads();
  const float inv = 1.f / (sred[0] + sred[1] + sred[2] + sred[3]);
  cnt = 0;
  for (int i = tid; i < 2032; i += 256) r[i] = vals[cnt++] * inv;
}

// ---------------------------------------------------------------------------
// red_reduce: red[b,d] += sum_{i in slice} |PV-e|[b,i,d] * att[b,i].
// ---------------------------------------------------------------------------
__global__ __launch_bounds__(256) void red_reduce_kernel(
    const float* __restrict__ emat, const float* __restrict__ PV,
    const float* __restrict__ att, float* __restrict__ red) {
  __shared__ float s_part[4][64];
  const int tid = threadIdx.x;
  const int lane = tid & 63, wave = tid >> 6;
  const int b = blockIdx.y;
  const int i0 = blockIdx.x * 127;
  float acc = 0.f;
  for (int i = i0 + wave; i < i0 + 127; i += 4) {
    const size_t idx = ((size_t)b * 2032 + i) * 64 + lane;
    acc = fmaf(fabsf(PV[idx] - emat[idx]), att[b * 2032 + i], acc);
  }
  s_part[wave][lane] = acc;
  __syncthreads();
  if (tid < 64)
    atomicAdd(&red[b * 64 + tid],
              s_part[0][tid] + s_part[1][tid] + s_part[2][tid] + s_part[3][tid]);
}

// ---------------------------------------------------------------------------
// mlp: h = relu(red@h_w^T + h_b); out = softmax(h@c_w^T + c_b). grid 4.
// ---------------------------------------------------------------------------
__global__ __launch_bounds__(128) void mlp_kernel(
    const float* __restrict__ red, const float* __restrict__ h_w,
    const float* __restrict__ h_b, const float* __restrict__ c_w,
    const float* __restrict__ c_b, float* __restrict__ out) {
  __shared__ float s_red[64];
  __shared__ float s_hv[128];
  const int tid = threadIdx.x;
  const int b = blockIdx.x;
  if (tid < 64) s_red[tid] = red[b * 64 + tid];
  __syncthreads();
  {
    float acc = h_b[tid];
    const float* hw = h_w + tid * 64;
    for (int d = 0; d < 64; ++d) acc = fmaf(s_red[d], hw[d], acc);
    s_hv[tid] = fmaxf(acc, 0.f);
  }
  __syncthreads();
  if (tid == 0) {
    float l0 = c_b[0], l1 = c_b[1];
    for (int j = 0; j < 128; ++j) {
      l0 = fmaf(s_hv[j], c_w[j], l0);
      l1 = fmaf(s_hv[j], c_w[128 + j], l1);
    }
    const float mm = fmaxf(l0, l1);
    const float e0 = __expf(l0 - mm), e1 = __expf(l1 - mm);
    const float invs = 1.f / (e0 + e1);
    out[b * 2 + 0] = e0 * invs;
    out[b * 2 + 1] = e1 * invs;
  }
}

// ===========================================================================
extern "C" void kernel_launch(void* const* d_in, const int* in_sizes, int n_in,
                              void* d_out, int out_size, void* d_ws, size_t ws_size,
                              hipStream_t stream) {
  const float* evaluation = (const float*)d_in[0];
  const float* templ      = (const float*)d_in[1];
  const float* e_w1 = (const float*)d_in[2];
  const float* e_b1 = (const float*)d_in[3];
  const float* e_w2 = (const float*)d_in[4];
  const float* e_b2 = (const float*)d_in[5];
  const float* e_w3 = (const float*)d_in[6];
  const float* e_b3 = (const float*)d_in[7];
  const float* el_w = (const float*)d_in[8];
  const float* el_b = (const float*)d_in[9];
  const float* eg_wih = (const float*)d_in[10];
  const float* eg_whh = (const float*)d_in[11];
  const float* eg_bih = (const float*)d_in[12];
  const float* eg_bhh = (const float*)d_in[13];
  const float* t_w1 = (const float*)d_in[14];
  const float* t_b1 = (const float*)d_in[15];
  const float* t_w2 = (const float*)d_in[16];
  const float* t_b2 = (const float*)d_in[17];
  const float* t_w3 = (const float*)d_in[18];
  const float* t_b3 = (const float*)d_in[19];
  const float* tl_w = (const float*)d_in[20];
  const float* tl_b = (const float*)d_in[21];
  const float* tg_wih = (const float*)d_in[22];
  const float* tg_whh = (const float*)d_in[23];
  const float* tg_bih = (const float*)d_in[24];
  const float* tg_bhh = (const float*)d_in[25];
  const float* a_w = (const float*)d_in[26];
  const float* a_b = (const float*)d_in[27];
  const float* h_w = (const float*)d_in[28];
  const float* h_b = (const float*)d_in[29];
  const float* c_w = (const float*)d_in[30];
  const float* c_b = (const float*)d_in[31];

  float* ws = (float*)d_ws;
  float* beff_e  = ws + OFF_BEFF_E;
  float* beff_t  = ws + OFF_BEFF_T;
  float* bias2_e = ws + OFF_BIAS2_E;
  float* bias2_t = ws + OFF_BIAS2_T;
  u16*   wbf_e   = (u16*)(ws + OFF_WBF_E);
  u16*   wbf_t   = (u16*)(ws + OFF_WBF_T);
  float* w12p_e  = ws + OFF_W12P_E;
  float* w12p_t  = ws + OFF_W12P_T;
  float* b12_e   = ws + OFF_B12_E;
  float* b12_t   = ws + OFF_B12_T;
  u16*   lwbf_e  = (u16*)(ws + OFF_LWBF_E);
  u16*   lwbf_t  = (u16*)(ws + OFF_LWBF_T);
  u16*   pool    = (u16*)(ws + OFF_POOL);
  float* gibuf   = ws + OFF_GI;
  u16*   Pbuf    = (u16*)(ws + OFF_P);
  float* PVbuf   = ws + OFF_PV;
  float* redbuf  = ws + OFF_RED;
  float* lin_e   = ws + OFF_LIN_E;
  float* lin_t   = ws + OFF_LIN_T;
  float* attbuf  = ws + OFF_ATT;

  // weight composition chain + folded gi biases + lw->bf16
  compose12_kernel<<<dim3(32, 2), 320, 0, stream>>>(
      e_w1, e_b1, e_w2, e_b2, t_w1, t_b1, t_w2, t_b2, w12p_e, w12p_t, b12_e, b12_t);
  compose_weff_kernel<<<dim3(64, 2), 256, 0, stream>>>(
      e_w3, e_b3, t_w3, t_b3, w12p_e, w12p_t, b12_e, b12_t, wbf_e, wbf_t, beff_e, beff_t);
  gi_bias_kernel<<<2, 256, 0, stream>>>(eg_wih, eg_bih, el_b, bias2_e,
                                        tg_wih, tg_bih, tl_b, bias2_t);
  tobf16_kernel<<<dim3(232, 2), 256, 0, stream>>>(el_w, tl_w, lwbf_e, lwbf_t);

  // zero lin_e + lin_t (contiguous) for split-K atomics
  hipMemsetAsync(lin_e, 0, (520192 + 262144) * sizeof(float), stream);

  // eval branch: MFMA conv+pool (bf16 out) -> MFMA split-K linear
  conv_pool_mfma_kernel<<<dim3(34, 58, 4), 256, 0, stream>>>(evaluation, wbf_e, beff_e, pool, 2048, 2032);
  gemm_splitk_mfma_kernel<<<dim3(127, 8), 256, 0, stream>>>(pool, lwbf_e, lin_e);
  // template branch
  conv_pool_mfma_kernel<<<dim3(18, 58, 4), 256, 0, stream>>>(templ, wbf_t, beff_t, pool, 1040, 1024);
  gemm_splitk_mfma_kernel<<<dim3(64, 8), 256, 0, stream>>>(pool, lwbf_t, lin_t);

  // zero PV + red (contiguous; lives in dead pool region, after last pool read)
  hipMemsetAsync(PVbuf, 0, (520192 + 256) * sizeof(float), stream);

  // GRU (scan over batch axis)
  gemm_nt_kernel<<<dim3(127, 3), 256, 0, stream>>>(lin_e, eg_wih, bias2_e, gibuf, 192, 64);
  gru_rec_kernel<<<127, 256, 0, stream>>>(lin_e, gibuf, eg_whh, eg_bhh, 2032);
  gemm_nt_kernel<<<dim3(64, 3), 256, 0, stream>>>(lin_t, tg_wih, bias2_t, gibuf, 192, 64);
  gru_rec_kernel<<<64, 256, 0, stream>>>(lin_t, gibuf, tg_whh, tg_bhh, 1024);

  // cross attention (P in bf16)
  scores_kernel<<<dim3(16, 16, 4), 256, 0, stream>>>(lin_t, lin_e, Pbuf);
  softmax_rows_kernel<<<4096, 256, 0, stream>>>(Pbuf);
  pv_kernel<<<dim3(32, 4, 4), 256, 0, stream>>>(Pbuf, lin_t, PVbuf);

  // head: logits -> softmax -> weighted reduce -> MLP
  att_logits_kernel<<<dim3(32, 4), 256, 0, stream>>>(lin_e, a_w, a_b, attbuf);
  att_softmax_kernel<<<4, 256, 0, stream>>>(attbuf);
  red_reduce_kernel<<<dim3(16, 4), 256, 0, stream>>>(lin_e, PVbuf, attbuf, redbuf);
  mlp_kernel<<<4, 128, 0, stream>>>(redbuf, h_w, h_b, c_w, c_b, (float*)d_out);
}

// Round 9
// 415.175 us; speedup vs baseline: 7.4801x; 1.1536x over previous
//
#include <hip/hip_runtime.h>
#include <cmath>

// ============================================================================
// DeepTemplateMatchingModule on MI355X — round 9.
// R8 post-mortem: work sums to ~240us but total is 479us — ~230us is the 23
// serialized graph-node boundaries. conv staging still double-writes x.
// R9:
//  (1) node collapse 23->13: eval+tmpl merged per stage (conv z=8 early-exit,
//      splitk 191x8, gi 191x3, gru 191 w/ fused att_logits for eval); prep
//      kernels merged; ONE upfront memset (lin/PV/red contiguous, un-aliased).
//  (2) conv parity moved into weights (wkxA slots 0-12 / wkxB slots 1-13):
//      both parities read the SAME aligned x fragment -> single x copy staged
//      as packed u32 row-pairs; pooling epilogue 135->79 fmax.
// ============================================================================

typedef unsigned short u16;
typedef unsigned int u32;
typedef __attribute__((ext_vector_type(8))) short bf16x8;
typedef __attribute__((ext_vector_type(8))) unsigned short u16x8;
typedef __attribute__((ext_vector_type(16))) float f32x16;

__device__ __forceinline__ u16 f2bf(float f) {
  unsigned int x = __float_as_uint(f);
  return (u16)((x + 0x7fffu + ((x >> 16) & 1u)) >> 16);
}
__device__ __forceinline__ float bf2f(u16 v) {
  return __uint_as_float(((unsigned int)v) << 16);
}

// ---- workspace layout (float offsets) ----
static const size_t OFF_BEFF_E  = 0;          // 64
static const size_t OFF_BEFF_T  = 64;         // 64
static const size_t OFF_BIAS2_E = 128;        // 192
static const size_t OFF_BIAS2_T = 320;        // 192
static const size_t OFF_WKX_E   = 512;        // 13312 f (2 parities x 13x64x16 u16)
static const size_t OFF_WKX_T   = 13824;      // 13312 f
static const size_t OFF_W12P_E  = 27136;      // 9248
static const size_t OFF_W12P_T  = 36384;      // 9248
static const size_t OFF_B12_E   = 45632;      // 32
static const size_t OFF_B12_T   = 45664;      // 32
static const size_t OFF_LWBF_E  = 45696;      // 118,784 f (237,568 u16)
static const size_t OFF_LWBF_T  = 164480;     // 118,784 f
static const size_t OFF_ATT     = 283264;     // 8,128 f
// one contiguous memset region: lin_e, lin_t, PV, red
static const size_t OFF_LIN_E   = 291392;     // 520,192 f
static const size_t OFF_LIN_T   = 811584;     // 262,144 f
static const size_t OFF_PV      = 1073728;    // 520,192 f
static const size_t OFF_RED     = 1593920;    // 256 f
static const size_t MEMSET_LEN  = 520192 + 262144 + 520192 + 256;  // 1,302,784 f
// both pools coexist (branches merged into single dispatches)
static const size_t OFF_POOL_E  = 1594176;    // u16 pool: 30,171,136 u16 (15,085,568 f)
static const size_t OFF_POOL_T  = 16679744;   // u16 pool: 15,204,352 u16 (7,602,176 f)
// dead-pool_e reuse (after splitk_both):
static const size_t OFF_GI_E    = OFF_POOL_E;             // 1,560,576 f
static const size_t OFF_GI_T    = OFF_POOL_E + 1560576;   // 786,432 f
static const size_t OFF_P       = OFF_POOL_E + 2347008;   // u16: 8,323,072 u16

// ---------------------------------------------------------------------------
// prep: merged compose12 (bx<64) + gi_bias (bx 64..65) + lw->bf16 (bx>=66).
// 320 threads. grid 530.
// ---------------------------------------------------------------------------
__global__ __launch_bounds__(320) void prep_kernel(
    const float* __restrict__ w1e, const float* __restrict__ b1e,
    const float* __restrict__ w2e, const float* __restrict__ b2e,
    const float* __restrict__ w1t, const float* __restrict__ b1t,
    const float* __restrict__ w2t, const float* __restrict__ b2t,
    float* __restrict__ w12p_e, float* __restrict__ w12p_t,
    float* __restrict__ b12o_e, float* __restrict__ b12o_t,
    const float* __restrict__ wih_e, const float* __restrict__ bih_e,
    const float* __restrict__ lb_e, float* __restrict__ bias2_e,
    const float* __restrict__ wih_t, const float* __restrict__ bih_t,
    const float* __restrict__ lb_t, float* __restrict__ bias2_t,
    const float* __restrict__ lwe, const float* __restrict__ lwt,
    u16* __restrict__ lwbf_e, u16* __restrict__ lwbf_t) {
  const int bx = blockIdx.x;
  const int tid = threadIdx.x;
  if (bx >= 66) {  // tobf16
    if (tid < 256) {
      const int k = bx - 66;
      const int br = k / 232, j = k - br * 232;
      const float* src = br ? lwt : lwe;
      u16* dst = br ? lwbf_t : lwbf_e;
      const int i = (j * 256 + tid) * 4;
      const float4 v = *(const float4*)&src[i];
      dst[i] = f2bf(v.x); dst[i + 1] = f2bf(v.y);
      dst[i + 2] = f2bf(v.z); dst[i + 3] = f2bf(v.w);
    }
    return;
  }
  if (bx >= 64) {  // gi_bias
    const int br = bx - 64;
    const float* wih = br ? wih_t : wih_e;
    const float* bih = br ? bih_t : bih_e;
    const float* lb = br ? lb_t : lb_e;
    float* bias2 = br ? bias2_t : bias2_e;
    __shared__ float s_lb[64];
    if (tid < 64) s_lb[tid] = lb[tid];
    __syncthreads();
    if (tid < 192) {
      float acc = bih[tid];
      const float* wr = wih + tid * 64;
      for (int d = 0; d < 64; ++d) acc = fmaf(wr[d], s_lb[d], acc);
      bias2[tid] = acc;
    }
    return;
  }
  // compose12
  const int br = bx >> 5;
  const float* w1 = br ? w1t : w1e;
  const float* b1 = br ? b1t : b1e;
  const float* w2 = br ? w2t : w2e;
  const float* b2 = br ? b2t : b2e;
  float* w12p = br ? w12p_t : w12p_e;
  float* b12o = br ? b12o_t : b12o_e;
  const int c12 = bx & 31;
  __shared__ float s_w1pad[16 * 169];
  __shared__ float s_w2c[400];
  __shared__ float s_b1[16];
  for (int i = tid; i < 2704; i += 320) s_w1pad[i] = 0.f;
  if (tid < 16) s_b1[tid] = b1[tid];
  __syncthreads();
  for (int i = tid; i < 400; i += 320) {
    const int c1 = i / 25, r = (i % 25) / 5, cc = i % 5;
    s_w1pad[c1 * 169 + (r + 4) * 13 + (cc + 4)] = w1[i];
    s_w2c[i] = w2[c12 * 400 + i];
  }
  __syncthreads();
  if (tid < 289) {
    const int py = tid / 17, px = tid % 17;
    float v = 0.f;
    if (py >= 4 && py <= 12 && px >= 4 && px <= 12) {
      const int sy = py - 4, sx = px - 4;
      float accs[2] = {0.f, 0.f};
      for (int c1 = 0; c1 < 16; ++c1) {
        const float* w2p = s_w2c + c1 * 25;
        const float* w1p = s_w1pad + c1 * 169 + (sy + 4) * 13 + (sx + 4);
#pragma unroll
      for (int uy = 0; uy < 5; ++uy)
#pragma unroll
        for (int ux = 0; ux < 5; ++ux)
          accs[uy & 1] = fmaf(w2p[uy * 5 + ux], w1p[-(uy * 13) - ux], accs[uy & 1]);
      }
      v = accs[0] + accs[1];
    }
    w12p[c12 * 289 + tid] = v;
  } else if (tid == 300) {
    float acc = b2[c12];
    for (int c1 = 0; c1 < 16; ++c1) {
      float sw = 0.f;
      for (int u = 0; u < 25; ++u) sw += s_w2c[c1 * 25 + u];
      acc = fmaf(sw, s_b1[c1], acc);
    }
    b12o[c12] = acc;
  }
}

// ---------------------------------------------------------------------------
// compose_weff: emits BOTH parity layouts wkx[(P*13+kx)*64+o][ky16] bf16:
// A: slots 0..12 = w[ky], 13..15 = 0 ; B: slots 1..13 = w[ky-1], 0,14,15 = 0.
// grid (64 o, 2 branches), 256 threads.
// ---------------------------------------------------------------------------
__global__ __launch_bounds__(256) void compose_weff_kernel(
    const float* __restrict__ w3e, const float* __restrict__ b3e,
    const float* __restrict__ w3t, const float* __restrict__ b3t,
    const float* __restrict__ w12p_e, const float* __restrict__ w12p_t,
    const float* __restrict__ b12_e, const float* __restrict__ b12_t,
    u16* __restrict__ wkx_e, u16* __restrict__ wkx_t,
    float* __restrict__ beff_e, float* __restrict__ beff_t) {
  const int br = blockIdx.y;
  const float* w3 = br ? w3t : w3e;
  const float* b3 = br ? b3t : b3e;
  const float* w12p = br ? w12p_t : w12p_e;
  const float* b12 = br ? b12_t : b12_e;
  u16* wkx = br ? wkx_t : wkx_e;
  float* beff = br ? beff_t : beff_e;
  const int o = blockIdx.x;
  __shared__ float s_pad[32 * 289];
  __shared__ float s_w3o[800];
  __shared__ float s_b12[32];
  const int tid = threadIdx.x;
  for (int i = tid; i < 9248; i += 256) s_pad[i] = w12p[i];
  for (int i = tid; i < 800; i += 256) s_w3o[i] = w3[o * 800 + i];
  if (tid < 32) s_b12[tid] = b12[tid];
  __syncthreads();
  if (tid < 169) {
    const int sy = tid / 13, sx = tid % 13;  // sy = ky, sx = kx
    float accs[4] = {0.f, 0.f, 0.f, 0.f};
#pragma unroll 4
    for (int c = 0; c < 32; ++c) {
      const float* w3p = s_w3o + c * 25;
      const float* wp = s_pad + c * 289 + (sy + 4) * 17 + (sx + 4);
#pragma unroll
      for (int uy = 0; uy < 5; ++uy)
#pragma unroll
        for (int ux = 0; ux < 5; ++ux)
          accs[c & 3] = fmaf(w3p[uy * 5 + ux], wp[-(uy * 17) - ux], accs[c & 3]);
    }
    const u16 v = f2bf(accs[0] + accs[1] + accs[2] + accs[3]);
    wkx[(sx * 64 + o) * 16 + sy] = v;               // parity A (conv row 2h)
    wkx[((13 + sx) * 64 + o) * 16 + sy + 1] = v;    // parity B (conv row 2h+1)
  } else if (tid < 208) {
    const int p = tid - 169, kx = p / 3, q = p % 3;
    wkx[(kx * 64 + o) * 16 + 13 + q] = 0;                       // A pads 13..15
    wkx[((13 + kx) * 64 + o) * 16 + (q == 0 ? 0 : 13 + q)] = 0; // B pads 0,14,15
  } else if (tid == 208) {
    float acc = b3[o];
    for (int c = 0; c < 32; ++c) {
      float sw = 0.f;
      for (int u = 0; u < 25; ++u) sw += s_w3o[c * 25 + u];
      acc = fmaf(sw, s_b12[c], acc);
    }
    beff[o] = acc;
  }
}

// ---------------------------------------------------------------------------
// MFMA conv13x13 + maxpool(2,5)/(2,1), BOTH branches (z<4 eval, z>=4 tmpl).
// Single x copy s_x[80][24] (u32 row-pair staging); parity carried by wkx
// (A/B weight layouts) so both parities read identical aligned fragments.
// grid (34, 58, 8); tmpl blocks with cb >= T early-exit.
// ---------------------------------------------------------------------------
__global__ __launch_bounds__(256, 4) void conv_pool_mfma_kernel(
    const float* __restrict__ xe, const u16* __restrict__ wkx_e,
    const float* __restrict__ beff_e, u16* __restrict__ pooled_e,
    const float* __restrict__ xt, const u16* __restrict__ wkx_t,
    const float* __restrict__ beff_t, u16* __restrict__ pooled_t) {
  const int zz = blockIdx.z;
  const bool ev = zz < 4;
  const int b = ev ? zz : zz - 4;
  const int W = ev ? 2048 : 1040;
  const int T = ev ? 2032 : 1024;
  const int cb = blockIdx.x * 60;
  if (cb >= T) return;
  const float* x = ev ? xe : xt;
  const u16* wkx = ev ? wkx_e : wkx_t;
  const float* beff = ev ? beff_e : beff_t;
  u16* pooled = ev ? pooled_e : pooled_t;

  __shared__ __align__(16) char s_all[24832];
  u16* s_x = (u16*)s_all;               // [80][24]: rows 0..13, slots 14..15 = 0
  u16* s_out = (u16*)s_all;             // [2][64][66] bf16 (after MFMA)
  u16* s_pool = (u16*)(s_all + 16896);  // [64][62] bf16

  const int tid = threadIdx.x;
  const int lane = tid & 63, wave = tid >> 6;
  const int h = blockIdx.y;
  const int rsel = wave & 1, cm = (wave >> 1) * 32;
  const int l31 = lane & 31, g8 = (lane >> 5) * 8;

  // weight fragments to VGPRs (parity baked into layout; L1/L2-hot)
  bf16x8 wfrag[13];
  {
    const u16* aw = wkx + ((rsel * 13) * 64 + cm + l31) * 16 + g8;
#pragma unroll
    for (int kx = 0; kx < 13; ++kx) wfrag[kx] = *(const bf16x8*)(aw + kx * 1024);
  }
  // zero ky-pad slots 14,15 (one u32 per col)
  if (tid < 80) *(u32*)&s_x[tid * 24 + 14] = 0;
  // stage x rows 0..13 as packed u32 row-pairs
  {
    const float* xb = x + ((size_t)b * 128 + 2 * h) * W;
    for (int i = tid; i < 560; i += 256) {  // 7 row-pairs x 80 cols
      const int pr = i / 80, c = i - pr * 80;
      int gc = cb + c;
      if (gc > W - 1) gc = W - 1;  // clamped cols never feed stored outputs
      const u16 v0 = f2bf(xb[(size_t)(2 * pr) * W + gc]);
      const u16 v1 = f2bf(xb[(size_t)(2 * pr + 1) * W + gc]);
      *(u32*)&s_x[c * 24 + 2 * pr] = (u32)v0 | ((u32)v1 << 16);
    }
  }
  __syncthreads();
  f32x16 acc0 = {}, acc1 = {};
  const u16* bx = s_x + g8;
#pragma unroll
  for (int kx = 0; kx < 13; ++kx) {
    bf16x8 b0 = *(const bf16x8*)(bx + (l31 + kx) * 24);
    bf16x8 b1 = *(const bf16x8*)(bx + (32 + l31 + kx) * 24);
    acc0 = __builtin_amdgcn_mfma_f32_32x32x16_bf16(wfrag[kx], b0, acc0, 0, 0, 0);
    acc1 = __builtin_amdgcn_mfma_f32_32x32x16_bf16(wfrag[kx], b1, acc1, 0, 0, 0);
  }
  __syncthreads();  // x tile dead; reuse LDS for epilogue
#pragma unroll
  for (int r = 0; r < 16; ++r) {
    const int c = cm + (r & 3) + 8 * (r >> 2) + (g8 >> 1);  // +4*(lane>>5)
    u16* o = s_out + (rsel * 64 + c) * 66;
    o[l31] = f2bf(acc0[r]);
    o[32 + l31] = f2bf(acc1[r]);
  }
  __syncthreads();
  {
    const int pc = tid & 63, tg = tid >> 6;
    const int t0 = tg * 15;  // 4 x 15 = 60 pooled cols
    const float bias = beff[pc];
    const u16* r0p = s_out + pc * 66 + t0;
    const u16* r1p = s_out + (64 + pc) * 66 + t0;
    float m01[19];
#pragma unroll
    for (int j = 0; j < 19; ++j) m01[j] = fmaxf(bf2f(r0p[j]), bf2f(r1p[j]));
#pragma unroll
    for (int i = 0; i < 15; ++i) {
      float m = m01[i];
#pragma unroll
      for (int k = 1; k < 5; ++k) m = fmaxf(m, m01[i + k]);
      s_pool[pc * 62 + t0 + i] = f2bf(m + bias);
    }
  }
  __syncthreads();
  // paired u32 stores (T, cb even -> pairs never straddle)
  for (int i = tid; i < 1920; i += 256) {
    const int c = i / 30, tp = i - c * 30;
    const int gt = cb + 2 * tp;
    if (gt < T) {
      const u32 pair = *(const u32*)&s_pool[c * 62 + 2 * tp];
      *(u32*)&pooled[(((size_t)b * 64 + c) * 58 + h) * T + gt] = pair;
    }
  }
}

// ---------------------------------------------------------------------------
// Split-K GEMM on bf16 MFMA, BOTH branches: grid (191, 8); bx<127 eval.
// ---------------------------------------------------------------------------
__global__ __launch_bounds__(256) void gemm_splitk_mfma_kernel(
    const u16* __restrict__ Ae, const u16* __restrict__ Bwe, float* __restrict__ oute,
    const u16* __restrict__ At, const u16* __restrict__ Bwt, float* __restrict__ outt) {
  const int bx = blockIdx.x;
  const bool ev = bx < 127;
  const u16* A = ev ? Ae : At;
  const u16* Bw = ev ? Bwe : Bwt;
  float* out = ev ? oute : outt;
  const int r0 = (ev ? bx : bx - 127) * 64;
  __shared__ __align__(16) u16 sA[64 * 72];
  __shared__ __align__(16) u16 sB[64 * 72];
  const int tid = threadIdx.x;
  const int s = blockIdx.y;
  const int ch0 = (s * 58) / 8, ch1 = ((s + 1) * 58) / 8;
  const int lane = tid & 63, wave = tid >> 6;
  const int l31 = lane & 31, g8 = (lane >> 5) * 8;
  const int mh = (wave & 1) * 32, nh = (wave >> 1) * 32;
  const int srow = tid >> 2, sseg = (tid & 3) * 16;
  f32x16 acc = {};
  for (int ch = ch0; ch < ch1; ++ch) {
    const int kc = ch * 64;
    __syncthreads();
    {
      const u16* ap = &A[(size_t)(r0 + srow) * 3712 + kc + sseg];
      const u16* bp = &Bw[(size_t)srow * 3712 + kc + sseg];
      u16* da = &sA[srow * 72 + sseg];
      u16* db = &sB[srow * 72 + sseg];
      *(u16x8*)da = *(const u16x8*)ap;
      *(u16x8*)(da + 8) = *(const u16x8*)(ap + 8);
      *(u16x8*)db = *(const u16x8*)bp;
      *(u16x8*)(db + 8) = *(const u16x8*)(bp + 8);
    }
    __syncthreads();
#pragma unroll
    for (int ks = 0; ks < 4; ++ks) {
      bf16x8 a = *(const bf16x8*)&sA[(mh + l31) * 72 + ks * 16 + g8];
      bf16x8 b = *(const bf16x8*)&sB[(nh + l31) * 72 + ks * 16 + g8];
      acc = __builtin_amdgcn_mfma_f32_32x32x16_bf16(a, b, acc, 0, 0, 0);
    }
  }
#pragma unroll
  for (int r = 0; r < 16; ++r) {
    const int row = mh + (r & 3) + 8 * (r >> 2) + (g8 >> 1);
    atomicAdd(&out[(size_t)(r0 + row) * 64 + nh + l31], acc[r]);
  }
}

// ---------------------------------------------------------------------------
// gi GEMM, BOTH branches: grid (191, 3); N=192, K=64.
// ---------------------------------------------------------------------------
__global__ __launch_bounds__(256) void gemm_gi_kernel(
    const float* __restrict__ Ae, const float* __restrict__ Wte,
    const float* __restrict__ biase, float* __restrict__ oute,
    const float* __restrict__ At, const float* __restrict__ Wtt,
    const float* __restrict__ biast, float* __restrict__ outt) {
  const int bx = blockIdx.x;
  const bool ev = bx < 127;
  const float* A = ev ? Ae : At;
  const float* Wt = ev ? Wte : Wtt;
  const float* bias = ev ? biase : biast;
  float* out = ev ? oute : outt;
  const int r0 = (ev ? bx : bx - 127) * 64;
  const int N = 192, K = 64;
  __shared__ float sA[64 * 33];
  __shared__ float sB[64 * 33];
  const int tid = threadIdx.x;
  const int n0 = blockIdx.y * 64;
  const int ty = tid >> 4, tx = tid & 15;
  float acc[4][4] = {};
  for (int kc = 0; kc < K; kc += 32) {
    __syncthreads();
#pragma unroll
    for (int rep = 0; rep < 8; ++rep) {
      const int l = tid + rep * 256;
      const int row = l >> 5, kk = l & 31;
      sA[row * 33 + kk] = A[(size_t)(r0 + row) * K + kc + kk];
      sB[row * 33 + kk] = Wt[(size_t)(n0 + row) * K + kc + kk];
    }
    __syncthreads();
#pragma unroll 8
    for (int kk = 0; kk < 32; ++kk) {
      const float a0 = sA[(ty * 4 + 0) * 33 + kk];
      const float a1 = sA[(ty * 4 + 1) * 33 + kk];
      const float a2 = sA[(ty * 4 + 2) * 33 + kk];
      const float a3 = sA[(ty * 4 + 3) * 33 + kk];
      const float b0 = sB[(tx * 4 + 0) * 33 + kk];
      const float b1 = sB[(tx * 4 + 1) * 33 + kk];
      const float b2 = sB[(tx * 4 + 2) * 33 + kk];
      const float b3 = sB[(tx * 4 + 3) * 33 + kk];
      acc[0][0] = fmaf(a0, b0, acc[0][0]); acc[0][1] = fmaf(a0, b1, acc[0][1]);
      acc[0][2] = fmaf(a0, b2, acc[0][2]); acc[0][3] = fmaf(a0, b3, acc[0][3]);
      acc[1][0] = fmaf(a1, b0, acc[1][0]); acc[1][1] = fmaf(a1, b1, acc[1][1]);
      acc[1][2] = fmaf(a1, b2, acc[1][2]); acc[1][3] = fmaf(a1, b3, acc[1][3]);
      acc[2][0] = fmaf(a2, b0, acc[2][0]); acc[2][1] = fmaf(a2, b1, acc[2][1]);
      acc[2][2] = fmaf(a2, b2, acc[2][2]); acc[2][3] = fmaf(a2, b3, acc[2][3]);
      acc[3][0] = fmaf(a3, b0, acc[3][0]); acc[3][1] = fmaf(a3, b1, acc[3][1]);
      acc[3][2] = fmaf(a3, b2, acc[3][2]); acc[3][3] = fmaf(a3, b3, acc[3][3]);
    }
  }
#pragma unroll
  for (int i = 0; i < 4; ++i)
#pragma unroll
    for (int j = 0; j < 4; ++j)
      out[(size_t)(r0 + ty * 4 + i) * N + n0 + tx * 4 + j] =
          acc[i][j] + bias[n0 + tx * 4 + j];
}

// ---------------------------------------------------------------------------
// GRU recurrence, BOTH branches (grid 191; bx<127 eval). Eval fuses
// att_logits: logit[b,t] = dot(h[b,t,:], a_w)+a_b via wave shuffle-reduce.
// ---------------------------------------------------------------------------
__global__ __launch_bounds__(256) void gru_rec_kernel(
    float* __restrict__ xyE, const float* __restrict__ giE,
    const float* __restrict__ whhE, const float* __restrict__ bhhE,
    float* __restrict__ xyT, const float* __restrict__ giT,
    const float* __restrict__ whhT, const float* __restrict__ bhhT,
    const float* __restrict__ a_w, const float* __restrict__ a_b,
    float* __restrict__ logits) {
  const int bxid = blockIdx.x;
  const bool ev = bxid < 127;
  float* xy = ev ? xyE : xyT;
  const float* gi = ev ? giE : giT;
  const float* whh = ev ? whhE : whhT;
  const float* bhh = ev ? bhhE : bhhT;
  const int T = ev ? 2032 : 1024;
  const int t0 = (ev ? bxid : bxid - 127) * 16;
  __shared__ float s_whh_t[64 * 192];
  __shared__ float s_h[16][64];
  __shared__ float s_aw[64];
  const int tid = threadIdx.x;
  const int lane = tid & 63, wave = tid >> 6;
  for (int i = tid; i < 192 * 64; i += 256) {
    const int j = i >> 6, d = i & 63;
    s_whh_t[d * 192 + j] = whh[i];
  }
  for (int i = tid; i < 16 * 64; i += 256) (&s_h[0][0])[i] = 0.f;
  if (tid < 64) s_aw[tid] = a_w[tid];
  const float ab = a_b[0];
  const float bhr = bhh[lane], bhz = bhh[64 + lane], bhn = bhh[128 + lane];
  __syncthreads();
  for (int b = 0; b < 4; ++b) {
    float gir[4], giz[4], gin[4];
#pragma unroll
    for (int sl = 0; sl < 4; ++sl) {
      int t = t0 + wave * 4 + sl; if (t > T - 1) t = T - 1;
      const float* girow = gi + ((size_t)b * T + t) * 192;
      gir[sl] = girow[lane]; giz[sl] = girow[64 + lane]; gin[sl] = girow[128 + lane];
    }
    float ahr[4] = {}, ahz[4] = {}, ahn[4] = {};
    for (int d = 0; d < 64; ++d) {
      const float wr_ = s_whh_t[d * 192 + lane];
      const float wz_ = s_whh_t[d * 192 + 64 + lane];
      const float wn_ = s_whh_t[d * 192 + 128 + lane];
#pragma unroll
      for (int sl = 0; sl < 4; ++sl) {
        const float hv = s_h[wave * 4 + sl][d];
        ahr[sl] = fmaf(wr_, hv, ahr[sl]);
        ahz[sl] = fmaf(wz_, hv, ahz[sl]);
        ahn[sl] = fmaf(wn_, hv, ahn[sl]);
      }
    }
    float hn[4];
#pragma unroll
    for (int sl = 0; sl < 4; ++sl) {
      const float r = 1.f / (1.f + __expf(-(gir[sl] + ahr[sl] + bhr)));
      const float z = 1.f / (1.f + __expf(-(giz[sl] + ahz[sl] + bhz)));
      const float n = tanhf(gin[sl] + r * (ahn[sl] + bhn));
      hn[sl] = (1.f - z) * n + z * s_h[wave * 4 + sl][lane];
    }
    __syncthreads();
#pragma unroll
    for (int sl = 0; sl < 4; ++sl) {
      const int t = t0 + wave * 4 + sl;
      s_h[wave * 4 + sl][lane] = hn[sl];
      if (t < T) xy[((size_t)b * T + t) * 64 + lane] = hn[sl];
      if (ev) {  // fused att logits (eval branch only)
        float v = hn[sl] * s_aw[lane];
#pragma unroll
        for (int off = 32; off > 0; off >>= 1) v += __shfl_down(v, off, 64);
        if (lane == 0) logits[b * 2032 + t] = v + ab;
      }
    }
    __syncthreads();
  }
}

// ---------------------------------------------------------------------------
// scores: P[b,tau,eps] = sum_d t[b,tau,d]*e[b,eps,d]; P stored bf16.
// ---------------------------------------------------------------------------
__global__ __launch_bounds__(256) void scores_kernel(
    const float* __restrict__ tmat, const float* __restrict__ emat,
    u16* __restrict__ P) {
  __shared__ __align__(16) float sT[64 * 68];
  __shared__ __align__(16) float sE[128 * 68];
  const int tid = threadIdx.x;
  const int b = blockIdx.z;
  const int tau0 = blockIdx.x * 64;
  const int e0 = blockIdx.y * 128;
#pragma unroll
  for (int r = 0; r < 4; ++r) {
    const int q = tid + r * 256;
    const int row = q >> 4, qq = q & 15;
    const float4 v = *(const float4*)&tmat[((size_t)b * 1024 + tau0 + row) * 64 + qq * 4];
    *(float4*)&sT[row * 68 + qq * 4] = v;
  }
#pragma unroll
  for (int r = 0; r < 8; ++r) {
    const int q = tid + r * 256;
    const int row = q >> 4, qq = q & 15;
    int eps = e0 + row; if (eps > 2031) eps = 2031;
    const float4 v = *(const float4*)&emat[((size_t)b * 2032 + eps) * 64 + qq * 4];
    *(float4*)&sE[row * 68 + qq * 4] = v;
  }
  __syncthreads();
  const int ty = tid >> 4, tx = tid & 15;
  float acc[4][8] = {};
#pragma unroll 4
  for (int q = 0; q < 16; ++q) {
    const int kk = q * 4;
    float4 av[4], bv[8];
#pragma unroll
    for (int i = 0; i < 4; ++i) av[i] = *(const float4*)&sT[(ty * 4 + i) * 68 + kk];
#pragma unroll
    for (int j = 0; j < 8; ++j) bv[j] = *(const float4*)&sE[(tx * 8 + j) * 68 + kk];
#pragma unroll
    for (int i = 0; i < 4; ++i)
#pragma unroll
      for (int j = 0; j < 8; ++j) {
        acc[i][j] = fmaf(av[i].x, bv[j].x, acc[i][j]);
        acc[i][j] = fmaf(av[i].y, bv[j].y, acc[i][j]);
        acc[i][j] = fmaf(av[i].z, bv[j].z, acc[i][j]);
        acc[i][j] = fmaf(av[i].w, bv[j].w, acc[i][j]);
      }
  }
#pragma unroll
  for (int i = 0; i < 4; ++i) {
    const size_t prow = ((size_t)b * 1024 + tau0 + ty * 4 + i) * 2032;
#pragma unroll
    for (int j = 0; j < 8; ++j) {
      const int eps = e0 + tx * 8 + j;
      if (eps < 2032) P[prow + eps] = f2bf(acc[i][j]);
    }
  }
}

// ---------------------------------------------------------------------------
// row softmax over eps (bf16 rows of 2032, fp32 math). grid 4096.
// ---------------------------------------------------------------------------
__global__ __launch_bounds__(256) void softmax_rows_kernel(u16* __restrict__ P) {
  __shared__ float s_row[2032];
  __shared__ float sred[4];
  u16* r = P + (size_t)blockIdx.x * 2032;
  const int tid = threadIdx.x;
  const int lane = tid & 63, wave = tid >> 6;
  float m = -3.4e38f;
  for (int i = tid; i < 2032; i += 256) {
    const float v = bf2f(r[i]);
    s_row[i] = v;
    m = fmaxf(m, v);
  }
#pragma unroll
  for (int off = 32; off > 0; off >>= 1) m = fmaxf(m, __shfl_down(m, off, 64));
  if (lane == 0) sred[wave] = m;
  __syncthreads();
  m = fmaxf(fmaxf(sred[0], sred[1]), fmaxf(sred[2], sred[3]));
  __syncthreads();
  float s = 0.f;
  float vals[8];
  int cnt = 0;
  for (int i = tid; i < 2032; i += 256) {
    const float v = __expf(s_row[i] - m);
    vals[cnt++] = v;
    s += v;
  }
#pragma unroll
  for (int off = 32; off > 0; off >>= 1) s += __shfl_down(s, off, 64);
  if (lane == 0) sred[wave] = s;
  __syncthreads();
  const float inv = 1.f / (sred[0] + sred[1] + sred[2] + sred[3]);
  cnt = 0;
  for (int i = tid; i < 2032; i += 256) r[i] = f2bf(vals[cnt++] * inv);
}

// ---------------------------------------------------------------------------
// pv partial: PV[b,eps,d] += sum_{tau slice} P[b,tau,eps]*t[b,tau,d] (P bf16)
// ---------------------------------------------------------------------------
__global__ __launch_bounds__(256) void pv_kernel(
    const u16* __restrict__ P, const float* __restrict__ tmat,
    float* __restrict__ PV) {
  __shared__ float sP[32 * 65];
  __shared__ float sT[32 * 65];
  const int tid = threadIdx.x;
  const int b = blockIdx.z;
  const int e0 = blockIdx.x * 64;
  const int tau_base = blockIdx.y * 256;
  const int ty = tid >> 4, tx = tid & 15;
  float acc[4][4] = {};
  for (int kc = tau_base; kc < tau_base + 256; kc += 32) {
    __syncthreads();
    for (int l = tid; l < 32 * 64; l += 256) {
      const int kk = l >> 6, j = l & 63;
      int eps = e0 + j; if (eps > 2031) eps = 2031;
      sP[kk * 65 + j] = bf2f(P[((size_t)b * 1024 + kc + kk) * 2032 + eps]);
      sT[kk * 65 + j] = tmat[((size_t)b * 1024 + kc + kk) * 64 + j];
    }
    __syncthreads();
#pragma unroll 8
    for (int kk = 0; kk < 32; ++kk) {
      const float a0 = sP[kk * 65 + ty * 4 + 0];
      const float a1 = sP[kk * 65 + ty * 4 + 1];
      const float a2 = sP[kk * 65 + ty * 4 + 2];
      const float a3 = sP[kk * 65 + ty * 4 + 3];
      const float b0 = sT[kk * 65 + tx * 4 + 0];
      const float b1 = sT[kk * 65 + tx * 4 + 1];
      const float b2 = sT[kk * 65 + tx * 4 + 2];
      const float b3 = sT[kk * 65 + tx * 4 + 3];
      acc[0][0] = fmaf(a0, b0, acc[0][0]); acc[0][1] = fmaf(a0, b1, acc[0][1]);
      acc[0][2] = fmaf(a0, b2, acc[0][2]); acc[0][3] = fmaf(a0, b3, acc[0][3]);
      acc[1][0] = fmaf(a1, b0, acc[1][0]); acc[1][1] = fmaf(a1, b1, acc[1][1]);
      acc[1][2] = fmaf(a1, b2, acc[1][2]); acc[1][3] = fmaf(a1, b3, acc[1][3]);
      acc[2][0] = fmaf(a2, b0, acc[2][0]); acc[2][1] = fmaf(a2, b1, acc[2][1]);
      acc[2][2] = fmaf(a2, b2, acc[2][2]); acc[2][3] = fmaf(a2, b3, acc[2][3]);
      acc[3][0] = fmaf(a3, b0, acc[3][0]); acc[3][1] = fmaf(a3, b1, acc[3][1]);
      acc[3][2] = fmaf(a3, b2, acc[3][2]); acc[3][3] = fmaf(a3, b3, acc[3][3]);
    }
  }
#pragma unroll
  for (int i = 0; i < 4; ++i) {
    const int eps = e0 + ty * 4 + i;
    if (eps < 2032) {
#pragma unroll
      for (int j = 0; j < 4; ++j)
        atomicAdd(&PV[((size_t)b * 2032 + eps) * 64 + tx * 4 + j], acc[i][j]);
    }
  }
}

// ---------------------------------------------------------------------------
// att_softmax: in-place softmax over 2032 logits per batch. grid 4.
// ---------------------------------------------------------------------------
__global__ __launch_bounds__(256) void att_softmax_kernel(float* __restrict__ att) {
  __shared__ float s_v[2032];
  __shared__ float sred[4];
  float* r = att + (size_t)blockIdx.x * 2032;
  const int tid = threadIdx.x;
  const int lane = tid & 63, wave = tid >> 6;
  float m = -3.4e38f;
  for (int i = tid; i < 2032; i += 256) {
    const float v = r[i];
    s_v[i] = v;
    m = fmaxf(m, v);
  }
#pragma unroll
  for (int off = 32; off > 0; off >>= 1) m = fmaxf(m, __shfl_down(m, off, 64));
  if (lane == 0) sred[wave] = m;
  __syncthreads();
  m = fmaxf(fmaxf(sred[0], sred[1]), fmaxf(sred[2], sred[3]));
  __syncthreads();
  float s = 0.f;
  float vals[8];
  int cnt = 0;
  for (int i = tid; i < 2032; i += 256) {
    const float v = __expf(s_v[i] - m);
    vals[cnt++] = v;
    s += v;
  }
#pragma unroll
  for (int off = 32; off > 0; off >>= 1) s += __shfl_down(s, off, 64);
  if (lane == 0) sred[wave] = s;
  __syncthreads();
  const float inv = 1.f / (sred[0] + sred[1] + sred[2] + sred[3]);
  cnt = 0;
  for (int i = tid; i < 2032; i += 256) r[i] = vals[cnt++] * inv;
}

// ---------------------------------------------------------------------------
// red_reduce: red[b,d] += sum_{i in slice} |PV-e|[b,i,d] * att[b,i].
// ---------------------------------------------------------------------------
__global__ __launch_bounds__(256) void red_reduce_kernel(
    const float* __restrict__ emat, const float* __restrict__ PV,
    const float* __restrict__ att, float* __restrict__ red) {
  __shared__ float s_part[4][64];
  const int tid = threadIdx.x;
  const int lane = tid & 63, wave = tid >> 6;
  const int b = blockIdx.y;
  const int i0 = blockIdx.x * 127;
  float acc = 0.f;
  for (int i = i0 + wave; i < i0 + 127; i += 4) {
    const size_t idx = ((size_t)b * 2032 + i) * 64 + lane;
    acc = fmaf(fabsf(PV[idx] - emat[idx]), att[b * 2032 + i], acc);
  }
  s_part[wave][lane] = acc;
  __syncthreads();
  if (tid < 64)
    atomicAdd(&red[b * 64 + tid],
              s_part[0][tid] + s_part[1][tid] + s_part[2][tid] + s_part[3][tid]);
}

// ---------------------------------------------------------------------------
// mlp: h = relu(red@h_w^T + h_b); out = softmax(h@c_w^T + c_b). grid 4.
// ---------------------------------------------------------------------------
__global__ __launch_bounds__(128) void mlp_kernel(
    const float* __restrict__ red, const float* __restrict__ h_w,
    const float* __restrict__ h_b, const float* __restrict__ c_w,
    const float* __restrict__ c_b, float* __restrict__ out) {
  __shared__ float s_red[64];
  __shared__ float s_hv[128];
  const int tid = threadIdx.x;
  const int b = blockIdx.x;
  if (tid < 64) s_red[tid] = red[b * 64 + tid];
  __syncthreads();
  {
    float acc = h_b[tid];
    const float* hw = h_w + tid * 64;
    for (int d = 0; d < 64; ++d) acc = fmaf(s_red[d], hw[d], acc);
    s_hv[tid] = fmaxf(acc, 0.f);
  }
  __syncthreads();
  if (tid == 0) {
    float l0 = c_b[0], l1 = c_b[1];
    for (int j = 0; j < 128; ++j) {
      l0 = fmaf(s_hv[j], c_w[j], l0);
      l1 = fmaf(s_hv[j], c_w[128 + j], l1);
    }
    const float mm = fmaxf(l0, l1);
    const float e0 = __expf(l0 - mm), e1 = __expf(l1 - mm);
    const float invs = 1.f / (e0 + e1);
    out[b * 2 + 0] = e0 * invs;
    out[b * 2 + 1] = e1 * invs;
  }
}

// ===========================================================================
extern "C" void kernel_launch(void* const* d_in, const int* in_sizes, int n_in,
                              void* d_out, int out_size, void* d_ws, size_t ws_size,
                              hipStream_t stream) {
  const float* evaluation = (const float*)d_in[0];
  const float* templ      = (const float*)d_in[1];
  const float* e_w1 = (const float*)d_in[2];
  const float* e_b1 = (const float*)d_in[3];
  const float* e_w2 = (const float*)d_in[4];
  const float* e_b2 = (const float*)d_in[5];
  const float* e_w3 = (const float*)d_in[6];
  const float* e_b3 = (const float*)d_in[7];
  const float* el_w = (const float*)d_in[8];
  const float* el_b = (const float*)d_in[9];
  const float* eg_wih = (const float*)d_in[10];
  const float* eg_whh = (const float*)d_in[11];
  const float* eg_bih = (const float*)d_in[12];
  const float* eg_bhh = (const float*)d_in[13];
  const float* t_w1 = (const float*)d_in[14];
  const float* t_b1 = (const float*)d_in[15];
  const float* t_w2 = (const float*)d_in[16];
  const float* t_b2 = (const float*)d_in[17];
  const float* t_w3 = (const float*)d_in[18];
  const float* t_b3 = (const float*)d_in[19];
  const float* tl_w = (const float*)d_in[20];
  const float* tl_b = (const float*)d_in[21];
  const float* tg_wih = (const float*)d_in[22];
  const float* tg_whh = (const float*)d_in[23];
  const float* tg_bih = (const float*)d_in[24];
  const float* tg_bhh = (const float*)d_in[25];
  const float* a_w = (const float*)d_in[26];
  const float* a_b = (const float*)d_in[27];
  const float* h_w = (const float*)d_in[28];
  const float* h_b = (const float*)d_in[29];
  const float* c_w = (const float*)d_in[30];
  const float* c_b = (const float*)d_in[31];

  float* ws = (float*)d_ws;
  float* beff_e  = ws + OFF_BEFF_E;
  float* beff_t  = ws + OFF_BEFF_T;
  float* bias2_e = ws + OFF_BIAS2_E;
  float* bias2_t = ws + OFF_BIAS2_T;
  u16*   wkx_e   = (u16*)(ws + OFF_WKX_E);
  u16*   wkx_t   = (u16*)(ws + OFF_WKX_T);
  float* w12p_e  = ws + OFF_W12P_E;
  float* w12p_t  = ws + OFF_W12P_T;
  float* b12_e   = ws + OFF_B12_E;
  float* b12_t   = ws + OFF_B12_T;
  u16*   lwbf_e  = (u16*)(ws + OFF_LWBF_E);
  u16*   lwbf_t  = (u16*)(ws + OFF_LWBF_T);
  float* attbuf  = ws + OFF_ATT;
  float* lin_e   = ws + OFF_LIN_E;
  float* lin_t   = ws + OFF_LIN_T;
  float* PVbuf   = ws + OFF_PV;
  float* redbuf  = ws + OFF_RED;
  u16*   pool_e  = (u16*)(ws + OFF_POOL_E);
  u16*   pool_t  = (u16*)(ws + OFF_POOL_T);
  float* gi_e    = ws + OFF_GI_E;
  float* gi_t    = ws + OFF_GI_T;
  u16*   Pbuf    = (u16*)(ws + OFF_P);

  // one memset for lin_e/lin_t/PV/red (contiguous, un-aliased)
  hipMemsetAsync(lin_e, 0, MEMSET_LEN * sizeof(float), stream);

  // merged prep (compose12 + gi_bias + lw->bf16), then weff (both parities)
  prep_kernel<<<530, 320, 0, stream>>>(
      e_w1, e_b1, e_w2, e_b2, t_w1, t_b1, t_w2, t_b2, w12p_e, w12p_t, b12_e, b12_t,
      eg_wih, eg_bih, el_b, bias2_e, tg_wih, tg_bih, tl_b, bias2_t,
      el_w, tl_w, lwbf_e, lwbf_t);
  compose_weff_kernel<<<dim3(64, 2), 256, 0, stream>>>(
      e_w3, e_b3, t_w3, t_b3, w12p_e, w12p_t, b12_e, b12_t, wkx_e, wkx_t, beff_e, beff_t);

  // merged mainline: conv both -> splitk both -> gi both -> gru both
  conv_pool_mfma_kernel<<<dim3(34, 58, 8), 256, 0, stream>>>(
      evaluation, wkx_e, beff_e, pool_e, templ, wkx_t, beff_t, pool_t);
  gemm_splitk_mfma_kernel<<<dim3(191, 8), 256, 0, stream>>>(
      pool_e, lwbf_e, lin_e, pool_t, lwbf_t, lin_t);
  gemm_gi_kernel<<<dim3(191, 3), 256, 0, stream>>>(
      lin_e, eg_wih, bias2_e, gi_e, lin_t, tg_wih, bias2_t, gi_t);
  gru_rec_kernel<<<191, 256, 0, stream>>>(
      lin_e, gi_e, eg_whh, eg_bhh, lin_t, gi_t, tg_whh, tg_bhh, a_w, a_b, attbuf);

  // cross attention (P in bf16)
  scores_kernel<<<dim3(16, 16, 4), 256, 0, stream>>>(lin_t, lin_e, Pbuf);
  softmax_rows_kernel<<<4096, 256, 0, stream>>>(Pbuf);
  pv_kernel<<<dim3(32, 4, 4), 256, 0, stream>>>(Pbuf, lin_t, PVbuf);

  // head: softmax -> weighted reduce -> MLP (logits fused into gru)
  att_softmax_kernel<<<4, 256, 0, stream>>>(attbuf);
  red_reduce_kernel<<<dim3(16, 4), 256, 0, stream>>>(lin_e, PVbuf, attbuf, redbuf);
  mlp_kernel<<<4, 128, 0, stream>>>(redbuf, h_w, h_b, c_w, c_b, (float*)d_out);
}

// Round 10
// 335.702 us; speedup vs baseline: 9.2509x; 1.2367x over previous
//
#include <hip/hip_runtime.h>
#include <cmath>

// ============================================================================
// DeepTemplateMatchingModule on MI355X — round 10.
// R9 post-mortem: conv 98us (both branches) MfmaUtil 17%; scores/pv are
// fp32-VALU GEMMs (~55us); 13 nodes still cost ~100us in boundaries.
// R10:
//  (1) conv: 2 pooled rows per block. x window = 16 rows EXACT (K=16, no
//      pads); 4 parity-shifted weight layouts (slot ky+p) cover conv rows
//      4by..4by+3 on one staged tile. Staging per output halved.
//  (2) scores -> bf16 MFMA (NT like splitk; gru emits bf16 copies).
//  (3) pv -> bf16 MFMA (gru scatter-writes t^T; P tile LDS-transposed).
//  (4) nodes 13->11: memset folded into prep; att_softmax folded into
//      red_reduce (redundant per-block softmax).
// ============================================================================

typedef unsigned short u16;
typedef unsigned int u32;
typedef __attribute__((ext_vector_type(8))) short bf16x8;
typedef __attribute__((ext_vector_type(8))) unsigned short u16x8;
typedef __attribute__((ext_vector_type(16))) float f32x16;

__device__ __forceinline__ u16 f2bf(float f) {
  unsigned int x = __float_as_uint(f);
  return (u16)((x + 0x7fffu + ((x >> 16) & 1u)) >> 16);
}
__device__ __forceinline__ float bf2f(u16 v) {
  return __uint_as_float(((unsigned int)v) << 16);
}

// ---- workspace layout (float offsets) ----
static const size_t OFF_BEFF_E  = 0;          // 64
static const size_t OFF_BEFF_T  = 64;
static const size_t OFF_BIAS2_E = 128;        // 192
static const size_t OFF_BIAS2_T = 320;
static const size_t OFF_WKX_E   = 512;        // 4 parities x 13x64x16 u16 = 26624 f
static const size_t OFF_WKX_T   = 27136;      // 26624 f
static const size_t OFF_W12P_E  = 53760;      // 9248
static const size_t OFF_W12P_T  = 63008;      // 9248
static const size_t OFF_B12_E   = 72256;      // 32
static const size_t OFF_B12_T   = 72288;      // 32
static const size_t OFF_LWBF_E  = 72320;      // 118784 f (237568 u16)
static const size_t OFF_LWBF_T  = 191104;     // 118784 f
static const size_t OFF_ATT     = 309888;     // 8128 f (raw logits)
static const size_t OFF_XYBF_E  = 318016;     // 260096 f (4x2032x64 u16)
static const size_t OFF_XYBF_T  = 578112;     // 131072 f (4x1024x64 u16)
static const size_t OFF_TTBF    = 709184;     // 131072 f (t^T: 4x64x1024 u16)
// contiguous zero region (zeroed by prep): lin_e, lin_t, PV, red
static const size_t OFF_LIN_E   = 840256;     // 520192 f
static const size_t OFF_LIN_T   = 1360448;    // 262144 f
static const size_t OFF_PV      = 1622592;    // 520192 f
static const size_t OFF_RED     = 2142784;    // 256 f
static const size_t ZERO_F4     = 325696;     // (1,302,784 f) / 4
// pools coexist
static const size_t OFF_POOL_E  = 2143040;    // u16: 30,171,136 u16
static const size_t OFF_POOL_T  = 17228608;   // u16: 15,204,352 u16
// dead-pool_e reuse (after splitk):
static const size_t OFF_GI_E    = 2143040;    // 1,560,576 f
static const size_t OFF_GI_T    = 3703616;    // 786,432 f
static const size_t OFF_P       = 4490048;    // u16: 8,323,072 u16

// ---------------------------------------------------------------------------
// prep: zero region + compose12 (bx<64) + gi_bias (64..65) + lw->bf16 (>=66).
// grid 530, 320 threads.
// ---------------------------------------------------------------------------
__global__ __launch_bounds__(320) void prep_kernel(
    const float* __restrict__ w1e, const float* __restrict__ b1e,
    const float* __restrict__ w2e, const float* __restrict__ b2e,
    const float* __restrict__ w1t, const float* __restrict__ b1t,
    const float* __restrict__ w2t, const float* __restrict__ b2t,
    float* __restrict__ w12p_e, float* __restrict__ w12p_t,
    float* __restrict__ b12o_e, float* __restrict__ b12o_t,
    const float* __restrict__ wih_e, const float* __restrict__ bih_e,
    const float* __restrict__ lb_e, float* __restrict__ bias2_e,
    const float* __restrict__ wih_t, const float* __restrict__ bih_t,
    const float* __restrict__ lb_t, float* __restrict__ bias2_t,
    const float* __restrict__ lwe, const float* __restrict__ lwt,
    u16* __restrict__ lwbf_e, u16* __restrict__ lwbf_t,
    float4* __restrict__ zbase) {
  const int bx = blockIdx.x;
  const int tid = threadIdx.x;
  // zero slice of lin/PV/red (float4)
  {
    const size_t base = (size_t)bx * 615;
    const float4 z = {0.f, 0.f, 0.f, 0.f};
    for (size_t i = base + tid; i < base + 615 && i < ZERO_F4; i += 320)
      zbase[i] = z;
  }
  if (bx >= 66) {  // lw -> bf16
    if (tid < 256) {
      const int k = bx - 66;
      const int br = k / 232, j = k - br * 232;
      const float* src = br ? lwt : lwe;
      u16* dst = br ? lwbf_t : lwbf_e;
      const int i = (j * 256 + tid) * 4;
      const float4 v = *(const float4*)&src[i];
      dst[i] = f2bf(v.x); dst[i + 1] = f2bf(v.y);
      dst[i + 2] = f2bf(v.z); dst[i + 3] = f2bf(v.w);
    }
    return;
  }
  if (bx >= 64) {  // gi_bias
    const int br = bx - 64;
    const float* wih = br ? wih_t : wih_e;
    const float* bih = br ? bih_t : bih_e;
    const float* lb = br ? lb_t : lb_e;
    float* bias2 = br ? bias2_t : bias2_e;
    __shared__ float s_lb[64];
    if (tid < 64) s_lb[tid] = lb[tid];
    __syncthreads();
    if (tid < 192) {
      float acc = bih[tid];
      const float* wr = wih + tid * 64;
      for (int d = 0; d < 64; ++d) acc = fmaf(wr[d], s_lb[d], acc);
      bias2[tid] = acc;
    }
    return;
  }
  // compose12
  const int br = bx >> 5;
  const float* w1 = br ? w1t : w1e;
  const float* b1 = br ? b1t : b1e;
  const float* w2 = br ? w2t : w2e;
  const float* b2 = br ? b2t : b2e;
  float* w12p = br ? w12p_t : w12p_e;
  float* b12o = br ? b12o_t : b12o_e;
  const int c12 = bx & 31;
  __shared__ float s_w1pad[16 * 169];
  __shared__ float s_w2c[400];
  __shared__ float s_b1[16];
  for (int i = tid; i < 2704; i += 320) s_w1pad[i] = 0.f;
  if (tid < 16) s_b1[tid] = b1[tid];
  __syncthreads();
  for (int i = tid; i < 400; i += 320) {
    const int c1 = i / 25, r = (i % 25) / 5, cc = i % 5;
    s_w1pad[c1 * 169 + (r + 4) * 13 + (cc + 4)] = w1[i];
    s_w2c[i] = w2[c12 * 400 + i];
  }
  __syncthreads();
  if (tid < 289) {
    const int py = tid / 17, px = tid % 17;
    float v = 0.f;
    if (py >= 4 && py <= 12 && px >= 4 && px <= 12) {
      const int sy = py - 4, sx = px - 4;
      float accs[2] = {0.f, 0.f};
      for (int c1 = 0; c1 < 16; ++c1) {
        const float* w2p = s_w2c + c1 * 25;
        const float* w1p = s_w1pad + c1 * 169 + (sy + 4) * 13 + (sx + 4);
#pragma unroll
        for (int uy = 0; uy < 5; ++uy)
#pragma unroll
          for (int ux = 0; ux < 5; ++ux)
            accs[uy & 1] = fmaf(w2p[uy * 5 + ux], w1p[-(uy * 13) - ux], accs[uy & 1]);
      }
      v = accs[0] + accs[1];
    }
    w12p[c12 * 289 + tid] = v;
  } else if (tid == 300) {
    float acc = b2[c12];
    for (int c1 = 0; c1 < 16; ++c1) {
      float sw = 0.f;
      for (int u = 0; u < 25; ++u) sw += s_w2c[c1 * 25 + u];
      acc = fmaf(sw, s_b1[c1], acc);
    }
    b12o[c12] = acc;
  }
}

// ---------------------------------------------------------------------------
// compose_weff: emits 4 parity layouts wkx[(p*13+kx)*64+o][16] bf16.
// Parity p places w[ky] at slot ky+p; zero slots {0..p-1} u {p+13..15}.
// grid (64 o, 2 branches).
// ---------------------------------------------------------------------------
__global__ __launch_bounds__(256) void compose_weff_kernel(
    const float* __restrict__ w3e, const float* __restrict__ b3e,
    const float* __restrict__ w3t, const float* __restrict__ b3t,
    const float* __restrict__ w12p_e, const float* __restrict__ w12p_t,
    const float* __restrict__ b12_e, const float* __restrict__ b12_t,
    u16* __restrict__ wkx_e, u16* __restrict__ wkx_t,
    float* __restrict__ beff_e, float* __restrict__ beff_t) {
  const int br = blockIdx.y;
  const float* w3 = br ? w3t : w3e;
  const float* b3 = br ? b3t : b3e;
  const float* w12p = br ? w12p_t : w12p_e;
  const float* b12 = br ? b12_t : b12_e;
  u16* wkx = br ? wkx_t : wkx_e;
  float* beff = br ? beff_t : beff_e;
  const int o = blockIdx.x;
  __shared__ float s_pad[32 * 289];
  __shared__ float s_w3o[800];
  __shared__ float s_b12[32];
  const int tid = threadIdx.x;
  for (int i = tid; i < 9248; i += 256) s_pad[i] = w12p[i];
  for (int i = tid; i < 800; i += 256) s_w3o[i] = w3[o * 800 + i];
  if (tid < 32) s_b12[tid] = b12[tid];
  __syncthreads();
  if (tid < 169) {
    const int sy = tid / 13, sx = tid % 13;  // sy = ky, sx = kx
    float accs[4] = {0.f, 0.f, 0.f, 0.f};
#pragma unroll 4
    for (int c = 0; c < 32; ++c) {
      const float* w3p = s_w3o + c * 25;
      const float* wp = s_pad + c * 289 + (sy + 4) * 17 + (sx + 4);
#pragma unroll
      for (int uy = 0; uy < 5; ++uy)
#pragma unroll
        for (int ux = 0; ux < 5; ++ux)
          accs[c & 3] = fmaf(w3p[uy * 5 + ux], wp[-(uy * 17) - ux], accs[c & 3]);
    }
    const u16 v = f2bf(accs[0] + accs[1] + accs[2] + accs[3]);
#pragma unroll
    for (int p = 0; p < 4; ++p)
      wkx[((p * 13 + sx) * 64 + o) * 16 + sy + p] = v;
  } else if (tid < 169 + 156) {  // 13 kx x 12 zero-slots
    const int t = tid - 169, kx = t / 12, q = t % 12;
    const int p = q / 3, idx = q % 3;
    const int slot = (idx < p) ? idx : (p + 13) + (idx - p);
    wkx[((p * 13 + kx) * 64 + o) * 16 + slot] = 0;
  } else if (tid == 330 - 5) {  // tid 325 <256? no — use 255
  }
  if (tid == 255) {
    float acc = b3[o];
    for (int c = 0; c < 32; ++c) {
      float sw = 0.f;
      for (int u = 0; u < 25; ++u) sw += s_w3o[c * 25 + u];
      acc = fmaf(sw, s_b12[c], acc);
    }
    beff[o] = acc;
  }
}

// ---------------------------------------------------------------------------
// MFMA conv13x13 + maxpool, 2 pooled rows per block, both branches.
// x window = rows 4by..4by+15 (16 rows exact, K=16). Wave (hh-loop):
// parity p = 2*hh + (wave&1); channels (wave>>1)*32; both 32-col tiles.
// grid (34, 29, 8); tmpl blocks cb >= 1024 exit.
// ---------------------------------------------------------------------------
__global__ __launch_bounds__(256, 4) void conv_pool_mfma_kernel(
    const float* __restrict__ xe, const u16* __restrict__ wkx_e,
    const float* __restrict__ beff_e, u16* __restrict__ pooled_e,
    const float* __restrict__ xt, const u16* __restrict__ wkx_t,
    const float* __restrict__ beff_t, u16* __restrict__ pooled_t) {
  const int zz = blockIdx.z;
  const bool ev = zz < 4;
  const int b = ev ? zz : zz - 4;
  const int W = ev ? 2048 : 1040;
  const int T = ev ? 2032 : 1024;
  const int cb = blockIdx.x * 60;
  if (cb >= T) return;
  const float* x = ev ? xe : xt;
  const u16* wkx = ev ? wkx_e : wkx_t;
  const float* beff = ev ? beff_e : beff_t;
  u16* pooled = ev ? pooled_e : pooled_t;

  __shared__ __align__(16) u16 s_x[80 * 24];     // rows at slots 0..15 (16..23 unused)
  __shared__ __align__(16) u16 s_out[2 * 64 * 66];
  __shared__ __align__(16) u16 s_pool[64 * 62];

  const int tid = threadIdx.x;
  const int lane = tid & 63, wave = tid >> 6;
  const int by = blockIdx.y;
  const int rsel = wave & 1, cm = (wave >> 1) * 32;
  const int l31 = lane & 31, g8 = (lane >> 5) * 8;
  const int r0 = 4 * by;

  // stage 16 x rows as packed u32 row-pairs
  {
    const float* xb = x + ((size_t)b * 128 + r0) * W;
    for (int i = tid; i < 640; i += 256) {  // 8 row-pairs x 80 cols
      const int pr = i / 80, c = i - pr * 80;
      int gc = cb + c;
      if (gc > W - 1) gc = W - 1;
      const u16 v0 = f2bf(xb[(size_t)(2 * pr) * W + gc]);
      const u16 v1 = f2bf(xb[(size_t)(2 * pr + 1) * W + gc]);
      *(u32*)&s_x[c * 24 + 2 * pr] = (u32)v0 | ((u32)v1 << 16);
    }
  }
  __syncthreads();
#pragma unroll
  for (int hh = 0; hh < 2; ++hh) {
    const int p = 2 * hh + rsel;
    const int h = 2 * by + hh;
    bf16x8 wfrag[13];
    {
      const u16* aw = wkx + ((p * 13) * 64 + cm + l31) * 16 + g8;
#pragma unroll
      for (int kx = 0; kx < 13; ++kx) wfrag[kx] = *(const bf16x8*)(aw + kx * 1024);
    }
    f32x16 acc0 = {}, acc1 = {};
    const u16* bx = s_x + g8;
#pragma unroll
    for (int kx = 0; kx < 13; ++kx) {
      bf16x8 b0 = *(const bf16x8*)(bx + (l31 + kx) * 24);
      bf16x8 b1 = *(const bf16x8*)(bx + (32 + l31 + kx) * 24);
      acc0 = __builtin_amdgcn_mfma_f32_32x32x16_bf16(wfrag[kx], b0, acc0, 0, 0, 0);
      acc1 = __builtin_amdgcn_mfma_f32_32x32x16_bf16(wfrag[kx], b1, acc1, 0, 0, 0);
    }
    // write C tiles (own tiles only; s_out disjoint from s_x)
#pragma unroll
    for (int r = 0; r < 16; ++r) {
      const int c = cm + (r & 3) + 8 * (r >> 2) + (g8 >> 1);
      u16* o = s_out + (rsel * 64 + c) * 66;
      o[l31] = f2bf(acc0[r]);
      o[32 + l31] = f2bf(acc1[r]);
    }
    __syncthreads();  // all s_out written (and prev store's s_pool reads done)
    {
      const int pc = tid & 63, tg = tid >> 6;
      const int t0 = tg * 15;
      const float bias = beff[pc];
      const u16* r0p = s_out + pc * 66 + t0;
      const u16* r1p = s_out + (64 + pc) * 66 + t0;
      float m01[19];
#pragma unroll
      for (int j = 0; j < 19; ++j) m01[j] = fmaxf(bf2f(r0p[j]), bf2f(r1p[j]));
#pragma unroll
      for (int i = 0; i < 15; ++i) {
        float m = m01[i];
#pragma unroll
        for (int k = 1; k < 5; ++k) m = fmaxf(m, m01[i + k]);
        s_pool[pc * 62 + t0 + i] = f2bf(m + bias);
      }
    }
    __syncthreads();  // s_pool written; s_out reads done
    for (int i = tid; i < 1920; i += 256) {
      const int c = i / 30, tp = i - c * 30;
      const int gt = cb + 2 * tp;
      if (gt < T) {
        const u32 pair = *(const u32*)&s_pool[c * 62 + 2 * tp];
        *(u32*)&pooled[(((size_t)b * 64 + c) * 58 + h) * T + gt] = pair;
      }
    }
  }
}

// ---------------------------------------------------------------------------
// Split-K GEMM on bf16 MFMA, both branches: grid (191, 8); bx<127 eval.
// ---------------------------------------------------------------------------
__global__ __launch_bounds__(256) void gemm_splitk_mfma_kernel(
    const u16* __restrict__ Ae, const u16* __restrict__ Bwe, float* __restrict__ oute,
    const u16* __restrict__ At, const u16* __restrict__ Bwt, float* __restrict__ outt) {
  const int bx = blockIdx.x;
  const bool ev = bx < 127;
  const u16* A = ev ? Ae : At;
  const u16* Bw = ev ? Bwe : Bwt;
  float* out = ev ? oute : outt;
  const int r0 = (ev ? bx : bx - 127) * 64;
  __shared__ __align__(16) u16 sA[64 * 72];
  __shared__ __align__(16) u16 sB[64 * 72];
  const int tid = threadIdx.x;
  const int s = blockIdx.y;
  const int ch0 = (s * 58) / 8, ch1 = ((s + 1) * 58) / 8;
  const int lane = tid & 63, wave = tid >> 6;
  const int l31 = lane & 31, g8 = (lane >> 5) * 8;
  const int mh = (wave & 1) * 32, nh = (wave >> 1) * 32;
  const int srow = tid >> 2, sseg = (tid & 3) * 16;
  f32x16 acc = {};
  for (int ch = ch0; ch < ch1; ++ch) {
    const int kc = ch * 64;
    __syncthreads();
    {
      const u16* ap = &A[(size_t)(r0 + srow) * 3712 + kc + sseg];
      const u16* bp = &Bw[(size_t)srow * 3712 + kc + sseg];
      u16* da = &sA[srow * 72 + sseg];
      u16* db = &sB[srow * 72 + sseg];
      *(u16x8*)da = *(const u16x8*)ap;
      *(u16x8*)(da + 8) = *(const u16x8*)(ap + 8);
      *(u16x8*)db = *(const u16x8*)bp;
      *(u16x8*)(db + 8) = *(const u16x8*)(bp + 8);
    }
    __syncthreads();
#pragma unroll
    for (int ks = 0; ks < 4; ++ks) {
      bf16x8 a = *(const bf16x8*)&sA[(mh + l31) * 72 + ks * 16 + g8];
      bf16x8 b = *(const bf16x8*)&sB[(nh + l31) * 72 + ks * 16 + g8];
      acc = __builtin_amdgcn_mfma_f32_32x32x16_bf16(a, b, acc, 0, 0, 0);
    }
  }
#pragma unroll
  for (int r = 0; r < 16; ++r) {
    const int row = mh + (r & 3) + 8 * (r >> 2) + (g8 >> 1);
    atomicAdd(&out[(size_t)(r0 + row) * 64 + nh + l31], acc[r]);
  }
}

// ---------------------------------------------------------------------------
// gi GEMM, both branches: grid (191, 3); N=192, K=64.
// ---------------------------------------------------------------------------
__global__ __launch_bounds__(256) void gemm_gi_kernel(
    const float* __restrict__ Ae, const float* __restrict__ Wte,
    const float* __restrict__ biase, float* __restrict__ oute,
    const float* __restrict__ At, const float* __restrict__ Wtt,
    const float* __restrict__ biast, float* __restrict__ outt) {
  const int bx = blockIdx.x;
  const bool ev = bx < 127;
  const float* A = ev ? Ae : At;
  const float* Wt = ev ? Wte : Wtt;
  const float* bias = ev ? biase : biast;
  float* out = ev ? oute : outt;
  const int r0 = (ev ? bx : bx - 127) * 64;
  const int N = 192, K = 64;
  __shared__ float sA[64 * 33];
  __shared__ float sB[64 * 33];
  const int tid = threadIdx.x;
  const int n0 = blockIdx.y * 64;
  const int ty = tid >> 4, tx = tid & 15;
  float acc[4][4] = {};
  for (int kc = 0; kc < K; kc += 32) {
    __syncthreads();
#pragma unroll
    for (int rep = 0; rep < 8; ++rep) {
      const int l = tid + rep * 256;
      const int row = l >> 5, kk = l & 31;
      sA[row * 33 + kk] = A[(size_t)(r0 + row) * K + kc + kk];
      sB[row * 33 + kk] = Wt[(size_t)(n0 + row) * K + kc + kk];
    }
    __syncthreads();
#pragma unroll 8
    for (int kk = 0; kk < 32; ++kk) {
      const float a0 = sA[(ty * 4 + 0) * 33 + kk];
      const float a1 = sA[(ty * 4 + 1) * 33 + kk];
      const float a2 = sA[(ty * 4 + 2) * 33 + kk];
      const float a3 = sA[(ty * 4 + 3) * 33 + kk];
      const float b0 = sB[(tx * 4 + 0) * 33 + kk];
      const float b1 = sB[(tx * 4 + 1) * 33 + kk];
      const float b2 = sB[(tx * 4 + 2) * 33 + kk];
      const float b3 = sB[(tx * 4 + 3) * 33 + kk];
      acc[0][0] = fmaf(a0, b0, acc[0][0]); acc[0][1] = fmaf(a0, b1, acc[0][1]);
      acc[0][2] = fmaf(a0, b2, acc[0][2]); acc[0][3] = fmaf(a0, b3, acc[0][3]);
      acc[1][0] = fmaf(a1, b0, acc[1][0]); acc[1][1] = fmaf(a1, b1, acc[1][1]);
      acc[1][2] = fmaf(a1, b2, acc[1][2]); acc[1][3] = fmaf(a1, b3, acc[1][3]);
      acc[2][0] = fmaf(a2, b0, acc[2][0]); acc[2][1] = fmaf(a2, b1, acc[2][1]);
      acc[2][2] = fmaf(a2, b2, acc[2][2]); acc[2][3] = fmaf(a2, b3, acc[2][3]);
      acc[3][0] = fmaf(a3, b0, acc[3][0]); acc[3][1] = fmaf(a3, b1, acc[3][1]);
      acc[3][2] = fmaf(a3, b2, acc[3][2]); acc[3][3] = fmaf(a3, b3, acc[3][3]);
    }
  }
#pragma unroll
  for (int i = 0; i < 4; ++i)
#pragma unroll
    for (int j = 0; j < 4; ++j)
      out[(size_t)(r0 + ty * 4 + i) * N + n0 + tx * 4 + j] =
          acc[i][j] + bias[n0 + tx * 4 + j];
}

// ---------------------------------------------------------------------------
// GRU, both branches (grid 191). Writes fp32 xy + bf16 xy_bf (both), raw
// att logits (eval), and t^T bf16 scatter (template, for pv MFMA).
// ---------------------------------------------------------------------------
__global__ __launch_bounds__(256) void gru_rec_kernel(
    float* __restrict__ xyE, const float* __restrict__ giE,
    const float* __restrict__ whhE, const float* __restrict__ bhhE,
    float* __restrict__ xyT, const float* __restrict__ giT,
    const float* __restrict__ whhT, const float* __restrict__ bhhT,
    u16* __restrict__ xybfE, u16* __restrict__ xybfT, u16* __restrict__ ttbf,
    const float* __restrict__ a_w, const float* __restrict__ a_b,
    float* __restrict__ logits) {
  const int bxid = blockIdx.x;
  const bool ev = bxid < 127;
  float* xy = ev ? xyE : xyT;
  u16* xybf = ev ? xybfE : xybfT;
  const float* gi = ev ? giE : giT;
  const float* whh = ev ? whhE : whhT;
  const float* bhh = ev ? bhhE : bhhT;
  const int T = ev ? 2032 : 1024;
  const int t0 = (ev ? bxid : bxid - 127) * 16;
  __shared__ float s_whh_t[64 * 192];
  __shared__ float s_h[16][64];
  __shared__ float s_aw[64];
  const int tid = threadIdx.x;
  const int lane = tid & 63, wave = tid >> 6;
  for (int i = tid; i < 192 * 64; i += 256) {
    const int j = i >> 6, d = i & 63;
    s_whh_t[d * 192 + j] = whh[i];
  }
  for (int i = tid; i < 16 * 64; i += 256) (&s_h[0][0])[i] = 0.f;
  if (tid < 64) s_aw[tid] = a_w[tid];
  const float ab = a_b[0];
  const float bhr = bhh[lane], bhz = bhh[64 + lane], bhn = bhh[128 + lane];
  __syncthreads();
  for (int b = 0; b < 4; ++b) {
    float gir[4], giz[4], gin[4];
#pragma unroll
    for (int sl = 0; sl < 4; ++sl) {
      int t = t0 + wave * 4 + sl; if (t > T - 1) t = T - 1;
      const float* girow = gi + ((size_t)b * T + t) * 192;
      gir[sl] = girow[lane]; giz[sl] = girow[64 + lane]; gin[sl] = girow[128 + lane];
    }
    float ahr[4] = {}, ahz[4] = {}, ahn[4] = {};
    for (int d = 0; d < 64; ++d) {
      const float wr_ = s_whh_t[d * 192 + lane];
      const float wz_ = s_whh_t[d * 192 + 64 + lane];
      const float wn_ = s_whh_t[d * 192 + 128 + lane];
#pragma unroll
      for (int sl = 0; sl < 4; ++sl) {
        const float hv = s_h[wave * 4 + sl][d];
        ahr[sl] = fmaf(wr_, hv, ahr[sl]);
        ahz[sl] = fmaf(wz_, hv, ahz[sl]);
        ahn[sl] = fmaf(wn_, hv, ahn[sl]);
      }
    }
    float hn[4];
#pragma unroll
    for (int sl = 0; sl < 4; ++sl) {
      const float r = 1.f / (1.f + __expf(-(gir[sl] + ahr[sl] + bhr)));
      const float z = 1.f / (1.f + __expf(-(giz[sl] + ahz[sl] + bhz)));
      const float n = tanhf(gin[sl] + r * (ahn[sl] + bhn));
      hn[sl] = (1.f - z) * n + z * s_h[wave * 4 + sl][lane];
    }
    __syncthreads();
#pragma unroll
    for (int sl = 0; sl < 4; ++sl) {
      const int t = t0 + wave * 4 + sl;
      s_h[wave * 4 + sl][lane] = hn[sl];
      if (t < T) {
        const size_t idx = ((size_t)b * T + t) * 64 + lane;
        xy[idx] = hn[sl];
        xybf[idx] = f2bf(hn[sl]);
        if (ev) {  // fused att logits
          float v = hn[sl] * s_aw[lane];
#pragma unroll
          for (int off = 32; off > 0; off >>= 1) v += __shfl_down(v, off, 64);
          if (lane == 0) logits[b * 2032 + t] = v + ab;
        } else {   // t^T for pv (scatter u16)
          ttbf[((size_t)b * 64 + lane) * 1024 + t] = f2bf(hn[sl]);
        }
      }
    }
    __syncthreads();
  }
}

// ---------------------------------------------------------------------------
// scores on bf16 MFMA: P[b,tau,eps] = sum_d t[tau,d] e[eps,d]; P bf16.
// grid (16 tau-tiles(64), 16 eps-tiles(128), 4b). Per wave: m-half x 2 n-tiles.
// ---------------------------------------------------------------------------
__global__ __launch_bounds__(256) void scores_mfma_kernel(
    const u16* __restrict__ tbf, const u16* __restrict__ ebf,
    u16* __restrict__ P) {
  __shared__ __align__(16) u16 sA[64 * 72];
  __shared__ __align__(16) u16 sB[128 * 72];
  const int tid = threadIdx.x;
  const int b = blockIdx.z;
  const int tau0 = blockIdx.x * 64;
  const int e0 = blockIdx.y * 128;
  const int lane = tid & 63, wave = tid >> 6;
  const int l31 = lane & 31, g8 = (lane >> 5) * 8;
  // stage A (t tile 64x64)
  {
    const int row = tid >> 2, seg = (tid & 3) * 16;  // 64 rows x 4 segs... 64*64=4096 u16: 2 u16x8/thread
    const u16* ap = &tbf[((size_t)b * 1024 + tau0 + row) * 64 + seg];
    u16* da = &sA[row * 72 + seg];
    *(u16x8*)da = *(const u16x8*)ap;
    *(u16x8*)(da + 8) = *(const u16x8*)(ap + 8);
  }
  // stage B (e tile 128x64): 128*8 segs = 1024 u16x8 / 256 = 4 per thread
#pragma unroll
  for (int r = 0; r < 4; ++r) {
    const int q = tid + r * 256;
    const int row = q >> 3, seg = (q & 7) * 8;
    int eps = e0 + row; if (eps > 2031) eps = 2031;
    *(u16x8*)&sB[row * 72 + seg] =
        *(const u16x8*)&ebf[((size_t)b * 2032 + eps) * 64 + seg];
  }
  __syncthreads();
  const int mh = (wave & 1) * 32;
  const int nq = (wave >> 1) * 64;
  f32x16 acc0 = {}, acc1 = {};
#pragma unroll
  for (int ks = 0; ks < 4; ++ks) {
    bf16x8 a = *(const bf16x8*)&sA[(mh + l31) * 72 + ks * 16 + g8];
    bf16x8 b0 = *(const bf16x8*)&sB[(nq + l31) * 72 + ks * 16 + g8];
    bf16x8 b1 = *(const bf16x8*)&sB[(nq + 32 + l31) * 72 + ks * 16 + g8];
    acc0 = __builtin_amdgcn_mfma_f32_32x32x16_bf16(a, b0, acc0, 0, 0, 0);
    acc1 = __builtin_amdgcn_mfma_f32_32x32x16_bf16(a, b1, acc1, 0, 0, 0);
  }
#pragma unroll
  for (int r = 0; r < 16; ++r) {
    const int tau = tau0 + mh + (r & 3) + 8 * (r >> 2) + (g8 >> 1);
    const size_t prow = ((size_t)b * 1024 + tau) * 2032;
    const int ep0 = e0 + nq + l31;
    if (ep0 < 2032) P[prow + ep0] = f2bf(acc0[r]);
    const int ep1 = ep0 + 32;
    if (ep1 < 2032) P[prow + ep1] = f2bf(acc1[r]);
  }
}

// ---------------------------------------------------------------------------
// row softmax over eps (bf16 rows of 2032, fp32 math). grid 4096.
// ---------------------------------------------------------------------------
__global__ __launch_bounds__(256) void softmax_rows_kernel(u16* __restrict__ P) {
  __shared__ float s_row[2032];
  __shared__ float sred[4];
  u16* r = P + (size_t)blockIdx.x * 2032;
  const int tid = threadIdx.x;
  const int lane = tid & 63, wave = tid >> 6;
  float m = -3.4e38f;
  for (int i = tid; i < 2032; i += 256) {
    const float v = bf2f(r[i]);
    s_row[i] = v;
    m = fmaxf(m, v);
  }
#pragma unroll
  for (int off = 32; off > 0; off >>= 1) m = fmaxf(m, __shfl_down(m, off, 64));
  if (lane == 0) sred[wave] = m;
  __syncthreads();
  m = fmaxf(fmaxf(sred[0], sred[1]), fmaxf(sred[2], sred[3]));
  __syncthreads();
  float s = 0.f;
  float vals[8];
  int cnt = 0;
  for (int i = tid; i < 2032; i += 256) {
    const float v = __expf(s_row[i] - m);
    vals[cnt++] = v;
    s += v;
  }
#pragma unroll
  for (int off = 32; off > 0; off >>= 1) s += __shfl_down(s, off, 64);
  if (lane == 0) sred[wave] = s;
  __syncthreads();
  const float inv = 1.f / (sred[0] + sred[1] + sred[2] + sred[3]);
  cnt = 0;
  for (int i = tid; i < 2032; i += 256) r[i] = f2bf(vals[cnt++] * inv);
}

// ---------------------------------------------------------------------------
// pv on bf16 MFMA: PV[b,eps,d] += sum_tau P[tau,eps] t[tau,d].
// A = P^T (LDS-transposed per 64-tau chunk), B = t^T (from gru).
// grid (32 eps-tiles(64), 4 tau-slices(256), 4b); atomic f32 epilogue.
// ---------------------------------------------------------------------------
__global__ __launch_bounds__(256) void pv_mfma_kernel(
    const u16* __restrict__ P, const u16* __restrict__ ttbf,
    float* __restrict__ PV) {
  __shared__ __align__(16) u16 sPT[64 * 72];  // [eps][tau]
  __shared__ __align__(16) u16 sTT[64 * 72];  // [d][tau]
  const int tid = threadIdx.x;
  const int b = blockIdx.z;
  const int e0 = blockIdx.x * 64;
  const int tau_base = blockIdx.y * 256;
  const int lane = tid & 63, wave = tid >> 6;
  const int l31 = lane & 31, g8 = (lane >> 5) * 8;
  const int mh = (wave & 1) * 32, nh = (wave >> 1) * 32;
  f32x16 acc = {};
  for (int cc = 0; cc < 4; ++cc) {
    const int tc = tau_base + cc * 64;
    __syncthreads();
    // stage P^T: read P[tau][eps] coalesced, write transposed
#pragma unroll
    for (int k = 0; k < 2; ++k) {
      const int q = tid + k * 256;
      const int row = q >> 3, seg = (q & 7) * 8;  // tau row, eps seg
      int er = e0 + seg;
      if (er > 2032 - 8) er = 2032 - 8;  // clamp (only fully-OOB segs affected)
      const u16x8 v = *(const u16x8*)&P[((size_t)b * 1024 + tc + row) * 2032 + er];
#pragma unroll
      for (int j = 0; j < 8; ++j) sPT[(seg + j) * 72 + row] = v[j];
    }
    // stage t^T: coalesced b128
#pragma unroll
    for (int k = 0; k < 2; ++k) {
      const int q = tid + k * 256;
      const int row = q >> 3, seg = (q & 7) * 8;  // d row, tau seg
      *(u16x8*)&sTT[row * 72 + seg] =
          *(const u16x8*)&ttbf[((size_t)b * 64 + row) * 1024 + tc + seg];
    }
    __syncthreads();
#pragma unroll
    for (int ks = 0; ks < 4; ++ks) {
      bf16x8 a = *(const bf16x8*)&sPT[(mh + l31) * 72 + ks * 16 + g8];
      bf16x8 bb = *(const bf16x8*)&sTT[(nh + l31) * 72 + ks * 16 + g8];
      acc = __builtin_amdgcn_mfma_f32_32x32x16_bf16(a, bb, acc, 0, 0, 0);
    }
  }
#pragma unroll
  for (int r = 0; r < 16; ++r) {
    const int eps = e0 + mh + (r & 3) + 8 * (r >> 2) + (g8 >> 1);
    if (eps < 2032)
      atomicAdd(&PV[((size_t)b * 2032 + eps) * 64 + nh + l31], acc[r]);
  }
}

// ---------------------------------------------------------------------------
// red_reduce with fused att softmax: each block softmaxes its batch's logits
// (redundant, cheap) then accumulates red[b,d] over its 127-slice.
// grid (16, 4).
// ---------------------------------------------------------------------------
__global__ __launch_bounds__(256) void red_reduce_kernel(
    const float* __restrict__ emat, const float* __restrict__ PV,
    const float* __restrict__ logits, float* __restrict__ red) {
  __shared__ float s_att[2032];
  __shared__ float sred[4];
  __shared__ float s_part[4][64];
  const int tid = threadIdx.x;
  const int lane = tid & 63, wave = tid >> 6;
  const int b = blockIdx.y;
  // softmax over logits[b][:]
  float m = -3.4e38f;
  for (int i = tid; i < 2032; i += 256) {
    const float v = logits[b * 2032 + i];
    s_att[i] = v;
    m = fmaxf(m, v);
  }
#pragma unroll
  for (int off = 32; off > 0; off >>= 1) m = fmaxf(m, __shfl_down(m, off, 64));
  if (lane == 0) sred[wave] = m;
  __syncthreads();
  m = fmaxf(fmaxf(sred[0], sred[1]), fmaxf(sred[2], sred[3]));
  __syncthreads();
  float ssum = 0.f;
  for (int i = tid; i < 2032; i += 256) {
    const float v = __expf(s_att[i] - m);
    s_att[i] = v;
    ssum += v;
  }
#pragma unroll
  for (int off = 32; off > 0; off >>= 1) ssum += __shfl_down(ssum, off, 64);
  if (lane == 0) sred[wave] = ssum;
  __syncthreads();
  const float inv = 1.f / (sred[0] + sred[1] + sred[2] + sred[3]);
  // weighted reduce over slice
  const int i0 = blockIdx.x * 127;
  float acc = 0.f;
  for (int i = i0 + wave; i < i0 + 127; i += 4) {
    const size_t idx = ((size_t)b * 2032 + i) * 64 + lane;
    acc = fmaf(fabsf(PV[idx] - emat[idx]), s_att[i], acc);
  }
  s_part[wave][lane] = acc;
  __syncthreads();
  if (tid < 64)
    atomicAdd(&red[b * 64 + tid],
              (s_part[0][tid] + s_part[1][tid] + s_part[2][tid] + s_part[3][tid]) * inv);
}

// ---------------------------------------------------------------------------
// mlp: h = relu(red@h_w^T + h_b); out = softmax(h@c_w^T + c_b). grid 4.
// ---------------------------------------------------------------------------
__global__ __launch_bounds__(128) void mlp_kernel(
    const float* __restrict__ red, const float* __restrict__ h_w,
    const float* __restrict__ h_b, const float* __restrict__ c_w,
    const float* __restrict__ c_b, float* __restrict__ out) {
  __shared__ float s_red[64];
  __shared__ float s_hv[128];
  const int tid = threadIdx.x;
  const int b = blockIdx.x;
  if (tid < 64) s_red[tid] = red[b * 64 + tid];
  __syncthreads();
  {
    float acc = h_b[tid];
    const float* hw = h_w + tid * 64;
    for (int d = 0; d < 64; ++d) acc = fmaf(s_red[d], hw[d], acc);
    s_hv[tid] = fmaxf(acc, 0.f);
  }
  __syncthreads();
  if (tid == 0) {
    float l0 = c_b[0], l1 = c_b[1];
    for (int j = 0; j < 128; ++j) {
      l0 = fmaf(s_hv[j], c_w[j], l0);
      l1 = fmaf(s_hv[j], c_w[128 + j], l1);
    }
    const float mm = fmaxf(l0, l1);
    const float e0 = __expf(l0 - mm), e1 = __expf(l1 - mm);
    const float invs = 1.f / (e0 + e1);
    out[b * 2 + 0] = e0 * invs;
    out[b * 2 + 1] = e1 * invs;
  }
}

// ===========================================================================
extern "C" void kernel_launch(void* const* d_in, const int* in_sizes, int n_in,
                              void* d_out, int out_size, void* d_ws, size_t ws_size,
                              hipStream_t stream) {
  const float* evaluation = (const float*)d_in[0];
  const float* templ      = (const float*)d_in[1];
  const float* e_w1 = (const float*)d_in[2];
  const float* e_b1 = (const float*)d_in[3];
  const float* e_w2 = (const float*)d_in[4];
  const float* e_b2 = (const float*)d_in[5];
  const float* e_w3 = (const float*)d_in[6];
  const float* e_b3 = (const float*)d_in[7];
  const float* el_w = (const float*)d_in[8];
  const float* el_b = (const float*)d_in[9];
  const float* eg_wih = (const float*)d_in[10];
  const float* eg_whh = (const float*)d_in[11];
  const float* eg_bih = (const float*)d_in[12];
  const float* eg_bhh = (const float*)d_in[13];
  const float* t_w1 = (const float*)d_in[14];
  const float* t_b1 = (const float*)d_in[15];
  const float* t_w2 = (const float*)d_in[16];
  const float* t_b2 = (const float*)d_in[17];
  const float* t_w3 = (const float*)d_in[18];
  const float* t_b3 = (const float*)d_in[19];
  const float* tl_w = (const float*)d_in[20];
  const float* tl_b = (const float*)d_in[21];
  const float* tg_wih = (const float*)d_in[22];
  const float* tg_whh = (const float*)d_in[23];
  const float* tg_bih = (const float*)d_in[24];
  const float* tg_bhh = (const float*)d_in[25];
  const float* a_w = (const float*)d_in[26];
  const float* a_b = (const float*)d_in[27];
  const float* h_w = (const float*)d_in[28];
  const float* h_b = (const float*)d_in[29];
  const float* c_w = (const float*)d_in[30];
  const float* c_b = (const float*)d_in[31];

  float* ws = (float*)d_ws;
  float* beff_e  = ws + OFF_BEFF_E;
  float* beff_t  = ws + OFF_BEFF_T;
  float* bias2_e = ws + OFF_BIAS2_E;
  float* bias2_t = ws + OFF_BIAS2_T;
  u16*   wkx_e   = (u16*)(ws + OFF_WKX_E);
  u16*   wkx_t   = (u16*)(ws + OFF_WKX_T);
  float* w12p_e  = ws + OFF_W12P_E;
  float* w12p_t  = ws + OFF_W12P_T;
  float* b12_e   = ws + OFF_B12_E;
  float* b12_t   = ws + OFF_B12_T;
  u16*   lwbf_e  = (u16*)(ws + OFF_LWBF_E);
  u16*   lwbf_t  = (u16*)(ws + OFF_LWBF_T);
  float* attbuf  = ws + OFF_ATT;
  u16*   xybf_e  = (u16*)(ws + OFF_XYBF_E);
  u16*   xybf_t  = (u16*)(ws + OFF_XYBF_T);
  u16*   ttbf    = (u16*)(ws + OFF_TTBF);
  float* lin_e   = ws + OFF_LIN_E;
  float* lin_t   = ws + OFF_LIN_T;
  float* PVbuf   = ws + OFF_PV;
  float* redbuf  = ws + OFF_RED;
  u16*   pool_e  = (u16*)(ws + OFF_POOL_E);
  u16*   pool_t  = (u16*)(ws + OFF_POOL_T);
  float* gi_e    = ws + OFF_GI_E;
  float* gi_t    = ws + OFF_GI_T;
  u16*   Pbuf    = (u16*)(ws + OFF_P);

  // prep (zeroes lin/PV/red + compose12 + gi_bias + lw->bf16), then weff
  prep_kernel<<<530, 320, 0, stream>>>(
      e_w1, e_b1, e_w2, e_b2, t_w1, t_b1, t_w2, t_b2, w12p_e, w12p_t, b12_e, b12_t,
      eg_wih, eg_bih, el_b, bias2_e, tg_wih, tg_bih, tl_b, bias2_t,
      el_w, tl_w, lwbf_e, lwbf_t, (float4*)lin_e);
  compose_weff_kernel<<<dim3(64, 2), 256, 0, stream>>>(
      e_w3, e_b3, t_w3, t_b3, w12p_e, w12p_t, b12_e, b12_t, wkx_e, wkx_t, beff_e, beff_t);

  // mainline
  conv_pool_mfma_kernel<<<dim3(34, 29, 8), 256, 0, stream>>>(
      evaluation, wkx_e, beff_e, pool_e, templ, wkx_t, beff_t, pool_t);
  gemm_splitk_mfma_kernel<<<dim3(191, 8), 256, 0, stream>>>(
      pool_e, lwbf_e, lin_e, pool_t, lwbf_t, lin_t);
  gemm_gi_kernel<<<dim3(191, 3), 256, 0, stream>>>(
      lin_e, eg_wih, bias2_e, gi_e, lin_t, tg_wih, bias2_t, gi_t);
  gru_rec_kernel<<<191, 256, 0, stream>>>(
      lin_e, gi_e, eg_whh, eg_bhh, lin_t, gi_t, tg_whh, tg_bhh,
      xybf_e, xybf_t, ttbf, a_w, a_b, attbuf);

  // cross attention (MFMA scores/pv, bf16 P)
  scores_mfma_kernel<<<dim3(16, 16, 4), 256, 0, stream>>>(xybf_t, xybf_e, Pbuf);
  softmax_rows_kernel<<<4096, 256, 0, stream>>>(Pbuf);
  pv_mfma_kernel<<<dim3(32, 4, 4), 256, 0, stream>>>(Pbuf, ttbf, PVbuf);

  // head: (softmax fused into) weighted reduce -> MLP
  red_reduce_kernel<<<dim3(16, 4), 256, 0, stream>>>(lin_e, PVbuf, attbuf, redbuf);
  mlp_kernel<<<4, 128, 0, stream>>>(redbuf, h_w, h_b, c_w, c_b, (float*)d_out);
}

// Round 12
// 320.753 us; speedup vs baseline: 9.6820x; 1.0466x over previous
//
#include <hip/hip_runtime.h>
#include <hip/hip_bf16.h>
#include <cmath>

// ============================================================================
// DeepTemplateMatchingModule on MI355X — round 12 (R11 fix: bit_cast ->
// memcpy; __hip_bfloat162 is not trivially copyable).
// R11 content: (1) softmax node deleted — |GRU h|<=1 => |score|<=64 =>
// exp(s) never overflows fp32, so scores emits P'=exp(s) + per-tau rowsums
// and pv folds 1/S into its P^T staging. (2) conv uses packed bf16 converts
// (__float22bfloat162_rn -> v_cvt_pk_bf16_f32). (3) rowsum zero in prep.
// ============================================================================

typedef unsigned short u16;
typedef unsigned int u32;
typedef __attribute__((ext_vector_type(8))) short bf16x8;
typedef __attribute__((ext_vector_type(8))) unsigned short u16x8;
typedef __attribute__((ext_vector_type(16))) float f32x16;

__device__ __forceinline__ u16 f2bf(float f) {
  unsigned int x = __float_as_uint(f);
  return (u16)((x + 0x7fffu + ((x >> 16) & 1u)) >> 16);
}
__device__ __forceinline__ float bf2f(u16 v) {
  return __uint_as_float(((unsigned int)v) << 16);
}
__device__ __forceinline__ u32 f2bf_pk(float a, float b) {
  __hip_bfloat162 h = __float22bfloat162_rn(float2{a, b});
  u32 r;
  __builtin_memcpy(&r, &h, 4);  // low 16 = a, high 16 = b
  return r;
}

// ---- workspace layout (float offsets) ----
static const size_t OFF_BEFF_E  = 0;          // 64
static const size_t OFF_BEFF_T  = 64;
static const size_t OFF_BIAS2_E = 128;        // 192
static const size_t OFF_BIAS2_T = 320;
static const size_t OFF_WKX_E   = 512;        // 4 parities x 13x64x16 u16 = 26624 f
static const size_t OFF_WKX_T   = 27136;      // 26624 f
static const size_t OFF_W12P_E  = 53760;      // 9248
static const size_t OFF_W12P_T  = 63008;      // 9248
static const size_t OFF_B12_E   = 72256;      // 32
static const size_t OFF_B12_T   = 72288;      // 32
static const size_t OFF_LWBF_E  = 72320;      // 118784 f (237568 u16)
static const size_t OFF_LWBF_T  = 191104;     // 118784 f
static const size_t OFF_ATT     = 309888;     // 8128 f (raw logits)
static const size_t OFF_XYBF_E  = 318016;     // 260096 f (4x2032x64 u16)
static const size_t OFF_XYBF_T  = 578112;     // 131072 f (4x1024x64 u16)
static const size_t OFF_TTBF    = 709184;     // 131072 f (t^T: 4x64x1024 u16)
// contiguous zero region (zeroed by prep): lin_e, lin_t, PV, red, rowsum
static const size_t OFF_LIN_E   = 840256;     // 520192 f
static const size_t OFF_LIN_T   = 1360448;    // 262144 f
static const size_t OFF_PV      = 1622592;    // 520192 f
static const size_t OFF_RED     = 2142784;    // 256 f
static const size_t OFF_RSUM    = 2143040;    // 4096 f
static const size_t ZERO_F4     = 326720;     // 1,306,880 f / 4
static const size_t ZSTRIDE     = 617;        // 530 * 617 >= 326720
// pools coexist
static const size_t OFF_POOL_E  = 2147136;    // u16: 30,171,136 u16
static const size_t OFF_POOL_T  = 17232704;   // u16: 15,204,352 u16
// dead-pool_e reuse (after splitk):
static const size_t OFF_GI_E    = 2147136;    // 1,560,576 f
static const size_t OFF_GI_T    = 3707712;    // 786,432 f
static const size_t OFF_P       = 4494144;    // u16: 8,323,072 u16

// ---------------------------------------------------------------------------
// prep: zero region + compose12 (bx<64) + gi_bias (64..65) + lw->bf16 (>=66).
// ---------------------------------------------------------------------------
__global__ __launch_bounds__(320) void prep_kernel(
    const float* __restrict__ w1e, const float* __restrict__ b1e,
    const float* __restrict__ w2e, const float* __restrict__ b2e,
    const float* __restrict__ w1t, const float* __restrict__ b1t,
    const float* __restrict__ w2t, const float* __restrict__ b2t,
    float* __restrict__ w12p_e, float* __restrict__ w12p_t,
    float* __restrict__ b12o_e, float* __restrict__ b12o_t,
    const float* __restrict__ wih_e, const float* __restrict__ bih_e,
    const float* __restrict__ lb_e, float* __restrict__ bias2_e,
    const float* __restrict__ wih_t, const float* __restrict__ bih_t,
    const float* __restrict__ lb_t, float* __restrict__ bias2_t,
    const float* __restrict__ lwe, const float* __restrict__ lwt,
    u16* __restrict__ lwbf_e, u16* __restrict__ lwbf_t,
    float4* __restrict__ zbase) {
  const int bx = blockIdx.x;
  const int tid = threadIdx.x;
  {
    const size_t base = (size_t)bx * ZSTRIDE;
    const float4 z = {0.f, 0.f, 0.f, 0.f};
    for (size_t i = base + tid; i < base + ZSTRIDE && i < ZERO_F4; i += 320)
      zbase[i] = z;
  }
  if (bx >= 66) {  // lw -> bf16
    if (tid < 256) {
      const int k = bx - 66;
      const int br = k / 232, j = k - br * 232;
      const float* src = br ? lwt : lwe;
      u16* dst = br ? lwbf_t : lwbf_e;
      const int i = (j * 256 + tid) * 4;
      const float4 v = *(const float4*)&src[i];
      *(u32*)&dst[i] = f2bf_pk(v.x, v.y);
      *(u32*)&dst[i + 2] = f2bf_pk(v.z, v.w);
    }
    return;
  }
  if (bx >= 64) {  // gi_bias
    const int br = bx - 64;
    const float* wih = br ? wih_t : wih_e;
    const float* bih = br ? bih_t : bih_e;
    const float* lb = br ? lb_t : lb_e;
    float* bias2 = br ? bias2_t : bias2_e;
    __shared__ float s_lb[64];
    if (tid < 64) s_lb[tid] = lb[tid];
    __syncthreads();
    if (tid < 192) {
      float acc = bih[tid];
      const float* wr = wih + tid * 64;
      for (int d = 0; d < 64; ++d) acc = fmaf(wr[d], s_lb[d], acc);
      bias2[tid] = acc;
    }
    return;
  }
  // compose12
  const int br = bx >> 5;
  const float* w1 = br ? w1t : w1e;
  const float* b1 = br ? b1t : b1e;
  const float* w2 = br ? w2t : w2e;
  const float* b2 = br ? b2t : b2e;
  float* w12p = br ? w12p_t : w12p_e;
  float* b12o = br ? b12o_t : b12o_e;
  const int c12 = bx & 31;
  __shared__ float s_w1pad[16 * 169];
  __shared__ float s_w2c[400];
  __shared__ float s_b1[16];
  for (int i = tid; i < 2704; i += 320) s_w1pad[i] = 0.f;
  if (tid < 16) s_b1[tid] = b1[tid];
  __syncthreads();
  for (int i = tid; i < 400; i += 320) {
    const int c1 = i / 25, r = (i % 25) / 5, cc = i % 5;
    s_w1pad[c1 * 169 + (r + 4) * 13 + (cc + 4)] = w1[i];
    s_w2c[i] = w2[c12 * 400 + i];
  }
  __syncthreads();
  if (tid < 289) {
    const int py = tid / 17, px = tid % 17;
    float v = 0.f;
    if (py >= 4 && py <= 12 && px >= 4 && px <= 12) {
      const int sy = py - 4, sx = px - 4;
      float accs[2] = {0.f, 0.f};
      for (int c1 = 0; c1 < 16; ++c1) {
        const float* w2p = s_w2c + c1 * 25;
        const float* w1p = s_w1pad + c1 * 169 + (sy + 4) * 13 + (sx + 4);
#pragma unroll
        for (int uy = 0; uy < 5; ++uy)
#pragma unroll
          for (int ux = 0; ux < 5; ++ux)
            accs[uy & 1] = fmaf(w2p[uy * 5 + ux], w1p[-(uy * 13) - ux], accs[uy & 1]);
      }
      v = accs[0] + accs[1];
    }
    w12p[c12 * 289 + tid] = v;
  } else if (tid == 300) {
    float acc = b2[c12];
    for (int c1 = 0; c1 < 16; ++c1) {
      float sw = 0.f;
      for (int u = 0; u < 25; ++u) sw += s_w2c[c1 * 25 + u];
      acc = fmaf(sw, s_b1[c1], acc);
    }
    b12o[c12] = acc;
  }
}

// ---------------------------------------------------------------------------
// compose_weff: 4 parity layouts wkx[(p*13+kx)*64+o][16] bf16 (slot ky+p).
// ---------------------------------------------------------------------------
__global__ __launch_bounds__(256) void compose_weff_kernel(
    const float* __restrict__ w3e, const float* __restrict__ b3e,
    const float* __restrict__ w3t, const float* __restrict__ b3t,
    const float* __restrict__ w12p_e, const float* __restrict__ w12p_t,
    const float* __restrict__ b12_e, const float* __restrict__ b12_t,
    u16* __restrict__ wkx_e, u16* __restrict__ wkx_t,
    float* __restrict__ beff_e, float* __restrict__ beff_t) {
  const int br = blockIdx.y;
  const float* w3 = br ? w3t : w3e;
  const float* b3 = br ? b3t : b3e;
  const float* w12p = br ? w12p_t : w12p_e;
  const float* b12 = br ? b12_t : b12_e;
  u16* wkx = br ? wkx_t : wkx_e;
  float* beff = br ? beff_t : beff_e;
  const int o = blockIdx.x;
  __shared__ float s_pad[32 * 289];
  __shared__ float s_w3o[800];
  __shared__ float s_b12[32];
  const int tid = threadIdx.x;
  for (int i = tid; i < 9248; i += 256) s_pad[i] = w12p[i];
  for (int i = tid; i < 800; i += 256) s_w3o[i] = w3[o * 800 + i];
  if (tid < 32) s_b12[tid] = b12[tid];
  __syncthreads();
  if (tid < 169) {
    const int sy = tid / 13, sx = tid % 13;
    float accs[4] = {0.f, 0.f, 0.f, 0.f};
#pragma unroll 4
    for (int c = 0; c < 32; ++c) {
      const float* w3p = s_w3o + c * 25;
      const float* wp = s_pad + c * 289 + (sy + 4) * 17 + (sx + 4);
#pragma unroll
      for (int uy = 0; uy < 5; ++uy)
#pragma unroll
        for (int ux = 0; ux < 5; ++ux)
          accs[c & 3] = fmaf(w3p[uy * 5 + ux], wp[-(uy * 17) - ux], accs[c & 3]);
    }
    const u16 v = f2bf(accs[0] + accs[1] + accs[2] + accs[3]);
#pragma unroll
    for (int p = 0; p < 4; ++p)
      wkx[((p * 13 + sx) * 64 + o) * 16 + sy + p] = v;
  } else if (tid < 169 + 156) {  // 13 kx x 12 zero-slots
    const int t = tid - 169, kx = t / 12, q = t % 12;
    const int p = q / 3, idx = q % 3;
    const int slot = (idx < p) ? idx : (p + 13) + (idx - p);
    wkx[((p * 13 + kx) * 64 + o) * 16 + slot] = 0;
  }
  if (tid == 255) {
    float acc = b3[o];
    for (int c = 0; c < 32; ++c) {
      float sw = 0.f;
      for (int u = 0; u < 25; ++u) sw += s_w3o[c * 25 + u];
      acc = fmaf(sw, s_b12[c], acc);
    }
    beff[o] = acc;
  }
}

// ---------------------------------------------------------------------------
// MFMA conv13x13 + maxpool, 2 pooled rows per block, both branches.
// Packed bf16 converts in staging / C-write / pooling. grid (34, 29, 8).
// ---------------------------------------------------------------------------
__global__ __launch_bounds__(256, 4) void conv_pool_mfma_kernel(
    const float* __restrict__ xe, const u16* __restrict__ wkx_e,
    const float* __restrict__ beff_e, u16* __restrict__ pooled_e,
    const float* __restrict__ xt, const u16* __restrict__ wkx_t,
    const float* __restrict__ beff_t, u16* __restrict__ pooled_t) {
  const int zz = blockIdx.z;
  const bool ev = zz < 4;
  const int b = ev ? zz : zz - 4;
  const int W = ev ? 2048 : 1040;
  const int T = ev ? 2032 : 1024;
  const int cb = blockIdx.x * 60;
  if (cb >= T) return;
  const float* x = ev ? xe : xt;
  const u16* wkx = ev ? wkx_e : wkx_t;
  const float* beff = ev ? beff_e : beff_t;
  u16* pooled = ev ? pooled_e : pooled_t;

  __shared__ __align__(16) u16 s_x[80 * 24];
  __shared__ __align__(16) u16 s_out[2 * 64 * 66];
  __shared__ __align__(16) u16 s_pool[64 * 62];

  const int tid = threadIdx.x;
  const int lane = tid & 63, wave = tid >> 6;
  const int by = blockIdx.y;
  const int rsel = wave & 1, cm = (wave >> 1) * 32;
  const int l31 = lane & 31, g8 = (lane >> 5) * 8;
  const int r0 = 4 * by;

  {
    const float* xb = x + ((size_t)b * 128 + r0) * W;
    for (int i = tid; i < 640; i += 256) {
      const int pr = i / 80, c = i - pr * 80;
      int gc = cb + c;
      if (gc > W - 1) gc = W - 1;
      *(u32*)&s_x[c * 24 + 2 * pr] =
          f2bf_pk(xb[(size_t)(2 * pr) * W + gc], xb[(size_t)(2 * pr + 1) * W + gc]);
    }
  }
  __syncthreads();
#pragma unroll
  for (int hh = 0; hh < 2; ++hh) {
    const int p = 2 * hh + rsel;
    const int h = 2 * by + hh;
    bf16x8 wfrag[13];
    {
      const u16* aw = wkx + ((p * 13) * 64 + cm + l31) * 16 + g8;
#pragma unroll
      for (int kx = 0; kx < 13; ++kx) wfrag[kx] = *(const bf16x8*)(aw + kx * 1024);
    }
    f32x16 acc0 = {}, acc1 = {};
    const u16* bx = s_x + g8;
#pragma unroll
    for (int kx = 0; kx < 13; ++kx) {
      bf16x8 b0 = *(const bf16x8*)(bx + (l31 + kx) * 24);
      bf16x8 b1 = *(const bf16x8*)(bx + (32 + l31 + kx) * 24);
      acc0 = __builtin_amdgcn_mfma_f32_32x32x16_bf16(wfrag[kx], b0, acc0, 0, 0, 0);
      acc1 = __builtin_amdgcn_mfma_f32_32x32x16_bf16(wfrag[kx], b1, acc1, 0, 0, 0);
    }
#pragma unroll
    for (int r = 0; r < 16; ++r) {
      const int c = cm + (r & 3) + 8 * (r >> 2) + (g8 >> 1);
      u16* o = s_out + (rsel * 64 + c) * 66;
      const u32 pk = f2bf_pk(acc0[r], acc1[r]);
      o[l31] = (u16)pk;
      o[32 + l31] = (u16)(pk >> 16);
    }
    __syncthreads();
    {
      const int pc = tid & 63, tg = tid >> 6;
      const int t0 = tg * 15;
      const float bias = beff[pc];
      const u16* r0p = s_out + pc * 66 + t0;
      const u16* r1p = s_out + (64 + pc) * 66 + t0;
      float m01[19];
#pragma unroll
      for (int j = 0; j < 19; ++j) m01[j] = fmaxf(bf2f(r0p[j]), bf2f(r1p[j]));
      float mm[15];
#pragma unroll
      for (int i = 0; i < 15; ++i) {
        float m = m01[i];
#pragma unroll
        for (int k = 1; k < 5; ++k) m = fmaxf(m, m01[i + k]);
        mm[i] = m + bias;
      }
      u16* sp = s_pool + pc * 62 + t0;
#pragma unroll
      for (int i = 0; i < 14; i += 2) {
        const u32 pk = f2bf_pk(mm[i], mm[i + 1]);
        sp[i] = (u16)pk;
        sp[i + 1] = (u16)(pk >> 16);
      }
      sp[14] = f2bf(mm[14]);
    }
    __syncthreads();
    for (int i = tid; i < 1920; i += 256) {
      const int c = i / 30, tp = i - c * 30;
      const int gt = cb + 2 * tp;
      if (gt < T) {
        const u32 pair = *(const u32*)&s_pool[c * 62 + 2 * tp];
        *(u32*)&pooled[(((size_t)b * 64 + c) * 58 + h) * T + gt] = pair;
      }
    }
  }
}

// ---------------------------------------------------------------------------
// Split-K GEMM on bf16 MFMA, both branches: grid (191, 8); bx<127 eval.
// ---------------------------------------------------------------------------
__global__ __launch_bounds__(256) void gemm_splitk_mfma_kernel(
    const u16* __restrict__ Ae, const u16* __restrict__ Bwe, float* __restrict__ oute,
    const u16* __restrict__ At, const u16* __restrict__ Bwt, float* __restrict__ outt) {
  const int bx = blockIdx.x;
  const bool ev = bx < 127;
  const u16* A = ev ? Ae : At;
  const u16* Bw = ev ? Bwe : Bwt;
  float* out = ev ? oute : outt;
  const int r0 = (ev ? bx : bx - 127) * 64;
  __shared__ __align__(16) u16 sA[64 * 72];
  __shared__ __align__(16) u16 sB[64 * 72];
  const int tid = threadIdx.x;
  const int s = blockIdx.y;
  const int ch0 = (s * 58) / 8, ch1 = ((s + 1) * 58) / 8;
  const int lane = tid & 63, wave = tid >> 6;
  const int l31 = lane & 31, g8 = (lane >> 5) * 8;
  const int mh = (wave & 1) * 32, nh = (wave >> 1) * 32;
  const int srow = tid >> 2, sseg = (tid & 3) * 16;
  f32x16 acc = {};
  for (int ch = ch0; ch < ch1; ++ch) {
    const int kc = ch * 64;
    __syncthreads();
    {
      const u16* ap = &A[(size_t)(r0 + srow) * 3712 + kc + sseg];
      const u16* bp = &Bw[(size_t)srow * 3712 + kc + sseg];
      u16* da = &sA[srow * 72 + sseg];
      u16* db = &sB[srow * 72 + sseg];
      *(u16x8*)da = *(const u16x8*)ap;
      *(u16x8*)(da + 8) = *(const u16x8*)(ap + 8);
      *(u16x8*)db = *(const u16x8*)bp;
      *(u16x8*)(db + 8) = *(const u16x8*)(bp + 8);
    }
    __syncthreads();
#pragma unroll
    for (int ks = 0; ks < 4; ++ks) {
      bf16x8 a = *(const bf16x8*)&sA[(mh + l31) * 72 + ks * 16 + g8];
      bf16x8 b = *(const bf16x8*)&sB[(nh + l31) * 72 + ks * 16 + g8];
      acc = __builtin_amdgcn_mfma_f32_32x32x16_bf16(a, b, acc, 0, 0, 0);
    }
  }
#pragma unroll
  for (int r = 0; r < 16; ++r) {
    const int row = mh + (r & 3) + 8 * (r >> 2) + (g8 >> 1);
    atomicAdd(&out[(size_t)(r0 + row) * 64 + nh + l31], acc[r]);
  }
}

// ---------------------------------------------------------------------------
// gi GEMM, both branches: grid (191, 3); N=192, K=64.
// ---------------------------------------------------------------------------
__global__ __launch_bounds__(256) void gemm_gi_kernel(
    const float* __restrict__ Ae, const float* __restrict__ Wte,
    const float* __restrict__ biase, float* __restrict__ oute,
    const float* __restrict__ At, const float* __restrict__ Wtt,
    const float* __restrict__ biast, float* __restrict__ outt) {
  const int bx = blockIdx.x;
  const bool ev = bx < 127;
  const float* A = ev ? Ae : At;
  const float* Wt = ev ? Wte : Wtt;
  const float* bias = ev ? biase : biast;
  float* out = ev ? oute : outt;
  const int r0 = (ev ? bx : bx - 127) * 64;
  const int N = 192, K = 64;
  __shared__ float sA[64 * 33];
  __shared__ float sB[64 * 33];
  const int tid = threadIdx.x;
  const int n0 = blockIdx.y * 64;
  const int ty = tid >> 4, tx = tid & 15;
  float acc[4][4] = {};
  for (int kc = 0; kc < K; kc += 32) {
    __syncthreads();
#pragma unroll
    for (int rep = 0; rep < 8; ++rep) {
      const int l = tid + rep * 256;
      const int row = l >> 5, kk = l & 31;
      sA[row * 33 + kk] = A[(size_t)(r0 + row) * K + kc + kk];
      sB[row * 33 + kk] = Wt[(size_t)(n0 + row) * K + kc + kk];
    }
    __syncthreads();
#pragma unroll 8
    for (int kk = 0; kk < 32; ++kk) {
      const float a0 = sA[(ty * 4 + 0) * 33 + kk];
      const float a1 = sA[(ty * 4 + 1) * 33 + kk];
      const float a2 = sA[(ty * 4 + 2) * 33 + kk];
      const float a3 = sA[(ty * 4 + 3) * 33 + kk];
      const float b0 = sB[(tx * 4 + 0) * 33 + kk];
      const float b1 = sB[(tx * 4 + 1) * 33 + kk];
      const float b2 = sB[(tx * 4 + 2) * 33 + kk];
      const float b3 = sB[(tx * 4 + 3) * 33 + kk];
      acc[0][0] = fmaf(a0, b0, acc[0][0]); acc[0][1] = fmaf(a0, b1, acc[0][1]);
      acc[0][2] = fmaf(a0, b2, acc[0][2]); acc[0][3] = fmaf(a0, b3, acc[0][3]);
      acc[1][0] = fmaf(a1, b0, acc[1][0]); acc[1][1] = fmaf(a1, b1, acc[1][1]);
      acc[1][2] = fmaf(a1, b2, acc[1][2]); acc[1][3] = fmaf(a1, b3, acc[1][3]);
      acc[2][0] = fmaf(a2, b0, acc[2][0]); acc[2][1] = fmaf(a2, b1, acc[2][1]);
      acc[2][2] = fmaf(a2, b2, acc[2][2]); acc[2][3] = fmaf(a2, b3, acc[2][3]);
      acc[3][0] = fmaf(a3, b0, acc[3][0]); acc[3][1] = fmaf(a3, b1, acc[3][1]);
      acc[3][2] = fmaf(a3, b2, acc[3][2]); acc[3][3] = fmaf(a3, b3, acc[3][3]);
    }
  }
#pragma unroll
  for (int i = 0; i < 4; ++i)
#pragma unroll
    for (int j = 0; j < 4; ++j)
      out[(size_t)(r0 + ty * 4 + i) * N + n0 + tx * 4 + j] =
          acc[i][j] + bias[n0 + tx * 4 + j];
}

// ---------------------------------------------------------------------------
// GRU, both branches (grid 191). fp32 xy + bf16 xy_bf; logits (eval);
// t^T bf16 scatter (template).
// ---------------------------------------------------------------------------
__global__ __launch_bounds__(256) void gru_rec_kernel(
    float* __restrict__ xyE, const float* __restrict__ giE,
    const float* __restrict__ whhE, const float* __restrict__ bhhE,
    float* __restrict__ xyT, const float* __restrict__ giT,
    const float* __restrict__ whhT, const float* __restrict__ bhhT,
    u16* __restrict__ xybfE, u16* __restrict__ xybfT, u16* __restrict__ ttbf,
    const float* __restrict__ a_w, const float* __restrict__ a_b,
    float* __restrict__ logits) {
  const int bxid = blockIdx.x;
  const bool ev = bxid < 127;
  float* xy = ev ? xyE : xyT;
  u16* xybf = ev ? xybfE : xybfT;
  const float* gi = ev ? giE : giT;
  const float* whh = ev ? whhE : whhT;
  const float* bhh = ev ? bhhE : bhhT;
  const int T = ev ? 2032 : 1024;
  const int t0 = (ev ? bxid : bxid - 127) * 16;
  __shared__ float s_whh_t[64 * 192];
  __shared__ float s_h[16][64];
  __shared__ float s_aw[64];
  const int tid = threadIdx.x;
  const int lane = tid & 63, wave = tid >> 6;
  for (int i = tid; i < 192 * 64; i += 256) {
    const int j = i >> 6, d = i & 63;
    s_whh_t[d * 192 + j] = whh[i];
  }
  for (int i = tid; i < 16 * 64; i += 256) (&s_h[0][0])[i] = 0.f;
  if (tid < 64) s_aw[tid] = a_w[tid];
  const float ab = a_b[0];
  const float bhr = bhh[lane], bhz = bhh[64 + lane], bhn = bhh[128 + lane];
  __syncthreads();
  for (int b = 0; b < 4; ++b) {
    float gir[4], giz[4], gin[4];
#pragma unroll
    for (int sl = 0; sl < 4; ++sl) {
      int t = t0 + wave * 4 + sl; if (t > T - 1) t = T - 1;
      const float* girow = gi + ((size_t)b * T + t) * 192;
      gir[sl] = girow[lane]; giz[sl] = girow[64 + lane]; gin[sl] = girow[128 + lane];
    }
    float ahr[4] = {}, ahz[4] = {}, ahn[4] = {};
    for (int d = 0; d < 64; ++d) {
      const float wr_ = s_whh_t[d * 192 + lane];
      const float wz_ = s_whh_t[d * 192 + 64 + lane];
      const float wn_ = s_whh_t[d * 192 + 128 + lane];
#pragma unroll
      for (int sl = 0; sl < 4; ++sl) {
        const float hv = s_h[wave * 4 + sl][d];
        ahr[sl] = fmaf(wr_, hv, ahr[sl]);
        ahz[sl] = fmaf(wz_, hv, ahz[sl]);
        ahn[sl] = fmaf(wn_, hv, ahn[sl]);
      }
    }
    float hn[4];
#pragma unroll
    for (int sl = 0; sl < 4; ++sl) {
      const float r = 1.f / (1.f + __expf(-(gir[sl] + ahr[sl] + bhr)));
      const float z = 1.f / (1.f + __expf(-(giz[sl] + ahz[sl] + bhz)));
      const float n = tanhf(gin[sl] + r * (ahn[sl] + bhn));
      hn[sl] = (1.f - z) * n + z * s_h[wave * 4 + sl][lane];
    }
    __syncthreads();
#pragma unroll
    for (int sl = 0; sl < 4; ++sl) {
      const int t = t0 + wave * 4 + sl;
      s_h[wave * 4 + sl][lane] = hn[sl];
      if (t < T) {
        const size_t idx = ((size_t)b * T + t) * 64 + lane;
        xy[idx] = hn[sl];
        xybf[idx] = f2bf(hn[sl]);
        if (ev) {
          float v = hn[sl] * s_aw[lane];
#pragma unroll
          for (int off = 32; off > 0; off >>= 1) v += __shfl_down(v, off, 64);
          if (lane == 0) logits[b * 2032 + t] = v + ab;
        } else {
          ttbf[((size_t)b * 64 + lane) * 1024 + t] = f2bf(hn[sl]);
        }
      }
    }
    __syncthreads();
  }
}

// ---------------------------------------------------------------------------
// scores: P'[b,tau,eps] = exp(sum_d t[tau,d] e[eps,d]); also accumulates
// per-tau rowsums (32-lane shuffle reduce + atomicAdd). |s| <= 64 so exp
// never overflows (GRU outputs are convex combos of tanh). grid (16,16,4).
// ---------------------------------------------------------------------------
__global__ __launch_bounds__(256) void scores_mfma_kernel(
    const u16* __restrict__ tbf, const u16* __restrict__ ebf,
    u16* __restrict__ P, float* __restrict__ rowsum) {
  __shared__ __align__(16) u16 sA[64 * 72];
  __shared__ __align__(16) u16 sB[128 * 72];
  const int tid = threadIdx.x;
  const int b = blockIdx.z;
  const int tau0 = blockIdx.x * 64;
  const int e0 = blockIdx.y * 128;
  const int lane = tid & 63, wave = tid >> 6;
  const int l31 = lane & 31, g8 = (lane >> 5) * 8;
  {
    const int row = tid >> 2, seg = (tid & 3) * 16;
    const u16* ap = &tbf[((size_t)b * 1024 + tau0 + row) * 64 + seg];
    u16* da = &sA[row * 72 + seg];
    *(u16x8*)da = *(const u16x8*)ap;
    *(u16x8*)(da + 8) = *(const u16x8*)(ap + 8);
  }
#pragma unroll
  for (int r = 0; r < 4; ++r) {
    const int q = tid + r * 256;
    const int row = q >> 3, seg = (q & 7) * 8;
    int eps = e0 + row; if (eps > 2031) eps = 2031;
    *(u16x8*)&sB[row * 72 + seg] =
        *(const u16x8*)&ebf[((size_t)b * 2032 + eps) * 64 + seg];
  }
  __syncthreads();
  const int mh = (wave & 1) * 32;
  const int nq = (wave >> 1) * 64;
  f32x16 acc0 = {}, acc1 = {};
#pragma unroll
  for (int ks = 0; ks < 4; ++ks) {
    bf16x8 a = *(const bf16x8*)&sA[(mh + l31) * 72 + ks * 16 + g8];
    bf16x8 b0 = *(const bf16x8*)&sB[(nq + l31) * 72 + ks * 16 + g8];
    bf16x8 b1 = *(const bf16x8*)&sB[(nq + 32 + l31) * 72 + ks * 16 + g8];
    acc0 = __builtin_amdgcn_mfma_f32_32x32x16_bf16(a, b0, acc0, 0, 0, 0);
    acc1 = __builtin_amdgcn_mfma_f32_32x32x16_bf16(a, b1, acc1, 0, 0, 0);
  }
  const int ep0 = e0 + nq + l31;
  const int ep1 = ep0 + 32;
#pragma unroll
  for (int r = 0; r < 16; ++r) {
    const int tau = tau0 + mh + (r & 3) + 8 * (r >> 2) + (g8 >> 1);
    const size_t prow = ((size_t)b * 1024 + tau) * 2032;
    const float e0v = __expf(acc0[r]);
    const float e1v = __expf(acc1[r]);
    float part = 0.f;
    if (ep0 < 2032) { P[prow + ep0] = f2bf(e0v); part += e0v; }
    if (ep1 < 2032) { P[prow + ep1] = f2bf(e1v); part += e1v; }
#pragma unroll
    for (int off = 16; off > 0; off >>= 1) part += __shfl_down(part, off, 32);
    if (l31 == 0) atomicAdd(&rowsum[b * 1024 + tau], part);
  }
}

// ---------------------------------------------------------------------------
// pv on bf16 MFMA with folded softmax normalization: sPT staged as
// P'[tau,eps] / rowsum[tau] (scale applied during the LDS transpose).
// grid (32 eps-tiles, 4 tau-slices, 4b); atomic f32 epilogue.
// ---------------------------------------------------------------------------
__global__ __launch_bounds__(256) void pv_mfma_kernel(
    const u16* __restrict__ P, const u16* __restrict__ ttbf,
    const float* __restrict__ rowsum, float* __restrict__ PV) {
  __shared__ __align__(16) u16 sPT[64 * 72];  // [eps][tau], pre-normalized
  __shared__ __align__(16) u16 sTT[64 * 72];  // [d][tau]
  const int tid = threadIdx.x;
  const int b = blockIdx.z;
  const int e0 = blockIdx.x * 64;
  const int tau_base = blockIdx.y * 256;
  const int lane = tid & 63, wave = tid >> 6;
  const int l31 = lane & 31, g8 = (lane >> 5) * 8;
  const int mh = (wave & 1) * 32, nh = (wave >> 1) * 32;
  f32x16 acc = {};
  for (int cc = 0; cc < 4; ++cc) {
    const int tc = tau_base + cc * 64;
    __syncthreads();
#pragma unroll
    for (int k = 0; k < 2; ++k) {
      const int q = tid + k * 256;
      const int row = q >> 3, seg = (q & 7) * 8;  // tau row, eps seg
      const float inv = 1.0f / rowsum[b * 1024 + tc + row];
      int er = e0 + seg;
      if (er > 2032 - 8) er = 2032 - 8;
      const u16x8 v = *(const u16x8*)&P[((size_t)b * 1024 + tc + row) * 2032 + er];
#pragma unroll
      for (int j = 0; j < 8; ++j)
        sPT[(seg + j) * 72 + row] = f2bf(bf2f(v[j]) * inv);
    }
#pragma unroll
    for (int k = 0; k < 2; ++k) {
      const int q = tid + k * 256;
      const int row = q >> 3, seg = (q & 7) * 8;
      *(u16x8*)&sTT[row * 72 + seg] =
          *(const u16x8*)&ttbf[((size_t)b * 64 + row) * 1024 + tc + seg];
    }
    __syncthreads();
#pragma unroll
    for (int ks = 0; ks < 4; ++ks) {
      bf16x8 a = *(const bf16x8*)&sPT[(mh + l31) * 72 + ks * 16 + g8];
      bf16x8 bb = *(const bf16x8*)&sTT[(nh + l31) * 72 + ks * 16 + g8];
      acc = __builtin_amdgcn_mfma_f32_32x32x16_bf16(a, bb, acc, 0, 0, 0);
    }
  }
#pragma unroll
  for (int r = 0; r < 16; ++r) {
    const int eps = e0 + mh + (r & 3) + 8 * (r >> 2) + (g8 >> 1);
    if (eps < 2032)
      atomicAdd(&PV[((size_t)b * 2032 + eps) * 64 + nh + l31], acc[r]);
  }
}

// ---------------------------------------------------------------------------
// red_reduce with fused att softmax (per-block redundant softmax of logits).
// grid (16, 4).
// ---------------------------------------------------------------------------
__global__ __launch_bounds__(256) void red_reduce_kernel(
    const float* __restrict__ emat, const float* __restrict__ PV,
    const float* __restrict__ logits, float* __restrict__ red) {
  __shared__ float s_att[2032];
  __shared__ float sred[4];
  __shared__ float s_part[4][64];
  const int tid = threadIdx.x;
  const int lane = tid & 63, wave = tid >> 6;
  const int b = blockIdx.y;
  float m = -3.4e38f;
  for (int i = tid; i < 2032; i += 256) {
    const float v = logits[b * 2032 + i];
    s_att[i] = v;
    m = fmaxf(m, v);
  }
#pragma unroll
  for (int off = 32; off > 0; off >>= 1) m = fmaxf(m, __shfl_down(m, off, 64));
  if (lane == 0) sred[wave] = m;
  __syncthreads();
  m = fmaxf(fmaxf(sred[0], sred[1]), fmaxf(sred[2], sred[3]));
  __syncthreads();
  float ssum = 0.f;
  for (int i = tid; i < 2032; i += 256) {
    const float v = __expf(s_att[i] - m);
    s_att[i] = v;
    ssum += v;
  }
#pragma unroll
  for (int off = 32; off > 0; off >>= 1) ssum += __shfl_down(ssum, off, 64);
  if (lane == 0) sred[wave] = ssum;
  __syncthreads();
  const float inv = 1.f / (sred[0] + sred[1] + sred[2] + sred[3]);
  const int i0 = blockIdx.x * 127;
  float acc = 0.f;
  for (int i = i0 + wave; i < i0 + 127; i += 4) {
    const size_t idx = ((size_t)b * 2032 + i) * 64 + lane;
    acc = fmaf(fabsf(PV[idx] - emat[idx]), s_att[i], acc);
  }
  s_part[wave][lane] = acc;
  __syncthreads();
  if (tid < 64)
    atomicAdd(&red[b * 64 + tid],
              (s_part[0][tid] + s_part[1][tid] + s_part[2][tid] + s_part[3][tid]) * inv);
}

// ---------------------------------------------------------------------------
// mlp: h = relu(red@h_w^T + h_b); out = softmax(h@c_w^T + c_b). grid 4.
// ---------------------------------------------------------------------------
__global__ __launch_bounds__(128) void mlp_kernel(
    const float* __restrict__ red, const float* __restrict__ h_w,
    const float* __restrict__ h_b, const float* __restrict__ c_w,
    const float* __restrict__ c_b, float* __restrict__ out) {
  __shared__ float s_red[64];
  __shared__ float s_hv[128];
  const int tid = threadIdx.x;
  const int b = blockIdx.x;
  if (tid < 64) s_red[tid] = red[b * 64 + tid];
  __syncthreads();
  {
    float acc = h_b[tid];
    const float* hw = h_w + tid * 64;
    for (int d = 0; d < 64; ++d) acc = fmaf(s_red[d], hw[d], acc);
    s_hv[tid] = fmaxf(acc, 0.f);
  }
  __syncthreads();
  if (tid == 0) {
    float l0 = c_b[0], l1 = c_b[1];
    for (int j = 0; j < 128; ++j) {
      l0 = fmaf(s_hv[j], c_w[j], l0);
      l1 = fmaf(s_hv[j], c_w[128 + j], l1);
    }
    const float mm = fmaxf(l0, l1);
    const float e0 = __expf(l0 - mm), e1 = __expf(l1 - mm);
    const float invs = 1.f / (e0 + e1);
    out[b * 2 + 0] = e0 * invs;
    out[b * 2 + 1] = e1 * invs;
  }
}

// ===========================================================================
extern "C" void kernel_launch(void* const* d_in, const int* in_sizes, int n_in,
                              void* d_out, int out_size, void* d_ws, size_t ws_size,
                              hipStream_t stream) {
  const float* evaluation = (const float*)d_in[0];
  const float* templ      = (const float*)d_in[1];
  const float* e_w1 = (const float*)d_in[2];
  const float* e_b1 = (const float*)d_in[3];
  const float* e_w2 = (const float*)d_in[4];
  const float* e_b2 = (const float*)d_in[5];
  const float* e_w3 = (const float*)d_in[6];
  const float* e_b3 = (const float*)d_in[7];
  const float* el_w = (const float*)d_in[8];
  const float* el_b = (const float*)d_in[9];
  const float* eg_wih = (const float*)d_in[10];
  const float* eg_whh = (const float*)d_in[11];
  const float* eg_bih = (const float*)d_in[12];
  const float* eg_bhh = (const float*)d_in[13];
  const float* t_w1 = (const float*)d_in[14];
  const float* t_b1 = (const float*)d_in[15];
  const float* t_w2 = (const float*)d_in[16];
  const float* t_b2 = (const float*)d_in[17];
  const float* t_w3 = (const float*)d_in[18];
  const float* t_b3 = (const float*)d_in[19];
  const float* tl_w = (const float*)d_in[20];
  const float* tl_b = (const float*)d_in[21];
  const float* tg_wih = (const float*)d_in[22];
  const float* tg_whh = (const float*)d_in[23];
  const float* tg_bih = (const float*)d_in[24];
  const float* tg_bhh = (const float*)d_in[25];
  const float* a_w = (const float*)d_in[26];
  const float* a_b = (const float*)d_in[27];
  const float* h_w = (const float*)d_in[28];
  const float* h_b = (const float*)d_in[29];
  const float* c_w = (const float*)d_in[30];
  const float* c_b = (const float*)d_in[31];

  float* ws = (float*)d_ws;
  float* beff_e  = ws + OFF_BEFF_E;
  float* beff_t  = ws + OFF_BEFF_T;
  float* bias2_e = ws + OFF_BIAS2_E;
  float* bias2_t = ws + OFF_BIAS2_T;
  u16*   wkx_e   = (u16*)(ws + OFF_WKX_E);
  u16*   wkx_t   = (u16*)(ws + OFF_WKX_T);
  float* w12p_e  = ws + OFF_W12P_E;
  float* w12p_t  = ws + OFF_W12P_T;
  float* b12_e   = ws + OFF_B12_E;
  float* b12_t   = ws + OFF_B12_T;
  u16*   lwbf_e  = (u16*)(ws + OFF_LWBF_E);
  u16*   lwbf_t  = (u16*)(ws + OFF_LWBF_T);
  float* attbuf  = ws + OFF_ATT;
  u16*   xybf_e  = (u16*)(ws + OFF_XYBF_E);
  u16*   xybf_t  = (u16*)(ws + OFF_XYBF_T);
  u16*   ttbf    = (u16*)(ws + OFF_TTBF);
  float* lin_e   = ws + OFF_LIN_E;
  float* lin_t   = ws + OFF_LIN_T;
  float* PVbuf   = ws + OFF_PV;
  float* redbuf  = ws + OFF_RED;
  float* rsum    = ws + OFF_RSUM;
  u16*   pool_e  = (u16*)(ws + OFF_POOL_E);
  u16*   pool_t  = (u16*)(ws + OFF_POOL_T);
  float* gi_e    = ws + OFF_GI_E;
  float* gi_t    = ws + OFF_GI_T;
  u16*   Pbuf    = (u16*)(ws + OFF_P);

  // prep (zeroes lin/PV/red/rowsum + compose12 + gi_bias + lw->bf16), weff
  prep_kernel<<<530, 320, 0, stream>>>(
      e_w1, e_b1, e_w2, e_b2, t_w1, t_b1, t_w2, t_b2, w12p_e, w12p_t, b12_e, b12_t,
      eg_wih, eg_bih, el_b, bias2_e, tg_wih, tg_bih, tl_b, bias2_t,
      el_w, tl_w, lwbf_e, lwbf_t, (float4*)lin_e);
  compose_weff_kernel<<<dim3(64, 2), 256, 0, stream>>>(
      e_w3, e_b3, t_w3, t_b3, w12p_e, w12p_t, b12_e, b12_t, wkx_e, wkx_t, beff_e, beff_t);

  // mainline
  conv_pool_mfma_kernel<<<dim3(34, 29, 8), 256, 0, stream>>>(
      evaluation, wkx_e, beff_e, pool_e, templ, wkx_t, beff_t, pool_t);
  gemm_splitk_mfma_kernel<<<dim3(191, 8), 256, 0, stream>>>(
      pool_e, lwbf_e, lin_e, pool_t, lwbf_t, lin_t);
  gemm_gi_kernel<<<dim3(191, 3), 256, 0, stream>>>(
      lin_e, eg_wih, bias2_e, gi_e, lin_t, tg_wih, bias2_t, gi_t);
  gru_rec_kernel<<<191, 256, 0, stream>>>(
      lin_e, gi_e, eg_whh, eg_bhh, lin_t, gi_t, tg_whh, tg_bhh,
      xybf_e, xybf_t, ttbf, a_w, a_b, attbuf);

  // cross attention: exp-scores (+rowsum) -> normalized pv (softmax folded)
  scores_mfma_kernel<<<dim3(16, 16, 4), 256, 0, stream>>>(xybf_t, xybf_e, Pbuf, rsum);
  pv_mfma_kernel<<<dim3(32, 4, 4), 256, 0, stream>>>(Pbuf, ttbf, rsum, PVbuf);

  // head: (att softmax fused into) weighted reduce -> MLP
  red_reduce_kernel<<<dim3(16, 4), 256, 0, stream>>>(lin_e, PVbuf, attbuf, redbuf);
  mlp_kernel<<<4, 128, 0, stream>>>(redbuf, h_w, h_b, c_w, c_b, (float*)d_out);
}

// Round 13
// 314.065 us; speedup vs baseline: 9.8882x; 1.0213x over previous
//
#include <hip/hip_runtime.h>
#include <hip/hip_bf16.h>
#include <cmath>

// ============================================================================
// DeepTemplateMatchingModule on MI355X — round 13.
// R12 post-mortem: conv not VALU-bound (packed cvts: VALU 41->37%, dur flat).
// The pooled tensor round-trip (90MB write + 90MB read + splitk node) exists
// only to apply lw — which decomposes exactly over conv blocks (each owns all
// c for 2 h and 60 t). R13: FUSE the linear into conv:
//   pooling writes s_poolT[t][c] (72-u16 stride, b128-aligned, bank-coprime);
//   4 MFMA/wave/h with A=s_poolT(m=t,k=c), B=lwT1[h][n][c] (prep-transposed
//   bf16, L2-hot); acc kept across both h; COALESCED f32 atomics into lin
//   (D col=lane=n). Deletes pooled bufs, splitk node, 180MB HBM. Nodes 10->9.
// ============================================================================

typedef unsigned short u16;
typedef unsigned int u32;
typedef __attribute__((ext_vector_type(8))) short bf16x8;
typedef __attribute__((ext_vector_type(8))) unsigned short u16x8;
typedef __attribute__((ext_vector_type(16))) float f32x16;

__device__ __forceinline__ u16 f2bf(float f) {
  unsigned int x = __float_as_uint(f);
  return (u16)((x + 0x7fffu + ((x >> 16) & 1u)) >> 16);
}
__device__ __forceinline__ float bf2f(u16 v) {
  return __uint_as_float(((unsigned int)v) << 16);
}
__device__ __forceinline__ u32 f2bf_pk(float a, float b) {
  __hip_bfloat162 h = __float22bfloat162_rn(float2{a, b});
  u32 r;
  __builtin_memcpy(&r, &h, 4);  // low 16 = a, high 16 = b
  return r;
}

// ---- workspace layout (float offsets) ----
static const size_t OFF_BEFF_E  = 0;          // 64
static const size_t OFF_BEFF_T  = 64;
static const size_t OFF_BIAS2_E = 128;        // 192
static const size_t OFF_BIAS2_T = 320;
static const size_t OFF_WKX_E   = 512;        // 4 parities x 13x64x16 u16 = 26624 f
static const size_t OFF_WKX_T   = 27136;      // 26624 f
static const size_t OFF_W12P_E  = 53760;      // 9248
static const size_t OFF_W12P_T  = 63008;      // 9248
static const size_t OFF_B12_E   = 72256;      // 32
static const size_t OFF_B12_T   = 72288;      // 32
static const size_t OFF_LWT1_E  = 72320;      // lwT1[h][n][c] bf16: 237568 u16 = 118784 f
static const size_t OFF_LWT1_T  = 191104;     // 118784 f
static const size_t OFF_ATT     = 309888;     // 8128 f (raw logits)
static const size_t OFF_XYBF_E  = 318016;     // 260096 f (4x2032x64 u16)
static const size_t OFF_XYBF_T  = 578112;     // 131072 f (4x1024x64 u16)
static const size_t OFF_TTBF    = 709184;     // 131072 f (t^T: 4x64x1024 u16)
// contiguous zero region (zeroed by prep): lin_e, lin_t, PV, red, rowsum
static const size_t OFF_LIN_E   = 840256;     // 520192 f
static const size_t OFF_LIN_T   = 1360448;    // 262144 f
static const size_t OFF_PV      = 1622592;    // 520192 f
static const size_t OFF_RED     = 2142784;    // 256 f
static const size_t OFF_RSUM    = 2143040;    // 4096 f
static const size_t ZERO_F4     = 326720;     // 1,306,880 f / 4
static const size_t ZSTRIDE     = 617;        // 530 * 617 >= 326720
static const size_t OFF_GI_E    = 2147136;    // 1,560,576 f
static const size_t OFF_GI_T    = 3707712;    // 786,432 f
static const size_t OFF_P       = 4494144;    // u16: 8,323,072 u16 (4,161,536 f)

// ---------------------------------------------------------------------------
// prep: zero region + compose12 (bx<64) + gi_bias (64..65) + lw->lwT1 (>=66).
// lwT1[h][n][c] = bf16(lw[n][c*58+h]); 237,568 els per branch.
// ---------------------------------------------------------------------------
__global__ __launch_bounds__(320) void prep_kernel(
    const float* __restrict__ w1e, const float* __restrict__ b1e,
    const float* __restrict__ w2e, const float* __restrict__ b2e,
    const float* __restrict__ w1t, const float* __restrict__ b1t,
    const float* __restrict__ w2t, const float* __restrict__ b2t,
    float* __restrict__ w12p_e, float* __restrict__ w12p_t,
    float* __restrict__ b12o_e, float* __restrict__ b12o_t,
    const float* __restrict__ wih_e, const float* __restrict__ bih_e,
    const float* __restrict__ lb_e, float* __restrict__ bias2_e,
    const float* __restrict__ wih_t, const float* __restrict__ bih_t,
    const float* __restrict__ lb_t, float* __restrict__ bias2_t,
    const float* __restrict__ lwe, const float* __restrict__ lwt,
    u16* __restrict__ lwt1_e, u16* __restrict__ lwt1_t,
    float4* __restrict__ zbase) {
  const int bx = blockIdx.x;
  const int tid = threadIdx.x;
  {
    const size_t base = (size_t)bx * ZSTRIDE;
    const float4 z = {0.f, 0.f, 0.f, 0.f};
    for (size_t i = base + tid; i < base + ZSTRIDE && i < ZERO_F4; i += 320)
      zbase[i] = z;
  }
  if (bx >= 66) {  // lw -> lwT1 (transpose + bf16)
    if (tid < 256) {
      const int k = bx - 66;
      const int br = k / 232, j = k - br * 232;
      const float* src = br ? lwt : lwe;
      u16* dst = br ? lwt1_t : lwt1_e;
      const int e = j * 1024 + tid * 4;   // 232*1024 = 237,568
      const int h = e >> 12;              // /4096
      const int rem = e & 4095;
      const int n = rem >> 6, c = rem & 63;
      const float* s = src + (size_t)n * 3712 + (size_t)c * 58 + h;
      const float v0 = s[0], v1 = s[58], v2 = s[116], v3 = s[174];
      *(u32*)&dst[e] = f2bf_pk(v0, v1);
      *(u32*)&dst[e + 2] = f2bf_pk(v2, v3);
    }
    return;
  }
  if (bx >= 64) {  // gi_bias
    const int br = bx - 64;
    const float* wih = br ? wih_t : wih_e;
    const float* bih = br ? bih_t : bih_e;
    const float* lb = br ? lb_t : lb_e;
    float* bias2 = br ? bias2_t : bias2_e;
    __shared__ float s_lb[64];
    if (tid < 64) s_lb[tid] = lb[tid];
    __syncthreads();
    if (tid < 192) {
      float acc = bih[tid];
      const float* wr = wih + tid * 64;
      for (int d = 0; d < 64; ++d) acc = fmaf(wr[d], s_lb[d], acc);
      bias2[tid] = acc;
    }
    return;
  }
  // compose12
  const int br = bx >> 5;
  const float* w1 = br ? w1t : w1e;
  const float* b1 = br ? b1t : b1e;
  const float* w2 = br ? w2t : w2e;
  const float* b2 = br ? b2t : b2e;
  float* w12p = br ? w12p_t : w12p_e;
  float* b12o = br ? b12o_t : b12o_e;
  const int c12 = bx & 31;
  __shared__ float s_w1pad[16 * 169];
  __shared__ float s_w2c[400];
  __shared__ float s_b1[16];
  for (int i = tid; i < 2704; i += 320) s_w1pad[i] = 0.f;
  if (tid < 16) s_b1[tid] = b1[tid];
  __syncthreads();
  for (int i = tid; i < 400; i += 320) {
    const int c1 = i / 25, r = (i % 25) / 5, cc = i % 5;
    s_w1pad[c1 * 169 + (r + 4) * 13 + (cc + 4)] = w1[i];
    s_w2c[i] = w2[c12 * 400 + i];
  }
  __syncthreads();
  if (tid < 289) {
    const int py = tid / 17, px = tid % 17;
    float v = 0.f;
    if (py >= 4 && py <= 12 && px >= 4 && px <= 12) {
      const int sy = py - 4, sx = px - 4;
      float accs[2] = {0.f, 0.f};
      for (int c1 = 0; c1 < 16; ++c1) {
        const float* w2p = s_w2c + c1 * 25;
        const float* w1p = s_w1pad + c1 * 169 + (sy + 4) * 13 + (sx + 4);
#pragma unroll
        for (int uy = 0; uy < 5; ++uy)
#pragma unroll
          for (int ux = 0; ux < 5; ++ux)
            accs[uy & 1] = fmaf(w2p[uy * 5 + ux], w1p[-(uy * 13) - ux], accs[uy & 1]);
      }
      v = accs[0] + accs[1];
    }
    w12p[c12 * 289 + tid] = v;
  } else if (tid == 300) {
    float acc = b2[c12];
    for (int c1 = 0; c1 < 16; ++c1) {
      float sw = 0.f;
      for (int u = 0; u < 25; ++u) sw += s_w2c[c1 * 25 + u];
      acc = fmaf(sw, s_b1[c1], acc);
    }
    b12o[c12] = acc;
  }
}

// ---------------------------------------------------------------------------
// compose_weff: 4 parity layouts wkx[(p*13+kx)*64+o][16] bf16 (slot ky+p).
// ---------------------------------------------------------------------------
__global__ __launch_bounds__(256) void compose_weff_kernel(
    const float* __restrict__ w3e, const float* __restrict__ b3e,
    const float* __restrict__ w3t, const float* __restrict__ b3t,
    const float* __restrict__ w12p_e, const float* __restrict__ w12p_t,
    const float* __restrict__ b12_e, const float* __restrict__ b12_t,
    u16* __restrict__ wkx_e, u16* __restrict__ wkx_t,
    float* __restrict__ beff_e, float* __restrict__ beff_t) {
  const int br = blockIdx.y;
  const float* w3 = br ? w3t : w3e;
  const float* b3 = br ? b3t : b3e;
  const float* w12p = br ? w12p_t : w12p_e;
  const float* b12 = br ? b12_t : b12_e;
  u16* wkx = br ? wkx_t : wkx_e;
  float* beff = br ? beff_t : beff_e;
  const int o = blockIdx.x;
  __shared__ float s_pad[32 * 289];
  __shared__ float s_w3o[800];
  __shared__ float s_b12[32];
  const int tid = threadIdx.x;
  for (int i = tid; i < 9248; i += 256) s_pad[i] = w12p[i];
  for (int i = tid; i < 800; i += 256) s_w3o[i] = w3[o * 800 + i];
  if (tid < 32) s_b12[tid] = b12[tid];
  __syncthreads();
  if (tid < 169) {
    const int sy = tid / 13, sx = tid % 13;
    float accs[4] = {0.f, 0.f, 0.f, 0.f};
#pragma unroll 4
    for (int c = 0; c < 32; ++c) {
      const float* w3p = s_w3o + c * 25;
      const float* wp = s_pad + c * 289 + (sy + 4) * 17 + (sx + 4);
#pragma unroll
      for (int uy = 0; uy < 5; ++uy)
#pragma unroll
        for (int ux = 0; ux < 5; ++ux)
          accs[c & 3] = fmaf(w3p[uy * 5 + ux], wp[-(uy * 17) - ux], accs[c & 3]);
    }
    const u16 v = f2bf(accs[0] + accs[1] + accs[2] + accs[3]);
#pragma unroll
    for (int p = 0; p < 4; ++p)
      wkx[((p * 13 + sx) * 64 + o) * 16 + sy + p] = v;
  } else if (tid < 169 + 156) {  // 13 kx x 12 zero-slots
    const int t = tid - 169, kx = t / 12, q = t % 12;
    const int p = q / 3, idx = q % 3;
    const int slot = (idx < p) ? idx : (p + 13) + (idx - p);
    wkx[((p * 13 + kx) * 64 + o) * 16 + slot] = 0;
  }
  if (tid == 255) {
    float acc = b3[o];
    for (int c = 0; c < 32; ++c) {
      float sw = 0.f;
      for (int u = 0; u < 25; ++u) sw += s_w3o[c * 25 + u];
      acc = fmaf(sw, s_b12[c], acc);
    }
    beff[o] = acc;
  }
}

// ---------------------------------------------------------------------------
// FUSED conv13x13 + maxpool + linear. Per hh: conv MFMA -> s_out -> pooling
// writes TRANSPOSED s_poolT[t][c] (+bias) -> 4 MFMA (A=s_poolT m=t k=c,
// B=lwT1[h][n][c]) accumulating accL across both h -> coalesced f32 atomics
// into lin[b,t,n]. grid (34, 29, 8); tmpl blocks cb>=1024 exit.
// ---------------------------------------------------------------------------
__global__ __launch_bounds__(256, 4) void conv_pool_lin_kernel(
    const float* __restrict__ xe, const u16* __restrict__ wkx_e,
    const float* __restrict__ beff_e, const u16* __restrict__ lwt1_e,
    float* __restrict__ lin_e,
    const float* __restrict__ xt, const u16* __restrict__ wkx_t,
    const float* __restrict__ beff_t, const u16* __restrict__ lwt1_t,
    float* __restrict__ lin_t) {
  const int zz = blockIdx.z;
  const bool ev = zz < 4;
  const int b = ev ? zz : zz - 4;
  const int W = ev ? 2048 : 1040;
  const int T = ev ? 2032 : 1024;
  const int cb = blockIdx.x * 60;
  if (cb >= T) return;
  const float* x = ev ? xe : xt;
  const u16* wkx = ev ? wkx_e : wkx_t;
  const float* beff = ev ? beff_e : beff_t;
  const u16* lwt1 = ev ? lwt1_e : lwt1_t;
  float* lin = ev ? lin_e : lin_t;

  __shared__ __align__(16) u16 s_x[80 * 24];       // 3840 B (alive both hh)
  __shared__ __align__(16) u16 s_out[2 * 64 * 66]; // 16896 B
  __shared__ __align__(16) u16 s_poolT[64 * 72];   // 9216 B ([t][c])

  const int tid = threadIdx.x;
  const int lane = tid & 63, wave = tid >> 6;
  const int by = blockIdx.y;
  const int rsel = wave & 1, cm = (wave >> 1) * 32;
  const int l31 = lane & 31, g8 = (lane >> 5) * 8;
  const int th = (wave & 1) * 32, nh = (wave >> 1) * 32;
  const int r0 = 4 * by;

  {
    const float* xb = x + ((size_t)b * 128 + r0) * W;
    for (int i = tid; i < 640; i += 256) {
      const int pr = i / 80, c = i - pr * 80;
      int gc = cb + c;
      if (gc > W - 1) gc = W - 1;
      *(u32*)&s_x[c * 24 + 2 * pr] =
          f2bf_pk(xb[(size_t)(2 * pr) * W + gc], xb[(size_t)(2 * pr + 1) * W + gc]);
    }
  }
  __syncthreads();
  f32x16 accL = {};
#pragma unroll
  for (int hh = 0; hh < 2; ++hh) {
    const int p = 2 * hh + rsel;
    const int h = 2 * by + hh;
    bf16x8 wfrag[13];
    {
      const u16* aw = wkx + ((p * 13) * 64 + cm + l31) * 16 + g8;
#pragma unroll
      for (int kx = 0; kx < 13; ++kx) wfrag[kx] = *(const bf16x8*)(aw + kx * 1024);
    }
    f32x16 acc0 = {}, acc1 = {};
    const u16* bx = s_x + g8;
#pragma unroll
    for (int kx = 0; kx < 13; ++kx) {
      bf16x8 b0 = *(const bf16x8*)(bx + (l31 + kx) * 24);
      bf16x8 b1 = *(const bf16x8*)(bx + (32 + l31 + kx) * 24);
      acc0 = __builtin_amdgcn_mfma_f32_32x32x16_bf16(wfrag[kx], b0, acc0, 0, 0, 0);
      acc1 = __builtin_amdgcn_mfma_f32_32x32x16_bf16(wfrag[kx], b1, acc1, 0, 0, 0);
    }
#pragma unroll
    for (int r = 0; r < 16; ++r) {
      const int c = cm + (r & 3) + 8 * (r >> 2) + (g8 >> 1);
      u16* o = s_out + (rsel * 64 + c) * 66;
      const u32 pk = f2bf_pk(acc0[r], acc1[r]);
      o[l31] = (u16)pk;
      o[32 + l31] = (u16)(pk >> 16);
    }
    __syncthreads();  // s_out complete; prior GEMM reads of s_poolT done
    {
      const int pc = tid & 63, tg = tid >> 6;
      const int t0 = tg * 15;
      const float bias = beff[pc];
      const u16* r0p = s_out + pc * 66 + t0;
      const u16* r1p = s_out + (64 + pc) * 66 + t0;
      float m01[19];
#pragma unroll
      for (int j = 0; j < 19; ++j) m01[j] = fmaxf(bf2f(r0p[j]), bf2f(r1p[j]));
#pragma unroll
      for (int i = 0; i < 15; ++i) {
        float m = m01[i];
#pragma unroll
        for (int k = 1; k < 5; ++k) m = fmaxf(m, m01[i + k]);
        s_poolT[(t0 + i) * 72 + pc] = f2bf(m + bias);  // transposed (+bias)
      }
    }
    __syncthreads();  // s_poolT complete
    // linear: accL[t][n] += sum_c poolT[t][c] * lwT1[h][n][c]
    {
      const u16* ap2 = s_poolT + (th + l31) * 72 + g8;
      const u16* bp2 = lwt1 + ((size_t)(h * 64 + nh + l31)) * 64 + g8;
#pragma unroll
      for (int ks = 0; ks < 4; ++ks) {
        bf16x8 a = *(const bf16x8*)(ap2 + ks * 16);
        bf16x8 bb = *(const bf16x8*)(bp2 + ks * 16);
        accL = __builtin_amdgcn_mfma_f32_32x32x16_bf16(a, bb, accL, 0, 0, 0);
      }
    }
  }
  // coalesced atomic epilogue: col(lane) = n, row = t
  {
    const int nn = nh + l31;
#pragma unroll
    for (int r = 0; r < 16; ++r) {
      const int t = th + (r & 3) + 8 * (r >> 2) + (g8 >> 1);
      const int tt = cb + t;
      if (t < 60 && tt < T)
        atomicAdd(&lin[((size_t)b * T + tt) * 64 + nn], accL[r]);
    }
  }
}

// ---------------------------------------------------------------------------
// gi GEMM, both branches: grid (191, 3); N=192, K=64.
// ---------------------------------------------------------------------------
__global__ __launch_bounds__(256) void gemm_gi_kernel(
    const float* __restrict__ Ae, const float* __restrict__ Wte,
    const float* __restrict__ biase, float* __restrict__ oute,
    const float* __restrict__ At, const float* __restrict__ Wtt,
    const float* __restrict__ biast, float* __restrict__ outt) {
  const int bx = blockIdx.x;
  const bool ev = bx < 127;
  const float* A = ev ? Ae : At;
  const float* Wt = ev ? Wte : Wtt;
  const float* bias = ev ? biase : biast;
  float* out = ev ? oute : outt;
  const int r0 = (ev ? bx : bx - 127) * 64;
  const int N = 192, K = 64;
  __shared__ float sA[64 * 33];
  __shared__ float sB[64 * 33];
  const int tid = threadIdx.x;
  const int n0 = blockIdx.y * 64;
  const int ty = tid >> 4, tx = tid & 15;
  float acc[4][4] = {};
  for (int kc = 0; kc < K; kc += 32) {
    __syncthreads();
#pragma unroll
    for (int rep = 0; rep < 8; ++rep) {
      const int l = tid + rep * 256;
      const int row = l >> 5, kk = l & 31;
      sA[row * 33 + kk] = A[(size_t)(r0 + row) * K + kc + kk];
      sB[row * 33 + kk] = Wt[(size_t)(n0 + row) * K + kc + kk];
    }
    __syncthreads();
#pragma unroll 8
    for (int kk = 0; kk < 32; ++kk) {
      const float a0 = sA[(ty * 4 + 0) * 33 + kk];
      const float a1 = sA[(ty * 4 + 1) * 33 + kk];
      const float a2 = sA[(ty * 4 + 2) * 33 + kk];
      const float a3 = sA[(ty * 4 + 3) * 33 + kk];
      const float b0 = sB[(tx * 4 + 0) * 33 + kk];
      const float b1 = sB[(tx * 4 + 1) * 33 + kk];
      const float b2 = sB[(tx * 4 + 2) * 33 + kk];
      const float b3 = sB[(tx * 4 + 3) * 33 + kk];
      acc[0][0] = fmaf(a0, b0, acc[0][0]); acc[0][1] = fmaf(a0, b1, acc[0][1]);
      acc[0][2] = fmaf(a0, b2, acc[0][2]); acc[0][3] = fmaf(a0, b3, acc[0][3]);
      acc[1][0] = fmaf(a1, b0, acc[1][0]); acc[1][1] = fmaf(a1, b1, acc[1][1]);
      acc[1][2] = fmaf(a1, b2, acc[1][2]); acc[1][3] = fmaf(a1, b3, acc[1][3]);
      acc[2][0] = fmaf(a2, b0, acc[2][0]); acc[2][1] = fmaf(a2, b1, acc[2][1]);
      acc[2][2] = fmaf(a2, b2, acc[2][2]); acc[2][3] = fmaf(a2, b3, acc[2][3]);
      acc[3][0] = fmaf(a3, b0, acc[3][0]); acc[3][1] = fmaf(a3, b1, acc[3][1]);
      acc[3][2] = fmaf(a3, b2, acc[3][2]); acc[3][3] = fmaf(a3, b3, acc[3][3]);
    }
  }
#pragma unroll
  for (int i = 0; i < 4; ++i)
#pragma unroll
    for (int j = 0; j < 4; ++j)
      out[(size_t)(r0 + ty * 4 + i) * N + n0 + tx * 4 + j] =
          acc[i][j] + bias[n0 + tx * 4 + j];
}

// ---------------------------------------------------------------------------
// GRU, both branches (grid 191). fp32 xy + bf16 xy_bf; logits (eval);
// t^T bf16 scatter (template).
// ---------------------------------------------------------------------------
__global__ __launch_bounds__(256) void gru_rec_kernel(
    float* __restrict__ xyE, const float* __restrict__ giE,
    const float* __restrict__ whhE, const float* __restrict__ bhhE,
    float* __restrict__ xyT, const float* __restrict__ giT,
    const float* __restrict__ whhT, const float* __restrict__ bhhT,
    u16* __restrict__ xybfE, u16* __restrict__ xybfT, u16* __restrict__ ttbf,
    const float* __restrict__ a_w, const float* __restrict__ a_b,
    float* __restrict__ logits) {
  const int bxid = blockIdx.x;
  const bool ev = bxid < 127;
  float* xy = ev ? xyE : xyT;
  u16* xybf = ev ? xybfE : xybfT;
  const float* gi = ev ? giE : giT;
  const float* whh = ev ? whhE : whhT;
  const float* bhh = ev ? bhhE : bhhT;
  const int T = ev ? 2032 : 1024;
  const int t0 = (ev ? bxid : bxid - 127) * 16;
  __shared__ float s_whh_t[64 * 192];
  __shared__ float s_h[16][64];
  __shared__ float s_aw[64];
  const int tid = threadIdx.x;
  const int lane = tid & 63, wave = tid >> 6;
  for (int i = tid; i < 192 * 64; i += 256) {
    const int j = i >> 6, d = i & 63;
    s_whh_t[d * 192 + j] = whh[i];
  }
  for (int i = tid; i < 16 * 64; i += 256) (&s_h[0][0])[i] = 0.f;
  if (tid < 64) s_aw[tid] = a_w[tid];
  const float ab = a_b[0];
  const float bhr = bhh[lane], bhz = bhh[64 + lane], bhn = bhh[128 + lane];
  __syncthreads();
  for (int b = 0; b < 4; ++b) {
    float gir[4], giz[4], gin[4];
#pragma unroll
    for (int sl = 0; sl < 4; ++sl) {
      int t = t0 + wave * 4 + sl; if (t > T - 1) t = T - 1;
      const float* girow = gi + ((size_t)b * T + t) * 192;
      gir[sl] = girow[lane]; giz[sl] = girow[64 + lane]; gin[sl] = girow[128 + lane];
    }
    float ahr[4] = {}, ahz[4] = {}, ahn[4] = {};
    for (int d = 0; d < 64; ++d) {
      const float wr_ = s_whh_t[d * 192 + lane];
      const float wz_ = s_whh_t[d * 192 + 64 + lane];
      const float wn_ = s_whh_t[d * 192 + 128 + lane];
#pragma unroll
      for (int sl = 0; sl < 4; ++sl) {
        const float hv = s_h[wave * 4 + sl][d];
        ahr[sl] = fmaf(wr_, hv, ahr[sl]);
        ahz[sl] = fmaf(wz_, hv, ahz[sl]);
        ahn[sl] = fmaf(wn_, hv, ahn[sl]);
      }
    }
    float hn[4];
#pragma unroll
    for (int sl = 0; sl < 4; ++sl) {
      const float r = 1.f / (1.f + __expf(-(gir[sl] + ahr[sl] + bhr)));
      const float z = 1.f / (1.f + __expf(-(giz[sl] + ahz[sl] + bhz)));
      const float n = tanhf(gin[sl] + r * (ahn[sl] + bhn));
      hn[sl] = (1.f - z) * n + z * s_h[wave * 4 + sl][lane];
    }
    __syncthreads();
#pragma unroll
    for (int sl = 0; sl < 4; ++sl) {
      const int t = t0 + wave * 4 + sl;
      s_h[wave * 4 + sl][lane] = hn[sl];
      if (t < T) {
        const size_t idx = ((size_t)b * T + t) * 64 + lane;
        xy[idx] = hn[sl];
        xybf[idx] = f2bf(hn[sl]);
        if (ev) {
          float v = hn[sl] * s_aw[lane];
#pragma unroll
          for (int off = 32; off > 0; off >>= 1) v += __shfl_down(v, off, 64);
          if (lane == 0) logits[b * 2032 + t] = v + ab;
        } else {
          ttbf[((size_t)b * 64 + lane) * 1024 + t] = f2bf(hn[sl]);
        }
      }
    }
    __syncthreads();
  }
}

// ---------------------------------------------------------------------------
// scores: P'[b,tau,eps] = exp(sum_d t[tau,d] e[eps,d]) + per-tau rowsums.
// |s| <= 64 so exp never overflows. grid (16,16,4).
// ---------------------------------------------------------------------------
__global__ __launch_bounds__(256) void scores_mfma_kernel(
    const u16* __restrict__ tbf, const u16* __restrict__ ebf,
    u16* __restrict__ P, float* __restrict__ rowsum) {
  __shared__ __align__(16) u16 sA[64 * 72];
  __shared__ __align__(16) u16 sB[128 * 72];
  const int tid = threadIdx.x;
  const int b = blockIdx.z;
  const int tau0 = blockIdx.x * 64;
  const int e0 = blockIdx.y * 128;
  const int lane = tid & 63, wave = tid >> 6;
  const int l31 = lane & 31, g8 = (lane >> 5) * 8;
  {
    const int row = tid >> 2, seg = (tid & 3) * 16;
    const u16* ap = &tbf[((size_t)b * 1024 + tau0 + row) * 64 + seg];
    u16* da = &sA[row * 72 + seg];
    *(u16x8*)da = *(const u16x8*)ap;
    *(u16x8*)(da + 8) = *(const u16x8*)(ap + 8);
  }
#pragma unroll
  for (int r = 0; r < 4; ++r) {
    const int q = tid + r * 256;
    const int row = q >> 3, seg = (q & 7) * 8;
    int eps = e0 + row; if (eps > 2031) eps = 2031;
    *(u16x8*)&sB[row * 72 + seg] =
        *(const u16x8*)&ebf[((size_t)b * 2032 + eps) * 64 + seg];
  }
  __syncthreads();
  const int mh = (wave & 1) * 32;
  const int nq = (wave >> 1) * 64;
  f32x16 acc0 = {}, acc1 = {};
#pragma unroll
  for (int ks = 0; ks < 4; ++ks) {
    bf16x8 a = *(const bf16x8*)&sA[(mh + l31) * 72 + ks * 16 + g8];
    bf16x8 b0 = *(const bf16x8*)&sB[(nq + l31) * 72 + ks * 16 + g8];
    bf16x8 b1 = *(const bf16x8*)&sB[(nq + 32 + l31) * 72 + ks * 16 + g8];
    acc0 = __builtin_amdgcn_mfma_f32_32x32x16_bf16(a, b0, acc0, 0, 0, 0);
    acc1 = __builtin_amdgcn_mfma_f32_32x32x16_bf16(a, b1, acc1, 0, 0, 0);
  }
  const int ep0 = e0 + nq + l31;
  const int ep1 = ep0 + 32;
#pragma unroll
  for (int r = 0; r < 16; ++r) {
    const int tau = tau0 + mh + (r & 3) + 8 * (r >> 2) + (g8 >> 1);
    const size_t prow = ((size_t)b * 1024 + tau) * 2032;
    const float e0v = __expf(acc0[r]);
    const float e1v = __expf(acc1[r]);
    float part = 0.f;
    if (ep0 < 2032) { P[prow + ep0] = f2bf(e0v); part += e0v; }
    if (ep1 < 2032) { P[prow + ep1] = f2bf(e1v); part += e1v; }
#pragma unroll
    for (int off = 16; off > 0; off >>= 1) part += __shfl_down(part, off, 32);
    if (l31 == 0) atomicAdd(&rowsum[b * 1024 + tau], part);
  }
}

// ---------------------------------------------------------------------------
// pv on bf16 MFMA with folded softmax normalization (1/rowsum applied in
// the P^T LDS transpose). grid (32, 4, 4); atomic f32 epilogue.
// ---------------------------------------------------------------------------
__global__ __launch_bounds__(256) void pv_mfma_kernel(
    const u16* __restrict__ P, const u16* __restrict__ ttbf,
    const float* __restrict__ rowsum, float* __restrict__ PV) {
  __shared__ __align__(16) u16 sPT[64 * 72];  // [eps][tau], pre-normalized
  __shared__ __align__(16) u16 sTT[64 * 72];  // [d][tau]
  const int tid = threadIdx.x;
  const int b = blockIdx.z;
  const int e0 = blockIdx.x * 64;
  const int tau_base = blockIdx.y * 256;
  const int lane = tid & 63, wave = tid >> 6;
  const int l31 = lane & 31, g8 = (lane >> 5) * 8;
  const int mh = (wave & 1) * 32, nh = (wave >> 1) * 32;
  f32x16 acc = {};
  for (int cc = 0; cc < 4; ++cc) {
    const int tc = tau_base + cc * 64;
    __syncthreads();
#pragma unroll
    for (int k = 0; k < 2; ++k) {
      const int q = tid + k * 256;
      const int row = q >> 3, seg = (q & 7) * 8;
      const float inv = 1.0f / rowsum[b * 1024 + tc + row];
      int er = e0 + seg;
      if (er > 2032 - 8) er = 2032 - 8;
      const u16x8 v = *(const u16x8*)&P[((size_t)b * 1024 + tc + row) * 2032 + er];
#pragma unroll
      for (int j = 0; j < 8; ++j)
        sPT[(seg + j) * 72 + row] = f2bf(bf2f(v[j]) * inv);
    }
#pragma unroll
    for (int k = 0; k < 2; ++k) {
      const int q = tid + k * 256;
      const int row = q >> 3, seg = (q & 7) * 8;
      *(u16x8*)&sTT[row * 72 + seg] =
          *(const u16x8*)&ttbf[((size_t)b * 64 + row) * 1024 + tc + seg];
    }
    __syncthreads();
#pragma unroll
    for (int ks = 0; ks < 4; ++ks) {
      bf16x8 a = *(const bf16x8*)&sPT[(mh + l31) * 72 + ks * 16 + g8];
      bf16x8 bb = *(const bf16x8*)&sTT[(nh + l31) * 72 + ks * 16 + g8];
      acc = __builtin_amdgcn_mfma_f32_32x32x16_bf16(a, bb, acc, 0, 0, 0);
    }
  }
#pragma unroll
  for (int r = 0; r < 16; ++r) {
    const int eps = e0 + mh + (r & 3) + 8 * (r >> 2) + (g8 >> 1);
    if (eps < 2032)
      atomicAdd(&PV[((size_t)b * 2032 + eps) * 64 + nh + l31], acc[r]);
  }
}

// ---------------------------------------------------------------------------
// red_reduce with fused att softmax (per-block redundant softmax of logits).
// grid (16, 4).
// ---------------------------------------------------------------------------
__global__ __launch_bounds__(256) void red_reduce_kernel(
    const float* __restrict__ emat, const float* __restrict__ PV,
    const float* __restrict__ logits, float* __restrict__ red) {
  __shared__ float s_att[2032];
  __shared__ float sred[4];
  __shared__ float s_part[4][64];
  const int tid = threadIdx.x;
  const int lane = tid & 63, wave = tid >> 6;
  const int b = blockIdx.y;
  float m = -3.4e38f;
  for (int i = tid; i < 2032; i += 256) {
    const float v = logits[b * 2032 + i];
    s_att[i] = v;
    m = fmaxf(m, v);
  }
#pragma unroll
  for (int off = 32; off > 0; off >>= 1) m = fmaxf(m, __shfl_down(m, off, 64));
  if (lane == 0) sred[wave] = m;
  __syncthreads();
  m = fmaxf(fmaxf(sred[0], sred[1]), fmaxf(sred[2], sred[3]));
  __syncthreads();
  float ssum = 0.f;
  for (int i = tid; i < 2032; i += 256) {
    const float v = __expf(s_att[i] - m);
    s_att[i] = v;
    ssum += v;
  }
#pragma unroll
  for (int off = 32; off > 0; off >>= 1) ssum += __shfl_down(ssum, off, 64);
  if (lane == 0) sred[wave] = ssum;
  __syncthreads();
  const float inv = 1.f / (sred[0] + sred[1] + sred[2] + sred[3]);
  const int i0 = blockIdx.x * 127;
  float acc = 0.f;
  for (int i = i0 + wave; i < i0 + 127; i += 4) {
    const size_t idx = ((size_t)b * 2032 + i) * 64 + lane;
    acc = fmaf(fabsf(PV[idx] - emat[idx]), s_att[i], acc);
  }
  s_part[wave][lane] = acc;
  __syncthreads();
  if (tid < 64)
    atomicAdd(&red[b * 64 + tid],
              (s_part[0][tid] + s_part[1][tid] + s_part[2][tid] + s_part[3][tid]) * inv);
}

// ---------------------------------------------------------------------------
// mlp: h = relu(red@h_w^T + h_b); out = softmax(h@c_w^T + c_b). grid 4.
// ---------------------------------------------------------------------------
__global__ __launch_bounds__(128) void mlp_kernel(
    const float* __restrict__ red, const float* __restrict__ h_w,
    const float* __restrict__ h_b, const float* __restrict__ c_w,
    const float* __restrict__ c_b, float* __restrict__ out) {
  __shared__ float s_red[64];
  __shared__ float s_hv[128];
  const int tid = threadIdx.x;
  const int b = blockIdx.x;
  if (tid < 64) s_red[tid] = red[b * 64 + tid];
  __syncthreads();
  {
    float acc = h_b[tid];
    const float* hw = h_w + tid * 64;
    for (int d = 0; d < 64; ++d) acc = fmaf(s_red[d], hw[d], acc);
    s_hv[tid] = fmaxf(acc, 0.f);
  }
  __syncthreads();
  if (tid == 0) {
    float l0 = c_b[0], l1 = c_b[1];
    for (int j = 0; j < 128; ++j) {
      l0 = fmaf(s_hv[j], c_w[j], l0);
      l1 = fmaf(s_hv[j], c_w[128 + j], l1);
    }
    const float mm = fmaxf(l0, l1);
    const float e0 = __expf(l0 - mm), e1 = __expf(l1 - mm);
    const float invs = 1.f / (e0 + e1);
    out[b * 2 + 0] = e0 * invs;
    out[b * 2 + 1] = e1 * invs;
  }
}

// ===========================================================================
extern "C" void kernel_launch(void* const* d_in, const int* in_sizes, int n_in,
                              void* d_out, int out_size, void* d_ws, size_t ws_size,
                              hipStream_t stream) {
  const float* evaluation = (const float*)d_in[0];
  const float* templ      = (const float*)d_in[1];
  const float* e_w1 = (const float*)d_in[2];
  const float* e_b1 = (const float*)d_in[3];
  const float* e_w2 = (const float*)d_in[4];
  const float* e_b2 = (const float*)d_in[5];
  const float* e_w3 = (const float*)d_in[6];
  const float* e_b3 = (const float*)d_in[7];
  const float* el_w = (const float*)d_in[8];
  const float* el_b = (const float*)d_in[9];
  const float* eg_wih = (const float*)d_in[10];
  const float* eg_whh = (const float*)d_in[11];
  const float* eg_bih = (const float*)d_in[12];
  const float* eg_bhh = (const float*)d_in[13];
  const float* t_w1 = (const float*)d_in[14];
  const float* t_b1 = (const float*)d_in[15];
  const float* t_w2 = (const float*)d_in[16];
  const float* t_b2 = (const float*)d_in[17];
  const float* t_w3 = (const float*)d_in[18];
  const float* t_b3 = (const float*)d_in[19];
  const float* tl_w = (const float*)d_in[20];
  const float* tl_b = (const float*)d_in[21];
  const float* tg_wih = (const float*)d_in[22];
  const float* tg_whh = (const float*)d_in[23];
  const float* tg_bih = (const float*)d_in[24];
  const float* tg_bhh = (const float*)d_in[25];
  const float* a_w = (const float*)d_in[26];
  const float* a_b = (const float*)d_in[27];
  const float* h_w = (const float*)d_in[28];
  const float* h_b = (const float*)d_in[29];
  const float* c_w = (const float*)d_in[30];
  const float* c_b = (const float*)d_in[31];

  float* ws = (float*)d_ws;
  float* beff_e  = ws + OFF_BEFF_E;
  float* beff_t  = ws + OFF_BEFF_T;
  float* bias2_e = ws + OFF_BIAS2_E;
  float* bias2_t = ws + OFF_BIAS2_T;
  u16*   wkx_e   = (u16*)(ws + OFF_WKX_E);
  u16*   wkx_t   = (u16*)(ws + OFF_WKX_T);
  float* w12p_e  = ws + OFF_W12P_E;
  float* w12p_t  = ws + OFF_W12P_T;
  float* b12_e   = ws + OFF_B12_E;
  float* b12_t   = ws + OFF_B12_T;
  u16*   lwt1_e  = (u16*)(ws + OFF_LWT1_E);
  u16*   lwt1_t  = (u16*)(ws + OFF_LWT1_T);
  float* attbuf  = ws + OFF_ATT;
  u16*   xybf_e  = (u16*)(ws + OFF_XYBF_E);
  u16*   xybf_t  = (u16*)(ws + OFF_XYBF_T);
  u16*   ttbf    = (u16*)(ws + OFF_TTBF);
  float* lin_e   = ws + OFF_LIN_E;
  float* lin_t   = ws + OFF_LIN_T;
  float* PVbuf   = ws + OFF_PV;
  float* redbuf  = ws + OFF_RED;
  float* rsum    = ws + OFF_RSUM;
  float* gi_e    = ws + OFF_GI_E;
  float* gi_t    = ws + OFF_GI_T;
  u16*   Pbuf    = (u16*)(ws + OFF_P);

  // prep (zeroes lin/PV/red/rowsum + compose12 + gi_bias + lw->lwT1), weff
  prep_kernel<<<530, 320, 0, stream>>>(
      e_w1, e_b1, e_w2, e_b2, t_w1, t_b1, t_w2, t_b2, w12p_e, w12p_t, b12_e, b12_t,
      eg_wih, eg_bih, el_b, bias2_e, tg_wih, tg_bih, tl_b, bias2_t,
      el_w, tl_w, lwt1_e, lwt1_t, (float4*)lin_e);
  compose_weff_kernel<<<dim3(64, 2), 256, 0, stream>>>(
      e_w3, e_b3, t_w3, t_b3, w12p_e, w12p_t, b12_e, b12_t, wkx_e, wkx_t, beff_e, beff_t);

  // fused conv+pool+linear (atomic into lin), then GRU chain
  conv_pool_lin_kernel<<<dim3(34, 29, 8), 256, 0, stream>>>(
      evaluation, wkx_e, beff_e, lwt1_e, lin_e,
      templ, wkx_t, beff_t, lwt1_t, lin_t);
  gemm_gi_kernel<<<dim3(191, 3), 256, 0, stream>>>(
      lin_e, eg_wih, bias2_e, gi_e, lin_t, tg_wih, bias2_t, gi_t);
  gru_rec_kernel<<<191, 256, 0, stream>>>(
      lin_e, gi_e, eg_whh, eg_bhh, lin_t, gi_t, tg_whh, tg_bhh,
      xybf_e, xybf_t, ttbf, a_w, a_b, attbuf);

  // cross attention: exp-scores (+rowsum) -> normalized pv (softmax folded)
  scores_mfma_kernel<<<dim3(16, 16, 4), 256, 0, stream>>>(xybf_t, xybf_e, Pbuf, rsum);
  pv_mfma_kernel<<<dim3(32, 4, 4), 256, 0, stream>>>(Pbuf, ttbf, rsum, PVbuf);

  // head: (att softmax fused into) weighted reduce -> MLP
  red_reduce_kernel<<<dim3(16, 4), 256, 0, stream>>>(lin_e, PVbuf, attbuf, redbuf);
  mlp_kernel<<<4, 128, 0, stream>>>(redbuf, h_w, h_b, c_w, c_b, (float*)d_out);
}